// Round 3
// baseline (2561.592 us; speedup 1.0000x reference)
//
#include <hip/hip_runtime.h>

#define NN 100000
#define HH 128
#define EE 600000
#define LL 2
#define RR 3
#define AAA 64
#define CC 16
#define SCAN_B 98   // 98 blocks x 1024 elems covers 100000

// ---------------- weight fusion ----------------
__global__ void k_fuse_w(const float* __restrict__ Wsrc, const float* __restrict__ Wdst,
                         const float* __restrict__ Wupd, float* __restrict__ fWd,
                         float* __restrict__ fWs) {
    int b = blockIdx.x;
    int lr = b >> 7, i = b & 127;
    int t = threadIdx.x;
    int j = t & 127;
    const float* wu = Wupd + (size_t)lr * 2 * HH * HH;
    float acc = 0.f;
    if (t < 128) {
        const float* wd = Wdst + ((size_t)lr * HH + i) * HH;
        for (int k = 0; k < HH; ++k) acc += wd[k] * wu[k * HH + j];
        fWd[((size_t)lr * HH + i) * HH + j] = acc;
    } else {
        const float* wsc = Wsrc + ((size_t)lr * HH + i) * HH;
        for (int k = 0; k < HH; ++k) acc += wsc[k] * wu[(HH + k) * HH + j];
        fWs[((size_t)lr * HH + i) * HH + j] = acc;
    }
}

__global__ void k_fuse_b(const float* __restrict__ bsrc, const float* __restrict__ bdst,
                         const float* __restrict__ bupd, const float* __restrict__ Wupd,
                         float* __restrict__ fB) {
    int lr = blockIdx.x;
    int j = threadIdx.x;
    const float* wu = Wupd + (size_t)lr * 2 * HH * HH;
    const float* bd = bdst + lr * HH;
    const float* bs = bsrc + lr * HH;
    float acc = bupd[lr * HH + j];
    for (int k = 0; k < HH; ++k)
        acc += bd[k] * wu[k * HH + j] + bs[k] * wu[(HH + k) * HH + j];
    fB[lr * HH + j] = acc;
}

// ---------------- CSR build ----------------
__global__ void k_count(const int* __restrict__ dst, int* __restrict__ cnt) {
    int i = blockIdx.x * 256 + threadIdx.x;
    if (i < EE) atomicAdd(&cnt[dst[i]], 1);
}

__global__ void k_scan1(const int* __restrict__ cnt, int* __restrict__ rs, int* __restrict__ bsum) {
    __shared__ int sd[256];
    int blk = blockIdx.x, tid = threadIdx.x;
    int base = blk * 1024 + tid * 4;
    int c0 = 0, c1 = 0, c2 = 0, c3 = 0;
    if (base + 0 < NN) c0 = cnt[base + 0];
    if (base + 1 < NN) c1 = cnt[base + 1];
    if (base + 2 < NN) c2 = cnt[base + 2];
    if (base + 3 < NN) c3 = cnt[base + 3];
    int s = c0 + c1 + c2 + c3;
    sd[tid] = s;
    __syncthreads();
    for (int off = 1; off < 256; off <<= 1) {
        int v = (tid >= off) ? sd[tid - off] : 0;
        __syncthreads();
        sd[tid] += v;
        __syncthreads();
    }
    int excl = sd[tid] - s;
    if (tid == 255) bsum[blk] = sd[255];
    if (base + 0 < NN) rs[base + 0] = excl;
    if (base + 1 < NN) rs[base + 1] = excl + c0;
    if (base + 2 < NN) rs[base + 2] = excl + c0 + c1;
    if (base + 3 < NN) rs[base + 3] = excl + c0 + c1 + c2;
}

__global__ void k_scan2(int* __restrict__ bsum) {  // 1 block, 128 threads
    __shared__ int sd[128];
    int tid = threadIdx.x;
    int v = (tid < SCAN_B) ? bsum[tid] : 0;
    sd[tid] = v;
    __syncthreads();
    for (int off = 1; off < 128; off <<= 1) {
        int u = (tid >= off) ? sd[tid - off] : 0;
        __syncthreads();
        sd[tid] += u;
        __syncthreads();
    }
    if (tid < SCAN_B) bsum[tid] = sd[tid] - v;  // exclusive
}

__global__ void k_scan3(int* __restrict__ rs, const int* __restrict__ bsum) {
    int i = blockIdx.x * 256 + threadIdx.x;
    if (i < NN) rs[i] += bsum[i >> 10];
}

__global__ void k_fill(const int* __restrict__ e, int* __restrict__ fill,
                       const int* __restrict__ rs, int* __restrict__ csr) {
    int i = blockIdx.x * 256 + threadIdx.x;
    if (i >= EE) return;
    int s = e[i], d = e[EE + i];
    int pos = rs[d] + atomicAdd(&fill[d], 1);
    csr[pos] = s;
}

// ---------------- aggregation: one wave per dst node ----------------
__global__ __launch_bounds__(256) void k_aggr(float* __restrict__ emb, const float* __restrict__ xs,
                                              const int* __restrict__ rs, const int* __restrict__ cnt,
                                              const int* __restrict__ csr) {
    int node = blockIdx.x * 4 + (threadIdx.x >> 6);
    if (node >= NN) return;
    int lane = threadIdx.x & 63;
    int beg = rs[node], deg = cnt[node];
    const float2* xs2 = (const float2*)xs;
    float ax = 0.f, ay = 0.f;
    int j = 0;
    for (; j + 1 < deg; j += 2) {
        int s0 = csr[beg + j], s1 = csr[beg + j + 1];
        float2 v0 = xs2[(size_t)s0 * 64 + lane];
        float2 v1 = xs2[(size_t)s1 * 64 + lane];
        ax += v0.x + v1.x;
        ay += v0.y + v1.y;
    }
    if (j < deg) {
        float2 v = xs2[(size_t)csr[beg + j] * 64 + lane];
        ax += v.x;
        ay += v.y;
    }
    float sc = 1.0f / fmaxf((float)deg, 1.0f);
    ((float2*)emb)[(size_t)node * 64 + lane] = make_float2(ax * sc, ay * sc);
}

// ---------------- fused conv GEMM: Y = X1@W1 + X2@W2 + bias ----------------
// k-chunked staging: LDS = Xl[128][36-pad] (18KB) + Wl[32][128] (16KB) = 34.8KB
// -> 3 blocks/CU (VGPR-capped), vs 1 block/CU before.
__global__ __launch_bounds__(256, 3) void k_cgemm(float* __restrict__ Y, const float* __restrict__ X1,
                                                  const float* __restrict__ X2, const float* __restrict__ W1f,
                                                  const float* __restrict__ W2f, const float* __restrict__ bias,
                                                  int nrows) {
    __shared__ float Xl[128 * 36];  // padded stride 36 dwords: conflict-free strided reads
    __shared__ float Wl[32 * 128];
    int tid = threadIdx.x;
    int row0 = blockIdx.x * 128;
    int tx = tid & 15, ty = tid >> 4;
    bool full = (row0 + 128 <= nrows);
    float acc[8][8];
#pragma unroll
    for (int i = 0; i < 8; ++i)
#pragma unroll
        for (int j = 0; j < 8; ++j) acc[i][j] = 0.f;

    for (int ph = 0; ph < 2; ++ph) {
        const float* W = ph ? W2f : W1f;
        const float* X = ph ? X2 : X1;
        for (int kc = 0; kc < HH; kc += 32) {
            __syncthreads();  // previous chunk's compute done before restage
            // stage W rows kc..kc+31 (contiguous 16KB)
            for (int i = tid * 4; i < 32 * HH; i += 1024)
                *(float4*)&Wl[i] = *(const float4*)&W[kc * HH + i];
            // stage X chunk [128 rows][32 k] -> Xl[r*36 + c]
            for (int idx = tid; idx < 1024; idx += 256) {
                int r = idx >> 3, c = idx & 7;
                float4 v = make_float4(0.f, 0.f, 0.f, 0.f);
                if (full || row0 + r < nrows)
                    v = *(const float4*)&X[(size_t)(row0 + r) * HH + kc + c * 4];
                *(float4*)&Xl[r * 36 + c * 4] = v;
            }
            __syncthreads();
#pragma unroll
            for (int k = 0; k < 32; k += 4) {
                float4 xv[8];
#pragma unroll
                for (int i = 0; i < 8; ++i) xv[i] = *(const float4*)&Xl[(ty + 16 * i) * 36 + k];
#pragma unroll
                for (int kk = 0; kk < 4; ++kk) {
                    float4 w0 = *(const float4*)&Wl[(k + kk) * HH + tx * 4];
                    float4 w1 = *(const float4*)&Wl[(k + kk) * HH + 64 + tx * 4];
#pragma unroll
                    for (int i = 0; i < 8; ++i) {
                        float xsv = (&xv[i].x)[kk];
                        acc[i][0] += xsv * w0.x; acc[i][1] += xsv * w0.y;
                        acc[i][2] += xsv * w0.z; acc[i][3] += xsv * w0.w;
                        acc[i][4] += xsv * w1.x; acc[i][5] += xsv * w1.y;
                        acc[i][6] += xsv * w1.z; acc[i][7] += xsv * w1.w;
                    }
                }
            }
        }
    }
    float4 b0 = *(const float4*)&bias[tx * 4];
    float4 b1 = *(const float4*)&bias[64 + tx * 4];
#pragma unroll
    for (int i = 0; i < 8; ++i) {
        int r = row0 + ty + 16 * i;
        if (r >= nrows) continue;
        float* yp = Y + (size_t)r * HH + tx * 4;
        *(float4*)yp = make_float4(acc[i][0] + b0.x, acc[i][1] + b0.y, acc[i][2] + b0.z, acc[i][3] + b0.w);
        *(float4*)(yp + 64) = make_float4(acc[i][4] + b1.x, acc[i][5] + b1.y, acc[i][6] + b1.z, acc[i][7] + b1.w);
    }
}

// ---------------- attention score partials ----------------
__global__ __launch_bounds__(256) void k_attn(const float* __restrict__ X, const float* __restrict__ W1,
                                              const float* __restrict__ b1, const float* __restrict__ w2,
                                              float* __restrict__ partial, int nrows) {
    __shared__ float W1l[HH * AAA];
    __shared__ float red[4];
    int tid = threadIdx.x;
    for (int i = tid * 4; i < HH * AAA; i += 1024)
        *(float4*)&W1l[i] = *(const float4*)&W1[i];
    int lane = tid & 63, wv = tid >> 6;
    float b1v = b1[lane], w2v = w2[lane];
    __syncthreads();
    float acc = 0.f;
    for (int n = blockIdx.x * 4 + wv; n < nrows; n += gridDim.x * 4) {
        const float4* x4 = (const float4*)(X + (size_t)n * HH);
        float s = b1v;
#pragma unroll
        for (int h4 = 0; h4 < 32; ++h4) {
            float4 xv = x4[h4];
            s += xv.x * W1l[(h4 * 4 + 0) * AAA + lane];
            s += xv.y * W1l[(h4 * 4 + 1) * AAA + lane];
            s += xv.z * W1l[(h4 * 4 + 2) * AAA + lane];
            s += xv.w * W1l[(h4 * 4 + 3) * AAA + lane];
        }
        acc += tanhf(s) * w2v;
    }
#pragma unroll
    for (int off = 32; off > 0; off >>= 1) acc += __shfl_down(acc, off);
    if (lane == 0) red[wv] = acc;
    __syncthreads();
    if (tid == 0) partial[blockIdx.x] = red[0] + red[1] + red[2] + red[3];
}

__global__ void k_alpha(const float* __restrict__ P1, const float* __restrict__ P2,
                        float* __restrict__ alpha, int nparts, float invn) {
    __shared__ float s1[256], s2[256];
    int tid = threadIdx.x;
    float a = 0.f, b = 0.f;
    for (int i = tid; i < nparts; i += 256) { a += P1[i]; b += P2[i]; }
    s1[tid] = a; s2[tid] = b;
    __syncthreads();
    for (int off = 128; off > 0; off >>= 1) {
        if (tid < off) { s1[tid] += s1[tid + off]; s2[tid] += s2[tid + off]; }
        __syncthreads();
    }
    if (tid == 0) {
        float m1 = s1[0] * invn, m2 = s2[0] * invn;
        float mx = fmaxf(m1, m2);
        float e1 = expf(m1 - mx), e2 = expf(m2 - mx);
        float inv = 1.f / (e1 + e2);
        alpha[0] = e1 * inv; alpha[1] = e2 * inv;
    }
}

// ---------------- combine + column stats ----------------
template <bool COMBINE>
__global__ __launch_bounds__(256) void k_comb(float* __restrict__ X, const float* __restrict__ Y,
                                              const float* __restrict__ alpha, float* __restrict__ colsum,
                                              float* __restrict__ colsq, int nrows) {
    int tid = threadIdx.x;
    int h = tid & 127, half = tid >> 7;
    float a0 = 1.f, a1 = 0.f;
    if (COMBINE) { a0 = alpha[0]; a1 = alpha[1]; }
    float s = 0.f, q = 0.f;
    for (int n = blockIdx.x * 2 + half; n < nrows; n += gridDim.x * 2) {
        size_t off = (size_t)n * HH + h;
        float v = X[off];
        if (COMBINE) { v = a0 * v + a1 * Y[off]; X[off] = v; }
        s += v; q += v * v;
    }
    __shared__ float ls[256], lq[256];
    ls[tid] = s; lq[tid] = q;
    __syncthreads();
    if (half == 0) {
        atomicAdd(&colsum[h], ls[tid] + ls[tid + 128]);
        atomicAdd(&colsq[h], lq[tid] + lq[tid + 128]);
    }
}

__global__ void k_bnp(const float* __restrict__ sum, const float* __restrict__ sq,
                      const float* __restrict__ gamma, const float* __restrict__ beta,
                      float* __restrict__ scale, float* __restrict__ shift, float invn) {
    int h = threadIdx.x;
    float mu = sum[h] * invn;
    float var = sq[h] * invn - mu * mu;
    float sc = gamma[h] * rsqrtf(var + 1.0f);
    scale[h] = sc;
    shift[h] = beta[h] - mu * sc;
}

__global__ void k_bna(float* __restrict__ X, const float* __restrict__ scale,
                      const float* __restrict__ shift) {
    int i = blockIdx.x * 256 + threadIdx.x;
    float4 v = ((float4*)X)[i];
    int h0 = (i & 31) * 4;
    float4 sc = *(const float4*)&scale[h0];
    float4 sf = *(const float4*)&shift[h0];
    v.x = v.x * sc.x + sf.x; v.y = v.y * sc.y + sf.y;
    v.z = v.z * sc.z + sf.z; v.w = v.w * sc.w + sf.w;
    v.x = v.x >= 0.f ? v.x : 0.01f * v.x;
    v.y = v.y >= 0.f ? v.y : 0.01f * v.y;
    v.z = v.z >= 0.f ? v.z : 0.01f * v.z;
    v.w = v.w >= 0.f ? v.w : 0.01f * v.w;
    ((float4*)X)[i] = v;
}

// ---------------- final FC ----------------
__global__ __launch_bounds__(256) void k_fc(const float* __restrict__ X, const float* __restrict__ W,
                                            const float* __restrict__ b, float* __restrict__ out, int nrows) {
    __shared__ float Wl[HH * CC];
    __shared__ float bl[CC];
    int tid = threadIdx.x;
    for (int i = tid * 4; i < HH * CC; i += 1024)
        *(float4*)&Wl[i] = *(const float4*)&W[i];
    if (tid < CC) bl[tid] = b[tid];
    __syncthreads();
    int c = tid & 15, nl = tid >> 4;
    for (int n = blockIdx.x * 16 + nl; n < nrows; n += gridDim.x * 16) {
        const float4* x4 = (const float4*)(X + (size_t)n * HH);
        float acc = bl[c];
#pragma unroll
        for (int h4 = 0; h4 < 32; ++h4) {
            float4 xv = x4[h4];
            acc += xv.x * Wl[(h4 * 4 + 0) * CC + c] + xv.y * Wl[(h4 * 4 + 1) * CC + c] +
                   xv.z * Wl[(h4 * 4 + 2) * CC + c] + xv.w * Wl[(h4 * 4 + 3) * CC + c];
        }
        out[(size_t)n * CC + c] = acc;
    }
}

extern "C" void kernel_launch(void* const* d_in, const int* in_sizes, int n_in,
                              void* d_out, int out_size, void* d_ws, size_t ws_size,
                              hipStream_t stream) {
    const float* xA = (const float*)d_in[0];
    const float* xB = (const float*)d_in[1];
    const float* Wsrc = (const float*)d_in[2];
    const float* bsrc = (const float*)d_in[3];
    const float* Wdst = (const float*)d_in[4];
    const float* bdst = (const float*)d_in[5];
    const float* Wupd = (const float*)d_in[6];
    const float* bupd = (const float*)d_in[7];
    const float* attnW1 = (const float*)d_in[8];
    const float* attnb1 = (const float*)d_in[9];
    const float* attnw2 = (const float*)d_in[10];
    const float* gamma = (const float*)d_in[11];
    const float* beta = (const float*)d_in[12];
    const float* fcW = (const float*)d_in[13];
    const float* fcb = (const float*)d_in[14];
    const int* eAB = (const int*)d_in[15];
    const int* eBB = (const int*)d_in[16];
    const int* eBA = (const int*)d_in[17];
    float* out = (float*)d_out;

    float* ws = (float*)d_ws;
    const size_t NH = (size_t)NN * HH;
    float* B0 = ws;
    float* B1 = B0 + NH;
    float* B2 = B1 + NH;
    float* B3 = B2 + NH;
    float* fWd = B3 + NH;
    float* fWs = fWd + (size_t)LL * RR * HH * HH;
    float* fB = fWs + (size_t)LL * RR * HH * HH;
    float* csA = fB + LL * RR * HH;
    float* csB = csA + 256;
    float* scA = csB + 256;
    float* scB = scA + 256;
    float* P1 = scB + 256;
    float* P2 = P1 + 1024;
    float* alp = P2 + 1024;
    int* icnt = (int*)(alp + 64);
    int* irs = icnt + 3 * NN;
    int* icsr = irs + 3 * NN;
    int* ifill = icsr + 3 * EE;
    int* ibsum = ifill + NN;
    const float invN = 1.0f / (float)NN;

    k_fuse_w<<<LL * RR * HH, 256, 0, stream>>>(Wsrc, Wdst, Wupd, fWd, fWs);
    k_fuse_b<<<LL * RR, HH, 0, stream>>>(bsrc, bdst, bupd, Wupd, fB);

    const int* eArr[3] = {eAB, eBB, eBA};
    for (int r = 0; r < 3; ++r) {
        const int* e = eArr[r];
        int* cnt = icnt + r * NN;
        int* rs = irs + r * NN;
        int* csr = icsr + (size_t)r * EE;
        hipMemsetAsync(cnt, 0, NN * 4, stream);
        hipMemsetAsync(ifill, 0, NN * 4, stream);
        k_count<<<(EE + 255) / 256, 256, 0, stream>>>(e + EE, cnt);
        k_scan1<<<SCAN_B, 256, 0, stream>>>(cnt, rs, ibsum);
        k_scan2<<<1, 128, 0, stream>>>(ibsum);
        k_scan3<<<(NN + 255) / 256, 256, 0, stream>>>(rs, ibsum);
        k_fill<<<(EE + 255) / 256, 256, 0, stream>>>(e, ifill, rs, csr);
    }

    const int GEMM_GRID = (NN + 127) / 128;
    const int AGGR_GRID = (NN + 3) / 4;

    auto conv = [&](float* emb, const float* xs, const float* xd, int rel, int lr) {
        k_aggr<<<AGGR_GRID, 256, 0, stream>>>(emb, xs, irs + rel * NN, icnt + rel * NN,
                                              icsr + (size_t)rel * EE);
        k_cgemm<<<GEMM_GRID, 256, 0, stream>>>(emb, emb, xd, fWs + (size_t)lr * HH * HH,
                                               fWd + (size_t)lr * HH * HH, fB + lr * HH, NN);
    };

    // ================= layer 0 =================
    conv(B0, xA, xB, 0, 0);  // embB1
    conv(B1, xB, xB, 1, 1);  // embB2
    conv(B2, xB, xA, 2, 2);  // embA
    k_attn<<<1024, 256, 0, stream>>>(B0, attnW1, attnb1, attnw2, P1, NN);
    k_attn<<<1024, 256, 0, stream>>>(B1, attnW1, attnb1, attnw2, P2, NN);
    k_alpha<<<1, 256, 0, stream>>>(P1, P2, alp, 1024, invN);
    hipMemsetAsync(csB, 0, 256 * 4, stream);
    k_comb<true><<<512, 256, 0, stream>>>(B0, B1, alp, csB, csB + 128, NN);
    hipMemsetAsync(csA, 0, 256 * 4, stream);
    k_comb<false><<<512, 256, 0, stream>>>(B2, nullptr, nullptr, csA, csA + 128, NN);
    k_bnp<<<1, 128, 0, stream>>>(csA, csA + 128, gamma + 0 * HH, beta + 0 * HH, scA, scA + 128, invN);
    k_bnp<<<1, 128, 0, stream>>>(csB, csB + 128, gamma + 1 * HH, beta + 1 * HH, scB, scB + 128, invN);
    k_bna<<<(int)(NH / 4 / 256), 256, 0, stream>>>(B2, scA, scA + 128);  // xA = B2
    k_bna<<<(int)(NH / 4 / 256), 256, 0, stream>>>(B0, scB, scB + 128);  // xB = B0

    // ================= layer 1 =================
    conv(B1, B2, B0, 0, 3);  // embB1'
    conv(B3, B0, B0, 1, 4);  // embB2'
    k_attn<<<1024, 256, 0, stream>>>(B1, attnW1 + HH * AAA, attnb1 + AAA, attnw2 + AAA, P1, NN);
    k_attn<<<1024, 256, 0, stream>>>(B3, attnW1 + HH * AAA, attnb1 + AAA, attnw2 + AAA, P2, NN);
    k_alpha<<<1, 256, 0, stream>>>(P1, P2, alp, 1024, invN);
    hipMemsetAsync(csB, 0, 256 * 4, stream);
    k_comb<true><<<512, 256, 0, stream>>>(B1, B3, alp, csB, csB + 128, NN);  // xB_new -> B1
    conv(B3, B0, B2, 2, 5);  // embA'
    hipMemsetAsync(csA, 0, 256 * 4, stream);
    k_comb<false><<<512, 256, 0, stream>>>(B3, nullptr, nullptr, csA, csA + 128, NN);
    k_bnp<<<1, 128, 0, stream>>>(csA, csA + 128, gamma + 2 * HH, beta + 2 * HH, scA, scA + 128, invN);
    k_bnp<<<1, 128, 0, stream>>>(csB, csB + 128, gamma + 3 * HH, beta + 3 * HH, scB, scB + 128, invN);
    k_bna<<<(int)(NH / 4 / 256), 256, 0, stream>>>(B3, scA, scA + 128);  // xA_final = B3
    k_bna<<<(int)(NH / 4 / 256), 256, 0, stream>>>(B1, scB, scB + 128);  // xB_final = B1

    // ================= head =================
    k_fc<<<2048, 256, 0, stream>>>(B3, fcW, fcb, out, NN);
    k_fc<<<2048, 256, 0, stream>>>(B1, fcW + HH * CC, fcb + CC, out + (size_t)NN * CC, NN);
}

// Round 4
// 2048.813 us; speedup vs baseline: 1.2503x; 1.2503x over previous
//
#include <hip/hip_runtime.h>

#define NN 100000
#define HH 128
#define EE 600000
#define LL 2
#define RR 3
#define AAA 64
#define CC 16
#define SCAN_B 98   // 98 blocks x 1024 elems covers 100000

// ---------------- weight fusion ----------------
__global__ void k_fuse_w(const float* __restrict__ Wsrc, const float* __restrict__ Wdst,
                         const float* __restrict__ Wupd, float* __restrict__ fWd,
                         float* __restrict__ fWs) {
    int b = blockIdx.x;
    int lr = b >> 7, i = b & 127;
    int t = threadIdx.x;
    int j = t & 127;
    const float* wu = Wupd + (size_t)lr * 2 * HH * HH;
    float acc = 0.f;
    if (t < 128) {
        const float* wd = Wdst + ((size_t)lr * HH + i) * HH;
        for (int k = 0; k < HH; ++k) acc += wd[k] * wu[k * HH + j];
        fWd[((size_t)lr * HH + i) * HH + j] = acc;
    } else {
        const float* wsc = Wsrc + ((size_t)lr * HH + i) * HH;
        for (int k = 0; k < HH; ++k) acc += wsc[k] * wu[(HH + k) * HH + j];
        fWs[((size_t)lr * HH + i) * HH + j] = acc;
    }
}

__global__ void k_fuse_b(const float* __restrict__ bsrc, const float* __restrict__ bdst,
                         const float* __restrict__ bupd, const float* __restrict__ Wupd,
                         float* __restrict__ fB) {
    int lr = blockIdx.x;
    int j = threadIdx.x;
    const float* wu = Wupd + (size_t)lr * 2 * HH * HH;
    const float* bd = bdst + lr * HH;
    const float* bs = bsrc + lr * HH;
    float acc = bupd[lr * HH + j];
    for (int k = 0; k < HH; ++k)
        acc += bd[k] * wu[k * HH + j] + bs[k] * wu[(HH + k) * HH + j];
    fB[lr * HH + j] = acc;
}

// ---------------- CSR build ----------------
__global__ void k_count(const int* __restrict__ dst, int* __restrict__ cnt) {
    int i = blockIdx.x * 256 + threadIdx.x;
    if (i < EE) atomicAdd(&cnt[dst[i]], 1);
}

__global__ void k_scan1(const int* __restrict__ cnt, int* __restrict__ rs, int* __restrict__ bsum) {
    __shared__ int sd[256];
    int blk = blockIdx.x, tid = threadIdx.x;
    int base = blk * 1024 + tid * 4;
    int c0 = 0, c1 = 0, c2 = 0, c3 = 0;
    if (base + 0 < NN) c0 = cnt[base + 0];
    if (base + 1 < NN) c1 = cnt[base + 1];
    if (base + 2 < NN) c2 = cnt[base + 2];
    if (base + 3 < NN) c3 = cnt[base + 3];
    int s = c0 + c1 + c2 + c3;
    sd[tid] = s;
    __syncthreads();
    for (int off = 1; off < 256; off <<= 1) {
        int v = (tid >= off) ? sd[tid - off] : 0;
        __syncthreads();
        sd[tid] += v;
        __syncthreads();
    }
    int excl = sd[tid] - s;
    if (tid == 255) bsum[blk] = sd[255];
    if (base + 0 < NN) rs[base + 0] = excl;
    if (base + 1 < NN) rs[base + 1] = excl + c0;
    if (base + 2 < NN) rs[base + 2] = excl + c0 + c1;
    if (base + 3 < NN) rs[base + 3] = excl + c0 + c1 + c2;
}

__global__ void k_scan2(int* __restrict__ bsum) {  // 1 block, 128 threads
    __shared__ int sd[128];
    int tid = threadIdx.x;
    int v = (tid < SCAN_B) ? bsum[tid] : 0;
    sd[tid] = v;
    __syncthreads();
    for (int off = 1; off < 128; off <<= 1) {
        int u = (tid >= off) ? sd[tid - off] : 0;
        __syncthreads();
        sd[tid] += u;
        __syncthreads();
    }
    if (tid < SCAN_B) bsum[tid] = sd[tid] - v;  // exclusive
}

__global__ void k_scan3(int* __restrict__ rs, const int* __restrict__ bsum) {
    int i = blockIdx.x * 256 + threadIdx.x;
    if (i < NN) rs[i] += bsum[i >> 10];
}

__global__ void k_fill(const int* __restrict__ e, int* __restrict__ fill,
                       const int* __restrict__ rs, int* __restrict__ csr) {
    int i = blockIdx.x * 256 + threadIdx.x;
    if (i >= EE) return;
    int s = e[i], d = e[EE + i];
    int pos = rs[d] + atomicAdd(&fill[d], 1);
    csr[pos] = s;
}

// ---------------- aggregation: one wave per dst node ----------------
__global__ __launch_bounds__(256) void k_aggr(float* __restrict__ emb, const float* __restrict__ xs,
                                              const int* __restrict__ rs, const int* __restrict__ cnt,
                                              const int* __restrict__ csr) {
    int node = blockIdx.x * 4 + (threadIdx.x >> 6);
    if (node >= NN) return;
    int lane = threadIdx.x & 63;
    int beg = rs[node], deg = cnt[node];
    const float2* xs2 = (const float2*)xs;
    float ax = 0.f, ay = 0.f;
    int j = 0;
    for (; j + 1 < deg; j += 2) {
        int s0 = csr[beg + j], s1 = csr[beg + j + 1];
        float2 v0 = xs2[(size_t)s0 * 64 + lane];
        float2 v1 = xs2[(size_t)s1 * 64 + lane];
        ax += v0.x + v1.x;
        ay += v0.y + v1.y;
    }
    if (j < deg) {
        float2 v = xs2[(size_t)csr[beg + j] * 64 + lane];
        ax += v.x;
        ay += v.y;
    }
    float sc = 1.0f / fmaxf((float)deg, 1.0f);
    ((float2*)emb)[(size_t)node * 64 + lane] = make_float2(ax * sc, ay * sc);
}

// ---------------- fused conv GEMM: Y = X1@W1 + X2@W2 + bias ----------------
// k-chunked staging: LDS = Xl[128][36-pad] (18KB) + Wl[32][128] (16KB) = 34.8KB.
// NO min-waves bound: (256,3) squeezed VGPR to 84 and spilled the 64-reg
// accumulator to scratch (286MB WRITE_SIZE, round-3 profile). Natural alloc
// ~132 VGPR -> 3 waves/SIMD, LDS allows 4 blocks/CU -> occupancy ~12 waves/CU.
__global__ __launch_bounds__(256) void k_cgemm(float* __restrict__ Y, const float* __restrict__ X1,
                                               const float* __restrict__ X2, const float* __restrict__ W1f,
                                               const float* __restrict__ W2f, const float* __restrict__ bias,
                                               int nrows) {
    __shared__ float Xl[128 * 36];  // padded stride 36 dwords: conflict-free strided reads
    __shared__ float Wl[32 * 128];
    int tid = threadIdx.x;
    int row0 = blockIdx.x * 128;
    int tx = tid & 15, ty = tid >> 4;
    bool full = (row0 + 128 <= nrows);
    float acc[8][8];
#pragma unroll
    for (int i = 0; i < 8; ++i)
#pragma unroll
        for (int j = 0; j < 8; ++j) acc[i][j] = 0.f;

    for (int ph = 0; ph < 2; ++ph) {
        const float* W = ph ? W2f : W1f;
        const float* X = ph ? X2 : X1;
        for (int kc = 0; kc < HH; kc += 32) {
            __syncthreads();  // previous chunk's compute done before restage
            // stage W rows kc..kc+31 (contiguous 16KB)
            for (int i = tid * 4; i < 32 * HH; i += 1024)
                *(float4*)&Wl[i] = *(const float4*)&W[kc * HH + i];
            // stage X chunk [128 rows][32 k] -> Xl[r*36 + c]
            for (int idx = tid; idx < 1024; idx += 256) {
                int r = idx >> 3, c = idx & 7;
                float4 v = make_float4(0.f, 0.f, 0.f, 0.f);
                if (full || row0 + r < nrows)
                    v = *(const float4*)&X[(size_t)(row0 + r) * HH + kc + c * 4];
                *(float4*)&Xl[r * 36 + c * 4] = v;
            }
            __syncthreads();
#pragma unroll
            for (int k = 0; k < 32; k += 4) {
                float4 xv[8];
#pragma unroll
                for (int i = 0; i < 8; ++i) xv[i] = *(const float4*)&Xl[(ty + 16 * i) * 36 + k];
#pragma unroll
                for (int kk = 0; kk < 4; ++kk) {
                    float4 w0 = *(const float4*)&Wl[(k + kk) * HH + tx * 4];
                    float4 w1 = *(const float4*)&Wl[(k + kk) * HH + 64 + tx * 4];
#pragma unroll
                    for (int i = 0; i < 8; ++i) {
                        float xsv = (&xv[i].x)[kk];
                        acc[i][0] += xsv * w0.x; acc[i][1] += xsv * w0.y;
                        acc[i][2] += xsv * w0.z; acc[i][3] += xsv * w0.w;
                        acc[i][4] += xsv * w1.x; acc[i][5] += xsv * w1.y;
                        acc[i][6] += xsv * w1.z; acc[i][7] += xsv * w1.w;
                    }
                }
            }
        }
    }
    float4 b0 = *(const float4*)&bias[tx * 4];
    float4 b1 = *(const float4*)&bias[64 + tx * 4];
#pragma unroll
    for (int i = 0; i < 8; ++i) {
        int r = row0 + ty + 16 * i;
        if (r >= nrows) continue;
        float* yp = Y + (size_t)r * HH + tx * 4;
        *(float4*)yp = make_float4(acc[i][0] + b0.x, acc[i][1] + b0.y, acc[i][2] + b0.z, acc[i][3] + b0.w);
        *(float4*)(yp + 64) = make_float4(acc[i][4] + b1.x, acc[i][5] + b1.y, acc[i][6] + b1.z, acc[i][7] + b1.w);
    }
}

// ---------------- attention score partials ----------------
__global__ __launch_bounds__(256) void k_attn(const float* __restrict__ X, const float* __restrict__ W1,
                                              const float* __restrict__ b1, const float* __restrict__ w2,
                                              float* __restrict__ partial, int nrows) {
    __shared__ float W1l[HH * AAA];
    __shared__ float red[4];
    int tid = threadIdx.x;
    for (int i = tid * 4; i < HH * AAA; i += 1024)
        *(float4*)&W1l[i] = *(const float4*)&W1[i];
    int lane = tid & 63, wv = tid >> 6;
    float b1v = b1[lane], w2v = w2[lane];
    __syncthreads();
    float acc = 0.f;
    for (int n = blockIdx.x * 4 + wv; n < nrows; n += gridDim.x * 4) {
        const float4* x4 = (const float4*)(X + (size_t)n * HH);
        float s = b1v;
#pragma unroll
        for (int h4 = 0; h4 < 32; ++h4) {
            float4 xv = x4[h4];
            s += xv.x * W1l[(h4 * 4 + 0) * AAA + lane];
            s += xv.y * W1l[(h4 * 4 + 1) * AAA + lane];
            s += xv.z * W1l[(h4 * 4 + 2) * AAA + lane];
            s += xv.w * W1l[(h4 * 4 + 3) * AAA + lane];
        }
        acc += tanhf(s) * w2v;
    }
#pragma unroll
    for (int off = 32; off > 0; off >>= 1) acc += __shfl_down(acc, off);
    if (lane == 0) red[wv] = acc;
    __syncthreads();
    if (tid == 0) partial[blockIdx.x] = red[0] + red[1] + red[2] + red[3];
}

__global__ void k_alpha(const float* __restrict__ P1, const float* __restrict__ P2,
                        float* __restrict__ alpha, int nparts, float invn) {
    __shared__ float s1[256], s2[256];
    int tid = threadIdx.x;
    float a = 0.f, b = 0.f;
    for (int i = tid; i < nparts; i += 256) { a += P1[i]; b += P2[i]; }
    s1[tid] = a; s2[tid] = b;
    __syncthreads();
    for (int off = 128; off > 0; off >>= 1) {
        if (tid < off) { s1[tid] += s1[tid + off]; s2[tid] += s2[tid + off]; }
        __syncthreads();
    }
    if (tid == 0) {
        float m1 = s1[0] * invn, m2 = s2[0] * invn;
        float mx = fmaxf(m1, m2);
        float e1 = expf(m1 - mx), e2 = expf(m2 - mx);
        float inv = 1.f / (e1 + e2);
        alpha[0] = e1 * inv; alpha[1] = e2 * inv;
    }
}

// ---------------- combine + column stats ----------------
template <bool COMBINE>
__global__ __launch_bounds__(256) void k_comb(float* __restrict__ X, const float* __restrict__ Y,
                                              const float* __restrict__ alpha, float* __restrict__ colsum,
                                              float* __restrict__ colsq, int nrows) {
    int tid = threadIdx.x;
    int h = tid & 127, half = tid >> 7;
    float a0 = 1.f, a1 = 0.f;
    if (COMBINE) { a0 = alpha[0]; a1 = alpha[1]; }
    float s = 0.f, q = 0.f;
    for (int n = blockIdx.x * 2 + half; n < nrows; n += gridDim.x * 2) {
        size_t off = (size_t)n * HH + h;
        float v = X[off];
        if (COMBINE) { v = a0 * v + a1 * Y[off]; X[off] = v; }
        s += v; q += v * v;
    }
    __shared__ float ls[256], lq[256];
    ls[tid] = s; lq[tid] = q;
    __syncthreads();
    if (half == 0) {
        atomicAdd(&colsum[h], ls[tid] + ls[tid + 128]);
        atomicAdd(&colsq[h], lq[tid] + lq[tid + 128]);
    }
}

__global__ void k_bnp(const float* __restrict__ sum, const float* __restrict__ sq,
                      const float* __restrict__ gamma, const float* __restrict__ beta,
                      float* __restrict__ scale, float* __restrict__ shift, float invn) {
    int h = threadIdx.x;
    float mu = sum[h] * invn;
    float var = sq[h] * invn - mu * mu;
    float sc = gamma[h] * rsqrtf(var + 1.0f);
    scale[h] = sc;
    shift[h] = beta[h] - mu * sc;
}

__global__ void k_bna(float* __restrict__ X, const float* __restrict__ scale,
                      const float* __restrict__ shift) {
    int i = blockIdx.x * 256 + threadIdx.x;
    float4 v = ((float4*)X)[i];
    int h0 = (i & 31) * 4;
    float4 sc = *(const float4*)&scale[h0];
    float4 sf = *(const float4*)&shift[h0];
    v.x = v.x * sc.x + sf.x; v.y = v.y * sc.y + sf.y;
    v.z = v.z * sc.z + sf.z; v.w = v.w * sc.w + sf.w;
    v.x = v.x >= 0.f ? v.x : 0.01f * v.x;
    v.y = v.y >= 0.f ? v.y : 0.01f * v.y;
    v.z = v.z >= 0.f ? v.z : 0.01f * v.z;
    v.w = v.w >= 0.f ? v.w : 0.01f * v.w;
    ((float4*)X)[i] = v;
}

// ---------------- final FC ----------------
__global__ __launch_bounds__(256) void k_fc(const float* __restrict__ X, const float* __restrict__ W,
                                            const float* __restrict__ b, float* __restrict__ out, int nrows) {
    __shared__ float Wl[HH * CC];
    __shared__ float bl[CC];
    int tid = threadIdx.x;
    for (int i = tid * 4; i < HH * CC; i += 1024)
        *(float4*)&Wl[i] = *(const float4*)&W[i];
    if (tid < CC) bl[tid] = b[tid];
    __syncthreads();
    int c = tid & 15, nl = tid >> 4;
    for (int n = blockIdx.x * 16 + nl; n < nrows; n += gridDim.x * 16) {
        const float4* x4 = (const float4*)(X + (size_t)n * HH);
        float acc = bl[c];
#pragma unroll
        for (int h4 = 0; h4 < 32; ++h4) {
            float4 xv = x4[h4];
            acc += xv.x * Wl[(h4 * 4 + 0) * CC + c] + xv.y * Wl[(h4 * 4 + 1) * CC + c] +
                   xv.z * Wl[(h4 * 4 + 2) * CC + c] + xv.w * Wl[(h4 * 4 + 3) * CC + c];
        }
        out[(size_t)n * CC + c] = acc;
    }
}

extern "C" void kernel_launch(void* const* d_in, const int* in_sizes, int n_in,
                              void* d_out, int out_size, void* d_ws, size_t ws_size,
                              hipStream_t stream) {
    const float* xA = (const float*)d_in[0];
    const float* xB = (const float*)d_in[1];
    const float* Wsrc = (const float*)d_in[2];
    const float* bsrc = (const float*)d_in[3];
    const float* Wdst = (const float*)d_in[4];
    const float* bdst = (const float*)d_in[5];
    const float* Wupd = (const float*)d_in[6];
    const float* bupd = (const float*)d_in[7];
    const float* attnW1 = (const float*)d_in[8];
    const float* attnb1 = (const float*)d_in[9];
    const float* attnw2 = (const float*)d_in[10];
    const float* gamma = (const float*)d_in[11];
    const float* beta = (const float*)d_in[12];
    const float* fcW = (const float*)d_in[13];
    const float* fcb = (const float*)d_in[14];
    const int* eAB = (const int*)d_in[15];
    const int* eBB = (const int*)d_in[16];
    const int* eBA = (const int*)d_in[17];
    float* out = (float*)d_out;

    float* ws = (float*)d_ws;
    const size_t NH = (size_t)NN * HH;
    float* B0 = ws;
    float* B1 = B0 + NH;
    float* B2 = B1 + NH;
    float* B3 = B2 + NH;
    float* fWd = B3 + NH;
    float* fWs = fWd + (size_t)LL * RR * HH * HH;
    float* fB = fWs + (size_t)LL * RR * HH * HH;
    float* csA = fB + LL * RR * HH;
    float* csB = csA + 256;
    float* scA = csB + 256;
    float* scB = scA + 256;
    float* P1 = scB + 256;
    float* P2 = P1 + 1024;
    float* alp = P2 + 1024;
    int* icnt = (int*)(alp + 64);
    int* irs = icnt + 3 * NN;
    int* icsr = irs + 3 * NN;
    int* ifill = icsr + 3 * EE;
    int* ibsum = ifill + NN;
    const float invN = 1.0f / (float)NN;

    k_fuse_w<<<LL * RR * HH, 256, 0, stream>>>(Wsrc, Wdst, Wupd, fWd, fWs);
    k_fuse_b<<<LL * RR, HH, 0, stream>>>(bsrc, bdst, bupd, Wupd, fB);

    const int* eArr[3] = {eAB, eBB, eBA};
    for (int r = 0; r < 3; ++r) {
        const int* e = eArr[r];
        int* cnt = icnt + r * NN;
        int* rs = irs + r * NN;
        int* csr = icsr + (size_t)r * EE;
        hipMemsetAsync(cnt, 0, NN * 4, stream);
        hipMemsetAsync(ifill, 0, NN * 4, stream);
        k_count<<<(EE + 255) / 256, 256, 0, stream>>>(e + EE, cnt);
        k_scan1<<<SCAN_B, 256, 0, stream>>>(cnt, rs, ibsum);
        k_scan2<<<1, 128, 0, stream>>>(ibsum);
        k_scan3<<<(NN + 255) / 256, 256, 0, stream>>>(rs, ibsum);
        k_fill<<<(EE + 255) / 256, 256, 0, stream>>>(e, ifill, rs, csr);
    }

    const int GEMM_GRID = (NN + 127) / 128;
    const int AGGR_GRID = (NN + 3) / 4;

    auto conv = [&](float* emb, const float* xs, const float* xd, int rel, int lr) {
        k_aggr<<<AGGR_GRID, 256, 0, stream>>>(emb, xs, irs + rel * NN, icnt + rel * NN,
                                              icsr + (size_t)rel * EE);
        k_cgemm<<<GEMM_GRID, 256, 0, stream>>>(emb, emb, xd, fWs + (size_t)lr * HH * HH,
                                               fWd + (size_t)lr * HH * HH, fB + lr * HH, NN);
    };

    // ================= layer 0 =================
    conv(B0, xA, xB, 0, 0);  // embB1
    conv(B1, xB, xB, 1, 1);  // embB2
    conv(B2, xB, xA, 2, 2);  // embA
    k_attn<<<1024, 256, 0, stream>>>(B0, attnW1, attnb1, attnw2, P1, NN);
    k_attn<<<1024, 256, 0, stream>>>(B1, attnW1, attnb1, attnw2, P2, NN);
    k_alpha<<<1, 256, 0, stream>>>(P1, P2, alp, 1024, invN);
    hipMemsetAsync(csB, 0, 256 * 4, stream);
    k_comb<true><<<512, 256, 0, stream>>>(B0, B1, alp, csB, csB + 128, NN);
    hipMemsetAsync(csA, 0, 256 * 4, stream);
    k_comb<false><<<512, 256, 0, stream>>>(B2, nullptr, nullptr, csA, csA + 128, NN);
    k_bnp<<<1, 128, 0, stream>>>(csA, csA + 128, gamma + 0 * HH, beta + 0 * HH, scA, scA + 128, invN);
    k_bnp<<<1, 128, 0, stream>>>(csB, csB + 128, gamma + 1 * HH, beta + 1 * HH, scB, scB + 128, invN);
    k_bna<<<(int)(NH / 4 / 256), 256, 0, stream>>>(B2, scA, scA + 128);  // xA = B2
    k_bna<<<(int)(NH / 4 / 256), 256, 0, stream>>>(B0, scB, scB + 128);  // xB = B0

    // ================= layer 1 =================
    conv(B1, B2, B0, 0, 3);  // embB1'
    conv(B3, B0, B0, 1, 4);  // embB2'
    k_attn<<<1024, 256, 0, stream>>>(B1, attnW1 + HH * AAA, attnb1 + AAA, attnw2 + AAA, P1, NN);
    k_attn<<<1024, 256, 0, stream>>>(B3, attnW1 + HH * AAA, attnb1 + AAA, attnw2 + AAA, P2, NN);
    k_alpha<<<1, 256, 0, stream>>>(P1, P2, alp, 1024, invN);
    hipMemsetAsync(csB, 0, 256 * 4, stream);
    k_comb<true><<<512, 256, 0, stream>>>(B1, B3, alp, csB, csB + 128, NN);  // xB_new -> B1
    conv(B3, B0, B2, 2, 5);  // embA'
    hipMemsetAsync(csA, 0, 256 * 4, stream);
    k_comb<false><<<512, 256, 0, stream>>>(B3, nullptr, nullptr, csA, csA + 128, NN);
    k_bnp<<<1, 128, 0, stream>>>(csA, csA + 128, gamma + 2 * HH, beta + 2 * HH, scA, scA + 128, invN);
    k_bnp<<<1, 128, 0, stream>>>(csB, csB + 128, gamma + 3 * HH, beta + 3 * HH, scB, scB + 128, invN);
    k_bna<<<(int)(NH / 4 / 256), 256, 0, stream>>>(B3, scA, scA + 128);  // xA_final = B3
    k_bna<<<(int)(NH / 4 / 256), 256, 0, stream>>>(B1, scB, scB + 128);  // xB_final = B1

    // ================= head =================
    k_fc<<<2048, 256, 0, stream>>>(B3, fcW, fcb, out, NN);
    k_fc<<<2048, 256, 0, stream>>>(B1, fcW + HH * CC, fcb + CC, out + (size_t)NN * CC, NN);
}

// Round 5
// 1694.746 us; speedup vs baseline: 1.5115x; 1.2089x over previous
//
#include <hip/hip_runtime.h>

#define NN 100000
#define HH 128
#define EE 600000
#define LL 2
#define RR 3
#define AAA 64
#define CC 16
#define SCAN_B 98   // 98 blocks x 1024 elems covers 100000
#define ATTN_GRID ((NN + 127) / 128)

// ---------------- weight fusion ----------------
__global__ void k_fuse_w(const float* __restrict__ Wsrc, const float* __restrict__ Wdst,
                         const float* __restrict__ Wupd, float* __restrict__ fWd,
                         float* __restrict__ fWs) {
    int b = blockIdx.x;
    int lr = b >> 7, i = b & 127;
    int t = threadIdx.x;
    int j = t & 127;
    const float* wu = Wupd + (size_t)lr * 2 * HH * HH;
    float acc = 0.f;
    if (t < 128) {
        const float* wd = Wdst + ((size_t)lr * HH + i) * HH;
        for (int k = 0; k < HH; ++k) acc += wd[k] * wu[k * HH + j];
        fWd[((size_t)lr * HH + i) * HH + j] = acc;
    } else {
        const float* wsc = Wsrc + ((size_t)lr * HH + i) * HH;
        for (int k = 0; k < HH; ++k) acc += wsc[k] * wu[(HH + k) * HH + j];
        fWs[((size_t)lr * HH + i) * HH + j] = acc;
    }
}

__global__ void k_fuse_b(const float* __restrict__ bsrc, const float* __restrict__ bdst,
                         const float* __restrict__ bupd, const float* __restrict__ Wupd,
                         float* __restrict__ fB) {
    int lr = blockIdx.x;
    int j = threadIdx.x;
    const float* wu = Wupd + (size_t)lr * 2 * HH * HH;
    const float* bd = bdst + lr * HH;
    const float* bs = bsrc + lr * HH;
    float acc = bupd[lr * HH + j];
    for (int k = 0; k < HH; ++k)
        acc += bd[k] * wu[k * HH + j] + bs[k] * wu[(HH + k) * HH + j];
    fB[lr * HH + j] = acc;
}

// ---------------- CSR build ----------------
__global__ void k_count(const int* __restrict__ dst, int* __restrict__ cnt) {
    int i = blockIdx.x * 256 + threadIdx.x;
    if (i < EE) atomicAdd(&cnt[dst[i]], 1);
}

__global__ void k_scan1(const int* __restrict__ cnt, int* __restrict__ rs, int* __restrict__ bsum) {
    __shared__ int sd[256];
    int blk = blockIdx.x, tid = threadIdx.x;
    int base = blk * 1024 + tid * 4;
    int c0 = 0, c1 = 0, c2 = 0, c3 = 0;
    if (base + 0 < NN) c0 = cnt[base + 0];
    if (base + 1 < NN) c1 = cnt[base + 1];
    if (base + 2 < NN) c2 = cnt[base + 2];
    if (base + 3 < NN) c3 = cnt[base + 3];
    int s = c0 + c1 + c2 + c3;
    sd[tid] = s;
    __syncthreads();
    for (int off = 1; off < 256; off <<= 1) {
        int v = (tid >= off) ? sd[tid - off] : 0;
        __syncthreads();
        sd[tid] += v;
        __syncthreads();
    }
    int excl = sd[tid] - s;
    if (tid == 255) bsum[blk] = sd[255];
    if (base + 0 < NN) rs[base + 0] = excl;
    if (base + 1 < NN) rs[base + 1] = excl + c0;
    if (base + 2 < NN) rs[base + 2] = excl + c0 + c1;
    if (base + 3 < NN) rs[base + 3] = excl + c0 + c1 + c2;
}

__global__ void k_scan2(int* __restrict__ bsum) {  // 1 block, 128 threads
    __shared__ int sd[128];
    int tid = threadIdx.x;
    int v = (tid < SCAN_B) ? bsum[tid] : 0;
    sd[tid] = v;
    __syncthreads();
    for (int off = 1; off < 128; off <<= 1) {
        int u = (tid >= off) ? sd[tid - off] : 0;
        __syncthreads();
        sd[tid] += u;
        __syncthreads();
    }
    if (tid < SCAN_B) bsum[tid] = sd[tid] - v;  // exclusive
}

__global__ void k_scan3(int* __restrict__ rs, const int* __restrict__ bsum) {
    int i = blockIdx.x * 256 + threadIdx.x;
    if (i < NN) rs[i] += bsum[i >> 10];
}

__global__ void k_fill(const int* __restrict__ e, int* __restrict__ fill,
                       const int* __restrict__ rs, int* __restrict__ csr) {
    int i = blockIdx.x * 256 + threadIdx.x;
    if (i >= EE) return;
    int s = e[i], d = e[EE + i];
    int pos = rs[d] + atomicAdd(&fill[d], 1);
    csr[pos] = s;
}

// ---------------- aggregation: one wave per dst node ----------------
__global__ __launch_bounds__(256) void k_aggr(float* __restrict__ emb, const float* __restrict__ xs,
                                              const int* __restrict__ rs, const int* __restrict__ cnt,
                                              const int* __restrict__ csr) {
    int node = blockIdx.x * 4 + (threadIdx.x >> 6);
    if (node >= NN) return;
    int lane = threadIdx.x & 63;
    int beg = rs[node], deg = cnt[node];
    const float2* xs2 = (const float2*)xs;
    float ax = 0.f, ay = 0.f;
    int j = 0;
    for (; j + 1 < deg; j += 2) {
        int s0 = csr[beg + j], s1 = csr[beg + j + 1];
        float2 v0 = xs2[(size_t)s0 * 64 + lane];
        float2 v1 = xs2[(size_t)s1 * 64 + lane];
        ax += v0.x + v1.x;
        ay += v0.y + v1.y;
    }
    if (j < deg) {
        float2 v = xs2[(size_t)csr[beg + j] * 64 + lane];
        ax += v.x;
        ay += v.y;
    }
    float sc = 1.0f / fmaxf((float)deg, 1.0f);
    ((float2*)emb)[(size_t)node * 64 + lane] = make_float2(ax * sc, ay * sc);
}

// ---------------- fused conv GEMM: Y = X1@W1 + X2@W2 + bias ----------------
// k-chunked staging: LDS = Xl[128][36-pad] (18KB) + Wl[32][128] (16KB) = 34.8KB.
// NO min-waves bound (round-3: (256,3) squeezed VGPR to 84 -> acc spilled).
__global__ __launch_bounds__(256) void k_cgemm(float* __restrict__ Y, const float* __restrict__ X1,
                                               const float* __restrict__ X2, const float* __restrict__ W1f,
                                               const float* __restrict__ W2f, const float* __restrict__ bias,
                                               int nrows) {
    __shared__ float Xl[128 * 36];  // padded stride 36 dwords: conflict-free strided reads
    __shared__ float Wl[32 * 128];
    int tid = threadIdx.x;
    int row0 = blockIdx.x * 128;
    int tx = tid & 15, ty = tid >> 4;
    bool full = (row0 + 128 <= nrows);
    float acc[8][8];
#pragma unroll
    for (int i = 0; i < 8; ++i)
#pragma unroll
        for (int j = 0; j < 8; ++j) acc[i][j] = 0.f;

    for (int ph = 0; ph < 2; ++ph) {
        const float* W = ph ? W2f : W1f;
        const float* X = ph ? X2 : X1;
        for (int kc = 0; kc < HH; kc += 32) {
            __syncthreads();  // previous chunk's compute done before restage
            for (int i = tid * 4; i < 32 * HH; i += 1024)
                *(float4*)&Wl[i] = *(const float4*)&W[kc * HH + i];
            for (int idx = tid; idx < 1024; idx += 256) {
                int r = idx >> 3, c = idx & 7;
                float4 v = make_float4(0.f, 0.f, 0.f, 0.f);
                if (full || row0 + r < nrows)
                    v = *(const float4*)&X[(size_t)(row0 + r) * HH + kc + c * 4];
                *(float4*)&Xl[r * 36 + c * 4] = v;
            }
            __syncthreads();
#pragma unroll
            for (int k = 0; k < 32; k += 4) {
                float4 xv[8];
#pragma unroll
                for (int i = 0; i < 8; ++i) xv[i] = *(const float4*)&Xl[(ty + 16 * i) * 36 + k];
#pragma unroll
                for (int kk = 0; kk < 4; ++kk) {
                    float4 w0 = *(const float4*)&Wl[(k + kk) * HH + tx * 4];
                    float4 w1 = *(const float4*)&Wl[(k + kk) * HH + 64 + tx * 4];
#pragma unroll
                    for (int i = 0; i < 8; ++i) {
                        float xsv = (&xv[i].x)[kk];
                        acc[i][0] += xsv * w0.x; acc[i][1] += xsv * w0.y;
                        acc[i][2] += xsv * w0.z; acc[i][3] += xsv * w0.w;
                        acc[i][4] += xsv * w1.x; acc[i][5] += xsv * w1.y;
                        acc[i][6] += xsv * w1.z; acc[i][7] += xsv * w1.w;
                    }
                }
            }
        }
    }
    float4 b0 = *(const float4*)&bias[tx * 4];
    float4 b1 = *(const float4*)&bias[64 + tx * 4];
#pragma unroll
    for (int i = 0; i < 8; ++i) {
        int r = row0 + ty + 16 * i;
        if (r >= nrows) continue;
        float* yp = Y + (size_t)r * HH + tx * 4;
        *(float4*)yp = make_float4(acc[i][0] + b0.x, acc[i][1] + b0.y, acc[i][2] + b0.z, acc[i][3] + b0.w);
        *(float4*)(yp + 64) = make_float4(acc[i][4] + b1.x, acc[i][5] + b1.y, acc[i][6] + b1.z, acc[i][7] + b1.w);
    }
}

// ---------------- attention score: tiled GEMM [128 rows/block] x W1[128,64], tanh, dot w2 ----------------
// partial[b] = sum over block's valid rows of tanh(x@W1+b1)@w2
__global__ __launch_bounds__(256) void k_attn(const float* __restrict__ X, const float* __restrict__ W1,
                                              const float* __restrict__ b1, const float* __restrict__ w2,
                                              float* __restrict__ partial, int nrows) {
    __shared__ float W1l[HH * AAA];  // 32 KiB, staged whole
    __shared__ float Xl[128 * 36];   // 18 KiB, k-chunked
    __shared__ float red[16];
    int tid = threadIdx.x;
    int row0 = blockIdx.x * 128;
    for (int i = tid * 4; i < HH * AAA; i += 1024)
        *(float4*)&W1l[i] = *(const float4*)&W1[i];
    int tx = tid & 15, ty = tid >> 4;
    bool full = (row0 + 128 <= nrows);
    float acc[8][4];
#pragma unroll
    for (int i = 0; i < 8; ++i)
#pragma unroll
        for (int j = 0; j < 4; ++j) acc[i][j] = 0.f;

    for (int kc = 0; kc < HH; kc += 32) {
        __syncthreads();
        for (int idx = tid; idx < 1024; idx += 256) {
            int r = idx >> 3, c = idx & 7;
            float4 v = make_float4(0.f, 0.f, 0.f, 0.f);
            if (full || row0 + r < nrows)
                v = *(const float4*)&X[(size_t)(row0 + r) * HH + kc + c * 4];
            *(float4*)&Xl[r * 36 + c * 4] = v;
        }
        __syncthreads();
#pragma unroll
        for (int k = 0; k < 32; k += 4) {
            float4 xv[8];
#pragma unroll
            for (int i = 0; i < 8; ++i) xv[i] = *(const float4*)&Xl[(ty + 16 * i) * 36 + k];
#pragma unroll
            for (int kk = 0; kk < 4; ++kk) {
                float4 w = *(const float4*)&W1l[(kc + k + kk) * AAA + tx * 4];
#pragma unroll
                for (int i = 0; i < 8; ++i) {
                    float xsv = (&xv[i].x)[kk];
                    acc[i][0] += xsv * w.x; acc[i][1] += xsv * w.y;
                    acc[i][2] += xsv * w.z; acc[i][3] += xsv * w.w;
                }
            }
        }
    }
    float4 b1v = *(const float4*)&b1[tx * 4];
    float4 w2v = *(const float4*)&w2[tx * 4];
    float tot = 0.f;
#pragma unroll
    for (int i = 0; i < 8; ++i) {
        float s = tanhf(acc[i][0] + b1v.x) * w2v.x + tanhf(acc[i][1] + b1v.y) * w2v.y +
                  tanhf(acc[i][2] + b1v.z) * w2v.z + tanhf(acc[i][3] + b1v.w) * w2v.w;
        // reduce across the 16 tx lanes (same ty group, contiguous lanes in wave)
        s += __shfl_xor(s, 1);
        s += __shfl_xor(s, 2);
        s += __shfl_xor(s, 4);
        s += __shfl_xor(s, 8);
        if (row0 + ty + 16 * i < nrows) tot += s;
    }
    if (tx == 0) red[ty] = tot;
    __syncthreads();
    if (tid == 0) {
        float p = 0.f;
#pragma unroll
        for (int i = 0; i < 16; ++i) p += red[i];
        partial[blockIdx.x] = p;
    }
}

__global__ void k_alpha(const float* __restrict__ P1, const float* __restrict__ P2,
                        float* __restrict__ alpha, int nparts, float invn) {
    __shared__ float s1[256], s2[256];
    int tid = threadIdx.x;
    float a = 0.f, b = 0.f;
    for (int i = tid; i < nparts; i += 256) { a += P1[i]; b += P2[i]; }
    s1[tid] = a; s2[tid] = b;
    __syncthreads();
    for (int off = 128; off > 0; off >>= 1) {
        if (tid < off) { s1[tid] += s1[tid + off]; s2[tid] += s2[tid + off]; }
        __syncthreads();
    }
    if (tid == 0) {
        float m1 = s1[0] * invn, m2 = s2[0] * invn;
        float mx = fmaxf(m1, m2);
        float e1 = expf(m1 - mx), e2 = expf(m2 - mx);
        float inv = 1.f / (e1 + e2);
        alpha[0] = e1 * inv; alpha[1] = e2 * inv;
    }
}

// ---------------- combine + column stats ----------------
template <bool COMBINE>
__global__ __launch_bounds__(256) void k_comb(float* __restrict__ X, const float* __restrict__ Y,
                                              const float* __restrict__ alpha, float* __restrict__ colsum,
                                              float* __restrict__ colsq, int nrows) {
    int tid = threadIdx.x;
    int h = tid & 127, half = tid >> 7;
    float a0 = 1.f, a1 = 0.f;
    if (COMBINE) { a0 = alpha[0]; a1 = alpha[1]; }
    float s = 0.f, q = 0.f;
    for (int n = blockIdx.x * 2 + half; n < nrows; n += gridDim.x * 2) {
        size_t off = (size_t)n * HH + h;
        float v = X[off];
        if (COMBINE) { v = a0 * v + a1 * Y[off]; X[off] = v; }
        s += v; q += v * v;
    }
    __shared__ float ls[256], lq[256];
    ls[tid] = s; lq[tid] = q;
    __syncthreads();
    if (half == 0) {
        atomicAdd(&colsum[h], ls[tid] + ls[tid + 128]);
        atomicAdd(&colsq[h], lq[tid] + lq[tid + 128]);
    }
}

__global__ void k_bnp(const float* __restrict__ sum, const float* __restrict__ sq,
                      const float* __restrict__ gamma, const float* __restrict__ beta,
                      float* __restrict__ scale, float* __restrict__ shift, float invn) {
    int h = threadIdx.x;
    float mu = sum[h] * invn;
    float var = sq[h] * invn - mu * mu;
    float sc = gamma[h] * rsqrtf(var + 1.0f);
    scale[h] = sc;
    shift[h] = beta[h] - mu * sc;
}

__global__ void k_bna(float* __restrict__ X, const float* __restrict__ scale,
                      const float* __restrict__ shift) {
    int i = blockIdx.x * 256 + threadIdx.x;
    float4 v = ((float4*)X)[i];
    int h0 = (i & 31) * 4;
    float4 sc = *(const float4*)&scale[h0];
    float4 sf = *(const float4*)&shift[h0];
    v.x = v.x * sc.x + sf.x; v.y = v.y * sc.y + sf.y;
    v.z = v.z * sc.z + sf.z; v.w = v.w * sc.w + sf.w;
    v.x = v.x >= 0.f ? v.x : 0.01f * v.x;
    v.y = v.y >= 0.f ? v.y : 0.01f * v.y;
    v.z = v.z >= 0.f ? v.z : 0.01f * v.z;
    v.w = v.w >= 0.f ? v.w : 0.01f * v.w;
    ((float4*)X)[i] = v;
}

// ---------------- final FC ----------------
__global__ __launch_bounds__(256) void k_fc(const float* __restrict__ X, const float* __restrict__ W,
                                            const float* __restrict__ b, float* __restrict__ out, int nrows) {
    __shared__ float Wl[HH * CC];
    __shared__ float bl[CC];
    int tid = threadIdx.x;
    for (int i = tid * 4; i < HH * CC; i += 1024)
        *(float4*)&Wl[i] = *(const float4*)&W[i];
    if (tid < CC) bl[tid] = b[tid];
    __syncthreads();
    int c = tid & 15, nl = tid >> 4;
    for (int n = blockIdx.x * 16 + nl; n < nrows; n += gridDim.x * 16) {
        const float4* x4 = (const float4*)(X + (size_t)n * HH);
        float acc = bl[c];
#pragma unroll
        for (int h4 = 0; h4 < 32; ++h4) {
            float4 xv = x4[h4];
            acc += xv.x * Wl[(h4 * 4 + 0) * CC + c] + xv.y * Wl[(h4 * 4 + 1) * CC + c] +
                   xv.z * Wl[(h4 * 4 + 2) * CC + c] + xv.w * Wl[(h4 * 4 + 3) * CC + c];
        }
        out[(size_t)n * CC + c] = acc;
    }
}

extern "C" void kernel_launch(void* const* d_in, const int* in_sizes, int n_in,
                              void* d_out, int out_size, void* d_ws, size_t ws_size,
                              hipStream_t stream) {
    const float* xA = (const float*)d_in[0];
    const float* xB = (const float*)d_in[1];
    const float* Wsrc = (const float*)d_in[2];
    const float* bsrc = (const float*)d_in[3];
    const float* Wdst = (const float*)d_in[4];
    const float* bdst = (const float*)d_in[5];
    const float* Wupd = (const float*)d_in[6];
    const float* bupd = (const float*)d_in[7];
    const float* attnW1 = (const float*)d_in[8];
    const float* attnb1 = (const float*)d_in[9];
    const float* attnw2 = (const float*)d_in[10];
    const float* gamma = (const float*)d_in[11];
    const float* beta = (const float*)d_in[12];
    const float* fcW = (const float*)d_in[13];
    const float* fcb = (const float*)d_in[14];
    const int* eAB = (const int*)d_in[15];
    const int* eBB = (const int*)d_in[16];
    const int* eBA = (const int*)d_in[17];
    float* out = (float*)d_out;

    float* ws = (float*)d_ws;
    const size_t NH = (size_t)NN * HH;
    float* B0 = ws;
    float* B1 = B0 + NH;
    float* B2 = B1 + NH;
    float* B3 = B2 + NH;
    float* fWd = B3 + NH;
    float* fWs = fWd + (size_t)LL * RR * HH * HH;
    float* fB = fWs + (size_t)LL * RR * HH * HH;
    float* csA = fB + LL * RR * HH;
    float* csB = csA + 256;
    float* scA = csB + 256;
    float* scB = scA + 256;
    float* P1 = scB + 256;
    float* P2 = P1 + 1024;
    float* alp = P2 + 1024;
    int* icnt = (int*)(alp + 64);
    int* irs = icnt + 3 * NN;
    int* icsr = irs + 3 * NN;
    int* ifill = icsr + 3 * EE;
    int* ibsum = ifill + NN;
    const float invN = 1.0f / (float)NN;

    k_fuse_w<<<LL * RR * HH, 256, 0, stream>>>(Wsrc, Wdst, Wupd, fWd, fWs);
    k_fuse_b<<<LL * RR, HH, 0, stream>>>(bsrc, bdst, bupd, Wupd, fB);

    const int* eArr[3] = {eAB, eBB, eBA};
    for (int r = 0; r < 3; ++r) {
        const int* e = eArr[r];
        int* cnt = icnt + r * NN;
        int* rs = irs + r * NN;
        int* csr = icsr + (size_t)r * EE;
        hipMemsetAsync(cnt, 0, NN * 4, stream);
        hipMemsetAsync(ifill, 0, NN * 4, stream);
        k_count<<<(EE + 255) / 256, 256, 0, stream>>>(e + EE, cnt);
        k_scan1<<<SCAN_B, 256, 0, stream>>>(cnt, rs, ibsum);
        k_scan2<<<1, 128, 0, stream>>>(ibsum);
        k_scan3<<<(NN + 255) / 256, 256, 0, stream>>>(rs, ibsum);
        k_fill<<<(EE + 255) / 256, 256, 0, stream>>>(e, ifill, rs, csr);
    }

    const int GEMM_GRID = (NN + 127) / 128;
    const int AGGR_GRID = (NN + 3) / 4;

    auto conv = [&](float* emb, const float* xs, const float* xd, int rel, int lr) {
        k_aggr<<<AGGR_GRID, 256, 0, stream>>>(emb, xs, irs + rel * NN, icnt + rel * NN,
                                              icsr + (size_t)rel * EE);
        k_cgemm<<<GEMM_GRID, 256, 0, stream>>>(emb, emb, xd, fWs + (size_t)lr * HH * HH,
                                               fWd + (size_t)lr * HH * HH, fB + lr * HH, NN);
    };

    // ================= layer 0 =================
    conv(B0, xA, xB, 0, 0);  // embB1
    conv(B1, xB, xB, 1, 1);  // embB2
    conv(B2, xB, xA, 2, 2);  // embA
    k_attn<<<ATTN_GRID, 256, 0, stream>>>(B0, attnW1, attnb1, attnw2, P1, NN);
    k_attn<<<ATTN_GRID, 256, 0, stream>>>(B1, attnW1, attnb1, attnw2, P2, NN);
    k_alpha<<<1, 256, 0, stream>>>(P1, P2, alp, ATTN_GRID, invN);
    hipMemsetAsync(csB, 0, 256 * 4, stream);
    k_comb<true><<<512, 256, 0, stream>>>(B0, B1, alp, csB, csB + 128, NN);
    hipMemsetAsync(csA, 0, 256 * 4, stream);
    k_comb<false><<<512, 256, 0, stream>>>(B2, nullptr, nullptr, csA, csA + 128, NN);
    k_bnp<<<1, 128, 0, stream>>>(csA, csA + 128, gamma + 0 * HH, beta + 0 * HH, scA, scA + 128, invN);
    k_bnp<<<1, 128, 0, stream>>>(csB, csB + 128, gamma + 1 * HH, beta + 1 * HH, scB, scB + 128, invN);
    k_bna<<<(int)(NH / 4 / 256), 256, 0, stream>>>(B2, scA, scA + 128);  // xA = B2
    k_bna<<<(int)(NH / 4 / 256), 256, 0, stream>>>(B0, scB, scB + 128);  // xB = B0

    // ================= layer 1 =================
    conv(B1, B2, B0, 0, 3);  // embB1'
    conv(B3, B0, B0, 1, 4);  // embB2'
    k_attn<<<ATTN_GRID, 256, 0, stream>>>(B1, attnW1 + HH * AAA, attnb1 + AAA, attnw2 + AAA, P1, NN);
    k_attn<<<ATTN_GRID, 256, 0, stream>>>(B3, attnW1 + HH * AAA, attnb1 + AAA, attnw2 + AAA, P2, NN);
    k_alpha<<<1, 256, 0, stream>>>(P1, P2, alp, ATTN_GRID, invN);
    hipMemsetAsync(csB, 0, 256 * 4, stream);
    k_comb<true><<<512, 256, 0, stream>>>(B1, B3, alp, csB, csB + 128, NN);  // xB_new -> B1
    conv(B3, B0, B2, 2, 5);  // embA'
    hipMemsetAsync(csA, 0, 256 * 4, stream);
    k_comb<false><<<512, 256, 0, stream>>>(B3, nullptr, nullptr, csA, csA + 128, NN);
    k_bnp<<<1, 128, 0, stream>>>(csA, csA + 128, gamma + 2 * HH, beta + 2 * HH, scA, scA + 128, invN);
    k_bnp<<<1, 128, 0, stream>>>(csB, csB + 128, gamma + 3 * HH, beta + 3 * HH, scB, scB + 128, invN);
    k_bna<<<(int)(NH / 4 / 256), 256, 0, stream>>>(B3, scA, scA + 128);  // xA_final = B3
    k_bna<<<(int)(NH / 4 / 256), 256, 0, stream>>>(B1, scB, scB + 128);  // xB_final = B1

    // ================= head =================
    k_fc<<<2048, 256, 0, stream>>>(B3, fcW, fcb, out, NN);
    k_fc<<<2048, 256, 0, stream>>>(B1, fcW + HH * CC, fcb + CC, out + (size_t)NN * CC, NN);
}

// Round 6
// 1463.321 us; speedup vs baseline: 1.7505x; 1.1582x over previous
//
#include <hip/hip_runtime.h>

#define NN 100000
#define HH 128
#define EE 600000
#define LL 2
#define RR 3
#define AAA 64
#define CC 16
#define SCAN_B 98   // 98 blocks x 1024 elems covers 100000
#define ATTN_GRID ((NN + 127) / 128)
#define XST 40      // LDS row stride in bf16 elems (80 B): balanced banks for frag b128 reads

typedef unsigned short u16;
typedef __attribute__((ext_vector_type(8))) short bf16x8;
typedef __attribute__((ext_vector_type(4))) short bf16x4;
typedef __attribute__((ext_vector_type(4))) float f32x4;

__device__ inline u16 f2bf(float f) {   // RNE f32 -> bf16
    unsigned int u = __float_as_uint(f);
    return (u16)((u + 0x7FFF + ((u >> 16) & 1)) >> 16);
}
__device__ inline float bf2f(u16 h) { return __uint_as_float((unsigned int)h << 16); }

// ---------------- weight fusion: write W transposed [n][k], split bf16 hi/lo ----------------
__global__ void k_fuse_w(const float* __restrict__ Wsrc, const float* __restrict__ Wdst,
                         const float* __restrict__ Wupd, u16* __restrict__ Wdt_hi,
                         u16* __restrict__ Wdt_lo, u16* __restrict__ Wst_hi,
                         u16* __restrict__ Wst_lo) {
    int b = blockIdx.x;
    int lr = b >> 7, i = b & 127;   // i = k index
    int t = threadIdx.x;
    int j = t & 127;                // j = n index
    const float* wu = Wupd + (size_t)lr * 2 * HH * HH;
    float acc = 0.f;
    size_t o = ((size_t)lr * HH + j) * HH + i;  // transposed store [n=j][k=i]
    if (t < 128) {
        const float* wd = Wdst + ((size_t)lr * HH + i) * HH;
        for (int k = 0; k < HH; ++k) acc += wd[k] * wu[k * HH + j];
        u16 h = f2bf(acc);
        Wdt_hi[o] = h;
        Wdt_lo[o] = f2bf(acc - bf2f(h));
    } else {
        const float* wsc = Wsrc + ((size_t)lr * HH + i) * HH;
        for (int k = 0; k < HH; ++k) acc += wsc[k] * wu[(HH + k) * HH + j];
        u16 h = f2bf(acc);
        Wst_hi[o] = h;
        Wst_lo[o] = f2bf(acc - bf2f(h));
    }
}

__global__ void k_fuse_b(const float* __restrict__ bsrc, const float* __restrict__ bdst,
                         const float* __restrict__ bupd, const float* __restrict__ Wupd,
                         float* __restrict__ fB) {
    int lr = blockIdx.x;
    int j = threadIdx.x;
    const float* wu = Wupd + (size_t)lr * 2 * HH * HH;
    const float* bd = bdst + lr * HH;
    const float* bs = bsrc + lr * HH;
    float acc = bupd[lr * HH + j];
    for (int k = 0; k < HH; ++k)
        acc += bd[k] * wu[k * HH + j] + bs[k] * wu[(HH + k) * HH + j];
    fB[lr * HH + j] = acc;
}

// ---------------- CSR build ----------------
__global__ void k_count(const int* __restrict__ dst, int* __restrict__ cnt) {
    int i = blockIdx.x * 256 + threadIdx.x;
    if (i < EE) atomicAdd(&cnt[dst[i]], 1);
}

__global__ void k_scan1(const int* __restrict__ cnt, int* __restrict__ rs, int* __restrict__ bsum) {
    __shared__ int sd[256];
    int blk = blockIdx.x, tid = threadIdx.x;
    int base = blk * 1024 + tid * 4;
    int c0 = 0, c1 = 0, c2 = 0, c3 = 0;
    if (base + 0 < NN) c0 = cnt[base + 0];
    if (base + 1 < NN) c1 = cnt[base + 1];
    if (base + 2 < NN) c2 = cnt[base + 2];
    if (base + 3 < NN) c3 = cnt[base + 3];
    int s = c0 + c1 + c2 + c3;
    sd[tid] = s;
    __syncthreads();
    for (int off = 1; off < 256; off <<= 1) {
        int v = (tid >= off) ? sd[tid - off] : 0;
        __syncthreads();
        sd[tid] += v;
        __syncthreads();
    }
    int excl = sd[tid] - s;
    if (tid == 255) bsum[blk] = sd[255];
    if (base + 0 < NN) rs[base + 0] = excl;
    if (base + 1 < NN) rs[base + 1] = excl + c0;
    if (base + 2 < NN) rs[base + 2] = excl + c0 + c1;
    if (base + 3 < NN) rs[base + 3] = excl + c0 + c1 + c2;
}

__global__ void k_scan2(int* __restrict__ bsum) {  // 1 block, 128 threads
    __shared__ int sd[128];
    int tid = threadIdx.x;
    int v = (tid < SCAN_B) ? bsum[tid] : 0;
    sd[tid] = v;
    __syncthreads();
    for (int off = 1; off < 128; off <<= 1) {
        int u = (tid >= off) ? sd[tid - off] : 0;
        __syncthreads();
        sd[tid] += u;
        __syncthreads();
    }
    if (tid < SCAN_B) bsum[tid] = sd[tid] - v;  // exclusive
}

__global__ void k_scan3(int* __restrict__ rs, const int* __restrict__ bsum) {
    int i = blockIdx.x * 256 + threadIdx.x;
    if (i < NN) rs[i] += bsum[i >> 10];
}

__global__ void k_fill(const int* __restrict__ e, int* __restrict__ fill,
                       const int* __restrict__ rs, int* __restrict__ csr) {
    int i = blockIdx.x * 256 + threadIdx.x;
    if (i >= EE) return;
    int s = e[i], d = e[EE + i];
    int pos = rs[d] + atomicAdd(&fill[d], 1);
    csr[pos] = s;
}

// ---------------- aggregation: one wave per dst node ----------------
__global__ __launch_bounds__(256) void k_aggr(float* __restrict__ emb, const float* __restrict__ xs,
                                              const int* __restrict__ rs, const int* __restrict__ cnt,
                                              const int* __restrict__ csr) {
    int node = blockIdx.x * 4 + (threadIdx.x >> 6);
    if (node >= NN) return;
    int lane = threadIdx.x & 63;
    int beg = rs[node], deg = cnt[node];
    const float2* xs2 = (const float2*)xs;
    float ax = 0.f, ay = 0.f;
    int j = 0;
    for (; j + 1 < deg; j += 2) {
        int s0 = csr[beg + j], s1 = csr[beg + j + 1];
        float2 v0 = xs2[(size_t)s0 * 64 + lane];
        float2 v1 = xs2[(size_t)s1 * 64 + lane];
        ax += v0.x + v1.x;
        ay += v0.y + v1.y;
    }
    if (j < deg) {
        float2 v = xs2[(size_t)csr[beg + j] * 64 + lane];
        ax += v.x;
        ay += v.y;
    }
    float sc = 1.0f / fmaxf((float)deg, 1.0f);
    ((float2*)emb)[(size_t)node * 64 + lane] = make_float2(ax * sc, ay * sc);
}

// ---------------- fused conv GEMM via split-bf16 MFMA ----------------
// Y = X1@W1 + X2@W2 + bias, each product as Xhi*Whi + Xhi*Wlo + Xlo*Whi (bf16x3 ~ f32 precision).
// W given transposed bf16 hi/lo [n][k]. X converted f32->hi/lo during LDS staging.
// LDS: 4 tiles [128][XST=40] bf16 = 40 KB. K chunked at 32 (one 16x16x32 MFMA step per chunk).
// 4 waves: wave wv owns n-tiles {2wv, 2wv+1}; per wave acc = 8 m-tiles x 2 n-tiles x f32x4 = 64 VGPR.
__global__ __launch_bounds__(256) void k_cgemm(float* __restrict__ Y, const float* __restrict__ X1,
                                               const float* __restrict__ X2,
                                               const u16* __restrict__ W1hi, const u16* __restrict__ W1lo,
                                               const u16* __restrict__ W2hi, const u16* __restrict__ W2lo,
                                               const float* __restrict__ bias, int nrows) {
    __shared__ __attribute__((aligned(16))) u16 Xhi[128 * XST];
    __shared__ __attribute__((aligned(16))) u16 Xlo[128 * XST];
    __shared__ __attribute__((aligned(16))) u16 Whi[128 * XST];
    __shared__ __attribute__((aligned(16))) u16 Wlo[128 * XST];
    int tid = threadIdx.x;
    int row0 = blockIdx.x * 128;
    int lane = tid & 63, wv = tid >> 6;
    int l15 = lane & 15, lg = lane >> 4;
    bool full = (row0 + 128 <= nrows);

    f32x4 acc[8][2];
#pragma unroll
    for (int i = 0; i < 8; ++i)
#pragma unroll
        for (int j = 0; j < 2; ++j) acc[i][j] = (f32x4)(0.f);

    for (int ph = 0; ph < 2; ++ph) {
        const float* X = ph ? X2 : X1;
        const u16* Wh = ph ? W2hi : W1hi;
        const u16* Wl = ph ? W2lo : W1lo;
        for (int kc = 0; kc < HH; kc += 32) {
            __syncthreads();  // previous chunk fully consumed
            // stage W chunk [128 n][32 k] hi+lo (already bf16, contiguous 16B groups)
            for (int idx = tid; idx < 512; idx += 256) {
                int n = idx >> 2, c8 = idx & 3;
                *(bf16x8*)&Whi[n * XST + c8 * 8] = *(const bf16x8*)&Wh[n * HH + kc + c8 * 8];
                *(bf16x8*)&Wlo[n * XST + c8 * 8] = *(const bf16x8*)&Wl[n * HH + kc + c8 * 8];
            }
            // stage X chunk [128 r][32 k]: f32 -> bf16 hi/lo in-flight
            for (int idx = tid; idx < 1024; idx += 256) {
                int r = idx >> 3, c4 = idx & 7;
                float4 v = make_float4(0.f, 0.f, 0.f, 0.f);
                if (full || row0 + r < nrows)
                    v = *(const float4*)&X[(size_t)(row0 + r) * HH + kc + c4 * 4];
                u16 h0 = f2bf(v.x), h1 = f2bf(v.y), h2 = f2bf(v.z), h3 = f2bf(v.w);
                bf16x4 hv = {(short)h0, (short)h1, (short)h2, (short)h3};
                bf16x4 lv = {(short)f2bf(v.x - bf2f(h0)), (short)f2bf(v.y - bf2f(h1)),
                             (short)f2bf(v.z - bf2f(h2)), (short)f2bf(v.w - bf2f(h3))};
                *(bf16x4*)&Xhi[r * XST + c4 * 4] = hv;
                *(bf16x4*)&Xlo[r * XST + c4 * 4] = lv;
            }
            __syncthreads();
            // B-frags: n = ntile*16 + l15, k-group lg*8 (k-permutation identical on A and B -> cancels)
            bf16x8 bh[2], bl[2];
#pragma unroll
            for (int nt = 0; nt < 2; ++nt) {
                int n = (wv * 2 + nt) * 16 + l15;
                bh[nt] = *(const bf16x8*)&Whi[n * XST + lg * 8];
                bl[nt] = *(const bf16x8*)&Wlo[n * XST + lg * 8];
            }
#pragma unroll
            for (int mt = 0; mt < 8; ++mt) {
                int r = mt * 16 + l15;
                bf16x8 ah = *(const bf16x8*)&Xhi[r * XST + lg * 8];
                bf16x8 al = *(const bf16x8*)&Xlo[r * XST + lg * 8];
#pragma unroll
                for (int nt = 0; nt < 2; ++nt) {
                    acc[mt][nt] = __builtin_amdgcn_mfma_f32_16x16x32_bf16(ah, bh[nt], acc[mt][nt], 0, 0, 0);
                    acc[mt][nt] = __builtin_amdgcn_mfma_f32_16x16x32_bf16(ah, bl[nt], acc[mt][nt], 0, 0, 0);
                    acc[mt][nt] = __builtin_amdgcn_mfma_f32_16x16x32_bf16(al, bh[nt], acc[mt][nt], 0, 0, 0);
                }
            }
        }
    }
    // epilogue: C/D layout col=lane&15, row=(lane>>4)*4+j  [m89-verified]
#pragma unroll
    for (int mt = 0; mt < 8; ++mt)
#pragma unroll
        for (int nt = 0; nt < 2; ++nt) {
            int ncol = (wv * 2 + nt) * 16 + l15;
            float bv = bias[ncol];
#pragma unroll
            for (int j = 0; j < 4; ++j) {
                int r = row0 + mt * 16 + lg * 4 + j;
                if (r < nrows) Y[(size_t)r * HH + ncol] = acc[mt][nt][j] + bv;
            }
        }
}

// ---------------- attention score: tiled GEMM + tanh + dot w2 ----------------
__global__ __launch_bounds__(256) void k_attn(const float* __restrict__ X, const float* __restrict__ W1,
                                              const float* __restrict__ b1, const float* __restrict__ w2,
                                              float* __restrict__ partial, int nrows) {
    __shared__ float W1l[HH * AAA];  // 32 KiB
    __shared__ float Xl[128 * 36];   // 18 KiB
    __shared__ float red[16];
    int tid = threadIdx.x;
    int row0 = blockIdx.x * 128;
    for (int i = tid * 4; i < HH * AAA; i += 1024)
        *(float4*)&W1l[i] = *(const float4*)&W1[i];
    int tx = tid & 15, ty = tid >> 4;
    bool full = (row0 + 128 <= nrows);
    float acc[8][4];
#pragma unroll
    for (int i = 0; i < 8; ++i)
#pragma unroll
        for (int j = 0; j < 4; ++j) acc[i][j] = 0.f;

    for (int kc = 0; kc < HH; kc += 32) {
        __syncthreads();
        for (int idx = tid; idx < 1024; idx += 256) {
            int r = idx >> 3, c = idx & 7;
            float4 v = make_float4(0.f, 0.f, 0.f, 0.f);
            if (full || row0 + r < nrows)
                v = *(const float4*)&X[(size_t)(row0 + r) * HH + kc + c * 4];
            *(float4*)&Xl[r * 36 + c * 4] = v;
        }
        __syncthreads();
#pragma unroll
        for (int k = 0; k < 32; k += 4) {
            float4 xv[8];
#pragma unroll
            for (int i = 0; i < 8; ++i) xv[i] = *(const float4*)&Xl[(ty + 16 * i) * 36 + k];
#pragma unroll
            for (int kk = 0; kk < 4; ++kk) {
                float4 w = *(const float4*)&W1l[(kc + k + kk) * AAA + tx * 4];
#pragma unroll
                for (int i = 0; i < 8; ++i) {
                    float xsv = (&xv[i].x)[kk];
                    acc[i][0] += xsv * w.x; acc[i][1] += xsv * w.y;
                    acc[i][2] += xsv * w.z; acc[i][3] += xsv * w.w;
                }
            }
        }
    }
    float4 b1v = *(const float4*)&b1[tx * 4];
    float4 w2v = *(const float4*)&w2[tx * 4];
    float tot = 0.f;
#pragma unroll
    for (int i = 0; i < 8; ++i) {
        float s = tanhf(acc[i][0] + b1v.x) * w2v.x + tanhf(acc[i][1] + b1v.y) * w2v.y +
                  tanhf(acc[i][2] + b1v.z) * w2v.z + tanhf(acc[i][3] + b1v.w) * w2v.w;
        s += __shfl_xor(s, 1);
        s += __shfl_xor(s, 2);
        s += __shfl_xor(s, 4);
        s += __shfl_xor(s, 8);
        if (row0 + ty + 16 * i < nrows) tot += s;
    }
    if (tx == 0) red[ty] = tot;
    __syncthreads();
    if (tid == 0) {
        float p = 0.f;
#pragma unroll
        for (int i = 0; i < 16; ++i) p += red[i];
        partial[blockIdx.x] = p;
    }
}

__global__ void k_alpha(const float* __restrict__ P1, const float* __restrict__ P2,
                        float* __restrict__ alpha, int nparts, float invn) {
    __shared__ float s1[256], s2[256];
    int tid = threadIdx.x;
    float a = 0.f, b = 0.f;
    for (int i = tid; i < nparts; i += 256) { a += P1[i]; b += P2[i]; }
    s1[tid] = a; s2[tid] = b;
    __syncthreads();
    for (int off = 128; off > 0; off >>= 1) {
        if (tid < off) { s1[tid] += s1[tid + off]; s2[tid] += s2[tid + off]; }
        __syncthreads();
    }
    if (tid == 0) {
        float m1 = s1[0] * invn, m2 = s2[0] * invn;
        float mx = fmaxf(m1, m2);
        float e1 = expf(m1 - mx), e2 = expf(m2 - mx);
        float inv = 1.f / (e1 + e2);
        alpha[0] = e1 * inv; alpha[1] = e2 * inv;
    }
}

// ---------------- combine + column stats ----------------
template <bool COMBINE>
__global__ __launch_bounds__(256) void k_comb(float* __restrict__ X, const float* __restrict__ Y,
                                              const float* __restrict__ alpha, float* __restrict__ colsum,
                                              float* __restrict__ colsq, int nrows) {
    int tid = threadIdx.x;
    int h = tid & 127, half = tid >> 7;
    float a0 = 1.f, a1 = 0.f;
    if (COMBINE) { a0 = alpha[0]; a1 = alpha[1]; }
    float s = 0.f, q = 0.f;
    for (int n = blockIdx.x * 2 + half; n < nrows; n += gridDim.x * 2) {
        size_t off = (size_t)n * HH + h;
        float v = X[off];
        if (COMBINE) { v = a0 * v + a1 * Y[off]; X[off] = v; }
        s += v; q += v * v;
    }
    __shared__ float ls[256], lq[256];
    ls[tid] = s; lq[tid] = q;
    __syncthreads();
    if (half == 0) {
        atomicAdd(&colsum[h], ls[tid] + ls[tid + 128]);
        atomicAdd(&colsq[h], lq[tid] + lq[tid + 128]);
    }
}

__global__ void k_bnp(const float* __restrict__ sum, const float* __restrict__ sq,
                      const float* __restrict__ gamma, const float* __restrict__ beta,
                      float* __restrict__ scale, float* __restrict__ shift, float invn) {
    int h = threadIdx.x;
    float mu = sum[h] * invn;
    float var = sq[h] * invn - mu * mu;
    float sc = gamma[h] * rsqrtf(var + 1.0f);
    scale[h] = sc;
    shift[h] = beta[h] - mu * sc;
}

__global__ void k_bna(float* __restrict__ X, const float* __restrict__ scale,
                      const float* __restrict__ shift) {
    int i = blockIdx.x * 256 + threadIdx.x;
    float4 v = ((float4*)X)[i];
    int h0 = (i & 31) * 4;
    float4 sc = *(const float4*)&scale[h0];
    float4 sf = *(const float4*)&shift[h0];
    v.x = v.x * sc.x + sf.x; v.y = v.y * sc.y + sf.y;
    v.z = v.z * sc.z + sf.z; v.w = v.w * sc.w + sf.w;
    v.x = v.x >= 0.f ? v.x : 0.01f * v.x;
    v.y = v.y >= 0.f ? v.y : 0.01f * v.y;
    v.z = v.z >= 0.f ? v.z : 0.01f * v.z;
    v.w = v.w >= 0.f ? v.w : 0.01f * v.w;
    ((float4*)X)[i] = v;
}

// ---------------- final FC ----------------
__global__ __launch_bounds__(256) void k_fc(const float* __restrict__ X, const float* __restrict__ W,
                                            const float* __restrict__ b, float* __restrict__ out, int nrows) {
    __shared__ float Wl[HH * CC];
    __shared__ float bl[CC];
    int tid = threadIdx.x;
    for (int i = tid * 4; i < HH * CC; i += 1024)
        *(float4*)&Wl[i] = *(const float4*)&W[i];
    if (tid < CC) bl[tid] = b[tid];
    __syncthreads();
    int c = tid & 15, nl = tid >> 4;
    for (int n = blockIdx.x * 16 + nl; n < nrows; n += gridDim.x * 16) {
        const float4* x4 = (const float4*)(X + (size_t)n * HH);
        float acc = bl[c];
#pragma unroll
        for (int h4 = 0; h4 < 32; ++h4) {
            float4 xv = x4[h4];
            acc += xv.x * Wl[(h4 * 4 + 0) * CC + c] + xv.y * Wl[(h4 * 4 + 1) * CC + c] +
                   xv.z * Wl[(h4 * 4 + 2) * CC + c] + xv.w * Wl[(h4 * 4 + 3) * CC + c];
        }
        out[(size_t)n * CC + c] = acc;
    }
}

extern "C" void kernel_launch(void* const* d_in, const int* in_sizes, int n_in,
                              void* d_out, int out_size, void* d_ws, size_t ws_size,
                              hipStream_t stream) {
    const float* xA = (const float*)d_in[0];
    const float* xB = (const float*)d_in[1];
    const float* Wsrc = (const float*)d_in[2];
    const float* bsrc = (const float*)d_in[3];
    const float* Wdst = (const float*)d_in[4];
    const float* bdst = (const float*)d_in[5];
    const float* Wupd = (const float*)d_in[6];
    const float* bupd = (const float*)d_in[7];
    const float* attnW1 = (const float*)d_in[8];
    const float* attnb1 = (const float*)d_in[9];
    const float* attnw2 = (const float*)d_in[10];
    const float* gamma = (const float*)d_in[11];
    const float* beta = (const float*)d_in[12];
    const float* fcW = (const float*)d_in[13];
    const float* fcb = (const float*)d_in[14];
    const int* eAB = (const int*)d_in[15];
    const int* eBB = (const int*)d_in[16];
    const int* eBA = (const int*)d_in[17];
    float* out = (float*)d_out;

    float* ws = (float*)d_ws;
    const size_t NH = (size_t)NN * HH;
    const size_t LRHH = (size_t)LL * RR * HH * HH;
    float* B0 = ws;
    float* B1 = B0 + NH;
    float* B2 = B1 + NH;
    float* B3 = B2 + NH;
    // W region: 4 u16 arrays (Wdt_hi, Wdt_lo, Wst_hi, Wst_lo) = same bytes as old 2 f32 arrays
    u16* uWdh = (u16*)(B3 + NH);
    u16* uWdl = uWdh + LRHH;
    u16* uWsh = uWdl + LRHH;
    u16* uWsl = uWsh + LRHH;
    float* fB = (float*)(uWsl + LRHH);
    float* csA = fB + LL * RR * HH;
    float* csB = csA + 256;
    float* scA = csB + 256;
    float* scB = scA + 256;
    float* P1 = scB + 256;
    float* P2 = P1 + 1024;
    float* alp = P2 + 1024;
    int* icnt = (int*)(alp + 64);
    int* irs = icnt + 3 * NN;
    int* icsr = irs + 3 * NN;
    int* ifill = icsr + 3 * EE;
    int* ibsum = ifill + NN;
    const float invN = 1.0f / (float)NN;

    k_fuse_w<<<LL * RR * HH, 256, 0, stream>>>(Wsrc, Wdst, Wupd, uWdh, uWdl, uWsh, uWsl);
    k_fuse_b<<<LL * RR, HH, 0, stream>>>(bsrc, bdst, bupd, Wupd, fB);

    const int* eArr[3] = {eAB, eBB, eBA};
    for (int r = 0; r < 3; ++r) {
        const int* e = eArr[r];
        int* cnt = icnt + r * NN;
        int* rs = irs + r * NN;
        int* csr = icsr + (size_t)r * EE;
        hipMemsetAsync(cnt, 0, NN * 4, stream);
        hipMemsetAsync(ifill, 0, NN * 4, stream);
        k_count<<<(EE + 255) / 256, 256, 0, stream>>>(e + EE, cnt);
        k_scan1<<<SCAN_B, 256, 0, stream>>>(cnt, rs, ibsum);
        k_scan2<<<1, 128, 0, stream>>>(ibsum);
        k_scan3<<<(NN + 255) / 256, 256, 0, stream>>>(rs, ibsum);
        k_fill<<<(EE + 255) / 256, 256, 0, stream>>>(e, ifill, rs, csr);
    }

    const int GEMM_GRID = (NN + 127) / 128;
    const int AGGR_GRID = (NN + 3) / 4;

    auto conv = [&](float* emb, const float* xs, const float* xd, int rel, int lr) {
        k_aggr<<<AGGR_GRID, 256, 0, stream>>>(emb, xs, irs + rel * NN, icnt + rel * NN,
                                              icsr + (size_t)rel * EE);
        k_cgemm<<<GEMM_GRID, 256, 0, stream>>>(emb, emb, xd,
                                               uWsh + lr * HH * HH, uWsl + lr * HH * HH,
                                               uWdh + lr * HH * HH, uWdl + lr * HH * HH,
                                               fB + lr * HH, NN);
    };

    // ================= layer 0 =================
    conv(B0, xA, xB, 0, 0);  // embB1
    conv(B1, xB, xB, 1, 1);  // embB2
    conv(B2, xB, xA, 2, 2);  // embA
    k_attn<<<ATTN_GRID, 256, 0, stream>>>(B0, attnW1, attnb1, attnw2, P1, NN);
    k_attn<<<ATTN_GRID, 256, 0, stream>>>(B1, attnW1, attnb1, attnw2, P2, NN);
    k_alpha<<<1, 256, 0, stream>>>(P1, P2, alp, ATTN_GRID, invN);
    hipMemsetAsync(csB, 0, 256 * 4, stream);
    k_comb<true><<<512, 256, 0, stream>>>(B0, B1, alp, csB, csB + 128, NN);
    hipMemsetAsync(csA, 0, 256 * 4, stream);
    k_comb<false><<<512, 256, 0, stream>>>(B2, nullptr, nullptr, csA, csA + 128, NN);
    k_bnp<<<1, 128, 0, stream>>>(csA, csA + 128, gamma + 0 * HH, beta + 0 * HH, scA, scA + 128, invN);
    k_bnp<<<1, 128, 0, stream>>>(csB, csB + 128, gamma + 1 * HH, beta + 1 * HH, scB, scB + 128, invN);
    k_bna<<<(int)(NH / 4 / 256), 256, 0, stream>>>(B2, scA, scA + 128);  // xA = B2
    k_bna<<<(int)(NH / 4 / 256), 256, 0, stream>>>(B0, scB, scB + 128);  // xB = B0

    // ================= layer 1 =================
    conv(B1, B2, B0, 0, 3);  // embB1'
    conv(B3, B0, B0, 1, 4);  // embB2'
    k_attn<<<ATTN_GRID, 256, 0, stream>>>(B1, attnW1 + HH * AAA, attnb1 + AAA, attnw2 + AAA, P1, NN);
    k_attn<<<ATTN_GRID, 256, 0, stream>>>(B3, attnW1 + HH * AAA, attnb1 + AAA, attnw2 + AAA, P2, NN);
    k_alpha<<<1, 256, 0, stream>>>(P1, P2, alp, ATTN_GRID, invN);
    hipMemsetAsync(csB, 0, 256 * 4, stream);
    k_comb<true><<<512, 256, 0, stream>>>(B1, B3, alp, csB, csB + 128, NN);  // xB_new -> B1
    conv(B3, B0, B2, 2, 5);  // embA'
    hipMemsetAsync(csA, 0, 256 * 4, stream);
    k_comb<false><<<512, 256, 0, stream>>>(B3, nullptr, nullptr, csA, csA + 128, NN);
    k_bnp<<<1, 128, 0, stream>>>(csA, csA + 128, gamma + 2 * HH, beta + 2 * HH, scA, scA + 128, invN);
    k_bnp<<<1, 128, 0, stream>>>(csB, csB + 128, gamma + 3 * HH, beta + 3 * HH, scB, scB + 128, invN);
    k_bna<<<(int)(NH / 4 / 256), 256, 0, stream>>>(B3, scA, scA + 128);  // xA_final = B3
    k_bna<<<(int)(NH / 4 / 256), 256, 0, stream>>>(B1, scB, scB + 128);  // xB_final = B1

    // ================= head =================
    k_fc<<<2048, 256, 0, stream>>>(B3, fcW, fcb, out, NN);
    k_fc<<<2048, 256, 0, stream>>>(B1, fcW + HH * CC, fcb + CC, out + (size_t)NN * CC, NN);
}

// Round 8
// 1351.858 us; speedup vs baseline: 1.8949x; 1.0825x over previous
//
#include <hip/hip_runtime.h>

#define NN 100000
#define HH 128
#define EE 600000
#define LL 2
#define RR 3
#define AAA 64
#define CC 16
#define SCAN_B 98   // 98 blocks x 1024 elems covers 100000
#define ATTN_GRID ((NN + 127) / 128)

typedef unsigned short u16;
typedef unsigned int u32;
typedef __attribute__((ext_vector_type(8))) short bf16x8;
typedef __attribute__((ext_vector_type(4))) float f32x4;

__device__ inline u16 f2bf(float f) {   // RNE f32 -> bf16
    unsigned int u = __float_as_uint(f);
    return (u16)((u + 0x7FFF + ((u >> 16) & 1)) >> 16);
}
__device__ inline float bf2f(u16 h) { return __uint_as_float((unsigned int)h << 16); }

// Packed X layout (per row: 512B, 4 chunks of 128B; chunk = 4 groups of [16B hi][16B lo],
// XOR-swizzled by row): producer (k_aggr / cgemm phase-2 staging) and consumer (cgemm
// frag reads) share these two formulas. r may be global row n or block-local row
// (row0 % 128 == 0 so r&7 identical).
__device__ __forceinline__ int hi_off(int gi, int r) { return (gi * 32) ^ ((r & 7) << 4); }
__device__ __forceinline__ int lo_off(int gi, int r) { return (gi * 32 + 16) ^ ((r & 7) << 4); }

// async global->LDS, 16B per lane; dest must be linear (wave-uniform base + lane*16)
__device__ __forceinline__ void stage16(const void* g, void* l) {
    __builtin_amdgcn_global_load_lds((const __attribute__((address_space(1))) unsigned int*)g,
                                     (__attribute__((address_space(3))) unsigned int*)l, 16, 0, 0);
}

// ---------------- weight fusion: W transposed [n][k], split bf16 hi/lo ----------------
__global__ void k_fuse_w(const float* __restrict__ Wsrc, const float* __restrict__ Wdst,
                         const float* __restrict__ Wupd, u16* __restrict__ Wdt_hi,
                         u16* __restrict__ Wdt_lo, u16* __restrict__ Wst_hi,
                         u16* __restrict__ Wst_lo) {
    int b = blockIdx.x;
    int lr = b >> 7, i = b & 127;   // i = k index
    int t = threadIdx.x;
    int j = t & 127;                // j = n index
    const float* wu = Wupd + (size_t)lr * 2 * HH * HH;
    float acc = 0.f;
    size_t o = ((size_t)lr * HH + j) * HH + i;  // transposed store [n=j][k=i]
    if (t < 128) {
        const float* wd = Wdst + ((size_t)lr * HH + i) * HH;
        for (int k = 0; k < HH; ++k) acc += wd[k] * wu[k * HH + j];
        u16 h = f2bf(acc);
        Wdt_hi[o] = h;
        Wdt_lo[o] = f2bf(acc - bf2f(h));
    } else {
        const float* wsc = Wsrc + ((size_t)lr * HH + i) * HH;
        for (int k = 0; k < HH; ++k) acc += wsc[k] * wu[(HH + k) * HH + j];
        u16 h = f2bf(acc);
        Wst_hi[o] = h;
        Wst_lo[o] = f2bf(acc - bf2f(h));
    }
}

__global__ void k_fuse_b(const float* __restrict__ bsrc, const float* __restrict__ bdst,
                         const float* __restrict__ bupd, const float* __restrict__ Wupd,
                         float* __restrict__ fB) {
    int lr = blockIdx.x;
    int j = threadIdx.x;
    const float* wu = Wupd + (size_t)lr * 2 * HH * HH;
    const float* bd = bdst + lr * HH;
    const float* bs = bsrc + lr * HH;
    float acc = bupd[lr * HH + j];
    for (int k = 0; k < HH; ++k)
        acc += bd[k] * wu[k * HH + j] + bs[k] * wu[(HH + k) * HH + j];
    fB[lr * HH + j] = acc;
}

// ---------------- CSR build ----------------
__global__ void k_count(const int* __restrict__ dst, int* __restrict__ cnt) {
    int i = blockIdx.x * 256 + threadIdx.x;
    if (i < EE) atomicAdd(&cnt[dst[i]], 1);
}

__global__ void k_scan1(const int* __restrict__ cnt, int* __restrict__ rs, int* __restrict__ bsum) {
    __shared__ int sd[256];
    int blk = blockIdx.x, tid = threadIdx.x;
    int base = blk * 1024 + tid * 4;
    int c0 = 0, c1 = 0, c2 = 0, c3 = 0;
    if (base + 0 < NN) c0 = cnt[base + 0];
    if (base + 1 < NN) c1 = cnt[base + 1];
    if (base + 2 < NN) c2 = cnt[base + 2];
    if (base + 3 < NN) c3 = cnt[base + 3];
    int s = c0 + c1 + c2 + c3;
    sd[tid] = s;
    __syncthreads();
    for (int off = 1; off < 256; off <<= 1) {
        int v = (tid >= off) ? sd[tid - off] : 0;
        __syncthreads();
        sd[tid] += v;
        __syncthreads();
    }
    int excl = sd[tid] - s;
    if (tid == 255) bsum[blk] = sd[255];
    if (base + 0 < NN) rs[base + 0] = excl;
    if (base + 1 < NN) rs[base + 1] = excl + c0;
    if (base + 2 < NN) rs[base + 2] = excl + c0 + c1;
    if (base + 3 < NN) rs[base + 3] = excl + c0 + c1 + c2;
}

__global__ void k_scan2(int* __restrict__ bsum) {  // 1 block, 128 threads
    __shared__ int sd[128];
    int tid = threadIdx.x;
    int v = (tid < SCAN_B) ? bsum[tid] : 0;
    sd[tid] = v;
    __syncthreads();
    for (int off = 1; off < 128; off <<= 1) {
        int u = (tid >= off) ? sd[tid - off] : 0;
        __syncthreads();
        sd[tid] += u;
        __syncthreads();
    }
    if (tid < SCAN_B) bsum[tid] = sd[tid] - v;  // exclusive
}

__global__ void k_scan3(int* __restrict__ rs, const int* __restrict__ bsum) {
    int i = blockIdx.x * 256 + threadIdx.x;
    if (i < NN) rs[i] += bsum[i >> 10];
}

__global__ void k_fill(const int* __restrict__ e, int* __restrict__ fill,
                       const int* __restrict__ rs, int* __restrict__ csr) {
    int i = blockIdx.x * 256 + threadIdx.x;
    if (i >= EE) return;
    int s = e[i], d = e[EE + i];
    int pos = rs[d] + atomicAdd(&fill[d], 1);
    csr[pos] = s;
}

// ---------------- aggregation: one wave per dst node, writes packed-swizzled hi/lo ----------------
__global__ __launch_bounds__(256) void k_aggr(u16* __restrict__ Xp, const float* __restrict__ xs,
                                              const int* __restrict__ rs, const int* __restrict__ cnt,
                                              const int* __restrict__ csr) {
    int node = blockIdx.x * 4 + (threadIdx.x >> 6);
    if (node >= NN) return;
    int lane = threadIdx.x & 63;
    int beg = rs[node], deg = cnt[node];
    const float2* xs2 = (const float2*)xs;
    float ax = 0.f, ay = 0.f;
    int j = 0;
    for (; j + 1 < deg; j += 2) {
        int s0 = csr[beg + j], s1 = csr[beg + j + 1];
        float2 v0 = xs2[(size_t)s0 * 64 + lane];
        float2 v1 = xs2[(size_t)s1 * 64 + lane];
        ax += v0.x + v1.x;
        ay += v0.y + v1.y;
    }
    if (j < deg) {
        float2 v = xs2[(size_t)csr[beg + j] * 64 + lane];
        ax += v.x;
        ay += v.y;
    }
    float sc = 1.0f / fmaxf((float)deg, 1.0f);
    float vx = ax * sc, vy = ay * sc;
    u16 hx = f2bf(vx), hy = f2bf(vy);
    u16 lx = f2bf(vx - bf2f(hx)), ly = f2bf(vy - bf2f(hy));
    // lane handles elems (2*lane, 2*lane+1): group g = lane>>2, chunk g>>2, gi g&3, u32 slot lane&3
    int g = lane >> 2;
    char* base = (char*)Xp + (size_t)node * 512 + (g >> 2) * 128;
    int jb = (lane & 3) * 4;
    *(u32*)(base + hi_off(g & 3, node) + jb) = ((u32)hy << 16) | hx;
    *(u32*)(base + lo_off(g & 3, node) + jb) = ((u32)ly << 16) | lx;
}

// ---------------- fused conv GEMM: Y = X1@W1 + X2@W2 + bias, bf16x3 MFMA ----------------
// X1 arrives PACKED+swizzled (k_aggr output, same buffer as Y: in-place safe, block reads only
// its own rows before its epilogue writes). Phase 1 stages it via global_load_lds (linear copy,
// swizzle baked in global). Phase 2 (xd) is f32: reg-stage + convert into the same swizzled
// LDS layout. Frag reads: quarter-wave spreads over 8 16B-slots = 2-way = free. LDS 16KB.
__global__ __launch_bounds__(256) void k_cgemm(float* Y, const u16* X1p,
                                               const float* __restrict__ X2,
                                               const u16* __restrict__ W1h, const u16* __restrict__ W1l,
                                               const u16* __restrict__ W2h, const u16* __restrict__ W2l,
                                               const float* __restrict__ bias, int nrows) {
    __shared__ __attribute__((aligned(16))) char Xt[16384];  // [128 rows][128B chunk]
    int tid = threadIdx.x;
    int row0 = blockIdx.x * 128;
    int lane = tid & 63, wv = tid >> 6;
    int l15 = lane & 15, lg = lane >> 4;
    bool full = (row0 + 128 <= nrows);

    f32x4 acc[8][2];
#pragma unroll
    for (int i = 0; i < 8; ++i)
#pragma unroll
        for (int j = 0; j < 2; ++j) acc[i][j] = (f32x4)(0.f);

    for (int ph = 0; ph < 2; ++ph) {
        const u16* Wh = ph ? W2h : W1h;
        const u16* Wl = ph ? W2l : W1l;
        for (int kc = 0; kc < HH; kc += 32) {
            __syncthreads();  // previous chunk fully consumed before overwrite
            if (ph == 0) {
                // DMA 4 x 16B/thread: LDS linear, global already swizzled
#pragma unroll
                for (int p = 0; p < 4; ++p) {
                    int tb = p * 4096 + tid * 16;
                    int r = tb >> 7, off = tb & 127;
                    stage16((const char*)X1p + (size_t)(row0 + r) * 512 + (kc >> 5) * 128 + off,
                            Xt + tb);
                }
            } else {
                // f32 -> hi/lo convert into swizzled LDS (2 groups of 8 elems per thread)
#pragma unroll
                for (int it = 0; it < 2; ++it) {
                    int g2 = tid + it * 256;
                    int r = g2 >> 2, gi = g2 & 3;
                    float4 a = make_float4(0.f, 0.f, 0.f, 0.f), b = a;
                    if (full || row0 + r < nrows) {
                        const float* xp = &X2[(size_t)(row0 + r) * HH + kc + gi * 8];
                        a = *(const float4*)xp;
                        b = *(const float4*)(xp + 4);
                    }
                    u16 h0 = f2bf(a.x), h1 = f2bf(a.y), h2 = f2bf(a.z), h3 = f2bf(a.w);
                    u16 h4 = f2bf(b.x), h5 = f2bf(b.y), h6 = f2bf(b.z), h7 = f2bf(b.w);
                    bf16x8 hv = {(short)h0, (short)h1, (short)h2, (short)h3,
                                 (short)h4, (short)h5, (short)h6, (short)h7};
                    bf16x8 lv = {(short)f2bf(a.x - bf2f(h0)), (short)f2bf(a.y - bf2f(h1)),
                                 (short)f2bf(a.z - bf2f(h2)), (short)f2bf(a.w - bf2f(h3)),
                                 (short)f2bf(b.x - bf2f(h4)), (short)f2bf(b.y - bf2f(h5)),
                                 (short)f2bf(b.z - bf2f(h6)), (short)f2bf(b.w - bf2f(h7))};
                    char* rb = Xt + r * 128;
                    *(bf16x8*)(rb + hi_off(gi, r)) = hv;
                    *(bf16x8*)(rb + lo_off(gi, r)) = lv;
                }
            }
            // W frags: global -> reg (L2-resident, 16B each)
            bf16x8 bh[2], bl[2];
#pragma unroll
            for (int nt = 0; nt < 2; ++nt) {
                int n = (wv * 2 + nt) * 16 + l15;
                bh[nt] = *(const bf16x8*)&Wh[(size_t)n * HH + kc + lg * 8];
                bl[nt] = *(const bf16x8*)&Wl[(size_t)n * HH + kc + lg * 8];
            }
            __syncthreads();  // drains DMA vmcnt + lds writes
#pragma unroll
            for (int mt = 0; mt < 8; ++mt) {
                int r = mt * 16 + l15;
                const char* rb = Xt + r * 128;
                bf16x8 ah = *(const bf16x8*)(rb + hi_off(lg, r));
                bf16x8 al = *(const bf16x8*)(rb + lo_off(lg, r));
#pragma unroll
                for (int nt = 0; nt < 2; ++nt) {
                    acc[mt][nt] = __builtin_amdgcn_mfma_f32_16x16x32_bf16(ah, bh[nt], acc[mt][nt], 0, 0, 0);
                    acc[mt][nt] = __builtin_amdgcn_mfma_f32_16x16x32_bf16(ah, bl[nt], acc[mt][nt], 0, 0, 0);
                    acc[mt][nt] = __builtin_amdgcn_mfma_f32_16x16x32_bf16(al, bh[nt], acc[mt][nt], 0, 0, 0);
                }
            }
        }
    }
    // epilogue: C/D layout col=lane&15, row=(lane>>4)*4+j  [m89-verified]
#pragma unroll
    for (int mt = 0; mt < 8; ++mt)
#pragma unroll
        for (int nt = 0; nt < 2; ++nt) {
            int ncol = (wv * 2 + nt) * 16 + l15;
            float bv = bias[ncol];
#pragma unroll
            for (int j = 0; j < 4; ++j) {
                int r = row0 + mt * 16 + lg * 4 + j;
                if (r < nrows) Y[(size_t)r * HH + ncol] = acc[mt][nt][j] + bv;
            }
        }
}

// ---------------- attention score: tiled GEMM + tanh + dot w2 ----------------
__global__ __launch_bounds__(256) void k_attn(const float* __restrict__ X, const float* __restrict__ W1,
                                              const float* __restrict__ b1, const float* __restrict__ w2,
                                              float* __restrict__ partial, int nrows) {
    __shared__ float W1l[HH * AAA];  // 32 KiB
    __shared__ float Xl[128 * 36];   // 18 KiB
    __shared__ float red[16];
    int tid = threadIdx.x;
    int row0 = blockIdx.x * 128;
    for (int i = tid * 4; i < HH * AAA; i += 1024)
        *(float4*)&W1l[i] = *(const float4*)&W1[i];
    int tx = tid & 15, ty = tid >> 4;
    bool full = (row0 + 128 <= nrows);
    float acc[8][4];
#pragma unroll
    for (int i = 0; i < 8; ++i)
#pragma unroll
        for (int j = 0; j < 4; ++j) acc[i][j] = 0.f;

    for (int kc = 0; kc < HH; kc += 32) {
        __syncthreads();
        for (int idx = tid; idx < 1024; idx += 256) {
            int r = idx >> 3, c = idx & 7;
            float4 v = make_float4(0.f, 0.f, 0.f, 0.f);
            if (full || row0 + r < nrows)
                v = *(const float4*)&X[(size_t)(row0 + r) * HH + kc + c * 4];
            *(float4*)&Xl[r * 36 + c * 4] = v;
        }
        __syncthreads();
#pragma unroll
        for (int k = 0; k < 32; k += 4) {
            float4 xv[8];
#pragma unroll
            for (int i = 0; i < 8; ++i) xv[i] = *(const float4*)&Xl[(ty + 16 * i) * 36 + k];
#pragma unroll
            for (int kk = 0; kk < 4; ++kk) {
                float4 w = *(const float4*)&W1l[(kc + k + kk) * AAA + tx * 4];
#pragma unroll
                for (int i = 0; i < 8; ++i) {
                    float xsv = (&xv[i].x)[kk];
                    acc[i][0] += xsv * w.x; acc[i][1] += xsv * w.y;
                    acc[i][2] += xsv * w.z; acc[i][3] += xsv * w.w;
                }
            }
        }
    }
    float4 b1v = *(const float4*)&b1[tx * 4];
    float4 w2v = *(const float4*)&w2[tx * 4];
    float tot = 0.f;
#pragma unroll
    for (int i = 0; i < 8; ++i) {
        float s = tanhf(acc[i][0] + b1v.x) * w2v.x + tanhf(acc[i][1] + b1v.y) * w2v.y +
                  tanhf(acc[i][2] + b1v.z) * w2v.z + tanhf(acc[i][3] + b1v.w) * w2v.w;
        s += __shfl_xor(s, 1);
        s += __shfl_xor(s, 2);
        s += __shfl_xor(s, 4);
        s += __shfl_xor(s, 8);
        if (row0 + ty + 16 * i < nrows) tot += s;
    }
    if (tx == 0) red[ty] = tot;
    __syncthreads();
    if (tid == 0) {
        float p = 0.f;
#pragma unroll
        for (int i = 0; i < 16; ++i) p += red[i];
        partial[blockIdx.x] = p;
    }
}

__global__ void k_alpha(const float* __restrict__ P1, const float* __restrict__ P2,
                        float* __restrict__ alpha, int nparts, float invn) {
    __shared__ float s1[256], s2[256];
    int tid = threadIdx.x;
    float a = 0.f, b = 0.f;
    for (int i = tid; i < nparts; i += 256) { a += P1[i]; b += P2[i]; }
    s1[tid] = a; s2[tid] = b;
    __syncthreads();
    for (int off = 128; off > 0; off >>= 1) {
        if (tid < off) { s1[tid] += s1[tid + off]; s2[tid] += s2[tid + off]; }
        __syncthreads();
    }
    if (tid == 0) {
        float m1 = s1[0] * invn, m2 = s2[0] * invn;
        float mx = fmaxf(m1, m2);
        float e1 = expf(m1 - mx), e2 = expf(m2 - mx);
        float inv = 1.f / (e1 + e2);
        alpha[0] = e1 * inv; alpha[1] = e2 * inv;
    }
}

// ---------------- combine + column stats ----------------
template <bool COMBINE>
__global__ __launch_bounds__(256) void k_comb(float* __restrict__ X, const float* __restrict__ Y,
                                              const float* __restrict__ alpha, float* __restrict__ colsum,
                                              float* __restrict__ colsq, int nrows) {
    int tid = threadIdx.x;
    int h = tid & 127, half = tid >> 7;
    float a0 = 1.f, a1 = 0.f;
    if (COMBINE) { a0 = alpha[0]; a1 = alpha[1]; }
    float s = 0.f, q = 0.f;
    for (int n = blockIdx.x * 2 + half; n < nrows; n += gridDim.x * 2) {
        size_t off = (size_t)n * HH + h;
        float v = X[off];
        if (COMBINE) { v = a0 * v + a1 * Y[off]; X[off] = v; }
        s += v; q += v * v;
    }
    __shared__ float ls[256], lq[256];
    ls[tid] = s; lq[tid] = q;
    __syncthreads();
    if (half == 0) {
        atomicAdd(&colsum[h], ls[tid] + ls[tid + 128]);
        atomicAdd(&colsq[h], lq[tid] + lq[tid + 128]);
    }
}

__global__ void k_bnp(const float* __restrict__ sum, const float* __restrict__ sq,
                      const float* __restrict__ gamma, const float* __restrict__ beta,
                      float* __restrict__ scale, float* __restrict__ shift, float invn) {
    int h = threadIdx.x;
    float mu = sum[h] * invn;
    float var = sq[h] * invn - mu * mu;
    float sc = gamma[h] * rsqrtf(var + 1.0f);
    scale[h] = sc;
    shift[h] = beta[h] - mu * sc;
}

__global__ void k_bna(float* __restrict__ X, const float* __restrict__ scale,
                      const float* __restrict__ shift) {
    int i = blockIdx.x * 256 + threadIdx.x;
    float4 v = ((float4*)X)[i];
    int h0 = (i & 31) * 4;
    float4 sc = *(const float4*)&scale[h0];
    float4 sf = *(const float4*)&shift[h0];
    v.x = v.x * sc.x + sf.x; v.y = v.y * sc.y + sf.y;
    v.z = v.z * sc.z + sf.z; v.w = v.w * sc.w + sf.w;
    v.x = v.x >= 0.f ? v.x : 0.01f * v.x;
    v.y = v.y >= 0.f ? v.y : 0.01f * v.y;
    v.z = v.z >= 0.f ? v.z : 0.01f * v.z;
    v.w = v.w >= 0.f ? v.w : 0.01f * v.w;
    ((float4*)X)[i] = v;
}

// ---------------- final FC ----------------
__global__ __launch_bounds__(256) void k_fc(const float* __restrict__ X, const float* __restrict__ W,
                                            const float* __restrict__ b, float* __restrict__ out, int nrows) {
    __shared__ float Wl[HH * CC];
    __shared__ float bl[CC];
    int tid = threadIdx.x;
    for (int i = tid * 4; i < HH * CC; i += 1024)
        *(float4*)&Wl[i] = *(const float4*)&W[i];
    if (tid < CC) bl[tid] = b[tid];
    __syncthreads();
    int c = tid & 15, nl = tid >> 4;
    for (int n = blockIdx.x * 16 + nl; n < nrows; n += gridDim.x * 16) {
        const float4* x4 = (const float4*)(X + (size_t)n * HH);
        float acc = bl[c];
#pragma unroll
        for (int h4 = 0; h4 < 32; ++h4) {
            float4 xv = x4[h4];
            acc += xv.x * Wl[(h4 * 4 + 0) * CC + c] + xv.y * Wl[(h4 * 4 + 1) * CC + c] +
                   xv.z * Wl[(h4 * 4 + 2) * CC + c] + xv.w * Wl[(h4 * 4 + 3) * CC + c];
        }
        out[(size_t)n * CC + c] = acc;
    }
}

extern "C" void kernel_launch(void* const* d_in, const int* in_sizes, int n_in,
                              void* d_out, int out_size, void* d_ws, size_t ws_size,
                              hipStream_t stream) {
    const float* xA = (const float*)d_in[0];
    const float* xB = (const float*)d_in[1];
    const float* Wsrc = (const float*)d_in[2];
    const float* bsrc = (const float*)d_in[3];
    const float* Wdst = (const float*)d_in[4];
    const float* bdst = (const float*)d_in[5];
    const float* Wupd = (const float*)d_in[6];
    const float* bupd = (const float*)d_in[7];
    const float* attnW1 = (const float*)d_in[8];
    const float* attnb1 = (const float*)d_in[9];
    const float* attnw2 = (const float*)d_in[10];
    const float* gamma = (const float*)d_in[11];
    const float* beta = (const float*)d_in[12];
    const float* fcW = (const float*)d_in[13];
    const float* fcb = (const float*)d_in[14];
    const int* eAB = (const int*)d_in[15];
    const int* eBB = (const int*)d_in[16];
    const int* eBA = (const int*)d_in[17];
    float* out = (float*)d_out;

    // workspace layout == round-6 passing footprint (~216 MB)
    float* ws = (float*)d_ws;
    const size_t NH = (size_t)NN * HH;
    const size_t LRHH = (size_t)LL * RR * HH * HH;
    float* B0 = ws;
    float* B1 = B0 + NH;
    float* B2 = B1 + NH;
    float* B3 = B2 + NH;
    u16* uWdh = (u16*)(B3 + NH);
    u16* uWdl = uWdh + LRHH;
    u16* uWsh = uWdl + LRHH;
    u16* uWsl = uWsh + LRHH;
    float* fB = (float*)(uWsl + LRHH);
    float* csA = fB + LL * RR * HH;
    float* csB = csA + 256;
    float* scA = csB + 256;
    float* scB = scA + 256;
    float* P1 = scB + 256;
    float* P2 = P1 + 1024;
    float* alp = P2 + 1024;
    int* icnt = (int*)(alp + 64);
    int* irs = icnt + 3 * NN;
    int* icsr = irs + 3 * NN;
    int* ifill = icsr + 3 * EE;
    int* ibsum = ifill + NN;
    const float invN = 1.0f / (float)NN;

    k_fuse_w<<<LL * RR * HH, 256, 0, stream>>>(Wsrc, Wdst, Wupd, uWdh, uWdl, uWsh, uWsl);
    k_fuse_b<<<LL * RR, HH, 0, stream>>>(bsrc, bdst, bupd, Wupd, fB);

    const int* eArr[3] = {eAB, eBB, eBA};
    for (int r = 0; r < 3; ++r) {
        const int* e = eArr[r];
        int* cnt = icnt + r * NN;
        int* rs = irs + r * NN;
        int* csr = icsr + (size_t)r * EE;
        hipMemsetAsync(cnt, 0, NN * 4, stream);
        hipMemsetAsync(ifill, 0, NN * 4, stream);
        k_count<<<(EE + 255) / 256, 256, 0, stream>>>(e + EE, cnt);
        k_scan1<<<SCAN_B, 256, 0, stream>>>(cnt, rs, ibsum);
        k_scan2<<<1, 128, 0, stream>>>(ibsum);
        k_scan3<<<(NN + 255) / 256, 256, 0, stream>>>(rs, ibsum);
        k_fill<<<(EE + 255) / 256, 256, 0, stream>>>(e, ifill, rs, csr);
    }

    const int GEMM_GRID = (NN + 127) / 128;
    const int AGGR_GRID = (NN + 3) / 4;

    // dest serves as packed X1 during aggr+cgemm, then holds f32 Y (in-place)
    auto conv = [&](float* dest, const float* xs, const float* xd, int rel, int lr) {
        k_aggr<<<AGGR_GRID, 256, 0, stream>>>((u16*)dest, xs, irs + rel * NN, icnt + rel * NN,
                                              icsr + (size_t)rel * EE);
        k_cgemm<<<GEMM_GRID, 256, 0, stream>>>(dest, (const u16*)dest, xd,
                                               uWsh + (size_t)lr * HH * HH, uWsl + (size_t)lr * HH * HH,
                                               uWdh + (size_t)lr * HH * HH, uWdl + (size_t)lr * HH * HH,
                                               fB + lr * HH, NN);
    };

    // ================= layer 0 =================
    conv(B0, xA, xB, 0, 0);  // embB1
    conv(B1, xB, xB, 1, 1);  // embB2
    conv(B2, xB, xA, 2, 2);  // embA
    k_attn<<<ATTN_GRID, 256, 0, stream>>>(B0, attnW1, attnb1, attnw2, P1, NN);
    k_attn<<<ATTN_GRID, 256, 0, stream>>>(B1, attnW1, attnb1, attnw2, P2, NN);
    k_alpha<<<1, 256, 0, stream>>>(P1, P2, alp, ATTN_GRID, invN);
    hipMemsetAsync(csB, 0, 256 * 4, stream);
    k_comb<true><<<512, 256, 0, stream>>>(B0, B1, alp, csB, csB + 128, NN);
    hipMemsetAsync(csA, 0, 256 * 4, stream);
    k_comb<false><<<512, 256, 0, stream>>>(B2, nullptr, nullptr, csA, csA + 128, NN);
    k_bnp<<<1, 128, 0, stream>>>(csA, csA + 128, gamma + 0 * HH, beta + 0 * HH, scA, scA + 128, invN);
    k_bnp<<<1, 128, 0, stream>>>(csB, csB + 128, gamma + 1 * HH, beta + 1 * HH, scB, scB + 128, invN);
    k_bna<<<(int)(NH / 4 / 256), 256, 0, stream>>>(B2, scA, scA + 128);  // xA = B2
    k_bna<<<(int)(NH / 4 / 256), 256, 0, stream>>>(B0, scB, scB + 128);  // xB = B0

    // ================= layer 1 =================
    conv(B1, B2, B0, 0, 3);  // embB1'
    conv(B3, B0, B0, 1, 4);  // embB2'
    k_attn<<<ATTN_GRID, 256, 0, stream>>>(B1, attnW1 + HH * AAA, attnb1 + AAA, attnw2 + AAA, P1, NN);
    k_attn<<<ATTN_GRID, 256, 0, stream>>>(B3, attnW1 + HH * AAA, attnb1 + AAA, attnw2 + AAA, P2, NN);
    k_alpha<<<1, 256, 0, stream>>>(P1, P2, alp, ATTN_GRID, invN);
    hipMemsetAsync(csB, 0, 256 * 4, stream);
    k_comb<true><<<512, 256, 0, stream>>>(B1, B3, alp, csB, csB + 128, NN);  // xB_new -> B1
    conv(B3, B0, B2, 2, 5);  // embA'
    hipMemsetAsync(csA, 0, 256 * 4, stream);
    k_comb<false><<<512, 256, 0, stream>>>(B3, nullptr, nullptr, csA, csA + 128, NN);
    k_bnp<<<1, 128, 0, stream>>>(csA, csA + 128, gamma + 2 * HH, beta + 2 * HH, scA, scA + 128, invN);
    k_bnp<<<1, 128, 0, stream>>>(csB, csB + 128, gamma + 3 * HH, beta + 3 * HH, scB, scB + 128, invN);
    k_bna<<<(int)(NH / 4 / 256), 256, 0, stream>>>(B3, scA, scA + 128);  // xA_final = B3
    k_bna<<<(int)(NH / 4 / 256), 256, 0, stream>>>(B1, scB, scB + 128);  // xB_final = B1

    // ================= head =================
    k_fc<<<2048, 256, 0, stream>>>(B3, fcW, fcb, out, NN);
    k_fc<<<2048, 256, 0, stream>>>(B1, fcW + HH * CC, fcb + CC, out + (size_t)NN * CC, NN);
}

// Round 9
// 1296.570 us; speedup vs baseline: 1.9757x; 1.0426x over previous
//
#include <hip/hip_runtime.h>

#define NN 100000
#define HH 128
#define EE 600000
#define LL 2
#define RR 3
#define AAA 64
#define CC 16
#define SCAN_B 98   // 98 blocks x 1024 elems covers 100000
#define ATTN_GRID ((NN + 127) / 128)

typedef unsigned short u16;
typedef unsigned int u32;
typedef __attribute__((ext_vector_type(8))) short bf16x8;
typedef __attribute__((ext_vector_type(4))) float f32x4;

__device__ inline u16 f2bf(float f) {   // RNE f32 -> bf16
    unsigned int u = __float_as_uint(f);
    return (u16)((u + 0x7FFF + ((u >> 16) & 1)) >> 16);
}
__device__ inline float bf2f(u16 h) { return __uint_as_float((unsigned int)h << 16); }

// Packed X layout (per row: 512B, 4 chunks of 128B; chunk = 4 groups of [16B hi][16B lo],
// XOR-swizzled by row). Shared by producer (k_aggr / cgemm phase-2 staging) and consumer
// (cgemm frag reads). row0 % 128 == 0 so block-local r has same r&7 as global row.
__device__ __forceinline__ int hi_off(int gi, int r) { return (gi * 32) ^ ((r & 7) << 4); }
__device__ __forceinline__ int lo_off(int gi, int r) { return (gi * 32 + 16) ^ ((r & 7) << 4); }

// async global->LDS, 16B per lane; dest must be linear (wave-uniform base + lane*16)
__device__ __forceinline__ void stage16(const void* g, void* l) {
    __builtin_amdgcn_global_load_lds((const __attribute__((address_space(1))) unsigned int*)g,
                                     (__attribute__((address_space(3))) unsigned int*)l, 16, 0, 0);
}

// ---------------- weight fusion: W transposed [n][k], split bf16 hi/lo ----------------
__global__ void k_fuse_w(const float* __restrict__ Wsrc, const float* __restrict__ Wdst,
                         const float* __restrict__ Wupd, u16* __restrict__ Wdt_hi,
                         u16* __restrict__ Wdt_lo, u16* __restrict__ Wst_hi,
                         u16* __restrict__ Wst_lo) {
    int b = blockIdx.x;
    int lr = b >> 7, i = b & 127;   // i = k index
    int t = threadIdx.x;
    int j = t & 127;                // j = n index
    const float* wu = Wupd + (size_t)lr * 2 * HH * HH;
    float acc = 0.f;
    size_t o = ((size_t)lr * HH + j) * HH + i;  // transposed store [n=j][k=i]
    if (t < 128) {
        const float* wd = Wdst + ((size_t)lr * HH + i) * HH;
        for (int k = 0; k < HH; ++k) acc += wd[k] * wu[k * HH + j];
        u16 h = f2bf(acc);
        Wdt_hi[o] = h;
        Wdt_lo[o] = f2bf(acc - bf2f(h));
    } else {
        const float* wsc = Wsrc + ((size_t)lr * HH + i) * HH;
        for (int k = 0; k < HH; ++k) acc += wsc[k] * wu[(HH + k) * HH + j];
        u16 h = f2bf(acc);
        Wst_hi[o] = h;
        Wst_lo[o] = f2bf(acc - bf2f(h));
    }
}

__global__ void k_fuse_b(const float* __restrict__ bsrc, const float* __restrict__ bdst,
                         const float* __restrict__ bupd, const float* __restrict__ Wupd,
                         float* __restrict__ fB) {
    int lr = blockIdx.x;
    int j = threadIdx.x;
    const float* wu = Wupd + (size_t)lr * 2 * HH * HH;
    const float* bd = bdst + lr * HH;
    const float* bs = bsrc + lr * HH;
    float acc = bupd[lr * HH + j];
    for (int k = 0; k < HH; ++k)
        acc += bd[k] * wu[k * HH + j] + bs[k] * wu[(HH + k) * HH + j];
    fB[lr * HH + j] = acc;
}

// ---------------- CSR build: batched over 3 relations (blockIdx.y = rel) ----------------
__global__ void k_count(const int* __restrict__ e0, const int* __restrict__ e1,
                        const int* __restrict__ e2, int* __restrict__ cnt) {
    int rel = blockIdx.y;
    const int* d = (rel == 0 ? e0 : rel == 1 ? e1 : e2) + EE;
    int i = blockIdx.x * 256 + threadIdx.x;
    if (i < EE) atomicAdd(&cnt[rel * NN + d[i]], 1);
}

__global__ void k_scan1(const int* __restrict__ cnt_all, int* __restrict__ rs_all,
                        int* __restrict__ bsum) {
    __shared__ int sd[256];
    int rel = blockIdx.y;
    const int* cnt = cnt_all + rel * NN;
    int* rs = rs_all + rel * NN;
    int blk = blockIdx.x, tid = threadIdx.x;
    int base = blk * 1024 + tid * 4;
    int c0 = 0, c1 = 0, c2 = 0, c3 = 0;
    if (base + 0 < NN) c0 = cnt[base + 0];
    if (base + 1 < NN) c1 = cnt[base + 1];
    if (base + 2 < NN) c2 = cnt[base + 2];
    if (base + 3 < NN) c3 = cnt[base + 3];
    int s = c0 + c1 + c2 + c3;
    sd[tid] = s;
    __syncthreads();
    for (int off = 1; off < 256; off <<= 1) {
        int v = (tid >= off) ? sd[tid - off] : 0;
        __syncthreads();
        sd[tid] += v;
        __syncthreads();
    }
    int excl = sd[tid] - s;
    if (tid == 255) bsum[rel * 128 + blk] = sd[255];
    if (base + 0 < NN) rs[base + 0] = excl;
    if (base + 1 < NN) rs[base + 1] = excl + c0;
    if (base + 2 < NN) rs[base + 2] = excl + c0 + c1;
    if (base + 3 < NN) rs[base + 3] = excl + c0 + c1 + c2;
}

__global__ void k_scan2(int* __restrict__ bsum) {  // grid = 3, 128 threads
    __shared__ int sd[128];
    int rel = blockIdx.x;
    int tid = threadIdx.x;
    int v = (tid < SCAN_B) ? bsum[rel * 128 + tid] : 0;
    sd[tid] = v;
    __syncthreads();
    for (int off = 1; off < 128; off <<= 1) {
        int u = (tid >= off) ? sd[tid - off] : 0;
        __syncthreads();
        sd[tid] += u;
        __syncthreads();
    }
    if (tid < SCAN_B) bsum[rel * 128 + tid] = sd[tid] - v;  // exclusive
}

__global__ void k_scan3(int* __restrict__ rs_all, const int* __restrict__ bsum) {
    int rel = blockIdx.y;
    int i = blockIdx.x * 256 + threadIdx.x;
    if (i < NN) rs_all[rel * NN + i] += bsum[rel * 128 + (i >> 10)];
}

__global__ void k_fill(const int* __restrict__ e0, const int* __restrict__ e1,
                       const int* __restrict__ e2, int* __restrict__ fill_all,
                       const int* __restrict__ rs_all, int* __restrict__ csr_all) {
    int rel = blockIdx.y;
    const int* e = rel == 0 ? e0 : rel == 1 ? e1 : e2;
    int i = blockIdx.x * 256 + threadIdx.x;
    if (i >= EE) return;
    int s = e[i], d = e[EE + i];
    int pos = rs_all[rel * NN + d] + atomicAdd(&fill_all[rel * NN + d], 1);
    csr_all[(size_t)rel * EE + pos] = s;
}

// ---------------- aggregation: one wave per dst node, 4-edge batched gather ----------------
__global__ __launch_bounds__(256) void k_aggr(u16* __restrict__ Xp, const float* __restrict__ xs,
                                              const int* __restrict__ rs, const int* __restrict__ cnt,
                                              const int* __restrict__ csr) {
    int node = blockIdx.x * 4 + (threadIdx.x >> 6);
    if (node >= NN) return;
    int lane = threadIdx.x & 63;
    int beg = rs[node], deg = cnt[node];
    const float2* xs2 = (const float2*)xs;
    float ax = 0.f, ay = 0.f;
    int j = 0;
    // 4-wide batch: 4 independent csr loads, then 4 independent row gathers (2x MLP vs 2-wide)
    for (; j + 4 <= deg; j += 4) {
        int s0 = csr[beg + j], s1 = csr[beg + j + 1];
        int s2 = csr[beg + j + 2], s3 = csr[beg + j + 3];
        float2 v0 = xs2[(size_t)s0 * 64 + lane];
        float2 v1 = xs2[(size_t)s1 * 64 + lane];
        float2 v2 = xs2[(size_t)s2 * 64 + lane];
        float2 v3 = xs2[(size_t)s3 * 64 + lane];
        ax += (v0.x + v1.x) + (v2.x + v3.x);
        ay += (v0.y + v1.y) + (v2.y + v3.y);
    }
    if (j + 2 <= deg) {
        int s0 = csr[beg + j], s1 = csr[beg + j + 1];
        float2 v0 = xs2[(size_t)s0 * 64 + lane];
        float2 v1 = xs2[(size_t)s1 * 64 + lane];
        ax += v0.x + v1.x;
        ay += v0.y + v1.y;
        j += 2;
    }
    if (j < deg) {
        float2 v = xs2[(size_t)csr[beg + j] * 64 + lane];
        ax += v.x;
        ay += v.y;
    }
    float sc = 1.0f / fmaxf((float)deg, 1.0f);
    float vx = ax * sc, vy = ay * sc;
    u16 hx = f2bf(vx), hy = f2bf(vy);
    u16 lx = f2bf(vx - bf2f(hx)), ly = f2bf(vy - bf2f(hy));
    // lane handles elems (2*lane, 2*lane+1): group g = lane>>2, chunk g>>2, gi g&3, u32 slot lane&3
    int g = lane >> 2;
    char* base = (char*)Xp + (size_t)node * 512 + (g >> 2) * 128;
    int jb = (lane & 3) * 4;
    // nontemporal: streaming output, don't evict gather working set from L2
    __builtin_nontemporal_store(((u32)hy << 16) | hx, (u32*)(base + hi_off(g & 3, node) + jb));
    __builtin_nontemporal_store(((u32)ly << 16) | lx, (u32*)(base + lo_off(g & 3, node) + jb));
}

// ---------------- fused conv GEMM: Y = X1@W1 + X2@W2 + bias, bf16x3 MFMA ----------------
// X1 arrives PACKED+swizzled (k_aggr output, same buffer as Y: in-place safe). Phase 1 stages
// via global_load_lds (linear copy, swizzle baked in global). Phase 2 (xd f32) reg-stages +
// converts into the same swizzled LDS layout. Frag reads 2-way = free. LDS 16KB.
__global__ __launch_bounds__(256) void k_cgemm(float* Y, const u16* X1p,
                                               const float* __restrict__ X2,
                                               const u16* __restrict__ W1h, const u16* __restrict__ W1l,
                                               const u16* __restrict__ W2h, const u16* __restrict__ W2l,
                                               const float* __restrict__ bias, int nrows) {
    __shared__ __attribute__((aligned(16))) char Xt[16384];  // [128 rows][128B chunk]
    int tid = threadIdx.x;
    int row0 = blockIdx.x * 128;
    int lane = tid & 63, wv = tid >> 6;
    int l15 = lane & 15, lg = lane >> 4;
    bool full = (row0 + 128 <= nrows);

    f32x4 acc[8][2];
#pragma unroll
    for (int i = 0; i < 8; ++i)
#pragma unroll
        for (int j = 0; j < 2; ++j) acc[i][j] = (f32x4)(0.f);

    for (int ph = 0; ph < 2; ++ph) {
        const u16* Wh = ph ? W2h : W1h;
        const u16* Wl = ph ? W2l : W1l;
        for (int kc = 0; kc < HH; kc += 32) {
            __syncthreads();  // previous chunk fully consumed before overwrite
            if (ph == 0) {
                // DMA 4 x 16B/thread: LDS linear, global already swizzled
#pragma unroll
                for (int p = 0; p < 4; ++p) {
                    int tb = p * 4096 + tid * 16;
                    int r = tb >> 7, off = tb & 127;
                    stage16((const char*)X1p + (size_t)(row0 + r) * 512 + (kc >> 5) * 128 + off,
                            Xt + tb);
                }
            } else {
                // f32 -> hi/lo convert into swizzled LDS (2 groups of 8 elems per thread)
#pragma unroll
                for (int it = 0; it < 2; ++it) {
                    int g2 = tid + it * 256;
                    int r = g2 >> 2, gi = g2 & 3;
                    float4 a = make_float4(0.f, 0.f, 0.f, 0.f), b = a;
                    if (full || row0 + r < nrows) {
                        const float* xp = &X2[(size_t)(row0 + r) * HH + kc + gi * 8];
                        a = *(const float4*)xp;
                        b = *(const float4*)(xp + 4);
                    }
                    u16 h0 = f2bf(a.x), h1 = f2bf(a.y), h2 = f2bf(a.z), h3 = f2bf(a.w);
                    u16 h4 = f2bf(b.x), h5 = f2bf(b.y), h6 = f2bf(b.z), h7 = f2bf(b.w);
                    bf16x8 hv = {(short)h0, (short)h1, (short)h2, (short)h3,
                                 (short)h4, (short)h5, (short)h6, (short)h7};
                    bf16x8 lv = {(short)f2bf(a.x - bf2f(h0)), (short)f2bf(a.y - bf2f(h1)),
                                 (short)f2bf(a.z - bf2f(h2)), (short)f2bf(a.w - bf2f(h3)),
                                 (short)f2bf(b.x - bf2f(h4)), (short)f2bf(b.y - bf2f(h5)),
                                 (short)f2bf(b.z - bf2f(h6)), (short)f2bf(b.w - bf2f(h7))};
                    char* rb = Xt + r * 128;
                    *(bf16x8*)(rb + hi_off(gi, r)) = hv;
                    *(bf16x8*)(rb + lo_off(gi, r)) = lv;
                }
            }
            // W frags: global -> reg (L2-resident, 16B each)
            bf16x8 bh[2], bl[2];
#pragma unroll
            for (int nt = 0; nt < 2; ++nt) {
                int n = (wv * 2 + nt) * 16 + l15;
                bh[nt] = *(const bf16x8*)&Wh[(size_t)n * HH + kc + lg * 8];
                bl[nt] = *(const bf16x8*)&Wl[(size_t)n * HH + kc + lg * 8];
            }
            __syncthreads();  // drains DMA vmcnt + lds writes
#pragma unroll
            for (int mt = 0; mt < 8; ++mt) {
                int r = mt * 16 + l15;
                const char* rb = Xt + r * 128;
                bf16x8 ah = *(const bf16x8*)(rb + hi_off(lg, r));
                bf16x8 al = *(const bf16x8*)(rb + lo_off(lg, r));
#pragma unroll
                for (int nt = 0; nt < 2; ++nt) {
                    acc[mt][nt] = __builtin_amdgcn_mfma_f32_16x16x32_bf16(ah, bh[nt], acc[mt][nt], 0, 0, 0);
                    acc[mt][nt] = __builtin_amdgcn_mfma_f32_16x16x32_bf16(ah, bl[nt], acc[mt][nt], 0, 0, 0);
                    acc[mt][nt] = __builtin_amdgcn_mfma_f32_16x16x32_bf16(al, bh[nt], acc[mt][nt], 0, 0, 0);
                }
            }
        }
    }
    // epilogue: C/D layout col=lane&15, row=(lane>>4)*4+j  [m89-verified]
#pragma unroll
    for (int mt = 0; mt < 8; ++mt)
#pragma unroll
        for (int nt = 0; nt < 2; ++nt) {
            int ncol = (wv * 2 + nt) * 16 + l15;
            float bv = bias[ncol];
#pragma unroll
            for (int j = 0; j < 4; ++j) {
                int r = row0 + mt * 16 + lg * 4 + j;
                if (r < nrows) Y[(size_t)r * HH + ncol] = acc[mt][nt][j] + bv;
            }
        }
}

// ---------------- attention score: both relations in one launch ----------------
__global__ __launch_bounds__(256) void k_attn(const float* __restrict__ XA, const float* __restrict__ XB,
                                              const float* __restrict__ W1,
                                              const float* __restrict__ b1, const float* __restrict__ w2,
                                              float* __restrict__ PA, float* __restrict__ PB, int nrows) {
    __shared__ float W1l[HH * AAA];  // 32 KiB
    __shared__ float Xl[128 * 36];   // 18 KiB
    __shared__ float red[16];
    int tid = threadIdx.x;
    bool second = blockIdx.x >= ATTN_GRID;
    const float* X = second ? XB : XA;
    float* partial = second ? PB : PA;
    int row0 = (second ? blockIdx.x - ATTN_GRID : blockIdx.x) * 128;
    for (int i = tid * 4; i < HH * AAA; i += 1024)
        *(float4*)&W1l[i] = *(const float4*)&W1[i];
    int tx = tid & 15, ty = tid >> 4;
    bool full = (row0 + 128 <= nrows);
    float acc[8][4];
#pragma unroll
    for (int i = 0; i < 8; ++i)
#pragma unroll
        for (int j = 0; j < 4; ++j) acc[i][j] = 0.f;

    for (int kc = 0; kc < HH; kc += 32) {
        __syncthreads();
        for (int idx = tid; idx < 1024; idx += 256) {
            int r = idx >> 3, c = idx & 7;
            float4 v = make_float4(0.f, 0.f, 0.f, 0.f);
            if (full || row0 + r < nrows)
                v = *(const float4*)&X[(size_t)(row0 + r) * HH + kc + c * 4];
            *(float4*)&Xl[r * 36 + c * 4] = v;
        }
        __syncthreads();
#pragma unroll
        for (int k = 0; k < 32; k += 4) {
            float4 xv[8];
#pragma unroll
            for (int i = 0; i < 8; ++i) xv[i] = *(const float4*)&Xl[(ty + 16 * i) * 36 + k];
#pragma unroll
            for (int kk = 0; kk < 4; ++kk) {
                float4 w = *(const float4*)&W1l[(kc + k + kk) * AAA + tx * 4];
#pragma unroll
                for (int i = 0; i < 8; ++i) {
                    float xsv = (&xv[i].x)[kk];
                    acc[i][0] += xsv * w.x; acc[i][1] += xsv * w.y;
                    acc[i][2] += xsv * w.z; acc[i][3] += xsv * w.w;
                }
            }
        }
    }
    float4 b1v = *(const float4*)&b1[tx * 4];
    float4 w2v = *(const float4*)&w2[tx * 4];
    float tot = 0.f;
#pragma unroll
    for (int i = 0; i < 8; ++i) {
        float s = tanhf(acc[i][0] + b1v.x) * w2v.x + tanhf(acc[i][1] + b1v.y) * w2v.y +
                  tanhf(acc[i][2] + b1v.z) * w2v.z + tanhf(acc[i][3] + b1v.w) * w2v.w;
        s += __shfl_xor(s, 1);
        s += __shfl_xor(s, 2);
        s += __shfl_xor(s, 4);
        s += __shfl_xor(s, 8);
        if (row0 + ty + 16 * i < nrows) tot += s;
    }
    if (tx == 0) red[ty] = tot;
    __syncthreads();
    if (tid == 0) {
        float p = 0.f;
#pragma unroll
        for (int i = 0; i < 16; ++i) p += red[i];
        partial[second ? (blockIdx.x - ATTN_GRID) : blockIdx.x] = p;
    }
}

__global__ void k_alpha(const float* __restrict__ P1, const float* __restrict__ P2,
                        float* __restrict__ alpha, int nparts, float invn) {
    __shared__ float s1[256], s2[256];
    int tid = threadIdx.x;
    float a = 0.f, b = 0.f;
    for (int i = tid; i < nparts; i += 256) { a += P1[i]; b += P2[i]; }
    s1[tid] = a; s2[tid] = b;
    __syncthreads();
    for (int off = 128; off > 0; off >>= 1) {
        if (tid < off) { s1[tid] += s1[tid + off]; s2[tid] += s2[tid + off]; }
        __syncthreads();
    }
    if (tid == 0) {
        float m1 = s1[0] * invn, m2 = s2[0] * invn;
        float mx = fmaxf(m1, m2);
        float e1 = expf(m1 - mx), e2 = expf(m2 - mx);
        float inv = 1.f / (e1 + e2);
        alpha[0] = e1 * inv; alpha[1] = e2 * inv;
    }
}

// ---------------- combine + column stats ----------------
template <bool COMBINE>
__global__ __launch_bounds__(256) void k_comb(float* __restrict__ X, const float* __restrict__ Y,
                                              const float* __restrict__ alpha, float* __restrict__ colsum,
                                              float* __restrict__ colsq, int nrows) {
    int tid = threadIdx.x;
    int h = tid & 127, half = tid >> 7;
    float a0 = 1.f, a1 = 0.f;
    if (COMBINE) { a0 = alpha[0]; a1 = alpha[1]; }
    float s = 0.f, q = 0.f;
    for (int n = blockIdx.x * 2 + half; n < nrows; n += gridDim.x * 2) {
        size_t off = (size_t)n * HH + h;
        float v = X[off];
        if (COMBINE) { v = a0 * v + a1 * Y[off]; X[off] = v; }
        s += v; q += v * v;
    }
    __shared__ float ls[256], lq[256];
    ls[tid] = s; lq[tid] = q;
    __syncthreads();
    if (half == 0) {
        atomicAdd(&colsum[h], ls[tid] + ls[tid + 128]);
        atomicAdd(&colsq[h], lq[tid] + lq[tid + 128]);
    }
}

__global__ void k_bnp(const float* __restrict__ sum, const float* __restrict__ sq,
                      const float* __restrict__ gamma, const float* __restrict__ beta,
                      float* __restrict__ scale, float* __restrict__ shift, float invn) {
    int h = threadIdx.x;
    float mu = sum[h] * invn;
    float var = sq[h] * invn - mu * mu;
    float sc = gamma[h] * rsqrtf(var + 1.0f);
    scale[h] = sc;
    shift[h] = beta[h] - mu * sc;
}

__global__ void k_bna(float* __restrict__ X, const float* __restrict__ scale,
                      const float* __restrict__ shift) {
    int i = blockIdx.x * 256 + threadIdx.x;
    float4 v = ((float4*)X)[i];
    int h0 = (i & 31) * 4;
    float4 sc = *(const float4*)&scale[h0];
    float4 sf = *(const float4*)&shift[h0];
    v.x = v.x * sc.x + sf.x; v.y = v.y * sc.y + sf.y;
    v.z = v.z * sc.z + sf.z; v.w = v.w * sc.w + sf.w;
    v.x = v.x >= 0.f ? v.x : 0.01f * v.x;
    v.y = v.y >= 0.f ? v.y : 0.01f * v.y;
    v.z = v.z >= 0.f ? v.z : 0.01f * v.z;
    v.w = v.w >= 0.f ? v.w : 0.01f * v.w;
    ((float4*)X)[i] = v;
}

// ---------------- final FC ----------------
__global__ __launch_bounds__(256) void k_fc(const float* __restrict__ X, const float* __restrict__ W,
                                            const float* __restrict__ b, float* __restrict__ out, int nrows) {
    __shared__ float Wl[HH * CC];
    __shared__ float bl[CC];
    int tid = threadIdx.x;
    for (int i = tid * 4; i < HH * CC; i += 1024)
        *(float4*)&Wl[i] = *(const float4*)&W[i];
    if (tid < CC) bl[tid] = b[tid];
    __syncthreads();
    int c = tid & 15, nl = tid >> 4;
    for (int n = blockIdx.x * 16 + nl; n < nrows; n += gridDim.x * 16) {
        const float4* x4 = (const float4*)(X + (size_t)n * HH);
        float acc = bl[c];
#pragma unroll
        for (int h4 = 0; h4 < 32; ++h4) {
            float4 xv = x4[h4];
            acc += xv.x * Wl[(h4 * 4 + 0) * CC + c] + xv.y * Wl[(h4 * 4 + 1) * CC + c] +
                   xv.z * Wl[(h4 * 4 + 2) * CC + c] + xv.w * Wl[(h4 * 4 + 3) * CC + c];
        }
        out[(size_t)n * CC + c] = acc;
    }
}

extern "C" void kernel_launch(void* const* d_in, const int* in_sizes, int n_in,
                              void* d_out, int out_size, void* d_ws, size_t ws_size,
                              hipStream_t stream) {
    const float* xA = (const float*)d_in[0];
    const float* xB = (const float*)d_in[1];
    const float* Wsrc = (const float*)d_in[2];
    const float* bsrc = (const float*)d_in[3];
    const float* Wdst = (const float*)d_in[4];
    const float* bdst = (const float*)d_in[5];
    const float* Wupd = (const float*)d_in[6];
    const float* bupd = (const float*)d_in[7];
    const float* attnW1 = (const float*)d_in[8];
    const float* attnb1 = (const float*)d_in[9];
    const float* attnw2 = (const float*)d_in[10];
    const float* gamma = (const float*)d_in[11];
    const float* beta = (const float*)d_in[12];
    const float* fcW = (const float*)d_in[13];
    const float* fcb = (const float*)d_in[14];
    const int* eAB = (const int*)d_in[15];
    const int* eBB = (const int*)d_in[16];
    const int* eBA = (const int*)d_in[17];
    float* out = (float*)d_out;

    // workspace layout == round-6/8 passing footprint (~216 MB)
    float* ws = (float*)d_ws;
    const size_t NH = (size_t)NN * HH;
    const size_t LRHH = (size_t)LL * RR * HH * HH;
    float* B0 = ws;
    float* B1 = B0 + NH;
    float* B2 = B1 + NH;
    float* B3 = B2 + NH;
    u16* uWdh = (u16*)(B3 + NH);
    u16* uWdl = uWdh + LRHH;
    u16* uWsh = uWdl + LRHH;
    u16* uWsl = uWsh + LRHH;
    float* fB = (float*)(uWsl + LRHH);
    float* csA = fB + LL * RR * HH;
    float* csB = csA + 256;
    float* scA = csB + 256;
    float* scB = scA + 256;
    float* P1 = scB + 256;
    float* P2 = P1 + 1024;
    float* alp = P2 + 1024;
    int* icnt = (int*)(alp + 64);
    int* irs = icnt + 3 * NN;
    int* icsr = irs + 3 * NN;
    int* ifill = icsr + 3 * EE;
    int* ibsum = ifill + 3 * NN;   // 3*128
    const float invN = 1.0f / (float)NN;

    k_fuse_w<<<LL * RR * HH, 256, 0, stream>>>(Wsrc, Wdst, Wupd, uWdh, uWdl, uWsh, uWsl);
    k_fuse_b<<<LL * RR, HH, 0, stream>>>(bsrc, bdst, bupd, Wupd, fB);

    // CSR build: all 3 relations per kernel (blockIdx.y = rel)
    hipMemsetAsync(icnt, 0, 3 * NN * 4, stream);
    hipMemsetAsync(ifill, 0, 3 * NN * 4, stream);
    k_count<<<dim3((EE + 255) / 256, 3), 256, 0, stream>>>(eAB, eBB, eBA, icnt);
    k_scan1<<<dim3(SCAN_B, 3), 256, 0, stream>>>(icnt, irs, ibsum);
    k_scan2<<<3, 128, 0, stream>>>(ibsum);
    k_scan3<<<dim3((NN + 255) / 256, 3), 256, 0, stream>>>(irs, ibsum);
    k_fill<<<dim3((EE + 255) / 256, 3), 256, 0, stream>>>(eAB, eBB, eBA, ifill, irs, icsr);

    const int GEMM_GRID = (NN + 127) / 128;
    const int AGGR_GRID = (NN + 3) / 4;

    // dest serves as packed X1 during aggr+cgemm, then holds f32 Y (in-place)
    auto conv = [&](float* dest, const float* xs, const float* xd, int rel, int lr) {
        k_aggr<<<AGGR_GRID, 256, 0, stream>>>((u16*)dest, xs, irs + rel * NN, icnt + rel * NN,
                                              icsr + (size_t)rel * EE);
        k_cgemm<<<GEMM_GRID, 256, 0, stream>>>(dest, (const u16*)dest, xd,
                                               uWsh + (size_t)lr * HH * HH, uWsl + (size_t)lr * HH * HH,
                                               uWdh + (size_t)lr * HH * HH, uWdl + (size_t)lr * HH * HH,
                                               fB + lr * HH, NN);
    };

    // ================= layer 0 =================
    conv(B0, xA, xB, 0, 0);  // embB1
    conv(B1, xB, xB, 1, 1);  // embB2
    conv(B2, xB, xA, 2, 2);  // embA
    k_attn<<<2 * ATTN_GRID, 256, 0, stream>>>(B0, B1, attnW1, attnb1, attnw2, P1, P2, NN);
    k_alpha<<<1, 256, 0, stream>>>(P1, P2, alp, ATTN_GRID, invN);
    hipMemsetAsync(csB, 0, 256 * 4, stream);
    k_comb<true><<<512, 256, 0, stream>>>(B0, B1, alp, csB, csB + 128, NN);
    hipMemsetAsync(csA, 0, 256 * 4, stream);
    k_comb<false><<<512, 256, 0, stream>>>(B2, nullptr, nullptr, csA, csA + 128, NN);
    k_bnp<<<1, 128, 0, stream>>>(csA, csA + 128, gamma + 0 * HH, beta + 0 * HH, scA, scA + 128, invN);
    k_bnp<<<1, 128, 0, stream>>>(csB, csB + 128, gamma + 1 * HH, beta + 1 * HH, scB, scB + 128, invN);
    k_bna<<<(int)(NH / 4 / 256), 256, 0, stream>>>(B2, scA, scA + 128);  // xA = B2
    k_bna<<<(int)(NH / 4 / 256), 256, 0, stream>>>(B0, scB, scB + 128);  // xB = B0

    // ================= layer 1 =================
    conv(B1, B2, B0, 0, 3);  // embB1'
    conv(B3, B0, B0, 1, 4);  // embB2'
    k_attn<<<2 * ATTN_GRID, 256, 0, stream>>>(B1, B3, attnW1 + HH * AAA, attnb1 + AAA,
                                              attnw2 + AAA, P1, P2, NN);
    k_alpha<<<1, 256, 0, stream>>>(P1, P2, alp, ATTN_GRID, invN);
    hipMemsetAsync(csB, 0, 256 * 4, stream);
    k_comb<true><<<512, 256, 0, stream>>>(B1, B3, alp, csB, csB + 128, NN);  // xB_new -> B1
    conv(B3, B0, B2, 2, 5);  // embA'
    hipMemsetAsync(csA, 0, 256 * 4, stream);
    k_comb<false><<<512, 256, 0, stream>>>(B3, nullptr, nullptr, csA, csA + 128, NN);
    k_bnp<<<1, 128, 0, stream>>>(csA, csA + 128, gamma + 2 * HH, beta + 2 * HH, scA, scA + 128, invN);
    k_bnp<<<1, 128, 0, stream>>>(csB, csB + 128, gamma + 3 * HH, beta + 3 * HH, scB, scB + 128, invN);
    k_bna<<<(int)(NH / 4 / 256), 256, 0, stream>>>(B3, scA, scA + 128);  // xA_final = B3
    k_bna<<<(int)(NH / 4 / 256), 256, 0, stream>>>(B1, scB, scB + 128);  // xB_final = B1

    // ================= head =================
    k_fc<<<2048, 256, 0, stream>>>(B3, fcW, fcb, out, NN);
    k_fc<<<2048, 256, 0, stream>>>(B1, fcW + HH * CC, fcb + CC, out + (size_t)NN * CC, NN);
}

// Round 10
// 1292.617 us; speedup vs baseline: 1.9817x; 1.0031x over previous
//
#include <hip/hip_runtime.h>

#define NN 100000
#define HH 128
#define EE 600000
#define LL 2
#define RR 3
#define AAA 64
#define CC 16
#define SCAN_B 98   // 98 blocks x 1024 elems covers 100000
#define ATTN_GRID ((NN + 127) / 128)

typedef unsigned short u16;
typedef unsigned int u32;
typedef __attribute__((ext_vector_type(8))) short bf16x8;
typedef __attribute__((ext_vector_type(4))) float f32x4;

__device__ inline u16 f2bf(float f) {   // RNE f32 -> bf16
    unsigned int u = __float_as_uint(f);
    return (u16)((u + 0x7FFF + ((u >> 16) & 1)) >> 16);
}
__device__ inline float bf2f(u16 h) { return __uint_as_float((unsigned int)h << 16); }

// Packed X layout (per row: 512B, 4 chunks of 128B; chunk = 4 groups of [16B hi][16B lo],
// XOR-swizzled by row). Shared by producer (k_aggr / cgemm phase-2 staging) and consumer
// (cgemm frag reads). row0 % 128 == 0 so block-local r has same r&7 as global row.
__device__ __forceinline__ int hi_off(int gi, int r) { return (gi * 32) ^ ((r & 7) << 4); }
__device__ __forceinline__ int lo_off(int gi, int r) { return (gi * 32 + 16) ^ ((r & 7) << 4); }

// async global->LDS, 16B per lane; dest must be linear (wave-uniform base + lane*16)
__device__ __forceinline__ void stage16(const void* g, void* l) {
    __builtin_amdgcn_global_load_lds((const __attribute__((address_space(1))) unsigned int*)g,
                                     (__attribute__((address_space(3))) unsigned int*)l, 16, 0, 0);
}

// ---------------- weight fusion: W transposed [n][k], split bf16 hi/lo ----------------
__global__ void k_fuse_w(const float* __restrict__ Wsrc, const float* __restrict__ Wdst,
                         const float* __restrict__ Wupd, u16* __restrict__ Wdt_hi,
                         u16* __restrict__ Wdt_lo, u16* __restrict__ Wst_hi,
                         u16* __restrict__ Wst_lo) {
    int b = blockIdx.x;
    int lr = b >> 7, i = b & 127;   // i = k index
    int t = threadIdx.x;
    int j = t & 127;                // j = n index
    const float* wu = Wupd + (size_t)lr * 2 * HH * HH;
    float acc = 0.f;
    size_t o = ((size_t)lr * HH + j) * HH + i;  // transposed store [n=j][k=i]
    if (t < 128) {
        const float* wd = Wdst + ((size_t)lr * HH + i) * HH;
        for (int k = 0; k < HH; ++k) acc += wd[k] * wu[k * HH + j];
        u16 h = f2bf(acc);
        Wdt_hi[o] = h;
        Wdt_lo[o] = f2bf(acc - bf2f(h));
    } else {
        const float* wsc = Wsrc + ((size_t)lr * HH + i) * HH;
        for (int k = 0; k < HH; ++k) acc += wsc[k] * wu[(HH + k) * HH + j];
        u16 h = f2bf(acc);
        Wst_hi[o] = h;
        Wst_lo[o] = f2bf(acc - bf2f(h));
    }
}

__global__ void k_fuse_b(const float* __restrict__ bsrc, const float* __restrict__ bdst,
                         const float* __restrict__ bupd, const float* __restrict__ Wupd,
                         float* __restrict__ fB) {
    int lr = blockIdx.x;
    int j = threadIdx.x;
    const float* wu = Wupd + (size_t)lr * 2 * HH * HH;
    const float* bd = bdst + lr * HH;
    const float* bs = bsrc + lr * HH;
    float acc = bupd[lr * HH + j];
    for (int k = 0; k < HH; ++k)
        acc += bd[k] * wu[k * HH + j] + bs[k] * wu[(HH + k) * HH + j];
    fB[lr * HH + j] = acc;
}

// ---------------- CSR build: batched over 3 relations; count stores per-edge slot ----------------
__global__ void k_count(const int* __restrict__ e0, const int* __restrict__ e1,
                        const int* __restrict__ e2, int* __restrict__ cnt,
                        int* __restrict__ pose) {
    int rel = blockIdx.y;
    const int* d = (rel == 0 ? e0 : rel == 1 ? e1 : e2) + EE;
    int i = blockIdx.x * 256 + threadIdx.x;
    if (i < EE) pose[rel * EE + i] = atomicAdd(&cnt[rel * NN + d[i]], 1);
}

__global__ void k_scan1(const int* __restrict__ cnt_all, int* __restrict__ rs_all,
                        int* __restrict__ bsum) {
    __shared__ int sd[256];
    int rel = blockIdx.y;
    const int* cnt = cnt_all + rel * NN;
    int* rs = rs_all + rel * NN;
    int blk = blockIdx.x, tid = threadIdx.x;
    int base = blk * 1024 + tid * 4;
    int c0 = 0, c1 = 0, c2 = 0, c3 = 0;
    if (base + 0 < NN) c0 = cnt[base + 0];
    if (base + 1 < NN) c1 = cnt[base + 1];
    if (base + 2 < NN) c2 = cnt[base + 2];
    if (base + 3 < NN) c3 = cnt[base + 3];
    int s = c0 + c1 + c2 + c3;
    sd[tid] = s;
    __syncthreads();
    for (int off = 1; off < 256; off <<= 1) {
        int v = (tid >= off) ? sd[tid - off] : 0;
        __syncthreads();
        sd[tid] += v;
        __syncthreads();
    }
    int excl = sd[tid] - s;
    if (tid == 255) bsum[rel * 128 + blk] = sd[255];
    if (base + 0 < NN) rs[base + 0] = excl;
    if (base + 1 < NN) rs[base + 1] = excl + c0;
    if (base + 2 < NN) rs[base + 2] = excl + c0 + c1;
    if (base + 3 < NN) rs[base + 3] = excl + c0 + c1 + c2;
}

__global__ void k_scan2(int* __restrict__ bsum) {  // grid = 3, 128 threads
    __shared__ int sd[128];
    int rel = blockIdx.x;
    int tid = threadIdx.x;
    int v = (tid < SCAN_B) ? bsum[rel * 128 + tid] : 0;
    sd[tid] = v;
    __syncthreads();
    for (int off = 1; off < 128; off <<= 1) {
        int u = (tid >= off) ? sd[tid - off] : 0;
        __syncthreads();
        sd[tid] += u;
        __syncthreads();
    }
    if (tid < SCAN_B) bsum[rel * 128 + tid] = sd[tid] - v;  // exclusive
}

__global__ void k_scan3(int* __restrict__ rs_all, const int* __restrict__ bsum) {
    int rel = blockIdx.y;
    int i = blockIdx.x * 256 + threadIdx.x;
    if (i < NN) rs_all[rel * NN + i] += bsum[rel * 128 + (i >> 10)];
}

// atomic-free scatter: slot precomputed by k_count
__global__ void k_fill(const int* __restrict__ e0, const int* __restrict__ e1,
                       const int* __restrict__ e2, const int* __restrict__ pose,
                       const int* __restrict__ rs_all, int* __restrict__ csr_all) {
    int rel = blockIdx.y;
    const int* e = rel == 0 ? e0 : rel == 1 ? e1 : e2;
    int i = blockIdx.x * 256 + threadIdx.x;
    if (i >= EE) return;
    int s = e[i], d = e[EE + i];
    csr_all[(size_t)rel * EE + rs_all[rel * NN + d] + pose[rel * EE + i]] = s;
}

// ---------------- aggregation: one wave per dst node, 4-edge batched gather ----------------
__global__ __launch_bounds__(256) void k_aggr(u16* __restrict__ Xp, const float* __restrict__ xs,
                                              const int* __restrict__ rs, const int* __restrict__ cnt,
                                              const int* __restrict__ csr) {
    int node = blockIdx.x * 4 + (threadIdx.x >> 6);
    if (node >= NN) return;
    int lane = threadIdx.x & 63;
    int beg = rs[node], deg = cnt[node];
    const float2* xs2 = (const float2*)xs;
    float ax = 0.f, ay = 0.f;
    int j = 0;
    for (; j + 4 <= deg; j += 4) {
        int s0 = csr[beg + j], s1 = csr[beg + j + 1];
        int s2 = csr[beg + j + 2], s3 = csr[beg + j + 3];
        float2 v0 = xs2[(size_t)s0 * 64 + lane];
        float2 v1 = xs2[(size_t)s1 * 64 + lane];
        float2 v2 = xs2[(size_t)s2 * 64 + lane];
        float2 v3 = xs2[(size_t)s3 * 64 + lane];
        ax += (v0.x + v1.x) + (v2.x + v3.x);
        ay += (v0.y + v1.y) + (v2.y + v3.y);
    }
    if (j + 2 <= deg) {
        int s0 = csr[beg + j], s1 = csr[beg + j + 1];
        float2 v0 = xs2[(size_t)s0 * 64 + lane];
        float2 v1 = xs2[(size_t)s1 * 64 + lane];
        ax += v0.x + v1.x;
        ay += v0.y + v1.y;
        j += 2;
    }
    if (j < deg) {
        float2 v = xs2[(size_t)csr[beg + j] * 64 + lane];
        ax += v.x;
        ay += v.y;
    }
    float sc = 1.0f / fmaxf((float)deg, 1.0f);
    float vx = ax * sc, vy = ay * sc;
    u16 hx = f2bf(vx), hy = f2bf(vy);
    u16 lx = f2bf(vx - bf2f(hx)), ly = f2bf(vy - bf2f(hy));
    int g = lane >> 2;
    char* base = (char*)Xp + (size_t)node * 512 + (g >> 2) * 128;
    int jb = (lane & 3) * 4;
    __builtin_nontemporal_store(((u32)hy << 16) | hx, (u32*)(base + hi_off(g & 3, node) + jb));
    __builtin_nontemporal_store(((u32)ly << 16) | lx, (u32*)(base + lo_off(g & 3, node) + jb));
}

// ---------------- fused conv GEMM: Y = X1@W1 + X2@W2 + bias, bf16x3 MFMA ----------------
__global__ __launch_bounds__(256) void k_cgemm(float* Y, const u16* X1p,
                                               const float* __restrict__ X2,
                                               const u16* __restrict__ W1h, const u16* __restrict__ W1l,
                                               const u16* __restrict__ W2h, const u16* __restrict__ W2l,
                                               const float* __restrict__ bias, int nrows) {
    __shared__ __attribute__((aligned(16))) char Xt[16384];  // [128 rows][128B chunk]
    int tid = threadIdx.x;
    int row0 = blockIdx.x * 128;
    int lane = tid & 63, wv = tid >> 6;
    int l15 = lane & 15, lg = lane >> 4;
    bool full = (row0 + 128 <= nrows);

    f32x4 acc[8][2];
#pragma unroll
    for (int i = 0; i < 8; ++i)
#pragma unroll
        for (int j = 0; j < 2; ++j) acc[i][j] = (f32x4)(0.f);

    for (int ph = 0; ph < 2; ++ph) {
        const u16* Wh = ph ? W2h : W1h;
        const u16* Wl = ph ? W2l : W1l;
        for (int kc = 0; kc < HH; kc += 32) {
            __syncthreads();  // previous chunk fully consumed before overwrite
            if (ph == 0) {
#pragma unroll
                for (int p = 0; p < 4; ++p) {
                    int tb = p * 4096 + tid * 16;
                    int r = tb >> 7, off = tb & 127;
                    stage16((const char*)X1p + (size_t)(row0 + r) * 512 + (kc >> 5) * 128 + off,
                            Xt + tb);
                }
            } else {
#pragma unroll
                for (int it = 0; it < 2; ++it) {
                    int g2 = tid + it * 256;
                    int r = g2 >> 2, gi = g2 & 3;
                    float4 a = make_float4(0.f, 0.f, 0.f, 0.f), b = a;
                    if (full || row0 + r < nrows) {
                        const float* xp = &X2[(size_t)(row0 + r) * HH + kc + gi * 8];
                        a = *(const float4*)xp;
                        b = *(const float4*)(xp + 4);
                    }
                    u16 h0 = f2bf(a.x), h1 = f2bf(a.y), h2 = f2bf(a.z), h3 = f2bf(a.w);
                    u16 h4 = f2bf(b.x), h5 = f2bf(b.y), h6 = f2bf(b.z), h7 = f2bf(b.w);
                    bf16x8 hv = {(short)h0, (short)h1, (short)h2, (short)h3,
                                 (short)h4, (short)h5, (short)h6, (short)h7};
                    bf16x8 lv = {(short)f2bf(a.x - bf2f(h0)), (short)f2bf(a.y - bf2f(h1)),
                                 (short)f2bf(a.z - bf2f(h2)), (short)f2bf(a.w - bf2f(h3)),
                                 (short)f2bf(b.x - bf2f(h4)), (short)f2bf(b.y - bf2f(h5)),
                                 (short)f2bf(b.z - bf2f(h6)), (short)f2bf(b.w - bf2f(h7))};
                    char* rb = Xt + r * 128;
                    *(bf16x8*)(rb + hi_off(gi, r)) = hv;
                    *(bf16x8*)(rb + lo_off(gi, r)) = lv;
                }
            }
            bf16x8 bh[2], bl[2];
#pragma unroll
            for (int nt = 0; nt < 2; ++nt) {
                int n = (wv * 2 + nt) * 16 + l15;
                bh[nt] = *(const bf16x8*)&Wh[(size_t)n * HH + kc + lg * 8];
                bl[nt] = *(const bf16x8*)&Wl[(size_t)n * HH + kc + lg * 8];
            }
            __syncthreads();  // drains DMA vmcnt + lds writes
#pragma unroll
            for (int mt = 0; mt < 8; ++mt) {
                int r = mt * 16 + l15;
                const char* rb = Xt + r * 128;
                bf16x8 ah = *(const bf16x8*)(rb + hi_off(lg, r));
                bf16x8 al = *(const bf16x8*)(rb + lo_off(lg, r));
#pragma unroll
                for (int nt = 0; nt < 2; ++nt) {
                    acc[mt][nt] = __builtin_amdgcn_mfma_f32_16x16x32_bf16(ah, bh[nt], acc[mt][nt], 0, 0, 0);
                    acc[mt][nt] = __builtin_amdgcn_mfma_f32_16x16x32_bf16(ah, bl[nt], acc[mt][nt], 0, 0, 0);
                    acc[mt][nt] = __builtin_amdgcn_mfma_f32_16x16x32_bf16(al, bh[nt], acc[mt][nt], 0, 0, 0);
                }
            }
        }
    }
#pragma unroll
    for (int mt = 0; mt < 8; ++mt)
#pragma unroll
        for (int nt = 0; nt < 2; ++nt) {
            int ncol = (wv * 2 + nt) * 16 + l15;
            float bv = bias[ncol];
#pragma unroll
            for (int j = 0; j < 4; ++j) {
                int r = row0 + mt * 16 + lg * 4 + j;
                if (r < nrows) Y[(size_t)r * HH + ncol] = acc[mt][nt][j] + bv;
            }
        }
}

// ---------------- attention score: W1 read from global (L1/L2-hot), X in LDS ----------------
// LDS 18.5KB (was 51.7KB) -> occupancy ~5 blocks/CU (VGPR-capped) vs 3.
__global__ __launch_bounds__(256) void k_attn(const float* __restrict__ XA, const float* __restrict__ XB,
                                              const float* __restrict__ W1,
                                              const float* __restrict__ b1, const float* __restrict__ w2,
                                              float* __restrict__ PA, float* __restrict__ PB, int nrows) {
    __shared__ float Xl[128 * 36];   // 18 KiB
    __shared__ float red[16];
    int tid = threadIdx.x;
    bool second = blockIdx.x >= ATTN_GRID;
    const float* X = second ? XB : XA;
    float* partial = second ? PB : PA;
    int row0 = (second ? blockIdx.x - ATTN_GRID : blockIdx.x) * 128;
    int tx = tid & 15, ty = tid >> 4;
    bool full = (row0 + 128 <= nrows);
    float acc[8][4];
#pragma unroll
    for (int i = 0; i < 8; ++i)
#pragma unroll
        for (int j = 0; j < 4; ++j) acc[i][j] = 0.f;

    for (int kc = 0; kc < HH; kc += 32) {
        __syncthreads();
        for (int idx = tid; idx < 1024; idx += 256) {
            int r = idx >> 3, c = idx & 7;
            float4 v = make_float4(0.f, 0.f, 0.f, 0.f);
            if (full || row0 + r < nrows)
                v = *(const float4*)&X[(size_t)(row0 + r) * HH + kc + c * 4];
            *(float4*)&Xl[r * 36 + c * 4] = v;
        }
        __syncthreads();
#pragma unroll
        for (int k = 0; k < 32; k += 4) {
            float4 xv[8];
#pragma unroll
            for (int i = 0; i < 8; ++i) xv[i] = *(const float4*)&Xl[(ty + 16 * i) * 36 + k];
#pragma unroll
            for (int kk = 0; kk < 4; ++kk) {
                float4 w = *(const float4*)&W1[(size_t)(kc + k + kk) * AAA + tx * 4];
#pragma unroll
                for (int i = 0; i < 8; ++i) {
                    float xsv = (&xv[i].x)[kk];
                    acc[i][0] += xsv * w.x; acc[i][1] += xsv * w.y;
                    acc[i][2] += xsv * w.z; acc[i][3] += xsv * w.w;
                }
            }
        }
    }
    float4 b1v = *(const float4*)&b1[tx * 4];
    float4 w2v = *(const float4*)&w2[tx * 4];
    float tot = 0.f;
#pragma unroll
    for (int i = 0; i < 8; ++i) {
        float s = tanhf(acc[i][0] + b1v.x) * w2v.x + tanhf(acc[i][1] + b1v.y) * w2v.y +
                  tanhf(acc[i][2] + b1v.z) * w2v.z + tanhf(acc[i][3] + b1v.w) * w2v.w;
        s += __shfl_xor(s, 1);
        s += __shfl_xor(s, 2);
        s += __shfl_xor(s, 4);
        s += __shfl_xor(s, 8);
        if (row0 + ty + 16 * i < nrows) tot += s;
    }
    if (tx == 0) red[ty] = tot;
    __syncthreads();
    if (tid == 0) {
        float p = 0.f;
#pragma unroll
        for (int i = 0; i < 16; ++i) p += red[i];
        partial[second ? (blockIdx.x - ATTN_GRID) : blockIdx.x] = p;
    }
}

__global__ void k_alpha(const float* __restrict__ P1, const float* __restrict__ P2,
                        float* __restrict__ alpha, int nparts, float invn) {
    __shared__ float s1[256], s2[256];
    int tid = threadIdx.x;
    float a = 0.f, b = 0.f;
    for (int i = tid; i < nparts; i += 256) { a += P1[i]; b += P2[i]; }
    s1[tid] = a; s2[tid] = b;
    __syncthreads();
    for (int off = 128; off > 0; off >>= 1) {
        if (tid < off) { s1[tid] += s1[tid + off]; s2[tid] += s2[tid + off]; }
        __syncthreads();
    }
    if (tid == 0) {
        float m1 = s1[0] * invn, m2 = s2[0] * invn;
        float mx = fmaxf(m1, m2);
        float e1 = expf(m1 - mx), e2 = expf(m2 - mx);
        float inv = 1.f / (e1 + e2);
        alpha[0] = e1 * inv; alpha[1] = e2 * inv;
    }
}

// ---------------- combine + column stats ----------------
template <bool COMBINE>
__global__ __launch_bounds__(256) void k_comb(float* __restrict__ X, const float* __restrict__ Y,
                                              const float* __restrict__ alpha, float* __restrict__ colsum,
                                              float* __restrict__ colsq, int nrows) {
    int tid = threadIdx.x;
    int h = tid & 127, half = tid >> 7;
    float a0 = 1.f, a1 = 0.f;
    if (COMBINE) { a0 = alpha[0]; a1 = alpha[1]; }
    float s = 0.f, q = 0.f;
    for (int n = blockIdx.x * 2 + half; n < nrows; n += gridDim.x * 2) {
        size_t off = (size_t)n * HH + h;
        float v = X[off];
        if (COMBINE) { v = a0 * v + a1 * Y[off]; X[off] = v; }
        s += v; q += v * v;
    }
    __shared__ float ls[256], lq[256];
    ls[tid] = s; lq[tid] = q;
    __syncthreads();
    if (half == 0) {
        atomicAdd(&colsum[h], ls[tid] + ls[tid + 128]);
        atomicAdd(&colsq[h], lq[tid] + lq[tid + 128]);
    }
}

__global__ void k_bnp(const float* __restrict__ sum, const float* __restrict__ sq,
                      const float* __restrict__ gamma, const float* __restrict__ beta,
                      float* __restrict__ scale, float* __restrict__ shift, float invn) {
    int h = threadIdx.x;
    float mu = sum[h] * invn;
    float var = sq[h] * invn - mu * mu;
    float sc = gamma[h] * rsqrtf(var + 1.0f);
    scale[h] = sc;
    shift[h] = beta[h] - mu * sc;
}

// BN apply + leaky, both buffers in one launch (blockIdx.y selects)
__global__ void k_bna(float* __restrict__ X0, float* __restrict__ X1,
                      const float* __restrict__ sc0, const float* __restrict__ sc1) {
    float* X = blockIdx.y ? X1 : X0;
    const float* scp = blockIdx.y ? sc1 : sc0;
    int i = blockIdx.x * 256 + threadIdx.x;
    float4 v = ((float4*)X)[i];
    int h0 = (i & 31) * 4;
    float4 sc = *(const float4*)&scp[h0];
    float4 sf = *(const float4*)&scp[128 + h0];
    v.x = v.x * sc.x + sf.x; v.y = v.y * sc.y + sf.y;
    v.z = v.z * sc.z + sf.z; v.w = v.w * sc.w + sf.w;
    v.x = v.x >= 0.f ? v.x : 0.01f * v.x;
    v.y = v.y >= 0.f ? v.y : 0.01f * v.y;
    v.z = v.z >= 0.f ? v.z : 0.01f * v.z;
    v.w = v.w >= 0.f ? v.w : 0.01f * v.w;
    ((float4*)X)[i] = v;
}

// ---------------- final FC with fused BN+leaky; both outputs in one launch ----------------
__global__ __launch_bounds__(256) void k_fc(const float* __restrict__ X0, const float* __restrict__ X1,
                                            const float* __restrict__ sc0, const float* __restrict__ sc1,
                                            const float* __restrict__ Wall, const float* __restrict__ ball,
                                            float* __restrict__ out, int nrows) {
    __shared__ float Wl[HH * CC];
    __shared__ float bl[CC];
    __shared__ float scl[HH], sfl[HH];
    int which = blockIdx.y;
    const float* X = which ? X1 : X0;
    const float* scp = which ? sc1 : sc0;
    const float* W = Wall + which * HH * CC;
    float* o = out + (size_t)which * NN * CC;
    int tid = threadIdx.x;
    for (int i = tid * 4; i < HH * CC; i += 1024)
        *(float4*)&Wl[i] = *(const float4*)&W[i];
    if (tid < CC) bl[tid] = ball[which * CC + tid];
    if (tid < HH) { scl[tid] = scp[tid]; sfl[tid] = scp[128 + tid]; }
    __syncthreads();
    int c = tid & 15, nl = tid >> 4;
    for (int n = blockIdx.x * 16 + nl; n < nrows; n += gridDim.x * 16) {
        const float4* x4 = (const float4*)(X + (size_t)n * HH);
        float acc = bl[c];
#pragma unroll
        for (int h4 = 0; h4 < 32; ++h4) {
            float4 xv = x4[h4];
            float e0 = xv.x * scl[h4 * 4 + 0] + sfl[h4 * 4 + 0];
            float e1 = xv.y * scl[h4 * 4 + 1] + sfl[h4 * 4 + 1];
            float e2 = xv.z * scl[h4 * 4 + 2] + sfl[h4 * 4 + 2];
            float e3 = xv.w * scl[h4 * 4 + 3] + sfl[h4 * 4 + 3];
            e0 = e0 >= 0.f ? e0 : 0.01f * e0;
            e1 = e1 >= 0.f ? e1 : 0.01f * e1;
            e2 = e2 >= 0.f ? e2 : 0.01f * e2;
            e3 = e3 >= 0.f ? e3 : 0.01f * e3;
            acc += e0 * Wl[(h4 * 4 + 0) * CC + c] + e1 * Wl[(h4 * 4 + 1) * CC + c] +
                   e2 * Wl[(h4 * 4 + 2) * CC + c] + e3 * Wl[(h4 * 4 + 3) * CC + c];
        }
        o[(size_t)n * CC + c] = acc;
    }
}

extern "C" void kernel_launch(void* const* d_in, const int* in_sizes, int n_in,
                              void* d_out, int out_size, void* d_ws, size_t ws_size,
                              hipStream_t stream) {
    const float* xA = (const float*)d_in[0];
    const float* xB = (const float*)d_in[1];
    const float* Wsrc = (const float*)d_in[2];
    const float* bsrc = (const float*)d_in[3];
    const float* Wdst = (const float*)d_in[4];
    const float* bdst = (const float*)d_in[5];
    const float* Wupd = (const float*)d_in[6];
    const float* bupd = (const float*)d_in[7];
    const float* attnW1 = (const float*)d_in[8];
    const float* attnb1 = (const float*)d_in[9];
    const float* attnw2 = (const float*)d_in[10];
    const float* gamma = (const float*)d_in[11];
    const float* beta = (const float*)d_in[12];
    const float* fcW = (const float*)d_in[13];
    const float* fcb = (const float*)d_in[14];
    const int* eAB = (const int*)d_in[15];
    const int* eBB = (const int*)d_in[16];
    const int* eBA = (const int*)d_in[17];
    float* out = (float*)d_out;

    // workspace layout == round-6/8 passing footprint (~216 MB)
    float* ws = (float*)d_ws;
    const size_t NH = (size_t)NN * HH;
    const size_t LRHH = (size_t)LL * RR * HH * HH;
    float* B0 = ws;
    float* B1 = B0 + NH;
    float* B2 = B1 + NH;
    float* B3 = B2 + NH;
    u16* uWdh = (u16*)(B3 + NH);
    u16* uWdl = uWdh + LRHH;
    u16* uWsh = uWdl + LRHH;
    u16* uWsl = uWsh + LRHH;
    float* fB = (float*)(uWsl + LRHH);
    float* csA = fB + LL * RR * HH;
    float* csB = csA + 256;
    float* scA = csB + 256;
    float* scB = scA + 256;
    float* P1 = scB + 256;
    float* P2 = P1 + 1024;
    float* alp = P2 + 1024;
    int* icnt = (int*)(alp + 64);
    int* irs = icnt + 3 * NN;
    int* icsr = irs + 3 * NN;
    int* ifill = icsr + 3 * EE;     // unused now (kept for layout stability)
    int* ibsum = ifill + 3 * NN;
    int* pose = (int*)B3;           // 3*EE ints = 7.2MB; B3 unused until layer 1
    const float invN = 1.0f / (float)NN;

    k_fuse_w<<<LL * RR * HH, 256, 0, stream>>>(Wsrc, Wdst, Wupd, uWdh, uWdl, uWsh, uWsl);
    k_fuse_b<<<LL * RR, HH, 0, stream>>>(bsrc, bdst, bupd, Wupd, fB);

    // CSR build: all 3 relations per kernel; k_count returns per-edge slot -> k_fill atomic-free
    hipMemsetAsync(icnt, 0, 3 * NN * 4, stream);
    k_count<<<dim3((EE + 255) / 256, 3), 256, 0, stream>>>(eAB, eBB, eBA, icnt, pose);
    k_scan1<<<dim3(SCAN_B, 3), 256, 0, stream>>>(icnt, irs, ibsum);
    k_scan2<<<3, 128, 0, stream>>>(ibsum);
    k_scan3<<<dim3((NN + 255) / 256, 3), 256, 0, stream>>>(irs, ibsum);
    k_fill<<<dim3((EE + 255) / 256, 3), 256, 0, stream>>>(eAB, eBB, eBA, pose, irs, icsr);

    const int GEMM_GRID = (NN + 127) / 128;
    const int AGGR_GRID = (NN + 3) / 4;

    // dest serves as packed X1 during aggr+cgemm, then holds f32 Y (in-place)
    auto conv = [&](float* dest, const float* xs, const float* xd, int rel, int lr) {
        k_aggr<<<AGGR_GRID, 256, 0, stream>>>((u16*)dest, xs, irs + rel * NN, icnt + rel * NN,
                                              icsr + (size_t)rel * EE);
        k_cgemm<<<GEMM_GRID, 256, 0, stream>>>(dest, (const u16*)dest, xd,
                                               uWsh + (size_t)lr * HH * HH, uWsl + (size_t)lr * HH * HH,
                                               uWdh + (size_t)lr * HH * HH, uWdl + (size_t)lr * HH * HH,
                                               fB + lr * HH, NN);
    };

    // ================= layer 0 =================
    conv(B0, xA, xB, 0, 0);  // embB1
    conv(B1, xB, xB, 1, 1);  // embB2
    conv(B2, xB, xA, 2, 2);  // embA
    k_attn<<<2 * ATTN_GRID, 256, 0, stream>>>(B0, B1, attnW1, attnb1, attnw2, P1, P2, NN);
    k_alpha<<<1, 256, 0, stream>>>(P1, P2, alp, ATTN_GRID, invN);
    hipMemsetAsync(csB, 0, 256 * 4, stream);
    k_comb<true><<<512, 256, 0, stream>>>(B0, B1, alp, csB, csB + 128, NN);
    hipMemsetAsync(csA, 0, 256 * 4, stream);
    k_comb<false><<<512, 256, 0, stream>>>(B2, nullptr, nullptr, csA, csA + 128, NN);
    k_bnp<<<1, 128, 0, stream>>>(csA, csA + 128, gamma + 0 * HH, beta + 0 * HH, scA, scA + 128, invN);
    k_bnp<<<1, 128, 0, stream>>>(csB, csB + 128, gamma + 1 * HH, beta + 1 * HH, scB, scB + 128, invN);
    k_bna<<<dim3((int)(NH / 4 / 256), 2), 256, 0, stream>>>(B2, B0, scA, scB);  // xA=B2, xB=B0

    // ================= layer 1 =================
    conv(B1, B2, B0, 0, 3);  // embB1'  (overwrites pose region? no - B1)
    conv(B3, B0, B0, 1, 4);  // embB2'  (B3: pose no longer needed)
    k_attn<<<2 * ATTN_GRID, 256, 0, stream>>>(B1, B3, attnW1 + HH * AAA, attnb1 + AAA,
                                              attnw2 + AAA, P1, P2, NN);
    k_alpha<<<1, 256, 0, stream>>>(P1, P2, alp, ATTN_GRID, invN);
    hipMemsetAsync(csB, 0, 256 * 4, stream);
    k_comb<true><<<512, 256, 0, stream>>>(B1, B3, alp, csB, csB + 128, NN);  // xB_new -> B1
    conv(B3, B0, B2, 2, 5);  // embA'
    hipMemsetAsync(csA, 0, 256 * 4, stream);
    k_comb<false><<<512, 256, 0, stream>>>(B3, nullptr, nullptr, csA, csA + 128, NN);
    k_bnp<<<1, 128, 0, stream>>>(csA, csA + 128, gamma + 2 * HH, beta + 2 * HH, scA, scA + 128, invN);
    k_bnp<<<1, 128, 0, stream>>>(csB, csB + 128, gamma + 3 * HH, beta + 3 * HH, scB, scB + 128, invN);

    // ================= head: BN+leaky fused into FC =================
    k_fc<<<dim3(2048, 2), 256, 0, stream>>>(B3, B1, scA, scB, fcW, fcb, out, NN);
}

// Round 11
// 1163.615 us; speedup vs baseline: 2.2014x; 1.1109x over previous
//
#include <hip/hip_runtime.h>

#define NN 100000
#define HH 128
#define EE 600000
#define LL 2
#define RR 3
#define AAA 64
#define CC 16
#define SCAN_B 98   // 98 blocks x 1024 elems covers 100000
#define ATTN_GRID ((NN + 127) / 128)

typedef unsigned short u16;
typedef unsigned int u32;
typedef __attribute__((ext_vector_type(8))) short bf16x8;
typedef __attribute__((ext_vector_type(4))) float f32x4;

__device__ inline u16 f2bf(float f) {   // RNE f32 -> bf16
    unsigned int u = __float_as_uint(f);
    return (u16)((u + 0x7FFF + ((u >> 16) & 1)) >> 16);
}
__device__ inline float bf2f(u16 h) { return __uint_as_float((unsigned int)h << 16); }

// Packed X layout (per row: 512B, 4 chunks of 128B; chunk = 4 groups of [16B hi][16B lo],
// XOR-swizzled by row). Shared by producer (k_aggr / cgemm phase-2 staging) and consumer
// (cgemm frag reads). row0 % 128 == 0 so block-local r has same r&7 as global row.
__device__ __forceinline__ int hi_off(int gi, int r) { return (gi * 32) ^ ((r & 7) << 4); }
__device__ __forceinline__ int lo_off(int gi, int r) { return (gi * 32 + 16) ^ ((r & 7) << 4); }

// async global->LDS, 16B per lane; dest must be linear (wave-uniform base + lane*16)
__device__ __forceinline__ void stage16(const void* g, void* l) {
    __builtin_amdgcn_global_load_lds((const __attribute__((address_space(1))) unsigned int*)g,
                                     (__attribute__((address_space(3))) unsigned int*)l, 16, 0, 0);
}

// ---------------- weight fusion: W transposed [n][k], split bf16 hi/lo ----------------
__global__ void k_fuse_w(const float* __restrict__ Wsrc, const float* __restrict__ Wdst,
                         const float* __restrict__ Wupd, u16* __restrict__ Wdt_hi,
                         u16* __restrict__ Wdt_lo, u16* __restrict__ Wst_hi,
                         u16* __restrict__ Wst_lo) {
    int b = blockIdx.x;
    int lr = b >> 7, i = b & 127;   // i = k index
    int t = threadIdx.x;
    int j = t & 127;                // j = n index
    const float* wu = Wupd + (size_t)lr * 2 * HH * HH;
    float acc = 0.f;
    size_t o = ((size_t)lr * HH + j) * HH + i;  // transposed store [n=j][k=i]
    if (t < 128) {
        const float* wd = Wdst + ((size_t)lr * HH + i) * HH;
        for (int k = 0; k < HH; ++k) acc += wd[k] * wu[k * HH + j];
        u16 h = f2bf(acc);
        Wdt_hi[o] = h;
        Wdt_lo[o] = f2bf(acc - bf2f(h));
    } else {
        const float* wsc = Wsrc + ((size_t)lr * HH + i) * HH;
        for (int k = 0; k < HH; ++k) acc += wsc[k] * wu[(HH + k) * HH + j];
        u16 h = f2bf(acc);
        Wst_hi[o] = h;
        Wst_lo[o] = f2bf(acc - bf2f(h));
    }
}

__global__ void k_fuse_b(const float* __restrict__ bsrc, const float* __restrict__ bdst,
                         const float* __restrict__ bupd, const float* __restrict__ Wupd,
                         float* __restrict__ fB) {
    int lr = blockIdx.x;
    int j = threadIdx.x;
    const float* wu = Wupd + (size_t)lr * 2 * HH * HH;
    const float* bd = bdst + lr * HH;
    const float* bs = bsrc + lr * HH;
    float acc = bupd[lr * HH + j];
    for (int k = 0; k < HH; ++k)
        acc += bd[k] * wu[k * HH + j] + bs[k] * wu[(HH + k) * HH + j];
    fB[lr * HH + j] = acc;
}

// ---------------- CSR build: batched over 3 relations; count stores per-edge slot ----------------
__global__ void k_count(const int* __restrict__ e0, const int* __restrict__ e1,
                        const int* __restrict__ e2, int* __restrict__ cnt,
                        int* __restrict__ pose) {
    int rel = blockIdx.y;
    const int* d = (rel == 0 ? e0 : rel == 1 ? e1 : e2) + EE;
    int i = blockIdx.x * 256 + threadIdx.x;
    if (i < EE) pose[rel * EE + i] = atomicAdd(&cnt[rel * NN + d[i]], 1);
}

__global__ void k_scan1(const int* __restrict__ cnt_all, int* __restrict__ rs_all,
                        int* __restrict__ bsum) {
    __shared__ int sd[256];
    int rel = blockIdx.y;
    const int* cnt = cnt_all + rel * NN;
    int* rs = rs_all + rel * NN;
    int blk = blockIdx.x, tid = threadIdx.x;
    int base = blk * 1024 + tid * 4;
    int c0 = 0, c1 = 0, c2 = 0, c3 = 0;
    if (base + 0 < NN) c0 = cnt[base + 0];
    if (base + 1 < NN) c1 = cnt[base + 1];
    if (base + 2 < NN) c2 = cnt[base + 2];
    if (base + 3 < NN) c3 = cnt[base + 3];
    int s = c0 + c1 + c2 + c3;
    sd[tid] = s;
    __syncthreads();
    for (int off = 1; off < 256; off <<= 1) {
        int v = (tid >= off) ? sd[tid - off] : 0;
        __syncthreads();
        sd[tid] += v;
        __syncthreads();
    }
    int excl = sd[tid] - s;
    if (tid == 255) bsum[rel * 128 + blk] = sd[255];
    if (base + 0 < NN) rs[base + 0] = excl;
    if (base + 1 < NN) rs[base + 1] = excl + c0;
    if (base + 2 < NN) rs[base + 2] = excl + c0 + c1;
    if (base + 3 < NN) rs[base + 3] = excl + c0 + c1 + c2;
}

__global__ void k_scan2(int* __restrict__ bsum) {  // grid = 3, 128 threads
    __shared__ int sd[128];
    int rel = blockIdx.x;
    int tid = threadIdx.x;
    int v = (tid < SCAN_B) ? bsum[rel * 128 + tid] : 0;
    sd[tid] = v;
    __syncthreads();
    for (int off = 1; off < 128; off <<= 1) {
        int u = (tid >= off) ? sd[tid - off] : 0;
        __syncthreads();
        sd[tid] += u;
        __syncthreads();
    }
    if (tid < SCAN_B) bsum[rel * 128 + tid] = sd[tid] - v;  // exclusive
}

__global__ void k_scan3(int* __restrict__ rs_all, const int* __restrict__ bsum) {
    int rel = blockIdx.y;
    int i = blockIdx.x * 256 + threadIdx.x;
    if (i < NN) rs_all[rel * NN + i] += bsum[rel * 128 + (i >> 10)];
}

// atomic-free scatter: slot precomputed by k_count
__global__ void k_fill(const int* __restrict__ e0, const int* __restrict__ e1,
                       const int* __restrict__ e2, const int* __restrict__ pose,
                       const int* __restrict__ rs_all, int* __restrict__ csr_all) {
    int rel = blockIdx.y;
    const int* e = rel == 0 ? e0 : rel == 1 ? e1 : e2;
    int i = blockIdx.x * 256 + threadIdx.x;
    if (i >= EE) return;
    int s = e[i], d = e[EE + i];
    csr_all[(size_t)rel * EE + rs_all[rel * NN + d] + pose[rel * EE + i]] = s;
}

// ---------------- aggregation: one wave per dst node, 4-edge batched gather ----------------
__global__ __launch_bounds__(256) void k_aggr(u16* __restrict__ Xp, const float* __restrict__ xs,
                                              const int* __restrict__ rs, const int* __restrict__ cnt,
                                              const int* __restrict__ csr) {
    int node = blockIdx.x * 4 + (threadIdx.x >> 6);
    if (node >= NN) return;
    int lane = threadIdx.x & 63;
    int beg = rs[node], deg = cnt[node];
    const float2* xs2 = (const float2*)xs;
    float ax = 0.f, ay = 0.f;
    int j = 0;
    for (; j + 4 <= deg; j += 4) {
        int s0 = csr[beg + j], s1 = csr[beg + j + 1];
        int s2 = csr[beg + j + 2], s3 = csr[beg + j + 3];
        float2 v0 = xs2[(size_t)s0 * 64 + lane];
        float2 v1 = xs2[(size_t)s1 * 64 + lane];
        float2 v2 = xs2[(size_t)s2 * 64 + lane];
        float2 v3 = xs2[(size_t)s3 * 64 + lane];
        ax += (v0.x + v1.x) + (v2.x + v3.x);
        ay += (v0.y + v1.y) + (v2.y + v3.y);
    }
    if (j + 2 <= deg) {
        int s0 = csr[beg + j], s1 = csr[beg + j + 1];
        float2 v0 = xs2[(size_t)s0 * 64 + lane];
        float2 v1 = xs2[(size_t)s1 * 64 + lane];
        ax += v0.x + v1.x;
        ay += v0.y + v1.y;
        j += 2;
    }
    if (j < deg) {
        float2 v = xs2[(size_t)csr[beg + j] * 64 + lane];
        ax += v.x;
        ay += v.y;
    }
    float sc = 1.0f / fmaxf((float)deg, 1.0f);
    float vx = ax * sc, vy = ay * sc;
    u16 hx = f2bf(vx), hy = f2bf(vy);
    u16 lx = f2bf(vx - bf2f(hx)), ly = f2bf(vy - bf2f(hy));
    int g = lane >> 2;
    char* base = (char*)Xp + (size_t)node * 512 + (g >> 2) * 128;
    int jb = (lane & 3) * 4;
    __builtin_nontemporal_store(((u32)hy << 16) | hx, (u32*)(base + hi_off(g & 3, node) + jb));
    __builtin_nontemporal_store(((u32)ly << 16) | lx, (u32*)(base + lo_off(g & 3, node) + jb));
}

// ---------------- fused conv GEMM: Y = X1@W1 + X2@W2 + bias, bf16x3 MFMA ----------------
__global__ __launch_bounds__(256) void k_cgemm(float* Y, const u16* X1p,
                                               const float* __restrict__ X2,
                                               const u16* __restrict__ W1h, const u16* __restrict__ W1l,
                                               const u16* __restrict__ W2h, const u16* __restrict__ W2l,
                                               const float* __restrict__ bias, int nrows) {
    __shared__ __attribute__((aligned(16))) char Xt[16384];  // [128 rows][128B chunk]
    int tid = threadIdx.x;
    int row0 = blockIdx.x * 128;
    int lane = tid & 63, wv = tid >> 6;
    int l15 = lane & 15, lg = lane >> 4;
    bool full = (row0 + 128 <= nrows);

    f32x4 acc[8][2];
#pragma unroll
    for (int i = 0; i < 8; ++i)
#pragma unroll
        for (int j = 0; j < 2; ++j) acc[i][j] = (f32x4)(0.f);

    for (int ph = 0; ph < 2; ++ph) {
        const u16* Wh = ph ? W2h : W1h;
        const u16* Wl = ph ? W2l : W1l;
        for (int kc = 0; kc < HH; kc += 32) {
            __syncthreads();  // previous chunk fully consumed before overwrite
            if (ph == 0) {
#pragma unroll
                for (int p = 0; p < 4; ++p) {
                    int tb = p * 4096 + tid * 16;
                    int r = tb >> 7, off = tb & 127;
                    stage16((const char*)X1p + (size_t)(row0 + r) * 512 + (kc >> 5) * 128 + off,
                            Xt + tb);
                }
            } else {
#pragma unroll
                for (int it = 0; it < 2; ++it) {
                    int g2 = tid + it * 256;
                    int r = g2 >> 2, gi = g2 & 3;
                    float4 a = make_float4(0.f, 0.f, 0.f, 0.f), b = a;
                    if (full || row0 + r < nrows) {
                        const float* xp = &X2[(size_t)(row0 + r) * HH + kc + gi * 8];
                        a = *(const float4*)xp;
                        b = *(const float4*)(xp + 4);
                    }
                    u16 h0 = f2bf(a.x), h1 = f2bf(a.y), h2 = f2bf(a.z), h3 = f2bf(a.w);
                    u16 h4 = f2bf(b.x), h5 = f2bf(b.y), h6 = f2bf(b.z), h7 = f2bf(b.w);
                    bf16x8 hv = {(short)h0, (short)h1, (short)h2, (short)h3,
                                 (short)h4, (short)h5, (short)h6, (short)h7};
                    bf16x8 lv = {(short)f2bf(a.x - bf2f(h0)), (short)f2bf(a.y - bf2f(h1)),
                                 (short)f2bf(a.z - bf2f(h2)), (short)f2bf(a.w - bf2f(h3)),
                                 (short)f2bf(b.x - bf2f(h4)), (short)f2bf(b.y - bf2f(h5)),
                                 (short)f2bf(b.z - bf2f(h6)), (short)f2bf(b.w - bf2f(h7))};
                    char* rb = Xt + r * 128;
                    *(bf16x8*)(rb + hi_off(gi, r)) = hv;
                    *(bf16x8*)(rb + lo_off(gi, r)) = lv;
                }
            }
            bf16x8 bh[2], bl[2];
#pragma unroll
            for (int nt = 0; nt < 2; ++nt) {
                int n = (wv * 2 + nt) * 16 + l15;
                bh[nt] = *(const bf16x8*)&Wh[(size_t)n * HH + kc + lg * 8];
                bl[nt] = *(const bf16x8*)&Wl[(size_t)n * HH + kc + lg * 8];
            }
            __syncthreads();  // drains DMA vmcnt + lds writes
#pragma unroll
            for (int mt = 0; mt < 8; ++mt) {
                int r = mt * 16 + l15;
                const char* rb = Xt + r * 128;
                bf16x8 ah = *(const bf16x8*)(rb + hi_off(lg, r));
                bf16x8 al = *(const bf16x8*)(rb + lo_off(lg, r));
#pragma unroll
                for (int nt = 0; nt < 2; ++nt) {
                    acc[mt][nt] = __builtin_amdgcn_mfma_f32_16x16x32_bf16(ah, bh[nt], acc[mt][nt], 0, 0, 0);
                    acc[mt][nt] = __builtin_amdgcn_mfma_f32_16x16x32_bf16(ah, bl[nt], acc[mt][nt], 0, 0, 0);
                    acc[mt][nt] = __builtin_amdgcn_mfma_f32_16x16x32_bf16(al, bh[nt], acc[mt][nt], 0, 0, 0);
                }
            }
        }
    }
#pragma unroll
    for (int mt = 0; mt < 8; ++mt)
#pragma unroll
        for (int nt = 0; nt < 2; ++nt) {
            int ncol = (wv * 2 + nt) * 16 + l15;
            float bv = bias[ncol];
#pragma unroll
            for (int j = 0; j < 4; ++j) {
                int r = row0 + mt * 16 + lg * 4 + j;
                if (r < nrows) Y[(size_t)r * HH + ncol] = acc[mt][nt][j] + bv;
            }
        }
}

// ---------------- attention score: W1 read from global (L1/L2-hot), X in LDS ----------------
__global__ __launch_bounds__(256) void k_attn(const float* __restrict__ XA, const float* __restrict__ XB,
                                              const float* __restrict__ W1,
                                              const float* __restrict__ b1, const float* __restrict__ w2,
                                              float* __restrict__ PA, float* __restrict__ PB, int nrows) {
    __shared__ float Xl[128 * 36];   // 18 KiB
    __shared__ float red[16];
    int tid = threadIdx.x;
    bool second = blockIdx.x >= ATTN_GRID;
    const float* X = second ? XB : XA;
    float* partial = second ? PB : PA;
    int row0 = (second ? blockIdx.x - ATTN_GRID : blockIdx.x) * 128;
    int tx = tid & 15, ty = tid >> 4;
    bool full = (row0 + 128 <= nrows);
    float acc[8][4];
#pragma unroll
    for (int i = 0; i < 8; ++i)
#pragma unroll
        for (int j = 0; j < 4; ++j) acc[i][j] = 0.f;

    for (int kc = 0; kc < HH; kc += 32) {
        __syncthreads();
        for (int idx = tid; idx < 1024; idx += 256) {
            int r = idx >> 3, c = idx & 7;
            float4 v = make_float4(0.f, 0.f, 0.f, 0.f);
            if (full || row0 + r < nrows)
                v = *(const float4*)&X[(size_t)(row0 + r) * HH + kc + c * 4];
            *(float4*)&Xl[r * 36 + c * 4] = v;
        }
        __syncthreads();
#pragma unroll
        for (int k = 0; k < 32; k += 4) {
            float4 xv[8];
#pragma unroll
            for (int i = 0; i < 8; ++i) xv[i] = *(const float4*)&Xl[(ty + 16 * i) * 36 + k];
#pragma unroll
            for (int kk = 0; kk < 4; ++kk) {
                float4 w = *(const float4*)&W1[(size_t)(kc + k + kk) * AAA + tx * 4];
#pragma unroll
                for (int i = 0; i < 8; ++i) {
                    float xsv = (&xv[i].x)[kk];
                    acc[i][0] += xsv * w.x; acc[i][1] += xsv * w.y;
                    acc[i][2] += xsv * w.z; acc[i][3] += xsv * w.w;
                }
            }
        }
    }
    float4 b1v = *(const float4*)&b1[tx * 4];
    float4 w2v = *(const float4*)&w2[tx * 4];
    float tot = 0.f;
#pragma unroll
    for (int i = 0; i < 8; ++i) {
        float s = tanhf(acc[i][0] + b1v.x) * w2v.x + tanhf(acc[i][1] + b1v.y) * w2v.y +
                  tanhf(acc[i][2] + b1v.z) * w2v.z + tanhf(acc[i][3] + b1v.w) * w2v.w;
        s += __shfl_xor(s, 1);
        s += __shfl_xor(s, 2);
        s += __shfl_xor(s, 4);
        s += __shfl_xor(s, 8);
        if (row0 + ty + 16 * i < nrows) tot += s;
    }
    if (tx == 0) red[ty] = tot;
    __syncthreads();
    if (tid == 0) {
        float p = 0.f;
#pragma unroll
        for (int i = 0; i < 16; ++i) p += red[i];
        partial[second ? (blockIdx.x - ATTN_GRID) : blockIdx.x] = p;
    }
}

__global__ void k_alpha(const float* __restrict__ P1, const float* __restrict__ P2,
                        float* __restrict__ alpha, int nparts, float invn) {
    __shared__ float s1[256], s2[256];
    int tid = threadIdx.x;
    float a = 0.f, b = 0.f;
    for (int i = tid; i < nparts; i += 256) { a += P1[i]; b += P2[i]; }
    s1[tid] = a; s2[tid] = b;
    __syncthreads();
    for (int off = 128; off > 0; off >>= 1) {
        if (tid < off) { s1[tid] += s1[tid + off]; s2[tid] += s2[tid + off]; }
        __syncthreads();
    }
    if (tid == 0) {
        float m1 = s1[0] * invn, m2 = s2[0] * invn;
        float mx = fmaxf(m1, m2);
        float e1 = expf(m1 - mx), e2 = expf(m2 - mx);
        float inv = 1.f / (e1 + e2);
        alpha[0] = e1 * inv; alpha[1] = e2 * inv;
    }
}

// ---------------- combine + column stats ----------------
template <bool COMBINE>
__global__ __launch_bounds__(256) void k_comb(float* __restrict__ X, const float* __restrict__ Y,
                                              const float* __restrict__ alpha, float* __restrict__ colsum,
                                              float* __restrict__ colsq, int nrows) {
    int tid = threadIdx.x;
    int h = tid & 127, half = tid >> 7;
    float a0 = 1.f, a1 = 0.f;
    if (COMBINE) { a0 = alpha[0]; a1 = alpha[1]; }
    float s = 0.f, q = 0.f;
    for (int n = blockIdx.x * 2 + half; n < nrows; n += gridDim.x * 2) {
        size_t off = (size_t)n * HH + h;
        float v = X[off];
        if (COMBINE) { v = a0 * v + a1 * Y[off]; X[off] = v; }
        s += v; q += v * v;
    }
    __shared__ float ls[256], lq[256];
    ls[tid] = s; lq[tid] = q;
    __syncthreads();
    if (half == 0) {
        atomicAdd(&colsum[h], ls[tid] + ls[tid + 128]);
        atomicAdd(&colsq[h], lq[tid] + lq[tid + 128]);
    }
}

__global__ void k_bnp(const float* __restrict__ sum, const float* __restrict__ sq,
                      const float* __restrict__ gamma, const float* __restrict__ beta,
                      float* __restrict__ scale, float* __restrict__ shift, float invn) {
    int h = threadIdx.x;
    float mu = sum[h] * invn;
    float var = sq[h] * invn - mu * mu;
    float sc = gamma[h] * rsqrtf(var + 1.0f);
    scale[h] = sc;
    shift[h] = beta[h] - mu * sc;
}

// BN apply + leaky, both buffers in one launch (blockIdx.y selects)
__global__ void k_bna(float* __restrict__ X0, float* __restrict__ X1,
                      const float* __restrict__ sc0, const float* __restrict__ sc1) {
    float* X = blockIdx.y ? X1 : X0;
    const float* scp = blockIdx.y ? sc1 : sc0;
    int i = blockIdx.x * 256 + threadIdx.x;
    float4 v = ((float4*)X)[i];
    int h0 = (i & 31) * 4;
    float4 sc = *(const float4*)&scp[h0];
    float4 sf = *(const float4*)&scp[128 + h0];
    v.x = v.x * sc.x + sf.x; v.y = v.y * sc.y + sf.y;
    v.z = v.z * sc.z + sf.z; v.w = v.w * sc.w + sf.w;
    v.x = v.x >= 0.f ? v.x : 0.01f * v.x;
    v.y = v.y >= 0.f ? v.y : 0.01f * v.y;
    v.z = v.z >= 0.f ? v.z : 0.01f * v.z;
    v.w = v.w >= 0.f ? v.w : 0.01f * v.w;
    ((float4*)X)[i] = v;
}

// ---------------- final FC: 64-row LDS tile, BN+leaky applied ONCE during staging ----------------
// Thread (c=tid&15, nl=tid>>4) accumulates rows {nl, nl+16, nl+32, nl+48}; per-h reads are
// LDS broadcasts (same addr across the 16 c-lanes). Stride 132 -> 2-way row aliasing (free).
__global__ __launch_bounds__(256) void k_fc(const float* __restrict__ X0, const float* __restrict__ X1,
                                            const float* __restrict__ sc0, const float* __restrict__ sc1,
                                            const float* __restrict__ Wall, const float* __restrict__ ball,
                                            float* __restrict__ out, int nrows) {
    __shared__ float Xl[64 * 132];   // 33 KB
    __shared__ float Wl[HH * CC];    // 8 KB
    __shared__ float bl[CC];
    __shared__ float scl[HH], sfl[HH];
    int which = blockIdx.y;
    const float* X = which ? X1 : X0;
    const float* scp = which ? sc1 : sc0;
    const float* W = Wall + which * HH * CC;
    float* o = out + (size_t)which * NN * CC;
    int tid = threadIdx.x;
    int row0 = blockIdx.x * 64;
    for (int i = tid * 4; i < HH * CC; i += 1024)
        *(float4*)&Wl[i] = *(const float4*)&W[i];
    if (tid < CC) bl[tid] = ball[which * CC + tid];
    if (tid < HH) { scl[tid] = scp[tid]; sfl[tid] = scp[128 + tid]; }
    __syncthreads();
    // stage 64 rows, applying BN+leaky exactly once per element
    for (int idx = tid; idx < 2048; idx += 256) {
        int r = idx >> 5, cc = idx & 31;
        int n = row0 + r;
        float4 v = make_float4(0.f, 0.f, 0.f, 0.f);
        if (n < nrows) v = *(const float4*)&X[(size_t)n * HH + cc * 4];
        float4 sc = *(const float4*)&scl[cc * 4];
        float4 sf = *(const float4*)&sfl[cc * 4];
        v.x = v.x * sc.x + sf.x; v.y = v.y * sc.y + sf.y;
        v.z = v.z * sc.z + sf.z; v.w = v.w * sc.w + sf.w;
        v.x = v.x >= 0.f ? v.x : 0.01f * v.x;
        v.y = v.y >= 0.f ? v.y : 0.01f * v.y;
        v.z = v.z >= 0.f ? v.z : 0.01f * v.z;
        v.w = v.w >= 0.f ? v.w : 0.01f * v.w;
        *(float4*)&Xl[r * 132 + cc * 4] = v;
    }
    __syncthreads();
    int c = tid & 15, nl = tid >> 4;
    const float* x0 = &Xl[(nl + 0) * 132];
    const float* x1 = &Xl[(nl + 16) * 132];
    const float* x2 = &Xl[(nl + 32) * 132];
    const float* x3 = &Xl[(nl + 48) * 132];
    float a0 = bl[c], a1 = a0, a2 = a0, a3 = a0;
#pragma unroll 8
    for (int h = 0; h < HH; ++h) {
        float w = Wl[h * CC + c];
        a0 += x0[h] * w;
        a1 += x1[h] * w;
        a2 += x2[h] * w;
        a3 += x3[h] * w;
    }
    int n0 = row0 + nl;
    if (n0 < nrows) o[(size_t)n0 * CC + c] = a0;
    if (n0 + 16 < nrows) o[(size_t)(n0 + 16) * CC + c] = a1;
    if (n0 + 32 < nrows) o[(size_t)(n0 + 32) * CC + c] = a2;
    if (n0 + 48 < nrows) o[(size_t)(n0 + 48) * CC + c] = a3;
}

extern "C" void kernel_launch(void* const* d_in, const int* in_sizes, int n_in,
                              void* d_out, int out_size, void* d_ws, size_t ws_size,
                              hipStream_t stream) {
    const float* xA = (const float*)d_in[0];
    const float* xB = (const float*)d_in[1];
    const float* Wsrc = (const float*)d_in[2];
    const float* bsrc = (const float*)d_in[3];
    const float* Wdst = (const float*)d_in[4];
    const float* bdst = (const float*)d_in[5];
    const float* Wupd = (const float*)d_in[6];
    const float* bupd = (const float*)d_in[7];
    const float* attnW1 = (const float*)d_in[8];
    const float* attnb1 = (const float*)d_in[9];
    const float* attnw2 = (const float*)d_in[10];
    const float* gamma = (const float*)d_in[11];
    const float* beta = (const float*)d_in[12];
    const float* fcW = (const float*)d_in[13];
    const float* fcb = (const float*)d_in[14];
    const int* eAB = (const int*)d_in[15];
    const int* eBB = (const int*)d_in[16];
    const int* eBA = (const int*)d_in[17];
    float* out = (float*)d_out;

    // workspace layout == round-6/8 passing footprint (~216 MB)
    float* ws = (float*)d_ws;
    const size_t NH = (size_t)NN * HH;
    const size_t LRHH = (size_t)LL * RR * HH * HH;
    float* B0 = ws;
    float* B1 = B0 + NH;
    float* B2 = B1 + NH;
    float* B3 = B2 + NH;
    u16* uWdh = (u16*)(B3 + NH);
    u16* uWdl = uWdh + LRHH;
    u16* uWsh = uWdl + LRHH;
    u16* uWsl = uWsh + LRHH;
    float* fB = (float*)(uWsl + LRHH);
    float* csA = fB + LL * RR * HH;
    float* csB = csA + 256;
    float* scA = csB + 256;
    float* scB = scA + 256;
    float* P1 = scB + 256;
    float* P2 = P1 + 1024;
    float* alp = P2 + 1024;
    int* icnt = (int*)(alp + 64);
    int* irs = icnt + 3 * NN;
    int* icsr = irs + 3 * NN;
    int* ifill = icsr + 3 * EE;     // unused now (kept for layout stability)
    int* ibsum = ifill + 3 * NN;
    int* pose = (int*)B3;           // 3*EE ints = 7.2MB; B3 unused until layer 1
    const float invN = 1.0f / (float)NN;

    k_fuse_w<<<LL * RR * HH, 256, 0, stream>>>(Wsrc, Wdst, Wupd, uWdh, uWdl, uWsh, uWsl);
    k_fuse_b<<<LL * RR, HH, 0, stream>>>(bsrc, bdst, bupd, Wupd, fB);

    // CSR build: all 3 relations per kernel; k_count returns per-edge slot -> k_fill atomic-free
    hipMemsetAsync(icnt, 0, 3 * NN * 4, stream);
    k_count<<<dim3((EE + 255) / 256, 3), 256, 0, stream>>>(eAB, eBB, eBA, icnt, pose);
    k_scan1<<<dim3(SCAN_B, 3), 256, 0, stream>>>(icnt, irs, ibsum);
    k_scan2<<<3, 128, 0, stream>>>(ibsum);
    k_scan3<<<dim3((NN + 255) / 256, 3), 256, 0, stream>>>(irs, ibsum);
    k_fill<<<dim3((EE + 255) / 256, 3), 256, 0, stream>>>(eAB, eBB, eBA, pose, irs, icsr);

    const int GEMM_GRID = (NN + 127) / 128;
    const int AGGR_GRID = (NN + 3) / 4;

    // dest serves as packed X1 during aggr+cgemm, then holds f32 Y (in-place)
    auto conv = [&](float* dest, const float* xs, const float* xd, int rel, int lr) {
        k_aggr<<<AGGR_GRID, 256, 0, stream>>>((u16*)dest, xs, irs + rel * NN, icnt + rel * NN,
                                              icsr + (size_t)rel * EE);
        k_cgemm<<<GEMM_GRID, 256, 0, stream>>>(dest, (const u16*)dest, xd,
                                               uWsh + (size_t)lr * HH * HH, uWsl + (size_t)lr * HH * HH,
                                               uWdh + (size_t)lr * HH * HH, uWdl + (size_t)lr * HH * HH,
                                               fB + lr * HH, NN);
    };

    // ================= layer 0 =================
    conv(B0, xA, xB, 0, 0);  // embB1
    conv(B1, xB, xB, 1, 1);  // embB2
    conv(B2, xB, xA, 2, 2);  // embA
    k_attn<<<2 * ATTN_GRID, 256, 0, stream>>>(B0, B1, attnW1, attnb1, attnw2, P1, P2, NN);
    k_alpha<<<1, 256, 0, stream>>>(P1, P2, alp, ATTN_GRID, invN);
    hipMemsetAsync(csB, 0, 256 * 4, stream);
    k_comb<true><<<512, 256, 0, stream>>>(B0, B1, alp, csB, csB + 128, NN);
    hipMemsetAsync(csA, 0, 256 * 4, stream);
    k_comb<false><<<512, 256, 0, stream>>>(B2, nullptr, nullptr, csA, csA + 128, NN);
    k_bnp<<<1, 128, 0, stream>>>(csA, csA + 128, gamma + 0 * HH, beta + 0 * HH, scA, scA + 128, invN);
    k_bnp<<<1, 128, 0, stream>>>(csB, csB + 128, gamma + 1 * HH, beta + 1 * HH, scB, scB + 128, invN);
    k_bna<<<dim3((int)(NH / 4 / 256), 2), 256, 0, stream>>>(B2, B0, scA, scB);  // xA=B2, xB=B0

    // ================= layer 1 =================
    conv(B1, B2, B0, 0, 3);  // embB1'
    conv(B3, B0, B0, 1, 4);  // embB2' (B3: pose no longer needed)
    k_attn<<<2 * ATTN_GRID, 256, 0, stream>>>(B1, B3, attnW1 + HH * AAA, attnb1 + AAA,
                                              attnw2 + AAA, P1, P2, NN);
    k_alpha<<<1, 256, 0, stream>>>(P1, P2, alp, ATTN_GRID, invN);
    hipMemsetAsync(csB, 0, 256 * 4, stream);
    k_comb<true><<<512, 256, 0, stream>>>(B1, B3, alp, csB, csB + 128, NN);  // xB_new -> B1
    conv(B3, B0, B2, 2, 5);  // embA'
    hipMemsetAsync(csA, 0, 256 * 4, stream);
    k_comb<false><<<512, 256, 0, stream>>>(B3, nullptr, nullptr, csA, csA + 128, NN);
    k_bnp<<<1, 128, 0, stream>>>(csA, csA + 128, gamma + 2 * HH, beta + 2 * HH, scA, scA + 128, invN);
    k_bnp<<<1, 128, 0, stream>>>(csB, csB + 128, gamma + 3 * HH, beta + 3 * HH, scB, scB + 128, invN);

    // ================= head: BN+leaky fused into FC staging =================
    k_fc<<<dim3((NN + 63) / 64, 2), 256, 0, stream>>>(B3, B1, scA, scB, fcW, fcb, out, NN);
}

// Round 12
// 1092.594 us; speedup vs baseline: 2.3445x; 1.0650x over previous
//
#include <hip/hip_runtime.h>

#define NN 100000
#define HH 128
#define EE 600000
#define LL 2
#define RR 3
#define AAA 64
#define CC 16
#define SCAN_B 98   // 98 blocks x 1024 elems covers 100000
#define ATTN_GRID ((NN + 127) / 128)

typedef unsigned short u16;
typedef unsigned int u32;
typedef __attribute__((ext_vector_type(8))) short bf16x8;
typedef __attribute__((ext_vector_type(4))) float f32x4;

__device__ inline u16 f2bf(float f) {   // RNE f32 -> bf16
    unsigned int u = __float_as_uint(f);
    return (u16)((u + 0x7FFF + ((u >> 16) & 1)) >> 16);
}
__device__ inline float bf2f(u16 h) { return __uint_as_float((unsigned int)h << 16); }

// Packed X layout (per row: 512B, 4 chunks of 128B; chunk = 4 groups of [16B hi][16B lo],
// XOR-swizzled by row). Shared by producer (k_aggr / cgemm phase-2 staging) and consumer
// (cgemm frag reads). row0 % 128 == 0 so block-local r has same r&7 as global row.
__device__ __forceinline__ int hi_off(int gi, int r) { return (gi * 32) ^ ((r & 7) << 4); }
__device__ __forceinline__ int lo_off(int gi, int r) { return (gi * 32 + 16) ^ ((r & 7) << 4); }

// async global->LDS, 16B per lane; dest must be linear (wave-uniform base + lane*16)
__device__ __forceinline__ void stage16(const void* g, void* l) {
    __builtin_amdgcn_global_load_lds((const __attribute__((address_space(1))) unsigned int*)g,
                                     (__attribute__((address_space(3))) unsigned int*)l, 16, 0, 0);
}

// ---------------- weight fusion: W transposed [n][k], split bf16 hi/lo ----------------
__global__ void k_fuse_w(const float* __restrict__ Wsrc, const float* __restrict__ Wdst,
                         const float* __restrict__ Wupd, u16* __restrict__ Wdt_hi,
                         u16* __restrict__ Wdt_lo, u16* __restrict__ Wst_hi,
                         u16* __restrict__ Wst_lo) {
    int b = blockIdx.x;
    int lr = b >> 7, i = b & 127;   // i = k index
    int t = threadIdx.x;
    int j = t & 127;                // j = n index
    const float* wu = Wupd + (size_t)lr * 2 * HH * HH;
    float acc = 0.f;
    size_t o = ((size_t)lr * HH + j) * HH + i;  // transposed store [n=j][k=i]
    if (t < 128) {
        const float* wd = Wdst + ((size_t)lr * HH + i) * HH;
        for (int k = 0; k < HH; ++k) acc += wd[k] * wu[k * HH + j];
        u16 h = f2bf(acc);
        Wdt_hi[o] = h;
        Wdt_lo[o] = f2bf(acc - bf2f(h));
    } else {
        const float* wsc = Wsrc + ((size_t)lr * HH + i) * HH;
        for (int k = 0; k < HH; ++k) acc += wsc[k] * wu[(HH + k) * HH + j];
        u16 h = f2bf(acc);
        Wst_hi[o] = h;
        Wst_lo[o] = f2bf(acc - bf2f(h));
    }
}

__global__ void k_fuse_b(const float* __restrict__ bsrc, const float* __restrict__ bdst,
                         const float* __restrict__ bupd, const float* __restrict__ Wupd,
                         float* __restrict__ fB) {
    int lr = blockIdx.x;
    int j = threadIdx.x;
    const float* wu = Wupd + (size_t)lr * 2 * HH * HH;
    const float* bd = bdst + lr * HH;
    const float* bs = bsrc + lr * HH;
    float acc = bupd[lr * HH + j];
    for (int k = 0; k < HH; ++k)
        acc += bd[k] * wu[k * HH + j] + bs[k] * wu[(HH + k) * HH + j];
    fB[lr * HH + j] = acc;
}

// attnW1 [L][H][A] -> transposed [L][A][H] bf16 hi/lo (for MFMA B-frags)
__global__ void k_fuse_a(const float* __restrict__ W1, u16* __restrict__ Ah,
                         u16* __restrict__ Al) {
    int b = blockIdx.x;            // l*AAA + a
    int l = b >> 6, a = b & 63;
    int k = threadIdx.x;           // 128 threads
    float v = W1[((size_t)l * HH + k) * AAA + a];
    u16 h = f2bf(v);
    size_t o = (size_t)b * HH + k;
    Ah[o] = h;
    Al[o] = f2bf(v - bf2f(h));
}

// ---------------- CSR build: batched over 3 relations; count stores per-edge slot ----------------
__global__ void k_count(const int* __restrict__ e0, const int* __restrict__ e1,
                        const int* __restrict__ e2, int* __restrict__ cnt,
                        int* __restrict__ pose) {
    int rel = blockIdx.y;
    const int* d = (rel == 0 ? e0 : rel == 1 ? e1 : e2) + EE;
    int i = blockIdx.x * 256 + threadIdx.x;
    if (i < EE) pose[rel * EE + i] = atomicAdd(&cnt[rel * NN + d[i]], 1);
}

__global__ void k_scan1(const int* __restrict__ cnt_all, int* __restrict__ rs_all,
                        int* __restrict__ bsum) {
    __shared__ int sd[256];
    int rel = blockIdx.y;
    const int* cnt = cnt_all + rel * NN;
    int* rs = rs_all + rel * NN;
    int blk = blockIdx.x, tid = threadIdx.x;
    int base = blk * 1024 + tid * 4;
    int c0 = 0, c1 = 0, c2 = 0, c3 = 0;
    if (base + 0 < NN) c0 = cnt[base + 0];
    if (base + 1 < NN) c1 = cnt[base + 1];
    if (base + 2 < NN) c2 = cnt[base + 2];
    if (base + 3 < NN) c3 = cnt[base + 3];
    int s = c0 + c1 + c2 + c3;
    sd[tid] = s;
    __syncthreads();
    for (int off = 1; off < 256; off <<= 1) {
        int v = (tid >= off) ? sd[tid - off] : 0;
        __syncthreads();
        sd[tid] += v;
        __syncthreads();
    }
    int excl = sd[tid] - s;
    if (tid == 255) bsum[rel * 128 + blk] = sd[255];
    if (base + 0 < NN) rs[base + 0] = excl;
    if (base + 1 < NN) rs[base + 1] = excl + c0;
    if (base + 2 < NN) rs[base + 2] = excl + c0 + c1;
    if (base + 3 < NN) rs[base + 3] = excl + c0 + c1 + c2;
}

__global__ void k_scan2(int* __restrict__ bsum) {  // grid = 3, 128 threads
    __shared__ int sd[128];
    int rel = blockIdx.x;
    int tid = threadIdx.x;
    int v = (tid < SCAN_B) ? bsum[rel * 128 + tid] : 0;
    sd[tid] = v;
    __syncthreads();
    for (int off = 1; off < 128; off <<= 1) {
        int u = (tid >= off) ? sd[tid - off] : 0;
        __syncthreads();
        sd[tid] += u;
        __syncthreads();
    }
    if (tid < SCAN_B) bsum[rel * 128 + tid] = sd[tid] - v;  // exclusive
}

__global__ void k_scan3(int* __restrict__ rs_all, const int* __restrict__ bsum) {
    int rel = blockIdx.y;
    int i = blockIdx.x * 256 + threadIdx.x;
    if (i < NN) rs_all[rel * NN + i] += bsum[rel * 128 + (i >> 10)];
}

// atomic-free scatter: slot precomputed by k_count
__global__ void k_fill(const int* __restrict__ e0, const int* __restrict__ e1,
                       const int* __restrict__ e2, const int* __restrict__ pose,
                       const int* __restrict__ rs_all, int* __restrict__ csr_all) {
    int rel = blockIdx.y;
    const int* e = rel == 0 ? e0 : rel == 1 ? e1 : e2;
    int i = blockIdx.x * 256 + threadIdx.x;
    if (i >= EE) return;
    int s = e[i], d = e[EE + i];
    csr_all[(size_t)rel * EE + rs_all[rel * NN + d] + pose[rel * EE + i]] = s;
}

// ---------------- aggregation: one wave per dst node, 4-edge batched gather ----------------
__global__ __launch_bounds__(256) void k_aggr(u16* __restrict__ Xp, const float* __restrict__ xs,
                                              const int* __restrict__ rs, const int* __restrict__ cnt,
                                              const int* __restrict__ csr) {
    int node = blockIdx.x * 4 + (threadIdx.x >> 6);
    if (node >= NN) return;
    int lane = threadIdx.x & 63;
    int beg = rs[node], deg = cnt[node];
    const float2* xs2 = (const float2*)xs;
    float ax = 0.f, ay = 0.f;
    int j = 0;
    for (; j + 4 <= deg; j += 4) {
        int s0 = csr[beg + j], s1 = csr[beg + j + 1];
        int s2 = csr[beg + j + 2], s3 = csr[beg + j + 3];
        float2 v0 = xs2[(size_t)s0 * 64 + lane];
        float2 v1 = xs2[(size_t)s1 * 64 + lane];
        float2 v2 = xs2[(size_t)s2 * 64 + lane];
        float2 v3 = xs2[(size_t)s3 * 64 + lane];
        ax += (v0.x + v1.x) + (v2.x + v3.x);
        ay += (v0.y + v1.y) + (v2.y + v3.y);
    }
    if (j + 2 <= deg) {
        int s0 = csr[beg + j], s1 = csr[beg + j + 1];
        float2 v0 = xs2[(size_t)s0 * 64 + lane];
        float2 v1 = xs2[(size_t)s1 * 64 + lane];
        ax += v0.x + v1.x;
        ay += v0.y + v1.y;
        j += 2;
    }
    if (j < deg) {
        float2 v = xs2[(size_t)csr[beg + j] * 64 + lane];
        ax += v.x;
        ay += v.y;
    }
    float sc = 1.0f / fmaxf((float)deg, 1.0f);
    float vx = ax * sc, vy = ay * sc;
    u16 hx = f2bf(vx), hy = f2bf(vy);
    u16 lx = f2bf(vx - bf2f(hx)), ly = f2bf(vy - bf2f(hy));
    int g = lane >> 2;
    char* base = (char*)Xp + (size_t)node * 512 + (g >> 2) * 128;
    int jb = (lane & 3) * 4;
    __builtin_nontemporal_store(((u32)hy << 16) | hx, (u32*)(base + hi_off(g & 3, node) + jb));
    __builtin_nontemporal_store(((u32)ly << 16) | lx, (u32*)(base + lo_off(g & 3, node) + jb));
}

// ---------------- fused conv GEMM: Y = X1@W1 + X2@W2 + bias, bf16x3 MFMA ----------------
__global__ __launch_bounds__(256) void k_cgemm(float* Y, const u16* X1p,
                                               const float* __restrict__ X2,
                                               const u16* __restrict__ W1h, const u16* __restrict__ W1l,
                                               const u16* __restrict__ W2h, const u16* __restrict__ W2l,
                                               const float* __restrict__ bias, int nrows) {
    __shared__ __attribute__((aligned(16))) char Xt[16384];  // [128 rows][128B chunk]
    int tid = threadIdx.x;
    int row0 = blockIdx.x * 128;
    int lane = tid & 63, wv = tid >> 6;
    int l15 = lane & 15, lg = lane >> 4;
    bool full = (row0 + 128 <= nrows);

    f32x4 acc[8][2];
#pragma unroll
    for (int i = 0; i < 8; ++i)
#pragma unroll
        for (int j = 0; j < 2; ++j) acc[i][j] = (f32x4)(0.f);

    for (int ph = 0; ph < 2; ++ph) {
        const u16* Wh = ph ? W2h : W1h;
        const u16* Wl = ph ? W2l : W1l;
        for (int kc = 0; kc < HH; kc += 32) {
            __syncthreads();  // previous chunk fully consumed before overwrite
            if (ph == 0) {
#pragma unroll
                for (int p = 0; p < 4; ++p) {
                    int tb = p * 4096 + tid * 16;
                    int r = tb >> 7, off = tb & 127;
                    stage16((const char*)X1p + (size_t)(row0 + r) * 512 + (kc >> 5) * 128 + off,
                            Xt + tb);
                }
            } else {
#pragma unroll
                for (int it = 0; it < 2; ++it) {
                    int g2 = tid + it * 256;
                    int r = g2 >> 2, gi = g2 & 3;
                    float4 a = make_float4(0.f, 0.f, 0.f, 0.f), b = a;
                    if (full || row0 + r < nrows) {
                        const float* xp = &X2[(size_t)(row0 + r) * HH + kc + gi * 8];
                        a = *(const float4*)xp;
                        b = *(const float4*)(xp + 4);
                    }
                    u16 h0 = f2bf(a.x), h1 = f2bf(a.y), h2 = f2bf(a.z), h3 = f2bf(a.w);
                    u16 h4 = f2bf(b.x), h5 = f2bf(b.y), h6 = f2bf(b.z), h7 = f2bf(b.w);
                    bf16x8 hv = {(short)h0, (short)h1, (short)h2, (short)h3,
                                 (short)h4, (short)h5, (short)h6, (short)h7};
                    bf16x8 lv = {(short)f2bf(a.x - bf2f(h0)), (short)f2bf(a.y - bf2f(h1)),
                                 (short)f2bf(a.z - bf2f(h2)), (short)f2bf(a.w - bf2f(h3)),
                                 (short)f2bf(b.x - bf2f(h4)), (short)f2bf(b.y - bf2f(h5)),
                                 (short)f2bf(b.z - bf2f(h6)), (short)f2bf(b.w - bf2f(h7))};
                    char* rb = Xt + r * 128;
                    *(bf16x8*)(rb + hi_off(gi, r)) = hv;
                    *(bf16x8*)(rb + lo_off(gi, r)) = lv;
                }
            }
            bf16x8 bh[2], bl[2];
#pragma unroll
            for (int nt = 0; nt < 2; ++nt) {
                int n = (wv * 2 + nt) * 16 + l15;
                bh[nt] = *(const bf16x8*)&Wh[(size_t)n * HH + kc + lg * 8];
                bl[nt] = *(const bf16x8*)&Wl[(size_t)n * HH + kc + lg * 8];
            }
            __syncthreads();  // drains DMA vmcnt + lds writes
#pragma unroll
            for (int mt = 0; mt < 8; ++mt) {
                int r = mt * 16 + l15;
                const char* rb = Xt + r * 128;
                bf16x8 ah = *(const bf16x8*)(rb + hi_off(lg, r));
                bf16x8 al = *(const bf16x8*)(rb + lo_off(lg, r));
#pragma unroll
                for (int nt = 0; nt < 2; ++nt) {
                    acc[mt][nt] = __builtin_amdgcn_mfma_f32_16x16x32_bf16(ah, bh[nt], acc[mt][nt], 0, 0, 0);
                    acc[mt][nt] = __builtin_amdgcn_mfma_f32_16x16x32_bf16(ah, bl[nt], acc[mt][nt], 0, 0, 0);
                    acc[mt][nt] = __builtin_amdgcn_mfma_f32_16x16x32_bf16(al, bh[nt], acc[mt][nt], 0, 0, 0);
                }
            }
        }
    }
#pragma unroll
    for (int mt = 0; mt < 8; ++mt)
#pragma unroll
        for (int nt = 0; nt < 2; ++nt) {
            int ncol = (wv * 2 + nt) * 16 + l15;
            float bv = bias[ncol];
#pragma unroll
            for (int j = 0; j < 4; ++j) {
                int r = row0 + mt * 16 + lg * 4 + j;
                if (r < nrows) Y[(size_t)r * HH + ncol] = acc[mt][nt][j] + bv;
            }
        }
}

// ---------------- attention score: bf16x3 MFMA S = X@W1, tanh, dot w2, block-sum ----------------
// Same staging machinery as cgemm phase-2; W1 transposed/split read direct from global.
// Wave wv owns n-tile wv (cols 16wv..16wv+15); acc[8] covers 128 rows x 16 cols.
__global__ __launch_bounds__(256) void k_attn(const float* __restrict__ XA, const float* __restrict__ XB,
                                              const u16* __restrict__ Ah, const u16* __restrict__ Al,
                                              const float* __restrict__ b1, const float* __restrict__ w2,
                                              float* __restrict__ PA, float* __restrict__ PB, int nrows) {
    __shared__ __attribute__((aligned(16))) char Xt[16384];
    __shared__ float red[4];
    int tid = threadIdx.x;
    bool second = blockIdx.x >= ATTN_GRID;
    const float* X = second ? XB : XA;
    float* partial = second ? PB : PA;
    int row0 = (second ? blockIdx.x - ATTN_GRID : blockIdx.x) * 128;
    int lane = tid & 63, wv = tid >> 6;
    int l15 = lane & 15, lg = lane >> 4;
    bool full = (row0 + 128 <= nrows);

    f32x4 acc[8];
#pragma unroll
    for (int i = 0; i < 8; ++i) acc[i] = (f32x4)(0.f);

    for (int kc = 0; kc < HH; kc += 32) {
        __syncthreads();
#pragma unroll
        for (int it = 0; it < 2; ++it) {
            int g2 = tid + it * 256;
            int r = g2 >> 2, gi = g2 & 3;
            float4 a = make_float4(0.f, 0.f, 0.f, 0.f), b = a;
            if (full || row0 + r < nrows) {
                const float* xp = &X[(size_t)(row0 + r) * HH + kc + gi * 8];
                a = *(const float4*)xp;
                b = *(const float4*)(xp + 4);
            }
            u16 h0 = f2bf(a.x), h1 = f2bf(a.y), h2 = f2bf(a.z), h3 = f2bf(a.w);
            u16 h4 = f2bf(b.x), h5 = f2bf(b.y), h6 = f2bf(b.z), h7 = f2bf(b.w);
            bf16x8 hv = {(short)h0, (short)h1, (short)h2, (short)h3,
                         (short)h4, (short)h5, (short)h6, (short)h7};
            bf16x8 lv = {(short)f2bf(a.x - bf2f(h0)), (short)f2bf(a.y - bf2f(h1)),
                         (short)f2bf(a.z - bf2f(h2)), (short)f2bf(a.w - bf2f(h3)),
                         (short)f2bf(b.x - bf2f(h4)), (short)f2bf(b.y - bf2f(h5)),
                         (short)f2bf(b.z - bf2f(h6)), (short)f2bf(b.w - bf2f(h7))};
            char* rb = Xt + r * 128;
            *(bf16x8*)(rb + hi_off(gi, r)) = hv;
            *(bf16x8*)(rb + lo_off(gi, r)) = lv;
        }
        // W1t frags: col a = wv*16 + l15, k-group lg (L2-resident, 16B each)
        int a = wv * 16 + l15;
        bf16x8 bh = *(const bf16x8*)&Ah[(size_t)a * HH + kc + lg * 8];
        bf16x8 bl = *(const bf16x8*)&Al[(size_t)a * HH + kc + lg * 8];
        __syncthreads();
#pragma unroll
        for (int mt = 0; mt < 8; ++mt) {
            int r = mt * 16 + l15;
            const char* rb = Xt + r * 128;
            bf16x8 ah = *(const bf16x8*)(rb + hi_off(lg, r));
            bf16x8 al = *(const bf16x8*)(rb + lo_off(lg, r));
            acc[mt] = __builtin_amdgcn_mfma_f32_16x16x32_bf16(ah, bh, acc[mt], 0, 0, 0);
            acc[mt] = __builtin_amdgcn_mfma_f32_16x16x32_bf16(ah, bl, acc[mt], 0, 0, 0);
            acc[mt] = __builtin_amdgcn_mfma_f32_16x16x32_bf16(al, bh, acc[mt], 0, 0, 0);
        }
    }
    // epilogue: C/D col=l15 (score col wv*16+l15), row=lg*4+j
    float b1v = b1[wv * 16 + l15];
    float w2v = w2[wv * 16 + l15];
    float tot = 0.f;
#pragma unroll
    for (int mt = 0; mt < 8; ++mt)
#pragma unroll
        for (int j = 0; j < 4; ++j) {
            int r = row0 + mt * 16 + lg * 4 + j;
            if (r < nrows) tot += tanhf(acc[mt][j] + b1v) * w2v;
        }
#pragma unroll
    for (int off = 32; off > 0; off >>= 1) tot += __shfl_xor(tot, off);
    if (lane == 0) red[wv] = tot;
    __syncthreads();
    if (tid == 0)
        partial[second ? (blockIdx.x - ATTN_GRID) : blockIdx.x] = red[0] + red[1] + red[2] + red[3];
}

__global__ void k_alpha(const float* __restrict__ P1, const float* __restrict__ P2,
                        float* __restrict__ alpha, int nparts, float invn) {
    __shared__ float s1[256], s2[256];
    int tid = threadIdx.x;
    float a = 0.f, b = 0.f;
    for (int i = tid; i < nparts; i += 256) { a += P1[i]; b += P2[i]; }
    s1[tid] = a; s2[tid] = b;
    __syncthreads();
    for (int off = 128; off > 0; off >>= 1) {
        if (tid < off) { s1[tid] += s1[tid + off]; s2[tid] += s2[tid + off]; }
        __syncthreads();
    }
    if (tid == 0) {
        float m1 = s1[0] * invn, m2 = s2[0] * invn;
        float mx = fmaxf(m1, m2);
        float e1 = expf(m1 - mx), e2 = expf(m2 - mx);
        float inv = 1.f / (e1 + e2);
        alpha[0] = e1 * inv; alpha[1] = e2 * inv;
    }
}

// ---------------- combine + column stats ----------------
template <bool COMBINE>
__global__ __launch_bounds__(256) void k_comb(float* __restrict__ X, const float* __restrict__ Y,
                                              const float* __restrict__ alpha, float* __restrict__ colsum,
                                              float* __restrict__ colsq, int nrows) {
    int tid = threadIdx.x;
    int h = tid & 127, half = tid >> 7;
    float a0 = 1.f, a1 = 0.f;
    if (COMBINE) { a0 = alpha[0]; a1 = alpha[1]; }
    float s = 0.f, q = 0.f;
    for (int n = blockIdx.x * 2 + half; n < nrows; n += gridDim.x * 2) {
        size_t off = (size_t)n * HH + h;
        float v = X[off];
        if (COMBINE) { v = a0 * v + a1 * Y[off]; X[off] = v; }
        s += v; q += v * v;
    }
    __shared__ float ls[256], lq[256];
    ls[tid] = s; lq[tid] = q;
    __syncthreads();
    if (half == 0) {
        atomicAdd(&colsum[h], ls[tid] + ls[tid + 128]);
        atomicAdd(&colsq[h], lq[tid] + lq[tid + 128]);
    }
}

__global__ void k_bnp(const float* __restrict__ sum, const float* __restrict__ sq,
                      const float* __restrict__ gamma, const float* __restrict__ beta,
                      float* __restrict__ scale, float* __restrict__ shift, float invn) {
    int h = threadIdx.x;
    float mu = sum[h] * invn;
    float var = sq[h] * invn - mu * mu;
    float sc = gamma[h] * rsqrtf(var + 1.0f);
    scale[h] = sc;
    shift[h] = beta[h] - mu * sc;
}

// BN apply + leaky, both buffers in one launch (blockIdx.y selects)
__global__ void k_bna(float* __restrict__ X0, float* __restrict__ X1,
                      const float* __restrict__ sc0, const float* __restrict__ sc1) {
    float* X = blockIdx.y ? X1 : X0;
    const float* scp = blockIdx.y ? sc1 : sc0;
    int i = blockIdx.x * 256 + threadIdx.x;
    float4 v = ((float4*)X)[i];
    int h0 = (i & 31) * 4;
    float4 sc = *(const float4*)&scp[h0];
    float4 sf = *(const float4*)&scp[128 + h0];
    v.x = v.x * sc.x + sf.x; v.y = v.y * sc.y + sf.y;
    v.z = v.z * sc.z + sf.z; v.w = v.w * sc.w + sf.w;
    v.x = v.x >= 0.f ? v.x : 0.01f * v.x;
    v.y = v.y >= 0.f ? v.y : 0.01f * v.y;
    v.z = v.z >= 0.f ? v.z : 0.01f * v.z;
    v.w = v.w >= 0.f ? v.w : 0.01f * v.w;
    ((float4*)X)[i] = v;
}

// ---------------- final FC: 64-row LDS tile, BN+leaky applied ONCE during staging ----------------
__global__ __launch_bounds__(256) void k_fc(const float* __restrict__ X0, const float* __restrict__ X1,
                                            const float* __restrict__ sc0, const float* __restrict__ sc1,
                                            const float* __restrict__ Wall, const float* __restrict__ ball,
                                            float* __restrict__ out, int nrows) {
    __shared__ float Xl[64 * 132];   // 33 KB
    __shared__ float Wl[HH * CC];    // 8 KB
    __shared__ float bl[CC];
    __shared__ float scl[HH], sfl[HH];
    int which = blockIdx.y;
    const float* X = which ? X1 : X0;
    const float* scp = which ? sc1 : sc0;
    const float* W = Wall + which * HH * CC;
    float* o = out + (size_t)which * NN * CC;
    int tid = threadIdx.x;
    int row0 = blockIdx.x * 64;
    for (int i = tid * 4; i < HH * CC; i += 1024)
        *(float4*)&Wl[i] = *(const float4*)&W[i];
    if (tid < CC) bl[tid] = ball[which * CC + tid];
    if (tid < HH) { scl[tid] = scp[tid]; sfl[tid] = scp[128 + tid]; }
    __syncthreads();
    for (int idx = tid; idx < 2048; idx += 256) {
        int r = idx >> 5, cc = idx & 31;
        int n = row0 + r;
        float4 v = make_float4(0.f, 0.f, 0.f, 0.f);
        if (n < nrows) v = *(const float4*)&X[(size_t)n * HH + cc * 4];
        float4 sc = *(const float4*)&scl[cc * 4];
        float4 sf = *(const float4*)&sfl[cc * 4];
        v.x = v.x * sc.x + sf.x; v.y = v.y * sc.y + sf.y;
        v.z = v.z * sc.z + sf.z; v.w = v.w * sc.w + sf.w;
        v.x = v.x >= 0.f ? v.x : 0.01f * v.x;
        v.y = v.y >= 0.f ? v.y : 0.01f * v.y;
        v.z = v.z >= 0.f ? v.z : 0.01f * v.z;
        v.w = v.w >= 0.f ? v.w : 0.01f * v.w;
        *(float4*)&Xl[r * 132 + cc * 4] = v;
    }
    __syncthreads();
    int c = tid & 15, nl = tid >> 4;
    const float* x0 = &Xl[(nl + 0) * 132];
    const float* x1 = &Xl[(nl + 16) * 132];
    const float* x2 = &Xl[(nl + 32) * 132];
    const float* x3 = &Xl[(nl + 48) * 132];
    float a0 = bl[c], a1 = a0, a2 = a0, a3 = a0;
#pragma unroll 8
    for (int h = 0; h < HH; ++h) {
        float w = Wl[h * CC + c];
        a0 += x0[h] * w;
        a1 += x1[h] * w;
        a2 += x2[h] * w;
        a3 += x3[h] * w;
    }
    int n0 = row0 + nl;
    if (n0 < nrows) o[(size_t)n0 * CC + c] = a0;
    if (n0 + 16 < nrows) o[(size_t)(n0 + 16) * CC + c] = a1;
    if (n0 + 32 < nrows) o[(size_t)(n0 + 32) * CC + c] = a2;
    if (n0 + 48 < nrows) o[(size_t)(n0 + 48) * CC + c] = a3;
}

extern "C" void kernel_launch(void* const* d_in, const int* in_sizes, int n_in,
                              void* d_out, int out_size, void* d_ws, size_t ws_size,
                              hipStream_t stream) {
    const float* xA = (const float*)d_in[0];
    const float* xB = (const float*)d_in[1];
    const float* Wsrc = (const float*)d_in[2];
    const float* bsrc = (const float*)d_in[3];
    const float* Wdst = (const float*)d_in[4];
    const float* bdst = (const float*)d_in[5];
    const float* Wupd = (const float*)d_in[6];
    const float* bupd = (const float*)d_in[7];
    const float* attnW1 = (const float*)d_in[8];
    const float* attnb1 = (const float*)d_in[9];
    const float* attnw2 = (const float*)d_in[10];
    const float* gamma = (const float*)d_in[11];
    const float* beta = (const float*)d_in[12];
    const float* fcW = (const float*)d_in[13];
    const float* fcb = (const float*)d_in[14];
    const int* eAB = (const int*)d_in[15];
    const int* eBB = (const int*)d_in[16];
    const int* eBA = (const int*)d_in[17];
    float* out = (float*)d_out;

    // workspace layout == round-6/8 passing footprint (~216 MB) + 64KB attn weights
    float* ws = (float*)d_ws;
    const size_t NH = (size_t)NN * HH;
    const size_t LRHH = (size_t)LL * RR * HH * HH;
    const size_t LAH = (size_t)LL * AAA * HH;
    float* B0 = ws;
    float* B1 = B0 + NH;
    float* B2 = B1 + NH;
    float* B3 = B2 + NH;
    u16* uWdh = (u16*)(B3 + NH);
    u16* uWdl = uWdh + LRHH;
    u16* uWsh = uWdl + LRHH;
    u16* uWsl = uWsh + LRHH;
    u16* uA1h = uWsl + LRHH;        // L*AAA*HH
    u16* uA1l = uA1h + LAH;
    float* fB = (float*)(uA1l + LAH);
    float* csA = fB + LL * RR * HH;
    float* csB = csA + 256;
    float* scA = csB + 256;
    float* scB = scA + 256;
    float* P1 = scB + 256;
    float* P2 = P1 + 1024;
    float* alp = P2 + 1024;
    int* icnt = (int*)(alp + 64);
    int* irs = icnt + 3 * NN;
    int* icsr = irs + 3 * NN;
    int* ifill = icsr + 3 * EE;     // unused (layout stability)
    int* ibsum = ifill + 3 * NN;
    int* pose = (int*)B3;           // 3*EE ints; B3 unused until layer 1
    const float invN = 1.0f / (float)NN;

    k_fuse_w<<<LL * RR * HH, 256, 0, stream>>>(Wsrc, Wdst, Wupd, uWdh, uWdl, uWsh, uWsl);
    k_fuse_b<<<LL * RR, HH, 0, stream>>>(bsrc, bdst, bupd, Wupd, fB);
    k_fuse_a<<<LL * AAA, HH, 0, stream>>>(attnW1, uA1h, uA1l);

    // CSR build: all 3 relations per kernel; k_count returns per-edge slot -> k_fill atomic-free
    hipMemsetAsync(icnt, 0, 3 * NN * 4, stream);
    k_count<<<dim3((EE + 255) / 256, 3), 256, 0, stream>>>(eAB, eBB, eBA, icnt, pose);
    k_scan1<<<dim3(SCAN_B, 3), 256, 0, stream>>>(icnt, irs, ibsum);
    k_scan2<<<3, 128, 0, stream>>>(ibsum);
    k_scan3<<<dim3((NN + 255) / 256, 3), 256, 0, stream>>>(irs, ibsum);
    k_fill<<<dim3((EE + 255) / 256, 3), 256, 0, stream>>>(eAB, eBB, eBA, pose, irs, icsr);

    const int GEMM_GRID = (NN + 127) / 128;
    const int AGGR_GRID = (NN + 3) / 4;

    // dest serves as packed X1 during aggr+cgemm, then holds f32 Y (in-place)
    auto conv = [&](float* dest, const float* xs, const float* xd, int rel, int lr) {
        k_aggr<<<AGGR_GRID, 256, 0, stream>>>((u16*)dest, xs, irs + rel * NN, icnt + rel * NN,
                                              icsr + (size_t)rel * EE);
        k_cgemm<<<GEMM_GRID, 256, 0, stream>>>(dest, (const u16*)dest, xd,
                                               uWsh + (size_t)lr * HH * HH, uWsl + (size_t)lr * HH * HH,
                                               uWdh + (size_t)lr * HH * HH, uWdl + (size_t)lr * HH * HH,
                                               fB + lr * HH, NN);
    };

    // ================= layer 0 =================
    conv(B0, xA, xB, 0, 0);  // embB1
    conv(B1, xB, xB, 1, 1);  // embB2
    conv(B2, xB, xA, 2, 2);  // embA
    k_attn<<<2 * ATTN_GRID, 256, 0, stream>>>(B0, B1, uA1h, uA1l, attnb1, attnw2, P1, P2, NN);
    k_alpha<<<1, 256, 0, stream>>>(P1, P2, alp, ATTN_GRID, invN);
    hipMemsetAsync(csB, 0, 256 * 4, stream);
    k_comb<true><<<512, 256, 0, stream>>>(B0, B1, alp, csB, csB + 128, NN);
    hipMemsetAsync(csA, 0, 256 * 4, stream);
    k_comb<false><<<512, 256, 0, stream>>>(B2, nullptr, nullptr, csA, csA + 128, NN);
    k_bnp<<<1, 128, 0, stream>>>(csA, csA + 128, gamma + 0 * HH, beta + 0 * HH, scA, scA + 128, invN);
    k_bnp<<<1, 128, 0, stream>>>(csB, csB + 128, gamma + 1 * HH, beta + 1 * HH, scB, scB + 128, invN);
    k_bna<<<dim3((int)(NH / 4 / 256), 2), 256, 0, stream>>>(B2, B0, scA, scB);  // xA=B2, xB=B0

    // ================= layer 1 =================
    conv(B1, B2, B0, 0, 3);  // embB1'
    conv(B3, B0, B0, 1, 4);  // embB2' (B3: pose no longer needed)
    k_attn<<<2 * ATTN_GRID, 256, 0, stream>>>(B1, B3, uA1h + LAH / 2 * 0 + (size_t)1 * AAA * HH,
                                              uA1l + (size_t)1 * AAA * HH,
                                              attnb1 + AAA, attnw2 + AAA, P1, P2, NN);
    k_alpha<<<1, 256, 0, stream>>>(P1, P2, alp, ATTN_GRID, invN);
    hipMemsetAsync(csB, 0, 256 * 4, stream);
    k_comb<true><<<512, 256, 0, stream>>>(B1, B3, alp, csB, csB + 128, NN);  // xB_new -> B1
    conv(B3, B0, B2, 2, 5);  // embA'
    hipMemsetAsync(csA, 0, 256 * 4, stream);
    k_comb<false><<<512, 256, 0, stream>>>(B3, nullptr, nullptr, csA, csA + 128, NN);
    k_bnp<<<1, 128, 0, stream>>>(csA, csA + 128, gamma + 2 * HH, beta + 2 * HH, scA, scA + 128, invN);
    k_bnp<<<1, 128, 0, stream>>>(csB, csB + 128, gamma + 3 * HH, beta + 3 * HH, scB, scB + 128, invN);

    // ================= head: BN+leaky fused into FC staging =================
    k_fc<<<dim3((NN + 63) / 64, 2), 256, 0, stream>>>(B3, B1, scA, scB, fcW, fcb, out, NN);
}

// Round 13
// 1057.064 us; speedup vs baseline: 2.4233x; 1.0336x over previous
//
#include <hip/hip_runtime.h>

#define NN 100000
#define HH 128
#define EE 600000
#define LL 2
#define RR 3
#define AAA 64
#define CC 16
#define SCAN_B 98   // 98 blocks x 1024 elems covers 100000
#define ATTN_GRID ((NN + 127) / 128)

typedef unsigned short u16;
typedef unsigned int u32;
typedef __attribute__((ext_vector_type(8))) short bf16x8;
typedef __attribute__((ext_vector_type(4))) float f32x4;

__device__ inline u16 f2bf(float f) {   // RNE f32 -> bf16
    unsigned int u = __float_as_uint(f);
    return (u16)((u + 0x7FFF + ((u >> 16) & 1)) >> 16);
}
__device__ inline float bf2f(u16 h) { return __uint_as_float((unsigned int)h << 16); }

// Packed X layout (per row: 512B, 4 chunks of 128B; chunk = 4 groups of [16B hi][16B lo],
// XOR-swizzled by row). Shared by producer (k_aggr / cgemm phase-2 staging) and consumer
// (cgemm frag reads). row0 % 128 == 0 so block-local r has same r&7 as global row.
__device__ __forceinline__ int hi_off(int gi, int r) { return (gi * 32) ^ ((r & 7) << 4); }
__device__ __forceinline__ int lo_off(int gi, int r) { return (gi * 32 + 16) ^ ((r & 7) << 4); }

// async global->LDS, 16B per lane; dest must be linear (wave-uniform base + lane*16)
__device__ __forceinline__ void stage16(const void* g, void* l) {
    __builtin_amdgcn_global_load_lds((const __attribute__((address_space(1))) unsigned int*)g,
                                     (__attribute__((address_space(3))) unsigned int*)l, 16, 0, 0);
}

// ---------------- weight fusion: W transposed [n][k], split bf16 hi/lo ----------------
__global__ void k_fuse_w(const float* __restrict__ Wsrc, const float* __restrict__ Wdst,
                         const float* __restrict__ Wupd, u16* __restrict__ Wdt_hi,
                         u16* __restrict__ Wdt_lo, u16* __restrict__ Wst_hi,
                         u16* __restrict__ Wst_lo) {
    int b = blockIdx.x;
    int lr = b >> 7, i = b & 127;   // i = k index
    int t = threadIdx.x;
    int j = t & 127;                // j = n index
    const float* wu = Wupd + (size_t)lr * 2 * HH * HH;
    float acc = 0.f;
    size_t o = ((size_t)lr * HH + j) * HH + i;  // transposed store [n=j][k=i]
    if (t < 128) {
        const float* wd = Wdst + ((size_t)lr * HH + i) * HH;
        for (int k = 0; k < HH; ++k) acc += wd[k] * wu[k * HH + j];
        u16 h = f2bf(acc);
        Wdt_hi[o] = h;
        Wdt_lo[o] = f2bf(acc - bf2f(h));
    } else {
        const float* wsc = Wsrc + ((size_t)lr * HH + i) * HH;
        for (int k = 0; k < HH; ++k) acc += wsc[k] * wu[(HH + k) * HH + j];
        u16 h = f2bf(acc);
        Wst_hi[o] = h;
        Wst_lo[o] = f2bf(acc - bf2f(h));
    }
}

__global__ void k_fuse_b(const float* __restrict__ bsrc, const float* __restrict__ bdst,
                         const float* __restrict__ bupd, const float* __restrict__ Wupd,
                         float* __restrict__ fB) {
    int lr = blockIdx.x;
    int j = threadIdx.x;
    const float* wu = Wupd + (size_t)lr * 2 * HH * HH;
    const float* bd = bdst + lr * HH;
    const float* bs = bsrc + lr * HH;
    float acc = bupd[lr * HH + j];
    for (int k = 0; k < HH; ++k)
        acc += bd[k] * wu[k * HH + j] + bs[k] * wu[(HH + k) * HH + j];
    fB[lr * HH + j] = acc;
}

// attnW1 [L][H][A] -> transposed [L][A][H] bf16 hi/lo (for MFMA B-frags)
__global__ void k_fuse_a(const float* __restrict__ W1, u16* __restrict__ Ah,
                         u16* __restrict__ Al) {
    int b = blockIdx.x;            // l*AAA + a
    int l = b >> 6, a = b & 63;
    int k = threadIdx.x;           // 128 threads
    float v = W1[((size_t)l * HH + k) * AAA + a];
    u16 h = f2bf(v);
    size_t o = (size_t)b * HH + k;
    Ah[o] = h;
    Al[o] = f2bf(v - bf2f(h));
}

// ---------------- CSR build: batched over 3 relations; count stores per-edge slot ----------------
__global__ void k_count(const int* __restrict__ e0, const int* __restrict__ e1,
                        const int* __restrict__ e2, int* __restrict__ cnt,
                        int* __restrict__ pose) {
    int rel = blockIdx.y;
    const int* d = (rel == 0 ? e0 : rel == 1 ? e1 : e2) + EE;
    int i = blockIdx.x * 256 + threadIdx.x;
    if (i < EE) pose[rel * EE + i] = atomicAdd(&cnt[rel * NN + d[i]], 1);
}

__global__ void k_scan1(const int* __restrict__ cnt_all, int* __restrict__ rs_all,
                        int* __restrict__ bsum) {
    __shared__ int sd[256];
    int rel = blockIdx.y;
    const int* cnt = cnt_all + rel * NN;
    int* rs = rs_all + rel * NN;
    int blk = blockIdx.x, tid = threadIdx.x;
    int base = blk * 1024 + tid * 4;
    int c0 = 0, c1 = 0, c2 = 0, c3 = 0;
    if (base + 0 < NN) c0 = cnt[base + 0];
    if (base + 1 < NN) c1 = cnt[base + 1];
    if (base + 2 < NN) c2 = cnt[base + 2];
    if (base + 3 < NN) c3 = cnt[base + 3];
    int s = c0 + c1 + c2 + c3;
    sd[tid] = s;
    __syncthreads();
    for (int off = 1; off < 256; off <<= 1) {
        int v = (tid >= off) ? sd[tid - off] : 0;
        __syncthreads();
        sd[tid] += v;
        __syncthreads();
    }
    int excl = sd[tid] - s;
    if (tid == 255) bsum[rel * 128 + blk] = sd[255];
    if (base + 0 < NN) rs[base + 0] = excl;
    if (base + 1 < NN) rs[base + 1] = excl + c0;
    if (base + 2 < NN) rs[base + 2] = excl + c0 + c1;
    if (base + 3 < NN) rs[base + 3] = excl + c0 + c1 + c2;
}

__global__ void k_scan2(int* __restrict__ bsum) {  // grid = 3, 128 threads
    __shared__ int sd[128];
    int rel = blockIdx.x;
    int tid = threadIdx.x;
    int v = (tid < SCAN_B) ? bsum[rel * 128 + tid] : 0;
    sd[tid] = v;
    __syncthreads();
    for (int off = 1; off < 128; off <<= 1) {
        int u = (tid >= off) ? sd[tid - off] : 0;
        __syncthreads();
        sd[tid] += u;
        __syncthreads();
    }
    if (tid < SCAN_B) bsum[rel * 128 + tid] = sd[tid] - v;  // exclusive
}

__global__ void k_scan3(int* __restrict__ rs_all, const int* __restrict__ bsum) {
    int rel = blockIdx.y;
    int i = blockIdx.x * 256 + threadIdx.x;
    if (i < NN) rs_all[rel * NN + i] += bsum[rel * 128 + (i >> 10)];
}

// atomic-free scatter: slot precomputed by k_count
__global__ void k_fill(const int* __restrict__ e0, const int* __restrict__ e1,
                       const int* __restrict__ e2, const int* __restrict__ pose,
                       const int* __restrict__ rs_all, int* __restrict__ csr_all) {
    int rel = blockIdx.y;
    const int* e = rel == 0 ? e0 : rel == 1 ? e1 : e2;
    int i = blockIdx.x * 256 + threadIdx.x;
    if (i >= EE) return;
    int s = e[i], d = e[EE + i];
    csr_all[(size_t)rel * EE + rs_all[rel * NN + d] + pose[rel * EE + i]] = s;
}

// ---------------- aggregation: one wave per dst node, 4-edge batched gather ----------------
// bnsc != nullptr: apply y = leaky(sc*x + sf) per gathered element ([sc(128)|sf(128)] layout)
// -- replaces the standalone BN-apply pass for layer-1 gather sources.
__global__ __launch_bounds__(256) void k_aggr(u16* __restrict__ Xp, const float* __restrict__ xs,
                                              const int* __restrict__ rs, const int* __restrict__ cnt,
                                              const int* __restrict__ csr,
                                              const float* __restrict__ bnsc) {
    int node = blockIdx.x * 4 + (threadIdx.x >> 6);
    if (node >= NN) return;
    int lane = threadIdx.x & 63;
    int beg = rs[node], deg = cnt[node];
    const float2* xs2 = (const float2*)xs;
    bool bn = bnsc != nullptr;
    float2 scv = make_float2(1.f, 1.f), sfv = make_float2(0.f, 0.f);
    if (bn) {
        scv = ((const float2*)bnsc)[lane];
        sfv = ((const float2*)(bnsc + 128))[lane];
    }
    auto xf = [&](float2 v) {
        if (bn) {
            v.x = v.x * scv.x + sfv.x;
            v.y = v.y * scv.y + sfv.y;
            v.x = v.x >= 0.f ? v.x : 0.01f * v.x;
            v.y = v.y >= 0.f ? v.y : 0.01f * v.y;
        }
        return v;
    };
    float ax = 0.f, ay = 0.f;
    int j = 0;
    for (; j + 4 <= deg; j += 4) {
        int s0 = csr[beg + j], s1 = csr[beg + j + 1];
        int s2 = csr[beg + j + 2], s3 = csr[beg + j + 3];
        float2 v0 = xf(xs2[(size_t)s0 * 64 + lane]);
        float2 v1 = xf(xs2[(size_t)s1 * 64 + lane]);
        float2 v2 = xf(xs2[(size_t)s2 * 64 + lane]);
        float2 v3 = xf(xs2[(size_t)s3 * 64 + lane]);
        ax += (v0.x + v1.x) + (v2.x + v3.x);
        ay += (v0.y + v1.y) + (v2.y + v3.y);
    }
    if (j + 2 <= deg) {
        int s0 = csr[beg + j], s1 = csr[beg + j + 1];
        float2 v0 = xf(xs2[(size_t)s0 * 64 + lane]);
        float2 v1 = xf(xs2[(size_t)s1 * 64 + lane]);
        ax += v0.x + v1.x;
        ay += v0.y + v1.y;
        j += 2;
    }
    if (j < deg) {
        float2 v = xf(xs2[(size_t)csr[beg + j] * 64 + lane]);
        ax += v.x;
        ay += v.y;
    }
    float sc = 1.0f / fmaxf((float)deg, 1.0f);
    float vx = ax * sc, vy = ay * sc;
    u16 hx = f2bf(vx), hy = f2bf(vy);
    u16 lx = f2bf(vx - bf2f(hx)), ly = f2bf(vy - bf2f(hy));
    int g = lane >> 2;
    char* base = (char*)Xp + (size_t)node * 512 + (g >> 2) * 128;
    int jb = (lane & 3) * 4;
    __builtin_nontemporal_store(((u32)hy << 16) | hx, (u32*)(base + hi_off(g & 3, node) + jb));
    __builtin_nontemporal_store(((u32)ly << 16) | lx, (u32*)(base + lo_off(g & 3, node) + jb));
}

// ---------------- fused conv GEMM: Y = X1@W1 + X2@W2 + bias, bf16x3 MFMA ----------------
// bnsc2 != nullptr: apply BN+leaky to X2 during phase-2 staging (pre-BN buffer input).
// colsum != nullptr: accumulate column sum/sumsq of Y into [colsum(128)|colsumsq(128)]
// (replaces the standalone stats pass for the embA convs).
__global__ __launch_bounds__(256) void k_cgemm(float* Y, const u16* X1p,
                                               const float* __restrict__ X2,
                                               const u16* __restrict__ W1h, const u16* __restrict__ W1l,
                                               const u16* __restrict__ W2h, const u16* __restrict__ W2l,
                                               const float* __restrict__ bias, int nrows,
                                               const float* __restrict__ bnsc2,
                                               float* __restrict__ colsum) {
    __shared__ __attribute__((aligned(16))) char Xt[16384];  // [128 rows][128B chunk]
    int tid = threadIdx.x;
    int row0 = blockIdx.x * 128;
    int lane = tid & 63, wv = tid >> 6;
    int l15 = lane & 15, lg = lane >> 4;
    bool full = (row0 + 128 <= nrows);

    f32x4 acc[8][2];
#pragma unroll
    for (int i = 0; i < 8; ++i)
#pragma unroll
        for (int j = 0; j < 2; ++j) acc[i][j] = (f32x4)(0.f);

    for (int ph = 0; ph < 2; ++ph) {
        const u16* Wh = ph ? W2h : W1h;
        const u16* Wl = ph ? W2l : W1l;
        for (int kc = 0; kc < HH; kc += 32) {
            __syncthreads();  // previous chunk fully consumed before overwrite
            if (ph == 0) {
#pragma unroll
                for (int p = 0; p < 4; ++p) {
                    int tb = p * 4096 + tid * 16;
                    int r = tb >> 7, off = tb & 127;
                    stage16((const char*)X1p + (size_t)(row0 + r) * 512 + (kc >> 5) * 128 + off,
                            Xt + tb);
                }
            } else {
#pragma unroll
                for (int it = 0; it < 2; ++it) {
                    int g2 = tid + it * 256;
                    int r = g2 >> 2, gi = g2 & 3;
                    float4 a = make_float4(0.f, 0.f, 0.f, 0.f), b = a;
                    if (full || row0 + r < nrows) {
                        const float* xp = &X2[(size_t)(row0 + r) * HH + kc + gi * 8];
                        a = *(const float4*)xp;
                        b = *(const float4*)(xp + 4);
                    }
                    if (bnsc2) {
                        const float* scp = bnsc2 + kc + gi * 8;
                        const float* sfp = bnsc2 + 128 + kc + gi * 8;
                        float4 s0 = *(const float4*)scp, s1 = *(const float4*)(scp + 4);
                        float4 f0 = *(const float4*)sfp, f1 = *(const float4*)(sfp + 4);
                        a.x = a.x * s0.x + f0.x; a.y = a.y * s0.y + f0.y;
                        a.z = a.z * s0.z + f0.z; a.w = a.w * s0.w + f0.w;
                        b.x = b.x * s1.x + f1.x; b.y = b.y * s1.y + f1.y;
                        b.z = b.z * s1.z + f1.z; b.w = b.w * s1.w + f1.w;
                        a.x = a.x >= 0.f ? a.x : 0.01f * a.x;
                        a.y = a.y >= 0.f ? a.y : 0.01f * a.y;
                        a.z = a.z >= 0.f ? a.z : 0.01f * a.z;
                        a.w = a.w >= 0.f ? a.w : 0.01f * a.w;
                        b.x = b.x >= 0.f ? b.x : 0.01f * b.x;
                        b.y = b.y >= 0.f ? b.y : 0.01f * b.y;
                        b.z = b.z >= 0.f ? b.z : 0.01f * b.z;
                        b.w = b.w >= 0.f ? b.w : 0.01f * b.w;
                    }
                    u16 h0 = f2bf(a.x), h1 = f2bf(a.y), h2 = f2bf(a.z), h3 = f2bf(a.w);
                    u16 h4 = f2bf(b.x), h5 = f2bf(b.y), h6 = f2bf(b.z), h7 = f2bf(b.w);
                    bf16x8 hv = {(short)h0, (short)h1, (short)h2, (short)h3,
                                 (short)h4, (short)h5, (short)h6, (short)h7};
                    bf16x8 lv = {(short)f2bf(a.x - bf2f(h0)), (short)f2bf(a.y - bf2f(h1)),
                                 (short)f2bf(a.z - bf2f(h2)), (short)f2bf(a.w - bf2f(h3)),
                                 (short)f2bf(b.x - bf2f(h4)), (short)f2bf(b.y - bf2f(h5)),
                                 (short)f2bf(b.z - bf2f(h6)), (short)f2bf(b.w - bf2f(h7))};
                    char* rb = Xt + r * 128;
                    *(bf16x8*)(rb + hi_off(gi, r)) = hv;
                    *(bf16x8*)(rb + lo_off(gi, r)) = lv;
                }
            }
            bf16x8 bh[2], bl[2];
#pragma unroll
            for (int nt = 0; nt < 2; ++nt) {
                int n = (wv * 2 + nt) * 16 + l15;
                bh[nt] = *(const bf16x8*)&Wh[(size_t)n * HH + kc + lg * 8];
                bl[nt] = *(const bf16x8*)&Wl[(size_t)n * HH + kc + lg * 8];
            }
            __syncthreads();  // drains DMA vmcnt + lds writes
#pragma unroll
            for (int mt = 0; mt < 8; ++mt) {
                int r = mt * 16 + l15;
                const char* rb = Xt + r * 128;
                bf16x8 ah = *(const bf16x8*)(rb + hi_off(lg, r));
                bf16x8 al = *(const bf16x8*)(rb + lo_off(lg, r));
#pragma unroll
                for (int nt = 0; nt < 2; ++nt) {
                    acc[mt][nt] = __builtin_amdgcn_mfma_f32_16x16x32_bf16(ah, bh[nt], acc[mt][nt], 0, 0, 0);
                    acc[mt][nt] = __builtin_amdgcn_mfma_f32_16x16x32_bf16(ah, bl[nt], acc[mt][nt], 0, 0, 0);
                    acc[mt][nt] = __builtin_amdgcn_mfma_f32_16x16x32_bf16(al, bh[nt], acc[mt][nt], 0, 0, 0);
                }
            }
        }
    }
    // epilogue: C/D col=lane&15, row=(lane>>4)*4+j [m89-verified]; optional column stats
#pragma unroll
    for (int nt = 0; nt < 2; ++nt) {
        int ncol = (wv * 2 + nt) * 16 + l15;
        float bv = bias[ncol];
        float s = 0.f, q = 0.f;
#pragma unroll
        for (int mt = 0; mt < 8; ++mt)
#pragma unroll
            for (int j = 0; j < 4; ++j) {
                int r = row0 + mt * 16 + lg * 4 + j;
                if (r < nrows) {
                    float y = acc[mt][nt][j] + bv;
                    Y[(size_t)r * HH + ncol] = y;
                    s += y;
                    q += y * y;
                }
            }
        if (colsum) {
            s += __shfl_xor(s, 16); s += __shfl_xor(s, 32);
            q += __shfl_xor(q, 16); q += __shfl_xor(q, 32);
            if (lg == 0) {
                atomicAdd(&colsum[ncol], s);
                atomicAdd(&colsum[128 + ncol], q);
            }
        }
    }
}

// ---------------- attention score: bf16x3 MFMA S = X@W1, tanh, dot w2, block-sum ----------------
__global__ __launch_bounds__(256) void k_attn(const float* __restrict__ XA, const float* __restrict__ XB,
                                              const u16* __restrict__ Ah, const u16* __restrict__ Al,
                                              const float* __restrict__ b1, const float* __restrict__ w2,
                                              float* __restrict__ PA, float* __restrict__ PB, int nrows) {
    __shared__ __attribute__((aligned(16))) char Xt[16384];
    __shared__ float red[4];
    int tid = threadIdx.x;
    bool second = blockIdx.x >= ATTN_GRID;
    const float* X = second ? XB : XA;
    float* partial = second ? PB : PA;
    int row0 = (second ? blockIdx.x - ATTN_GRID : blockIdx.x) * 128;
    int lane = tid & 63, wv = tid >> 6;
    int l15 = lane & 15, lg = lane >> 4;
    bool full = (row0 + 128 <= nrows);

    f32x4 acc[8];
#pragma unroll
    for (int i = 0; i < 8; ++i) acc[i] = (f32x4)(0.f);

    for (int kc = 0; kc < HH; kc += 32) {
        __syncthreads();
#pragma unroll
        for (int it = 0; it < 2; ++it) {
            int g2 = tid + it * 256;
            int r = g2 >> 2, gi = g2 & 3;
            float4 a = make_float4(0.f, 0.f, 0.f, 0.f), b = a;
            if (full || row0 + r < nrows) {
                const float* xp = &X[(size_t)(row0 + r) * HH + kc + gi * 8];
                a = *(const float4*)xp;
                b = *(const float4*)(xp + 4);
            }
            u16 h0 = f2bf(a.x), h1 = f2bf(a.y), h2 = f2bf(a.z), h3 = f2bf(a.w);
            u16 h4 = f2bf(b.x), h5 = f2bf(b.y), h6 = f2bf(b.z), h7 = f2bf(b.w);
            bf16x8 hv = {(short)h0, (short)h1, (short)h2, (short)h3,
                         (short)h4, (short)h5, (short)h6, (short)h7};
            bf16x8 lv = {(short)f2bf(a.x - bf2f(h0)), (short)f2bf(a.y - bf2f(h1)),
                         (short)f2bf(a.z - bf2f(h2)), (short)f2bf(a.w - bf2f(h3)),
                         (short)f2bf(b.x - bf2f(h4)), (short)f2bf(b.y - bf2f(h5)),
                         (short)f2bf(b.z - bf2f(h6)), (short)f2bf(b.w - bf2f(h7))};
            char* rb = Xt + r * 128;
            *(bf16x8*)(rb + hi_off(gi, r)) = hv;
            *(bf16x8*)(rb + lo_off(gi, r)) = lv;
        }
        int a = wv * 16 + l15;
        bf16x8 bh = *(const bf16x8*)&Ah[(size_t)a * HH + kc + lg * 8];
        bf16x8 bl = *(const bf16x8*)&Al[(size_t)a * HH + kc + lg * 8];
        __syncthreads();
#pragma unroll
        for (int mt = 0; mt < 8; ++mt) {
            int r = mt * 16 + l15;
            const char* rb = Xt + r * 128;
            bf16x8 ah = *(const bf16x8*)(rb + hi_off(lg, r));
            bf16x8 al = *(const bf16x8*)(rb + lo_off(lg, r));
            acc[mt] = __builtin_amdgcn_mfma_f32_16x16x32_bf16(ah, bh, acc[mt], 0, 0, 0);
            acc[mt] = __builtin_amdgcn_mfma_f32_16x16x32_bf16(ah, bl, acc[mt], 0, 0, 0);
            acc[mt] = __builtin_amdgcn_mfma_f32_16x16x32_bf16(al, bh, acc[mt], 0, 0, 0);
        }
    }
    float b1v = b1[wv * 16 + l15];
    float w2v = w2[wv * 16 + l15];
    float tot = 0.f;
#pragma unroll
    for (int mt = 0; mt < 8; ++mt)
#pragma unroll
        for (int j = 0; j < 4; ++j) {
            int r = row0 + mt * 16 + lg * 4 + j;
            if (r < nrows) tot += tanhf(acc[mt][j] + b1v) * w2v;
        }
#pragma unroll
    for (int off = 32; off > 0; off >>= 1) tot += __shfl_xor(tot, off);
    if (lane == 0) red[wv] = tot;
    __syncthreads();
    if (tid == 0)
        partial[second ? (blockIdx.x - ATTN_GRID) : blockIdx.x] = red[0] + red[1] + red[2] + red[3];
}

__global__ void k_alpha(const float* __restrict__ P1, const float* __restrict__ P2,
                        float* __restrict__ alpha, int nparts, float invn) {
    __shared__ float s1[256], s2[256];
    int tid = threadIdx.x;
    float a = 0.f, b = 0.f;
    for (int i = tid; i < nparts; i += 256) { a += P1[i]; b += P2[i]; }
    s1[tid] = a; s2[tid] = b;
    __syncthreads();
    for (int off = 128; off > 0; off >>= 1) {
        if (tid < off) { s1[tid] += s1[tid + off]; s2[tid] += s2[tid + off]; }
        __syncthreads();
    }
    if (tid == 0) {
        float m1 = s1[0] * invn, m2 = s2[0] * invn;
        float mx = fmaxf(m1, m2);
        float e1 = expf(m1 - mx), e2 = expf(m2 - mx);
        float inv = 1.f / (e1 + e2);
        alpha[0] = e1 * inv; alpha[1] = e2 * inv;
    }
}

// ---------------- combine (attention mix) + column stats ----------------
__global__ __launch_bounds__(256) void k_comb(float* __restrict__ X, const float* __restrict__ Y,
                                              const float* __restrict__ alpha, float* __restrict__ colsum,
                                              float* __restrict__ colsq, int nrows) {
    int tid = threadIdx.x;
    int h = tid & 127, half = tid >> 7;
    float a0 = alpha[0], a1 = alpha[1];
    float s = 0.f, q = 0.f;
    for (int n = blockIdx.x * 2 + half; n < nrows; n += gridDim.x * 2) {
        size_t off = (size_t)n * HH + h;
        float v = a0 * X[off] + a1 * Y[off];
        X[off] = v;
        s += v; q += v * v;
    }
    __shared__ float ls[256], lq[256];
    ls[tid] = s; lq[tid] = q;
    __syncthreads();
    if (half == 0) {
        atomicAdd(&colsum[h], ls[tid] + ls[tid + 128]);
        atomicAdd(&colsq[h], lq[tid] + lq[tid + 128]);
    }
}

__global__ void k_bnp(const float* __restrict__ sum, const float* __restrict__ sq,
                      const float* __restrict__ gamma, const float* __restrict__ beta,
                      float* __restrict__ scale, float* __restrict__ shift, float invn) {
    int h = threadIdx.x;
    float mu = sum[h] * invn;
    float var = sq[h] * invn - mu * mu;
    float sc = gamma[h] * rsqrtf(var + 1.0f);
    scale[h] = sc;
    shift[h] = beta[h] - mu * sc;
}

// ---------------- final FC: 64-row LDS tile, BN+leaky applied ONCE during staging ----------------
__global__ __launch_bounds__(256) void k_fc(const float* __restrict__ X0, const float* __restrict__ X1,
                                            const float* __restrict__ sc0, const float* __restrict__ sc1,
                                            const float* __restrict__ Wall, const float* __restrict__ ball,
                                            float* __restrict__ out, int nrows) {
    __shared__ float Xl[64 * 132];   // 33 KB
    __shared__ float Wl[HH * CC];    // 8 KB
    __shared__ float bl[CC];
    __shared__ float scl[HH], sfl[HH];
    int which = blockIdx.y;
    const float* X = which ? X1 : X0;
    const float* scp = which ? sc1 : sc0;
    const float* W = Wall + which * HH * CC;
    float* o = out + (size_t)which * NN * CC;
    int tid = threadIdx.x;
    int row0 = blockIdx.x * 64;
    for (int i = tid * 4; i < HH * CC; i += 1024)
        *(float4*)&Wl[i] = *(const float4*)&W[i];
    if (tid < CC) bl[tid] = ball[which * CC + tid];
    if (tid < HH) { scl[tid] = scp[tid]; sfl[tid] = scp[128 + tid]; }
    __syncthreads();
    for (int idx = tid; idx < 2048; idx += 256) {
        int r = idx >> 5, cc = idx & 31;
        int n = row0 + r;
        float4 v = make_float4(0.f, 0.f, 0.f, 0.f);
        if (n < nrows) v = *(const float4*)&X[(size_t)n * HH + cc * 4];
        float4 sc = *(const float4*)&scl[cc * 4];
        float4 sf = *(const float4*)&sfl[cc * 4];
        v.x = v.x * sc.x + sf.x; v.y = v.y * sc.y + sf.y;
        v.z = v.z * sc.z + sf.z; v.w = v.w * sc.w + sf.w;
        v.x = v.x >= 0.f ? v.x : 0.01f * v.x;
        v.y = v.y >= 0.f ? v.y : 0.01f * v.y;
        v.z = v.z >= 0.f ? v.z : 0.01f * v.z;
        v.w = v.w >= 0.f ? v.w : 0.01f * v.w;
        *(float4*)&Xl[r * 132 + cc * 4] = v;
    }
    __syncthreads();
    int c = tid & 15, nl = tid >> 4;
    const float* x0 = &Xl[(nl + 0) * 132];
    const float* x1 = &Xl[(nl + 16) * 132];
    const float* x2 = &Xl[(nl + 32) * 132];
    const float* x3 = &Xl[(nl + 48) * 132];
    float a0 = bl[c], a1 = a0, a2 = a0, a3 = a0;
#pragma unroll 8
    for (int h = 0; h < HH; ++h) {
        float w = Wl[h * CC + c];
        a0 += x0[h] * w;
        a1 += x1[h] * w;
        a2 += x2[h] * w;
        a3 += x3[h] * w;
    }
    int n0 = row0 + nl;
    if (n0 < nrows) o[(size_t)n0 * CC + c] = a0;
    if (n0 + 16 < nrows) o[(size_t)(n0 + 16) * CC + c] = a1;
    if (n0 + 32 < nrows) o[(size_t)(n0 + 32) * CC + c] = a2;
    if (n0 + 48 < nrows) o[(size_t)(n0 + 48) * CC + c] = a3;
}

extern "C" void kernel_launch(void* const* d_in, const int* in_sizes, int n_in,
                              void* d_out, int out_size, void* d_ws, size_t ws_size,
                              hipStream_t stream) {
    const float* xA = (const float*)d_in[0];
    const float* xB = (const float*)d_in[1];
    const float* Wsrc = (const float*)d_in[2];
    const float* bsrc = (const float*)d_in[3];
    const float* Wdst = (const float*)d_in[4];
    const float* bdst = (const float*)d_in[5];
    const float* Wupd = (const float*)d_in[6];
    const float* bupd = (const float*)d_in[7];
    const float* attnW1 = (const float*)d_in[8];
    const float* attnb1 = (const float*)d_in[9];
    const float* attnw2 = (const float*)d_in[10];
    const float* gamma = (const float*)d_in[11];
    const float* beta = (const float*)d_in[12];
    const float* fcW = (const float*)d_in[13];
    const float* fcb = (const float*)d_in[14];
    const int* eAB = (const int*)d_in[15];
    const int* eBB = (const int*)d_in[16];
    const int* eBA = (const int*)d_in[17];
    float* out = (float*)d_out;

    // workspace layout == round-12 passing footprint (+2KB for scA2/scB2)
    float* ws = (float*)d_ws;
    const size_t NH = (size_t)NN * HH;
    const size_t LRHH = (size_t)LL * RR * HH * HH;
    const size_t LAH = (size_t)LL * AAA * HH;
    float* B0 = ws;
    float* B1 = B0 + NH;
    float* B2 = B1 + NH;
    float* B3 = B2 + NH;
    u16* uWdh = (u16*)(B3 + NH);
    u16* uWdl = uWdh + LRHH;
    u16* uWsh = uWdl + LRHH;
    u16* uWsl = uWsh + LRHH;
    u16* uA1h = uWsl + LRHH;        // L*AAA*HH
    u16* uA1l = uA1h + LAH;
    float* fB = (float*)(uA1l + LAH);
    float* csA = fB + LL * RR * HH;  // [sum|sumsq] 256
    float* csB = csA + 256;          // adjacent: one memset covers both
    float* scA = csB + 256;
    float* scB = scA + 256;
    float* scA2 = scB + 256;         // layer-1 head scales (layer-0 scales stay live)
    float* scB2 = scA2 + 256;
    float* P1 = scB2 + 256;
    float* P2 = P1 + 1024;
    float* alp = P2 + 1024;
    int* icnt = (int*)(alp + 64);
    int* irs = icnt + 3 * NN;
    int* icsr = irs + 3 * NN;
    int* ifill = icsr + 3 * EE;     // unused (layout stability)
    int* ibsum = ifill + 3 * NN;
    int* pose = (int*)B3;           // 3*EE ints; B3 unused until layer 1
    const float invN = 1.0f / (float)NN;

    k_fuse_w<<<LL * RR * HH, 256, 0, stream>>>(Wsrc, Wdst, Wupd, uWdh, uWdl, uWsh, uWsl);
    k_fuse_b<<<LL * RR, HH, 0, stream>>>(bsrc, bdst, bupd, Wupd, fB);
    k_fuse_a<<<LL * AAA, HH, 0, stream>>>(attnW1, uA1h, uA1l);

    // CSR build: all 3 relations per kernel; k_count returns per-edge slot -> k_fill atomic-free
    hipMemsetAsync(icnt, 0, 3 * NN * 4, stream);
    k_count<<<dim3((EE + 255) / 256, 3), 256, 0, stream>>>(eAB, eBB, eBA, icnt, pose);
    k_scan1<<<dim3(SCAN_B, 3), 256, 0, stream>>>(icnt, irs, ibsum);
    k_scan2<<<3, 128, 0, stream>>>(ibsum);
    k_scan3<<<dim3((NN + 255) / 256, 3), 256, 0, stream>>>(irs, ibsum);
    k_fill<<<dim3((EE + 255) / 256, 3), 256, 0, stream>>>(eAB, eBB, eBA, pose, irs, icsr);

    const int GEMM_GRID = (NN + 127) / 128;
    const int AGGR_GRID = (NN + 3) / 4;

    // dest serves as packed X1 during aggr+cgemm, then holds f32 Y (in-place)
    auto conv = [&](float* dest, const float* xs, const float* xd, int rel, int lr,
                    const float* bn_xs, const float* bn_xd, float* stats) {
        k_aggr<<<AGGR_GRID, 256, 0, stream>>>((u16*)dest, xs, irs + rel * NN, icnt + rel * NN,
                                              icsr + (size_t)rel * EE, bn_xs);
        k_cgemm<<<GEMM_GRID, 256, 0, stream>>>(dest, (const u16*)dest, xd,
                                               uWsh + (size_t)lr * HH * HH, uWsl + (size_t)lr * HH * HH,
                                               uWdh + (size_t)lr * HH * HH, uWdl + (size_t)lr * HH * HH,
                                               fB + lr * HH, NN, bn_xd, stats);
    };

    // ================= layer 0 =================
    hipMemsetAsync(csA, 0, 512 * 4, stream);  // csA + csB
    conv(B0, xA, xB, 0, 0, nullptr, nullptr, nullptr);  // embB1
    conv(B1, xB, xB, 1, 1, nullptr, nullptr, nullptr);  // embB2
    conv(B2, xB, xA, 2, 2, nullptr, nullptr, csA);      // embA + stats
    k_attn<<<2 * ATTN_GRID, 256, 0, stream>>>(B0, B1, uA1h, uA1l, attnb1, attnw2, P1, P2, NN);
    k_alpha<<<1, 256, 0, stream>>>(P1, P2, alp, ATTN_GRID, invN);
    k_comb<<<512, 256, 0, stream>>>(B0, B1, alp, csB, csB + 128, NN);  // xB_new -> B0 (+stats)
    k_bnp<<<1, 128, 0, stream>>>(csA, csA + 128, gamma + 0 * HH, beta + 0 * HH, scA, scA + 128, invN);
    k_bnp<<<1, 128, 0, stream>>>(csB, csB + 128, gamma + 1 * HH, beta + 1 * HH, scB, scB + 128, invN);
    // NOTE: no BN-apply pass; B2 (=embA) and B0 (=xB_new) stay pre-BN; scA/scB applied by consumers.

    // ================= layer 1 =================
    hipMemsetAsync(csA, 0, 512 * 4, stream);  // csA + csB (after layer-0 bnp consumed them)
    conv(B1, B2, B0, 0, 3, scA, scB, nullptr);  // embB1' (xs=xA w/scA, xd=xB w/scB)
    conv(B3, B0, B0, 1, 4, scB, scB, nullptr);  // embB2'
    k_attn<<<2 * ATTN_GRID, 256, 0, stream>>>(B1, B3, uA1h + (size_t)AAA * HH,
                                              uA1l + (size_t)AAA * HH,
                                              attnb1 + AAA, attnw2 + AAA, P1, P2, NN);
    k_alpha<<<1, 256, 0, stream>>>(P1, P2, alp, ATTN_GRID, invN);
    k_comb<<<512, 256, 0, stream>>>(B1, B3, alp, csB, csB + 128, NN);  // xB_new -> B1 (+stats)
    conv(B3, B0, B2, 2, 5, scB, scA, csA);  // embA' + stats (xs=xB w/scB, xd=xA w/scA)
    k_bnp<<<1, 128, 0, stream>>>(csA, csA + 128, gamma + 2 * HH, beta + 2 * HH, scA2, scA2 + 128, invN);
    k_bnp<<<1, 128, 0, stream>>>(csB, csB + 128, gamma + 3 * HH, beta + 3 * HH, scB2, scB2 + 128, invN);

    // ================= head: BN+leaky fused into FC staging =================
    k_fc<<<dim3((NN + 63) / 64, 2), 256, 0, stream>>>(B3, B1, scA2, scB2, fcW, fcb, out, NN);
}

// Round 14
// 1024.867 us; speedup vs baseline: 2.4994x; 1.0314x over previous
//
#include <hip/hip_runtime.h>

#define NN 100000
#define HH 128
#define EE 600000
#define LL 2
#define RR 3
#define AAA 64
#define CC 16
#define SCAN_B 98   // 98 blocks x 1024 elems covers 100000
#define ATTN_GRID ((NN + 127) / 128)

typedef unsigned short u16;
typedef unsigned int u32;
typedef __attribute__((ext_vector_type(8))) short bf16x8;
typedef __attribute__((ext_vector_type(4))) float f32x4;

__device__ inline u16 f2bf(float f) {   // RNE f32 -> bf16
    unsigned int u = __float_as_uint(f);
    return (u16)((u + 0x7FFF + ((u >> 16) & 1)) >> 16);
}
__device__ inline float bf2f(u16 h) { return __uint_as_float((unsigned int)h << 16); }

// Packed X layout (per row: 512B, 4 chunks of 128B; chunk = 4 groups of [16B hi][16B lo],
// XOR-swizzled by row). Shared by producer (k_aggr / cgemm phase-2 staging) and consumer
// (cgemm frag reads). row0 % 128 == 0 so block-local r has same r&7 as global row.
__device__ __forceinline__ int hi_off(int gi, int r) { return (gi * 32) ^ ((r & 7) << 4); }
__device__ __forceinline__ int lo_off(int gi, int r) { return (gi * 32 + 16) ^ ((r & 7) << 4); }

// async global->LDS, 16B per lane; dest must be linear (wave-uniform base + lane*16)
__device__ __forceinline__ void stage16(const void* g, void* l) {
    __builtin_amdgcn_global_load_lds((const __attribute__((address_space(1))) unsigned int*)g,
                                     (__attribute__((address_space(3))) unsigned int*)l, 16, 0, 0);
}

// ---------------- weight fusion: W transposed [n][k], split bf16 hi/lo ----------------
__global__ void k_fuse_w(const float* __restrict__ Wsrc, const float* __restrict__ Wdst,
                         const float* __restrict__ Wupd, u16* __restrict__ Wdt_hi,
                         u16* __restrict__ Wdt_lo, u16* __restrict__ Wst_hi,
                         u16* __restrict__ Wst_lo) {
    int b = blockIdx.x;
    int lr = b >> 7, i = b & 127;   // i = k index
    int t = threadIdx.x;
    int j = t & 127;                // j = n index
    const float* wu = Wupd + (size_t)lr * 2 * HH * HH;
    float acc = 0.f;
    size_t o = ((size_t)lr * HH + j) * HH + i;  // transposed store [n=j][k=i]
    if (t < 128) {
        const float* wd = Wdst + ((size_t)lr * HH + i) * HH;
        for (int k = 0; k < HH; ++k) acc += wd[k] * wu[k * HH + j];
        u16 h = f2bf(acc);
        Wdt_hi[o] = h;
        Wdt_lo[o] = f2bf(acc - bf2f(h));
    } else {
        const float* wsc = Wsrc + ((size_t)lr * HH + i) * HH;
        for (int k = 0; k < HH; ++k) acc += wsc[k] * wu[(HH + k) * HH + j];
        u16 h = f2bf(acc);
        Wst_hi[o] = h;
        Wst_lo[o] = f2bf(acc - bf2f(h));
    }
}

__global__ void k_fuse_b(const float* __restrict__ bsrc, const float* __restrict__ bdst,
                         const float* __restrict__ bupd, const float* __restrict__ Wupd,
                         float* __restrict__ fB) {
    int lr = blockIdx.x;
    int j = threadIdx.x;
    const float* wu = Wupd + (size_t)lr * 2 * HH * HH;
    const float* bd = bdst + lr * HH;
    const float* bs = bsrc + lr * HH;
    float acc = bupd[lr * HH + j];
    for (int k = 0; k < HH; ++k)
        acc += bd[k] * wu[k * HH + j] + bs[k] * wu[(HH + k) * HH + j];
    fB[lr * HH + j] = acc;
}

// attnW1 [L][H][A] -> transposed [L][A][H] bf16 hi/lo (for MFMA B-frags)
__global__ void k_fuse_a(const float* __restrict__ W1, u16* __restrict__ Ah,
                         u16* __restrict__ Al) {
    int b = blockIdx.x;            // l*AAA + a
    int l = b >> 6, a = b & 63;
    int k = threadIdx.x;           // 128 threads
    float v = W1[((size_t)l * HH + k) * AAA + a];
    u16 h = f2bf(v);
    size_t o = (size_t)b * HH + k;
    Ah[o] = h;
    Al[o] = f2bf(v - bf2f(h));
}

// ---------------- CSR build: batched over 3 relations; count stores per-edge slot ----------------
__global__ void k_count(const int* __restrict__ e0, const int* __restrict__ e1,
                        const int* __restrict__ e2, int* __restrict__ cnt,
                        int* __restrict__ pose) {
    int rel = blockIdx.y;
    const int* d = (rel == 0 ? e0 : rel == 1 ? e1 : e2) + EE;
    int i = blockIdx.x * 256 + threadIdx.x;
    if (i < EE) pose[rel * EE + i] = atomicAdd(&cnt[rel * NN + d[i]], 1);
}

__global__ void k_scan1(const int* __restrict__ cnt_all, int* __restrict__ rs_all,
                        int* __restrict__ bsum) {
    __shared__ int sd[256];
    int rel = blockIdx.y;
    const int* cnt = cnt_all + rel * NN;
    int* rs = rs_all + rel * NN;
    int blk = blockIdx.x, tid = threadIdx.x;
    int base = blk * 1024 + tid * 4;
    int c0 = 0, c1 = 0, c2 = 0, c3 = 0;
    if (base + 0 < NN) c0 = cnt[base + 0];
    if (base + 1 < NN) c1 = cnt[base + 1];
    if (base + 2 < NN) c2 = cnt[base + 2];
    if (base + 3 < NN) c3 = cnt[base + 3];
    int s = c0 + c1 + c2 + c3;
    sd[tid] = s;
    __syncthreads();
    for (int off = 1; off < 256; off <<= 1) {
        int v = (tid >= off) ? sd[tid - off] : 0;
        __syncthreads();
        sd[tid] += v;
        __syncthreads();
    }
    int excl = sd[tid] - s;
    if (tid == 255) bsum[rel * 128 + blk] = sd[255];
    if (base + 0 < NN) rs[base + 0] = excl;
    if (base + 1 < NN) rs[base + 1] = excl + c0;
    if (base + 2 < NN) rs[base + 2] = excl + c0 + c1;
    if (base + 3 < NN) rs[base + 3] = excl + c0 + c1 + c2;
}

__global__ void k_scan2(int* __restrict__ bsum) {  // grid = 3, 128 threads
    __shared__ int sd[128];
    int rel = blockIdx.x;
    int tid = threadIdx.x;
    int v = (tid < SCAN_B) ? bsum[rel * 128 + tid] : 0;
    sd[tid] = v;
    __syncthreads();
    for (int off = 1; off < 128; off <<= 1) {
        int u = (tid >= off) ? sd[tid - off] : 0;
        __syncthreads();
        sd[tid] += u;
        __syncthreads();
    }
    if (tid < SCAN_B) bsum[rel * 128 + tid] = sd[tid] - v;  // exclusive
}

__global__ void k_scan3(int* __restrict__ rs_all, const int* __restrict__ bsum) {
    int rel = blockIdx.y;
    int i = blockIdx.x * 256 + threadIdx.x;
    if (i < NN) rs_all[rel * NN + i] += bsum[rel * 128 + (i >> 10)];
}

// atomic-free scatter: slot precomputed by k_count
__global__ void k_fill(const int* __restrict__ e0, const int* __restrict__ e1,
                       const int* __restrict__ e2, const int* __restrict__ pose,
                       const int* __restrict__ rs_all, int* __restrict__ csr_all) {
    int rel = blockIdx.y;
    const int* e = rel == 0 ? e0 : rel == 1 ? e1 : e2;
    int i = blockIdx.x * 256 + threadIdx.x;
    if (i >= EE) return;
    int s = e[i], d = e[EE + i];
    csr_all[(size_t)rel * EE + rs_all[rel * NN + d] + pose[rel * EE + i]] = s;
}

// ---------------- aggregation: one wave per dst node, 4-edge batched gather ----------------
__global__ __launch_bounds__(256) void k_aggr(u16* __restrict__ Xp, const float* __restrict__ xs,
                                              const int* __restrict__ rs, const int* __restrict__ cnt,
                                              const int* __restrict__ csr,
                                              const float* __restrict__ bnsc) {
    int node = blockIdx.x * 4 + (threadIdx.x >> 6);
    if (node >= NN) return;
    int lane = threadIdx.x & 63;
    int beg = rs[node], deg = cnt[node];
    const float2* xs2 = (const float2*)xs;
    bool bn = bnsc != nullptr;
    float2 scv = make_float2(1.f, 1.f), sfv = make_float2(0.f, 0.f);
    if (bn) {
        scv = ((const float2*)bnsc)[lane];
        sfv = ((const float2*)(bnsc + 128))[lane];
    }
    auto xf = [&](float2 v) {
        if (bn) {
            v.x = v.x * scv.x + sfv.x;
            v.y = v.y * scv.y + sfv.y;
            v.x = v.x >= 0.f ? v.x : 0.01f * v.x;
            v.y = v.y >= 0.f ? v.y : 0.01f * v.y;
        }
        return v;
    };
    float ax = 0.f, ay = 0.f;
    int j = 0;
    for (; j + 4 <= deg; j += 4) {
        int s0 = csr[beg + j], s1 = csr[beg + j + 1];
        int s2 = csr[beg + j + 2], s3 = csr[beg + j + 3];
        float2 v0 = xf(xs2[(size_t)s0 * 64 + lane]);
        float2 v1 = xf(xs2[(size_t)s1 * 64 + lane]);
        float2 v2 = xf(xs2[(size_t)s2 * 64 + lane]);
        float2 v3 = xf(xs2[(size_t)s3 * 64 + lane]);
        ax += (v0.x + v1.x) + (v2.x + v3.x);
        ay += (v0.y + v1.y) + (v2.y + v3.y);
    }
    if (j + 2 <= deg) {
        int s0 = csr[beg + j], s1 = csr[beg + j + 1];
        float2 v0 = xf(xs2[(size_t)s0 * 64 + lane]);
        float2 v1 = xf(xs2[(size_t)s1 * 64 + lane]);
        ax += v0.x + v1.x;
        ay += v0.y + v1.y;
        j += 2;
    }
    if (j < deg) {
        float2 v = xf(xs2[(size_t)csr[beg + j] * 64 + lane]);
        ax += v.x;
        ay += v.y;
    }
    float sc = 1.0f / fmaxf((float)deg, 1.0f);
    float vx = ax * sc, vy = ay * sc;
    u16 hx = f2bf(vx), hy = f2bf(vy);
    u16 lx = f2bf(vx - bf2f(hx)), ly = f2bf(vy - bf2f(hy));
    int g = lane >> 2;
    char* base = (char*)Xp + (size_t)node * 512 + (g >> 2) * 128;
    int jb = (lane & 3) * 4;
    __builtin_nontemporal_store(((u32)hy << 16) | hx, (u32*)(base + hi_off(g & 3, node) + jb));
    __builtin_nontemporal_store(((u32)ly << 16) | lx, (u32*)(base + lo_off(g & 3, node) + jb));
}

// ---------------- fused conv GEMM: Y = X1@W1 + X2@W2 + bias, bf16x3 MFMA ----------------
// Chunk-level double-buffered LDS: stage chunk c+1 while MFMA on chunk c (one barrier/chunk,
// staging latency hidden under compute). bnsc2/colsum as in round 13.
__global__ __launch_bounds__(256) void k_cgemm(float* Y, const u16* X1p,
                                               const float* __restrict__ X2,
                                               const u16* __restrict__ W1h, const u16* __restrict__ W1l,
                                               const u16* __restrict__ W2h, const u16* __restrict__ W2l,
                                               const float* __restrict__ bias, int nrows,
                                               const float* __restrict__ bnsc2,
                                               float* __restrict__ colsum) {
    __shared__ __attribute__((aligned(16))) char Xt[2][16384];  // double-buffered chunk tiles
    int tid = threadIdx.x;
    int row0 = blockIdx.x * 128;
    int lane = tid & 63, wv = tid >> 6;
    int l15 = lane & 15, lg = lane >> 4;
    bool full = (row0 + 128 <= nrows);

    f32x4 acc[8][2];
#pragma unroll
    for (int i = 0; i < 8; ++i)
#pragma unroll
        for (int j = 0; j < 2; ++j) acc[i][j] = (f32x4)(0.f);

    // stage chunk c (c in [0,8): phase = c>>2, kc = (c&3)*32) into Xt[c&1]
    auto stage_chunk = [&](int c) {
        char* dst = Xt[c & 1];
        if (c < 4) {
            // phase-1: DMA packed+pre-swizzled X1 (linear LDS dest)
#pragma unroll
            for (int p = 0; p < 4; ++p) {
                int tb = p * 4096 + tid * 16;
                int r = tb >> 7, off = tb & 127;
                stage16((const char*)X1p + (size_t)(row0 + r) * 512 + (c & 3) * 128 + off,
                        dst + tb);
            }
        } else {
            int kc = (c & 3) * 32;
            // phase-2: f32 -> (optional BN+leaky) -> hi/lo bf16 into swizzled LDS
#pragma unroll
            for (int it = 0; it < 2; ++it) {
                int g2 = tid + it * 256;
                int r = g2 >> 2, gi = g2 & 3;
                float4 a = make_float4(0.f, 0.f, 0.f, 0.f), b = a;
                if (full || row0 + r < nrows) {
                    const float* xp = &X2[(size_t)(row0 + r) * HH + kc + gi * 8];
                    a = *(const float4*)xp;
                    b = *(const float4*)(xp + 4);
                }
                if (bnsc2) {
                    const float* scp = bnsc2 + kc + gi * 8;
                    const float* sfp = bnsc2 + 128 + kc + gi * 8;
                    float4 s0 = *(const float4*)scp, s1 = *(const float4*)(scp + 4);
                    float4 f0 = *(const float4*)sfp, f1 = *(const float4*)(sfp + 4);
                    a.x = a.x * s0.x + f0.x; a.y = a.y * s0.y + f0.y;
                    a.z = a.z * s0.z + f0.z; a.w = a.w * s0.w + f0.w;
                    b.x = b.x * s1.x + f1.x; b.y = b.y * s1.y + f1.y;
                    b.z = b.z * s1.z + f1.z; b.w = b.w * s1.w + f1.w;
                    a.x = a.x >= 0.f ? a.x : 0.01f * a.x;
                    a.y = a.y >= 0.f ? a.y : 0.01f * a.y;
                    a.z = a.z >= 0.f ? a.z : 0.01f * a.z;
                    a.w = a.w >= 0.f ? a.w : 0.01f * a.w;
                    b.x = b.x >= 0.f ? b.x : 0.01f * b.x;
                    b.y = b.y >= 0.f ? b.y : 0.01f * b.y;
                    b.z = b.z >= 0.f ? b.z : 0.01f * b.z;
                    b.w = b.w >= 0.f ? b.w : 0.01f * b.w;
                }
                u16 h0 = f2bf(a.x), h1 = f2bf(a.y), h2 = f2bf(a.z), h3 = f2bf(a.w);
                u16 h4 = f2bf(b.x), h5 = f2bf(b.y), h6 = f2bf(b.z), h7 = f2bf(b.w);
                bf16x8 hv = {(short)h0, (short)h1, (short)h2, (short)h3,
                             (short)h4, (short)h5, (short)h6, (short)h7};
                bf16x8 lv = {(short)f2bf(a.x - bf2f(h0)), (short)f2bf(a.y - bf2f(h1)),
                             (short)f2bf(a.z - bf2f(h2)), (short)f2bf(a.w - bf2f(h3)),
                             (short)f2bf(b.x - bf2f(h4)), (short)f2bf(b.y - bf2f(h5)),
                             (short)f2bf(b.z - bf2f(h6)), (short)f2bf(b.w - bf2f(h7))};
                char* rb = dst + r * 128;
                *(bf16x8*)(rb + hi_off(gi, r)) = hv;
                *(bf16x8*)(rb + lo_off(gi, r)) = lv;
            }
        }
    };

    stage_chunk(0);
#pragma unroll
    for (int c = 0; c < 8; ++c) {
        const u16* Wh = (c < 4) ? W1h : W2h;
        const u16* Wl = (c < 4) ? W1l : W2l;
        int kc = (c & 3) * 32;
        // W frags: global -> reg (no LDS dependency; before barrier)
        bf16x8 bh[2], bl[2];
#pragma unroll
        for (int nt = 0; nt < 2; ++nt) {
            int n = (wv * 2 + nt) * 16 + l15;
            bh[nt] = *(const bf16x8*)&Wh[(size_t)n * HH + kc + lg * 8];
            bl[nt] = *(const bf16x8*)&Wl[(size_t)n * HH + kc + lg * 8];
        }
        __syncthreads();  // chunk c staged & chunk c-1 fully consumed
        if (c < 7) stage_chunk(c + 1);  // overlaps with MFMA below
        const char* buf = Xt[c & 1];
#pragma unroll
        for (int mt = 0; mt < 8; ++mt) {
            int r = mt * 16 + l15;
            const char* rb = buf + r * 128;
            bf16x8 ah = *(const bf16x8*)(rb + hi_off(lg, r));
            bf16x8 al = *(const bf16x8*)(rb + lo_off(lg, r));
#pragma unroll
            for (int nt = 0; nt < 2; ++nt) {
                acc[mt][nt] = __builtin_amdgcn_mfma_f32_16x16x32_bf16(ah, bh[nt], acc[mt][nt], 0, 0, 0);
                acc[mt][nt] = __builtin_amdgcn_mfma_f32_16x16x32_bf16(ah, bl[nt], acc[mt][nt], 0, 0, 0);
                acc[mt][nt] = __builtin_amdgcn_mfma_f32_16x16x32_bf16(al, bh[nt], acc[mt][nt], 0, 0, 0);
            }
        }
    }
    // epilogue: C/D col=lane&15, row=(lane>>4)*4+j [m89-verified]; optional column stats
#pragma unroll
    for (int nt = 0; nt < 2; ++nt) {
        int ncol = (wv * 2 + nt) * 16 + l15;
        float bv = bias[ncol];
        float s = 0.f, q = 0.f;
#pragma unroll
        for (int mt = 0; mt < 8; ++mt)
#pragma unroll
            for (int j = 0; j < 4; ++j) {
                int r = row0 + mt * 16 + lg * 4 + j;
                if (r < nrows) {
                    float y = acc[mt][nt][j] + bv;
                    Y[(size_t)r * HH + ncol] = y;
                    s += y;
                    q += y * y;
                }
            }
        if (colsum) {
            s += __shfl_xor(s, 16); s += __shfl_xor(s, 32);
            q += __shfl_xor(q, 16); q += __shfl_xor(q, 32);
            if (lg == 0) {
                atomicAdd(&colsum[ncol], s);
                atomicAdd(&colsum[128 + ncol], q);
            }
        }
    }
}

// ---------------- attention score: bf16x3 MFMA S = X@W1, tanh, dot w2, block-sum ----------------
// Same double-buffered chunk pipeline as cgemm.
__global__ __launch_bounds__(256) void k_attn(const float* __restrict__ XA, const float* __restrict__ XB,
                                              const u16* __restrict__ Ah, const u16* __restrict__ Al,
                                              const float* __restrict__ b1, const float* __restrict__ w2,
                                              float* __restrict__ PA, float* __restrict__ PB, int nrows) {
    __shared__ __attribute__((aligned(16))) char Xt[2][16384];
    __shared__ float red[4];
    int tid = threadIdx.x;
    bool second = blockIdx.x >= ATTN_GRID;
    const float* X = second ? XB : XA;
    float* partial = second ? PB : PA;
    int row0 = (second ? blockIdx.x - ATTN_GRID : blockIdx.x) * 128;
    int lane = tid & 63, wv = tid >> 6;
    int l15 = lane & 15, lg = lane >> 4;
    bool full = (row0 + 128 <= nrows);

    f32x4 acc[8];
#pragma unroll
    for (int i = 0; i < 8; ++i) acc[i] = (f32x4)(0.f);

    auto stage_chunk = [&](int c) {
        char* dst = Xt[c & 1];
        int kc = c * 32;
#pragma unroll
        for (int it = 0; it < 2; ++it) {
            int g2 = tid + it * 256;
            int r = g2 >> 2, gi = g2 & 3;
            float4 a = make_float4(0.f, 0.f, 0.f, 0.f), b = a;
            if (full || row0 + r < nrows) {
                const float* xp = &X[(size_t)(row0 + r) * HH + kc + gi * 8];
                a = *(const float4*)xp;
                b = *(const float4*)(xp + 4);
            }
            u16 h0 = f2bf(a.x), h1 = f2bf(a.y), h2 = f2bf(a.z), h3 = f2bf(a.w);
            u16 h4 = f2bf(b.x), h5 = f2bf(b.y), h6 = f2bf(b.z), h7 = f2bf(b.w);
            bf16x8 hv = {(short)h0, (short)h1, (short)h2, (short)h3,
                         (short)h4, (short)h5, (short)h6, (short)h7};
            bf16x8 lv = {(short)f2bf(a.x - bf2f(h0)), (short)f2bf(a.y - bf2f(h1)),
                         (short)f2bf(a.z - bf2f(h2)), (short)f2bf(a.w - bf2f(h3)),
                         (short)f2bf(b.x - bf2f(h4)), (short)f2bf(b.y - bf2f(h5)),
                         (short)f2bf(b.z - bf2f(h6)), (short)f2bf(b.w - bf2f(h7))};
            char* rb = dst + r * 128;
            *(bf16x8*)(rb + hi_off(gi, r)) = hv;
            *(bf16x8*)(rb + lo_off(gi, r)) = lv;
        }
    };

    stage_chunk(0);
#pragma unroll
    for (int c = 0; c < 4; ++c) {
        int kc = c * 32;
        int a = wv * 16 + l15;
        bf16x8 bh = *(const bf16x8*)&Ah[(size_t)a * HH + kc + lg * 8];
        bf16x8 bl = *(const bf16x8*)&Al[(size_t)a * HH + kc + lg * 8];
        __syncthreads();
        if (c < 3) stage_chunk(c + 1);
        const char* buf = Xt[c & 1];
#pragma unroll
        for (int mt = 0; mt < 8; ++mt) {
            int r = mt * 16 + l15;
            const char* rb = buf + r * 128;
            bf16x8 ah = *(const bf16x8*)(rb + hi_off(lg, r));
            bf16x8 al = *(const bf16x8*)(rb + lo_off(lg, r));
            acc[mt] = __builtin_amdgcn_mfma_f32_16x16x32_bf16(ah, bh, acc[mt], 0, 0, 0);
            acc[mt] = __builtin_amdgcn_mfma_f32_16x16x32_bf16(ah, bl, acc[mt], 0, 0, 0);
            acc[mt] = __builtin_amdgcn_mfma_f32_16x16x32_bf16(al, bh, acc[mt], 0, 0, 0);
        }
    }
    float b1v = b1[wv * 16 + l15];
    float w2v = w2[wv * 16 + l15];
    float tot = 0.f;
#pragma unroll
    for (int mt = 0; mt < 8; ++mt)
#pragma unroll
        for (int j = 0; j < 4; ++j) {
            int r = row0 + mt * 16 + lg * 4 + j;
            if (r < nrows) tot += tanhf(acc[mt][j] + b1v) * w2v;
        }
#pragma unroll
    for (int off = 32; off > 0; off >>= 1) tot += __shfl_xor(tot, off);
    if (lane == 0) red[wv] = tot;
    __syncthreads();
    if (tid == 0)
        partial[second ? (blockIdx.x - ATTN_GRID) : blockIdx.x] = red[0] + red[1] + red[2] + red[3];
}

__global__ void k_alpha(const float* __restrict__ P1, const float* __restrict__ P2,
                        float* __restrict__ alpha, int nparts, float invn) {
    __shared__ float s1[256], s2[256];
    int tid = threadIdx.x;
    float a = 0.f, b = 0.f;
    for (int i = tid; i < nparts; i += 256) { a += P1[i]; b += P2[i]; }
    s1[tid] = a; s2[tid] = b;
    __syncthreads();
    for (int off = 128; off > 0; off >>= 1) {
        if (tid < off) { s1[tid] += s1[tid + off]; s2[tid] += s2[tid + off]; }
        __syncthreads();
    }
    if (tid == 0) {
        float m1 = s1[0] * invn, m2 = s2[0] * invn;
        float mx = fmaxf(m1, m2);
        float e1 = expf(m1 - mx), e2 = expf(m2 - mx);
        float inv = 1.f / (e1 + e2);
        alpha[0] = e1 * inv; alpha[1] = e2 * inv;
    }
}

// ---------------- combine (attention mix) + column stats ----------------
__global__ __launch_bounds__(256) void k_comb(float* __restrict__ X, const float* __restrict__ Y,
                                              const float* __restrict__ alpha, float* __restrict__ colsum,
                                              float* __restrict__ colsq, int nrows) {
    int tid = threadIdx.x;
    int h = tid & 127, half = tid >> 7;
    float a0 = alpha[0], a1 = alpha[1];
    float s = 0.f, q = 0.f;
    for (int n = blockIdx.x * 2 + half; n < nrows; n += gridDim.x * 2) {
        size_t off = (size_t)n * HH + h;
        float v = a0 * X[off] + a1 * Y[off];
        X[off] = v;
        s += v; q += v * v;
    }
    __shared__ float ls[256], lq[256];
    ls[tid] = s; lq[tid] = q;
    __syncthreads();
    if (half == 0) {
        atomicAdd(&colsum[h], ls[tid] + ls[tid + 128]);
        atomicAdd(&colsq[h], lq[tid] + lq[tid + 128]);
    }
}

__global__ void k_bnp(const float* __restrict__ sum, const float* __restrict__ sq,
                      const float* __restrict__ gamma, const float* __restrict__ beta,
                      float* __restrict__ scale, float* __restrict__ shift, float invn) {
    int h = threadIdx.x;
    float mu = sum[h] * invn;
    float var = sq[h] * invn - mu * mu;
    float sc = gamma[h] * rsqrtf(var + 1.0f);
    scale[h] = sc;
    shift[h] = beta[h] - mu * sc;
}

// ---------------- final FC: 64-row LDS tile, BN+leaky applied ONCE during staging ----------------
__global__ __launch_bounds__(256) void k_fc(const float* __restrict__ X0, const float* __restrict__ X1,
                                            const float* __restrict__ sc0, const float* __restrict__ sc1,
                                            const float* __restrict__ Wall, const float* __restrict__ ball,
                                            float* __restrict__ out, int nrows) {
    __shared__ float Xl[64 * 132];   // 33 KB
    __shared__ float Wl[HH * CC];    // 8 KB
    __shared__ float bl[CC];
    __shared__ float scl[HH], sfl[HH];
    int which = blockIdx.y;
    const float* X = which ? X1 : X0;
    const float* scp = which ? sc1 : sc0;
    const float* W = Wall + which * HH * CC;
    float* o = out + (size_t)which * NN * CC;
    int tid = threadIdx.x;
    int row0 = blockIdx.x * 64;
    for (int i = tid * 4; i < HH * CC; i += 1024)
        *(float4*)&Wl[i] = *(const float4*)&W[i];
    if (tid < CC) bl[tid] = ball[which * CC + tid];
    if (tid < HH) { scl[tid] = scp[tid]; sfl[tid] = scp[128 + tid]; }
    __syncthreads();
    for (int idx = tid; idx < 2048; idx += 256) {
        int r = idx >> 5, cc = idx & 31;
        int n = row0 + r;
        float4 v = make_float4(0.f, 0.f, 0.f, 0.f);
        if (n < nrows) v = *(const float4*)&X[(size_t)n * HH + cc * 4];
        float4 sc = *(const float4*)&scl[cc * 4];
        float4 sf = *(const float4*)&sfl[cc * 4];
        v.x = v.x * sc.x + sf.x; v.y = v.y * sc.y + sf.y;
        v.z = v.z * sc.z + sf.z; v.w = v.w * sc.w + sf.w;
        v.x = v.x >= 0.f ? v.x : 0.01f * v.x;
        v.y = v.y >= 0.f ? v.y : 0.01f * v.y;
        v.z = v.z >= 0.f ? v.z : 0.01f * v.z;
        v.w = v.w >= 0.f ? v.w : 0.01f * v.w;
        *(float4*)&Xl[r * 132 + cc * 4] = v;
    }
    __syncthreads();
    int c = tid & 15, nl = tid >> 4;
    const float* x0 = &Xl[(nl + 0) * 132];
    const float* x1 = &Xl[(nl + 16) * 132];
    const float* x2 = &Xl[(nl + 32) * 132];
    const float* x3 = &Xl[(nl + 48) * 132];
    float a0 = bl[c], a1 = a0, a2 = a0, a3 = a0;
#pragma unroll 8
    for (int h = 0; h < HH; ++h) {
        float w = Wl[h * CC + c];
        a0 += x0[h] * w;
        a1 += x1[h] * w;
        a2 += x2[h] * w;
        a3 += x3[h] * w;
    }
    int n0 = row0 + nl;
    if (n0 < nrows) o[(size_t)n0 * CC + c] = a0;
    if (n0 + 16 < nrows) o[(size_t)(n0 + 16) * CC + c] = a1;
    if (n0 + 32 < nrows) o[(size_t)(n0 + 32) * CC + c] = a2;
    if (n0 + 48 < nrows) o[(size_t)(n0 + 48) * CC + c] = a3;
}

extern "C" void kernel_launch(void* const* d_in, const int* in_sizes, int n_in,
                              void* d_out, int out_size, void* d_ws, size_t ws_size,
                              hipStream_t stream) {
    const float* xA = (const float*)d_in[0];
    const float* xB = (const float*)d_in[1];
    const float* Wsrc = (const float*)d_in[2];
    const float* bsrc = (const float*)d_in[3];
    const float* Wdst = (const float*)d_in[4];
    const float* bdst = (const float*)d_in[5];
    const float* Wupd = (const float*)d_in[6];
    const float* bupd = (const float*)d_in[7];
    const float* attnW1 = (const float*)d_in[8];
    const float* attnb1 = (const float*)d_in[9];
    const float* attnw2 = (const float*)d_in[10];
    const float* gamma = (const float*)d_in[11];
    const float* beta = (const float*)d_in[12];
    const float* fcW = (const float*)d_in[13];
    const float* fcb = (const float*)d_in[14];
    const int* eAB = (const int*)d_in[15];
    const int* eBB = (const int*)d_in[16];
    const int* eBA = (const int*)d_in[17];
    float* out = (float*)d_out;

    // workspace layout == round-13 passing footprint
    float* ws = (float*)d_ws;
    const size_t NH = (size_t)NN * HH;
    const size_t LRHH = (size_t)LL * RR * HH * HH;
    const size_t LAH = (size_t)LL * AAA * HH;
    float* B0 = ws;
    float* B1 = B0 + NH;
    float* B2 = B1 + NH;
    float* B3 = B2 + NH;
    u16* uWdh = (u16*)(B3 + NH);
    u16* uWdl = uWdh + LRHH;
    u16* uWsh = uWdl + LRHH;
    u16* uWsl = uWsh + LRHH;
    u16* uA1h = uWsl + LRHH;        // L*AAA*HH
    u16* uA1l = uA1h + LAH;
    float* fB = (float*)(uA1l + LAH);
    float* csA = fB + LL * RR * HH;  // [sum|sumsq] 256
    float* csB = csA + 256;          // adjacent: one memset covers both
    float* scA = csB + 256;
    float* scB = scA + 256;
    float* scA2 = scB + 256;         // layer-1 head scales
    float* scB2 = scA2 + 256;
    float* P1 = scB2 + 256;
    float* P2 = P1 + 1024;
    float* alp = P2 + 1024;
    int* icnt = (int*)(alp + 64);
    int* irs = icnt + 3 * NN;
    int* icsr = irs + 3 * NN;
    int* ifill = icsr + 3 * EE;     // unused (layout stability)
    int* ibsum = ifill + 3 * NN;
    int* pose = (int*)B3;           // 3*EE ints; B3 unused until layer 1
    const float invN = 1.0f / (float)NN;

    k_fuse_w<<<LL * RR * HH, 256, 0, stream>>>(Wsrc, Wdst, Wupd, uWdh, uWdl, uWsh, uWsl);
    k_fuse_b<<<LL * RR, HH, 0, stream>>>(bsrc, bdst, bupd, Wupd, fB);
    k_fuse_a<<<LL * AAA, HH, 0, stream>>>(attnW1, uA1h, uA1l);

    // CSR build: all 3 relations per kernel; k_count returns per-edge slot -> k_fill atomic-free
    hipMemsetAsync(icnt, 0, 3 * NN * 4, stream);
    k_count<<<dim3((EE + 255) / 256, 3), 256, 0, stream>>>(eAB, eBB, eBA, icnt, pose);
    k_scan1<<<dim3(SCAN_B, 3), 256, 0, stream>>>(icnt, irs, ibsum);
    k_scan2<<<3, 128, 0, stream>>>(ibsum);
    k_scan3<<<dim3((NN + 255) / 256, 3), 256, 0, stream>>>(irs, ibsum);
    k_fill<<<dim3((EE + 255) / 256, 3), 256, 0, stream>>>(eAB, eBB, eBA, pose, irs, icsr);

    const int GEMM_GRID = (NN + 127) / 128;
    const int AGGR_GRID = (NN + 3) / 4;

    // dest serves as packed X1 during aggr+cgemm, then holds f32 Y (in-place)
    auto conv = [&](float* dest, const float* xs, const float* xd, int rel, int lr,
                    const float* bn_xs, const float* bn_xd, float* stats) {
        k_aggr<<<AGGR_GRID, 256, 0, stream>>>((u16*)dest, xs, irs + rel * NN, icnt + rel * NN,
                                              icsr + (size_t)rel * EE, bn_xs);
        k_cgemm<<<GEMM_GRID, 256, 0, stream>>>(dest, (const u16*)dest, xd,
                                               uWsh + (size_t)lr * HH * HH, uWsl + (size_t)lr * HH * HH,
                                               uWdh + (size_t)lr * HH * HH, uWdl + (size_t)lr * HH * HH,
                                               fB + lr * HH, NN, bn_xd, stats);
    };

    // ================= layer 0 =================
    hipMemsetAsync(csA, 0, 512 * 4, stream);  // csA + csB
    conv(B0, xA, xB, 0, 0, nullptr, nullptr, nullptr);  // embB1
    conv(B1, xB, xB, 1, 1, nullptr, nullptr, nullptr);  // embB2
    conv(B2, xB, xA, 2, 2, nullptr, nullptr, csA);      // embA + stats
    k_attn<<<2 * ATTN_GRID, 256, 0, stream>>>(B0, B1, uA1h, uA1l, attnb1, attnw2, P1, P2, NN);
    k_alpha<<<1, 256, 0, stream>>>(P1, P2, alp, ATTN_GRID, invN);
    k_comb<<<512, 256, 0, stream>>>(B0, B1, alp, csB, csB + 128, NN);  // xB_new -> B0 (+stats)
    k_bnp<<<1, 128, 0, stream>>>(csA, csA + 128, gamma + 0 * HH, beta + 0 * HH, scA, scA + 128, invN);
    k_bnp<<<1, 128, 0, stream>>>(csB, csB + 128, gamma + 1 * HH, beta + 1 * HH, scB, scB + 128, invN);
    // no BN-apply pass: B2/B0 stay pre-BN; scA/scB applied by layer-1 consumers.

    // ================= layer 1 =================
    hipMemsetAsync(csA, 0, 512 * 4, stream);  // csA + csB
    conv(B1, B2, B0, 0, 3, scA, scB, nullptr);  // embB1'
    conv(B3, B0, B0, 1, 4, scB, scB, nullptr);  // embB2'
    k_attn<<<2 * ATTN_GRID, 256, 0, stream>>>(B1, B3, uA1h + (size_t)AAA * HH,
                                              uA1l + (size_t)AAA * HH,
                                              attnb1 + AAA, attnw2 + AAA, P1, P2, NN);
    k_alpha<<<1, 256, 0, stream>>>(P1, P2, alp, ATTN_GRID, invN);
    k_comb<<<512, 256, 0, stream>>>(B1, B3, alp, csB, csB + 128, NN);  // xB_new -> B1 (+stats)
    conv(B3, B0, B2, 2, 5, scB, scA, csA);  // embA' + stats
    k_bnp<<<1, 128, 0, stream>>>(csA, csA + 128, gamma + 2 * HH, beta + 2 * HH, scA2, scA2 + 128, invN);
    k_bnp<<<1, 128, 0, stream>>>(csB, csB + 128, gamma + 3 * HH, beta + 3 * HH, scB2, scB2 + 128, invN);

    // ================= head: BN+leaky fused into FC staging =================
    k_fc<<<dim3((NN + 63) / 64, 2), 256, 0, stream>>>(B3, B1, scA2, scB2, fcW, fcb, out, NN);
}

// Round 15
// 989.099 us; speedup vs baseline: 2.5898x; 1.0362x over previous
//
#include <hip/hip_runtime.h>

#define NN 100000
#define HH 128
#define EE 600000
#define LL 2
#define RR 3
#define AAA 64
#define CC 16
#define SCAN_B 98   // 98 blocks x 1024 elems covers 100000
#define ATTN_GRID ((NN + 127) / 128)

typedef unsigned short u16;
typedef unsigned int u32;
typedef __attribute__((ext_vector_type(8))) short bf16x8;
typedef __attribute__((ext_vector_type(4))) float f32x4;

__device__ inline u16 f2bf(float f) {   // RNE f32 -> bf16
    unsigned int u = __float_as_uint(f);
    return (u16)((u + 0x7FFF + ((u >> 16) & 1)) >> 16);
}
__device__ inline float bf2f(u16 h) { return __uint_as_float((unsigned int)h << 16); }

// Packed X layout (per row: 512B, 4 chunks of 128B; chunk = 4 groups of [16B hi][16B lo],
// XOR-swizzled by row). Shared by producer (k_aggr / cgemm phase-2 staging) and consumer
// (cgemm frag reads). row0 % 128 == 0 so block-local r has same r&7 as global row.
__device__ __forceinline__ int hi_off(int gi, int r) { return (gi * 32) ^ ((r & 7) << 4); }
__device__ __forceinline__ int lo_off(int gi, int r) { return (gi * 32 + 16) ^ ((r & 7) << 4); }

// async global->LDS, 16B per lane; dest must be linear (wave-uniform base + lane*16)
__device__ __forceinline__ void stage16(const void* g, void* l) {
    __builtin_amdgcn_global_load_lds((const __attribute__((address_space(1))) unsigned int*)g,
                                     (__attribute__((address_space(3))) unsigned int*)l, 16, 0, 0);
}

// ---------------- weight fusion: W transposed [n][k], split bf16 hi/lo ----------------
__global__ void k_fuse_w(const float* __restrict__ Wsrc, const float* __restrict__ Wdst,
                         const float* __restrict__ Wupd, u16* __restrict__ Wdt_hi,
                         u16* __restrict__ Wdt_lo, u16* __restrict__ Wst_hi,
                         u16* __restrict__ Wst_lo) {
    int b = blockIdx.x;
    int lr = b >> 7, i = b & 127;   // i = k index
    int t = threadIdx.x;
    int j = t & 127;                // j = n index
    const float* wu = Wupd + (size_t)lr * 2 * HH * HH;
    float acc = 0.f;
    size_t o = ((size_t)lr * HH + j) * HH + i;  // transposed store [n=j][k=i]
    if (t < 128) {
        const float* wd = Wdst + ((size_t)lr * HH + i) * HH;
        for (int k = 0; k < HH; ++k) acc += wd[k] * wu[k * HH + j];
        u16 h = f2bf(acc);
        Wdt_hi[o] = h;
        Wdt_lo[o] = f2bf(acc - bf2f(h));
    } else {
        const float* wsc = Wsrc + ((size_t)lr * HH + i) * HH;
        for (int k = 0; k < HH; ++k) acc += wsc[k] * wu[(HH + k) * HH + j];
        u16 h = f2bf(acc);
        Wst_hi[o] = h;
        Wst_lo[o] = f2bf(acc - bf2f(h));
    }
}

__global__ void k_fuse_b(const float* __restrict__ bsrc, const float* __restrict__ bdst,
                         const float* __restrict__ bupd, const float* __restrict__ Wupd,
                         float* __restrict__ fB) {
    int lr = blockIdx.x;
    int j = threadIdx.x;
    const float* wu = Wupd + (size_t)lr * 2 * HH * HH;
    const float* bd = bdst + lr * HH;
    const float* bs = bsrc + lr * HH;
    float acc = bupd[lr * HH + j];
    for (int k = 0; k < HH; ++k)
        acc += bd[k] * wu[k * HH + j] + bs[k] * wu[(HH + k) * HH + j];
    fB[lr * HH + j] = acc;
}

// attnW1 [L][H][A] -> transposed [L][A][H] bf16 hi/lo (for MFMA B-frags)
__global__ void k_fuse_a(const float* __restrict__ W1, u16* __restrict__ Ah,
                         u16* __restrict__ Al) {
    int b = blockIdx.x;            // l*AAA + a
    int l = b >> 6, a = b & 63;
    int k = threadIdx.x;           // 128 threads
    float v = W1[((size_t)l * HH + k) * AAA + a];
    u16 h = f2bf(v);
    size_t o = (size_t)b * HH + k;
    Ah[o] = h;
    Al[o] = f2bf(v - bf2f(h));
}

// ---------------- CSR build: batched over 3 relations; count stores per-edge slot ----------------
__global__ void k_count(const int* __restrict__ e0, const int* __restrict__ e1,
                        const int* __restrict__ e2, int* __restrict__ cnt,
                        int* __restrict__ pose) {
    int rel = blockIdx.y;
    const int* d = (rel == 0 ? e0 : rel == 1 ? e1 : e2) + EE;
    int i = blockIdx.x * 256 + threadIdx.x;
    if (i < EE) pose[rel * EE + i] = atomicAdd(&cnt[rel * NN + d[i]], 1);
}

__global__ void k_scan1(const int* __restrict__ cnt_all, int* __restrict__ rs_all,
                        int* __restrict__ bsum) {
    __shared__ int sd[256];
    int rel = blockIdx.y;
    const int* cnt = cnt_all + rel * NN;
    int* rs = rs_all + rel * NN;
    int blk = blockIdx.x, tid = threadIdx.x;
    int base = blk * 1024 + tid * 4;
    int c0 = 0, c1 = 0, c2 = 0, c3 = 0;
    if (base + 0 < NN) c0 = cnt[base + 0];
    if (base + 1 < NN) c1 = cnt[base + 1];
    if (base + 2 < NN) c2 = cnt[base + 2];
    if (base + 3 < NN) c3 = cnt[base + 3];
    int s = c0 + c1 + c2 + c3;
    sd[tid] = s;
    __syncthreads();
    for (int off = 1; off < 256; off <<= 1) {
        int v = (tid >= off) ? sd[tid - off] : 0;
        __syncthreads();
        sd[tid] += v;
        __syncthreads();
    }
    int excl = sd[tid] - s;
    if (tid == 255) bsum[rel * 128 + blk] = sd[255];
    if (base + 0 < NN) rs[base + 0] = excl;
    if (base + 1 < NN) rs[base + 1] = excl + c0;
    if (base + 2 < NN) rs[base + 2] = excl + c0 + c1;
    if (base + 3 < NN) rs[base + 3] = excl + c0 + c1 + c2;
}

__global__ void k_scan2(int* __restrict__ bsum) {  // grid = 3, 128 threads
    __shared__ int sd[128];
    int rel = blockIdx.x;
    int tid = threadIdx.x;
    int v = (tid < SCAN_B) ? bsum[rel * 128 + tid] : 0;
    sd[tid] = v;
    __syncthreads();
    for (int off = 1; off < 128; off <<= 1) {
        int u = (tid >= off) ? sd[tid - off] : 0;
        __syncthreads();
        sd[tid] += u;
        __syncthreads();
    }
    if (tid < SCAN_B) bsum[rel * 128 + tid] = sd[tid] - v;  // exclusive
}

__global__ void k_scan3(int* __restrict__ rs_all, const int* __restrict__ bsum) {
    int rel = blockIdx.y;
    int i = blockIdx.x * 256 + threadIdx.x;
    if (i < NN) rs_all[rel * NN + i] += bsum[rel * 128 + (i >> 10)];
}

// atomic-free scatter: slot precomputed by k_count
__global__ void k_fill(const int* __restrict__ e0, const int* __restrict__ e1,
                       const int* __restrict__ e2, const int* __restrict__ pose,
                       const int* __restrict__ rs_all, int* __restrict__ csr_all) {
    int rel = blockIdx.y;
    const int* e = rel == 0 ? e0 : rel == 1 ? e1 : e2;
    int i = blockIdx.x * 256 + threadIdx.x;
    if (i >= EE) return;
    int s = e[i], d = e[EE + i];
    csr_all[(size_t)rel * EE + rs_all[rel * NN + d] + pose[rel * EE + i]] = s;
}

// ---------------- aggregation: TWO nodes per wave (32 lanes/node), 4-edge batched gather ----------------
// Each half-wave owns one node; one wave64 vmem instruction spans two gathered rows -> 2x MLP.
// Lane l(0..31) covers elems 4l..4l+3 (float4, 512B row coalesced).
__global__ __launch_bounds__(256) void k_aggr(u16* __restrict__ Xp, const float* __restrict__ xs,
                                              const int* __restrict__ rs, const int* __restrict__ cnt,
                                              const int* __restrict__ csr,
                                              const float* __restrict__ bnsc) {
    int node = blockIdx.x * 8 + (threadIdx.x >> 5);
    if (node >= NN) return;
    int l = threadIdx.x & 31;
    int beg = rs[node], deg = cnt[node];
    const float4* xs4 = (const float4*)xs;
    bool bn = bnsc != nullptr;
    float4 scv = make_float4(1.f, 1.f, 1.f, 1.f), sfv = make_float4(0.f, 0.f, 0.f, 0.f);
    if (bn) {
        scv = *(const float4*)&bnsc[l * 4];
        sfv = *(const float4*)&bnsc[128 + l * 4];
    }
    auto xf = [&](float4 v) {
        if (bn) {
            v.x = v.x * scv.x + sfv.x; v.y = v.y * scv.y + sfv.y;
            v.z = v.z * scv.z + sfv.z; v.w = v.w * scv.w + sfv.w;
            v.x = v.x >= 0.f ? v.x : 0.01f * v.x;
            v.y = v.y >= 0.f ? v.y : 0.01f * v.y;
            v.z = v.z >= 0.f ? v.z : 0.01f * v.z;
            v.w = v.w >= 0.f ? v.w : 0.01f * v.w;
        }
        return v;
    };
    float ax = 0.f, ay = 0.f, az = 0.f, aw = 0.f;
    int j = 0;
    for (; j + 4 <= deg; j += 4) {
        int s0 = csr[beg + j], s1 = csr[beg + j + 1];
        int s2 = csr[beg + j + 2], s3 = csr[beg + j + 3];
        float4 v0 = xf(xs4[(size_t)s0 * 32 + l]);
        float4 v1 = xf(xs4[(size_t)s1 * 32 + l]);
        float4 v2 = xf(xs4[(size_t)s2 * 32 + l]);
        float4 v3 = xf(xs4[(size_t)s3 * 32 + l]);
        ax += (v0.x + v1.x) + (v2.x + v3.x);
        ay += (v0.y + v1.y) + (v2.y + v3.y);
        az += (v0.z + v1.z) + (v2.z + v3.z);
        aw += (v0.w + v1.w) + (v2.w + v3.w);
    }
    if (j + 2 <= deg) {
        int s0 = csr[beg + j], s1 = csr[beg + j + 1];
        float4 v0 = xf(xs4[(size_t)s0 * 32 + l]);
        float4 v1 = xf(xs4[(size_t)s1 * 32 + l]);
        ax += v0.x + v1.x; ay += v0.y + v1.y;
        az += v0.z + v1.z; aw += v0.w + v1.w;
        j += 2;
    }
    if (j < deg) {
        float4 v = xf(xs4[(size_t)csr[beg + j] * 32 + l]);
        ax += v.x; ay += v.y; az += v.z; aw += v.w;
    }
    float sc = 1.0f / fmaxf((float)deg, 1.0f);
    float vx = ax * sc, vy = ay * sc, vz = az * sc, vw = aw * sc;
    u16 h0 = f2bf(vx), h1 = f2bf(vy), h2 = f2bf(vz), h3 = f2bf(vw);
    u16 l0 = f2bf(vx - bf2f(h0)), l1 = f2bf(vy - bf2f(h1));
    u16 l2 = f2bf(vz - bf2f(h2)), l3 = f2bf(vw - bf2f(h3));
    // elems 4l..4l+3: 16-elem group g16 = l>>1 -> chunk g16>>2 (=l>>3), gi = g16&3, 8B slot (l&1)*8
    int gi = (l >> 1) & 3;
    char* base = (char*)Xp + (size_t)node * 512 + (l >> 3) * 128;
    int jb = (l & 1) * 8;
    u32* hp = (u32*)(base + hi_off(gi, node) + jb);
    u32* lp = (u32*)(base + lo_off(gi, node) + jb);
    __builtin_nontemporal_store(((u32)h1 << 16) | h0, hp);
    __builtin_nontemporal_store(((u32)h3 << 16) | h2, hp + 1);
    __builtin_nontemporal_store(((u32)l1 << 16) | l0, lp);
    __builtin_nontemporal_store(((u32)l3 << 16) | l2, lp + 1);
}

// ---------------- fused conv GEMM: Y = X1@W1 + X2@W2 + bias, bf16x3 MFMA ----------------
// Chunk-level double-buffered LDS: stage chunk c+1 while MFMA on chunk c.
__global__ __launch_bounds__(256) void k_cgemm(float* Y, const u16* X1p,
                                               const float* __restrict__ X2,
                                               const u16* __restrict__ W1h, const u16* __restrict__ W1l,
                                               const u16* __restrict__ W2h, const u16* __restrict__ W2l,
                                               const float* __restrict__ bias, int nrows,
                                               const float* __restrict__ bnsc2,
                                               float* __restrict__ colsum) {
    __shared__ __attribute__((aligned(16))) char Xt[2][16384];  // double-buffered chunk tiles
    int tid = threadIdx.x;
    int row0 = blockIdx.x * 128;
    int lane = tid & 63, wv = tid >> 6;
    int l15 = lane & 15, lg = lane >> 4;
    bool full = (row0 + 128 <= nrows);

    f32x4 acc[8][2];
#pragma unroll
    for (int i = 0; i < 8; ++i)
#pragma unroll
        for (int j = 0; j < 2; ++j) acc[i][j] = (f32x4)(0.f);

    auto stage_chunk = [&](int c) {
        char* dst = Xt[c & 1];
        if (c < 4) {
#pragma unroll
            for (int p = 0; p < 4; ++p) {
                int tb = p * 4096 + tid * 16;
                int r = tb >> 7, off = tb & 127;
                stage16((const char*)X1p + (size_t)(row0 + r) * 512 + (c & 3) * 128 + off,
                        dst + tb);
            }
        } else {
            int kc = (c & 3) * 32;
#pragma unroll
            for (int it = 0; it < 2; ++it) {
                int g2 = tid + it * 256;
                int r = g2 >> 2, gi = g2 & 3;
                float4 a = make_float4(0.f, 0.f, 0.f, 0.f), b = a;
                if (full || row0 + r < nrows) {
                    const float* xp = &X2[(size_t)(row0 + r) * HH + kc + gi * 8];
                    a = *(const float4*)xp;
                    b = *(const float4*)(xp + 4);
                }
                if (bnsc2) {
                    const float* scp = bnsc2 + kc + gi * 8;
                    const float* sfp = bnsc2 + 128 + kc + gi * 8;
                    float4 s0 = *(const float4*)scp, s1 = *(const float4*)(scp + 4);
                    float4 f0 = *(const float4*)sfp, f1 = *(const float4*)(sfp + 4);
                    a.x = a.x * s0.x + f0.x; a.y = a.y * s0.y + f0.y;
                    a.z = a.z * s0.z + f0.z; a.w = a.w * s0.w + f0.w;
                    b.x = b.x * s1.x + f1.x; b.y = b.y * s1.y + f1.y;
                    b.z = b.z * s1.z + f1.z; b.w = b.w * s1.w + f1.w;
                    a.x = a.x >= 0.f ? a.x : 0.01f * a.x;
                    a.y = a.y >= 0.f ? a.y : 0.01f * a.y;
                    a.z = a.z >= 0.f ? a.z : 0.01f * a.z;
                    a.w = a.w >= 0.f ? a.w : 0.01f * a.w;
                    b.x = b.x >= 0.f ? b.x : 0.01f * b.x;
                    b.y = b.y >= 0.f ? b.y : 0.01f * b.y;
                    b.z = b.z >= 0.f ? b.z : 0.01f * b.z;
                    b.w = b.w >= 0.f ? b.w : 0.01f * b.w;
                }
                u16 h0 = f2bf(a.x), h1 = f2bf(a.y), h2 = f2bf(a.z), h3 = f2bf(a.w);
                u16 h4 = f2bf(b.x), h5 = f2bf(b.y), h6 = f2bf(b.z), h7 = f2bf(b.w);
                bf16x8 hv = {(short)h0, (short)h1, (short)h2, (short)h3,
                             (short)h4, (short)h5, (short)h6, (short)h7};
                bf16x8 lv = {(short)f2bf(a.x - bf2f(h0)), (short)f2bf(a.y - bf2f(h1)),
                             (short)f2bf(a.z - bf2f(h2)), (short)f2bf(a.w - bf2f(h3)),
                             (short)f2bf(b.x - bf2f(h4)), (short)f2bf(b.y - bf2f(h5)),
                             (short)f2bf(b.z - bf2f(h6)), (short)f2bf(b.w - bf2f(h7))};
                char* rb = dst + r * 128;
                *(bf16x8*)(rb + hi_off(gi, r)) = hv;
                *(bf16x8*)(rb + lo_off(gi, r)) = lv;
            }
        }
    };

    stage_chunk(0);
#pragma unroll
    for (int c = 0; c < 8; ++c) {
        const u16* Wh = (c < 4) ? W1h : W2h;
        const u16* Wl = (c < 4) ? W1l : W2l;
        int kc = (c & 3) * 32;
        bf16x8 bh[2], bl[2];
#pragma unroll
        for (int nt = 0; nt < 2; ++nt) {
            int n = (wv * 2 + nt) * 16 + l15;
            bh[nt] = *(const bf16x8*)&Wh[(size_t)n * HH + kc + lg * 8];
            bl[nt] = *(const bf16x8*)&Wl[(size_t)n * HH + kc + lg * 8];
        }
        __syncthreads();  // chunk c staged & chunk c-1 fully consumed
        if (c < 7) stage_chunk(c + 1);  // overlaps with MFMA below
        const char* buf = Xt[c & 1];
#pragma unroll
        for (int mt = 0; mt < 8; ++mt) {
            int r = mt * 16 + l15;
            const char* rb = buf + r * 128;
            bf16x8 ah = *(const bf16x8*)(rb + hi_off(lg, r));
            bf16x8 al = *(const bf16x8*)(rb + lo_off(lg, r));
#pragma unroll
            for (int nt = 0; nt < 2; ++nt) {
                acc[mt][nt] = __builtin_amdgcn_mfma_f32_16x16x32_bf16(ah, bh[nt], acc[mt][nt], 0, 0, 0);
                acc[mt][nt] = __builtin_amdgcn_mfma_f32_16x16x32_bf16(ah, bl[nt], acc[mt][nt], 0, 0, 0);
                acc[mt][nt] = __builtin_amdgcn_mfma_f32_16x16x32_bf16(al, bh[nt], acc[mt][nt], 0, 0, 0);
            }
        }
    }
#pragma unroll
    for (int nt = 0; nt < 2; ++nt) {
        int ncol = (wv * 2 + nt) * 16 + l15;
        float bv = bias[ncol];
        float s = 0.f, q = 0.f;
#pragma unroll
        for (int mt = 0; mt < 8; ++mt)
#pragma unroll
            for (int j = 0; j < 4; ++j) {
                int r = row0 + mt * 16 + lg * 4 + j;
                if (r < nrows) {
                    float y = acc[mt][nt][j] + bv;
                    Y[(size_t)r * HH + ncol] = y;
                    s += y;
                    q += y * y;
                }
            }
        if (colsum) {
            s += __shfl_xor(s, 16); s += __shfl_xor(s, 32);
            q += __shfl_xor(q, 16); q += __shfl_xor(q, 32);
            if (lg == 0) {
                atomicAdd(&colsum[ncol], s);
                atomicAdd(&colsum[128 + ncol], q);
            }
        }
    }
}

// ---------------- attention score: bf16x3 MFMA S = X@W1, tanh, dot w2, block-sum ----------------
__global__ __launch_bounds__(256) void k_attn(const float* __restrict__ XA, const float* __restrict__ XB,
                                              const u16* __restrict__ Ah, const u16* __restrict__ Al,
                                              const float* __restrict__ b1, const float* __restrict__ w2,
                                              float* __restrict__ PA, float* __restrict__ PB, int nrows) {
    __shared__ __attribute__((aligned(16))) char Xt[2][16384];
    __shared__ float red[4];
    int tid = threadIdx.x;
    bool second = blockIdx.x >= ATTN_GRID;
    const float* X = second ? XB : XA;
    float* partial = second ? PB : PA;
    int row0 = (second ? blockIdx.x - ATTN_GRID : blockIdx.x) * 128;
    int lane = tid & 63, wv = tid >> 6;
    int l15 = lane & 15, lg = lane >> 4;
    bool full = (row0 + 128 <= nrows);

    f32x4 acc[8];
#pragma unroll
    for (int i = 0; i < 8; ++i) acc[i] = (f32x4)(0.f);

    auto stage_chunk = [&](int c) {
        char* dst = Xt[c & 1];
        int kc = c * 32;
#pragma unroll
        for (int it = 0; it < 2; ++it) {
            int g2 = tid + it * 256;
            int r = g2 >> 2, gi = g2 & 3;
            float4 a = make_float4(0.f, 0.f, 0.f, 0.f), b = a;
            if (full || row0 + r < nrows) {
                const float* xp = &X[(size_t)(row0 + r) * HH + kc + gi * 8];
                a = *(const float4*)xp;
                b = *(const float4*)(xp + 4);
            }
            u16 h0 = f2bf(a.x), h1 = f2bf(a.y), h2 = f2bf(a.z), h3 = f2bf(a.w);
            u16 h4 = f2bf(b.x), h5 = f2bf(b.y), h6 = f2bf(b.z), h7 = f2bf(b.w);
            bf16x8 hv = {(short)h0, (short)h1, (short)h2, (short)h3,
                         (short)h4, (short)h5, (short)h6, (short)h7};
            bf16x8 lv = {(short)f2bf(a.x - bf2f(h0)), (short)f2bf(a.y - bf2f(h1)),
                         (short)f2bf(a.z - bf2f(h2)), (short)f2bf(a.w - bf2f(h3)),
                         (short)f2bf(b.x - bf2f(h4)), (short)f2bf(b.y - bf2f(h5)),
                         (short)f2bf(b.z - bf2f(h6)), (short)f2bf(b.w - bf2f(h7))};
            char* rb = dst + r * 128;
            *(bf16x8*)(rb + hi_off(gi, r)) = hv;
            *(bf16x8*)(rb + lo_off(gi, r)) = lv;
        }
    };

    stage_chunk(0);
#pragma unroll
    for (int c = 0; c < 4; ++c) {
        int kc = c * 32;
        int a = wv * 16 + l15;
        bf16x8 bh = *(const bf16x8*)&Ah[(size_t)a * HH + kc + lg * 8];
        bf16x8 bl = *(const bf16x8*)&Al[(size_t)a * HH + kc + lg * 8];
        __syncthreads();
        if (c < 3) stage_chunk(c + 1);
        const char* buf = Xt[c & 1];
#pragma unroll
        for (int mt = 0; mt < 8; ++mt) {
            int r = mt * 16 + l15;
            const char* rb = buf + r * 128;
            bf16x8 ah = *(const bf16x8*)(rb + hi_off(lg, r));
            bf16x8 al = *(const bf16x8*)(rb + lo_off(lg, r));
            acc[mt] = __builtin_amdgcn_mfma_f32_16x16x32_bf16(ah, bh, acc[mt], 0, 0, 0);
            acc[mt] = __builtin_amdgcn_mfma_f32_16x16x32_bf16(ah, bl, acc[mt], 0, 0, 0);
            acc[mt] = __builtin_amdgcn_mfma_f32_16x16x32_bf16(al, bh, acc[mt], 0, 0, 0);
        }
    }
    float b1v = b1[wv * 16 + l15];
    float w2v = w2[wv * 16 + l15];
    float tot = 0.f;
#pragma unroll
    for (int mt = 0; mt < 8; ++mt)
#pragma unroll
        for (int j = 0; j < 4; ++j) {
            int r = row0 + mt * 16 + lg * 4 + j;
            if (r < nrows) tot += tanhf(acc[mt][j] + b1v) * w2v;
        }
#pragma unroll
    for (int off = 32; off > 0; off >>= 1) tot += __shfl_xor(tot, off);
    if (lane == 0) red[wv] = tot;
    __syncthreads();
    if (tid == 0)
        partial[second ? (blockIdx.x - ATTN_GRID) : blockIdx.x] = red[0] + red[1] + red[2] + red[3];
}

__global__ void k_alpha(const float* __restrict__ P1, const float* __restrict__ P2,
                        float* __restrict__ alpha, int nparts, float invn) {
    __shared__ float s1[256], s2[256];
    int tid = threadIdx.x;
    float a = 0.f, b = 0.f;
    for (int i = tid; i < nparts; i += 256) { a += P1[i]; b += P2[i]; }
    s1[tid] = a; s2[tid] = b;
    __syncthreads();
    for (int off = 128; off > 0; off >>= 1) {
        if (tid < off) { s1[tid] += s1[tid + off]; s2[tid] += s2[tid + off]; }
        __syncthreads();
    }
    if (tid == 0) {
        float m1 = s1[0] * invn, m2 = s2[0] * invn;
        float mx = fmaxf(m1, m2);
        float e1 = expf(m1 - mx), e2 = expf(m2 - mx);
        float inv = 1.f / (e1 + e2);
        alpha[0] = e1 * inv; alpha[1] = e2 * inv;
    }
}

// ---------------- combine (attention mix) + column stats ----------------
__global__ __launch_bounds__(256) void k_comb(float* __restrict__ X, const float* __restrict__ Y,
                                              const float* __restrict__ alpha, float* __restrict__ colsum,
                                              float* __restrict__ colsq, int nrows) {
    int tid = threadIdx.x;
    int h = tid & 127, half = tid >> 7;
    float a0 = alpha[0], a1 = alpha[1];
    float s = 0.f, q = 0.f;
    for (int n = blockIdx.x * 2 + half; n < nrows; n += gridDim.x * 2) {
        size_t off = (size_t)n * HH + h;
        float v = a0 * X[off] + a1 * Y[off];
        X[off] = v;
        s += v; q += v * v;
    }
    __shared__ float ls[256], lq[256];
    ls[tid] = s; lq[tid] = q;
    __syncthreads();
    if (half == 0) {
        atomicAdd(&colsum[h], ls[tid] + ls[tid + 128]);
        atomicAdd(&colsq[h], lq[tid] + lq[tid + 128]);
    }
}

// both BN-param computations in one launch: blockIdx.x = which (0/1)
// cs = [sumA(128)|sqA(128)|sumB(128)|sqB(128)], scout = [scA|sfA|scB|sfB]
__global__ void k_bnp2(const float* __restrict__ cs, const float* __restrict__ gamma,
                       const float* __restrict__ beta, float* __restrict__ scout, float invn) {
    int which = blockIdx.x;
    int h = threadIdx.x;
    float mu = cs[which * 256 + h] * invn;
    float var = cs[which * 256 + 128 + h] * invn - mu * mu;
    float sc = gamma[which * HH + h] * rsqrtf(var + 1.0f);
    scout[which * 256 + h] = sc;
    scout[which * 256 + 128 + h] = beta[which * HH + h] - mu * sc;
}

// ---------------- final FC: 64-row LDS tile, BN+leaky applied ONCE during staging ----------------
__global__ __launch_bounds__(256) void k_fc(const float* __restrict__ X0, const float* __restrict__ X1,
                                            const float* __restrict__ sc0, const float* __restrict__ sc1,
                                            const float* __restrict__ Wall, const float* __restrict__ ball,
                                            float* __restrict__ out, int nrows) {
    __shared__ float Xl[64 * 132];   // 33 KB
    __shared__ float Wl[HH * CC];    // 8 KB
    __shared__ float bl[CC];
    __shared__ float scl[HH], sfl[HH];
    int which = blockIdx.y;
    const float* X = which ? X1 : X0;
    const float* scp = which ? sc1 : sc0;
    const float* W = Wall + which * HH * CC;
    float* o = out + (size_t)which * NN * CC;
    int tid = threadIdx.x;
    int row0 = blockIdx.x * 64;
    for (int i = tid * 4; i < HH * CC; i += 1024)
        *(float4*)&Wl[i] = *(const float4*)&W[i];
    if (tid < CC) bl[tid] = ball[which * CC + tid];
    if (tid < HH) { scl[tid] = scp[tid]; sfl[tid] = scp[128 + tid]; }
    __syncthreads();
    for (int idx = tid; idx < 2048; idx += 256) {
        int r = idx >> 5, cc = idx & 31;
        int n = row0 + r;
        float4 v = make_float4(0.f, 0.f, 0.f, 0.f);
        if (n < nrows) v = *(const float4*)&X[(size_t)n * HH + cc * 4];
        float4 sc = *(const float4*)&scl[cc * 4];
        float4 sf = *(const float4*)&sfl[cc * 4];
        v.x = v.x * sc.x + sf.x; v.y = v.y * sc.y + sf.y;
        v.z = v.z * sc.z + sf.z; v.w = v.w * sc.w + sf.w;
        v.x = v.x >= 0.f ? v.x : 0.01f * v.x;
        v.y = v.y >= 0.f ? v.y : 0.01f * v.y;
        v.z = v.z >= 0.f ? v.z : 0.01f * v.z;
        v.w = v.w >= 0.f ? v.w : 0.01f * v.w;
        *(float4*)&Xl[r * 132 + cc * 4] = v;
    }
    __syncthreads();
    int c = tid & 15, nl = tid >> 4;
    const float* x0 = &Xl[(nl + 0) * 132];
    const float* x1 = &Xl[(nl + 16) * 132];
    const float* x2 = &Xl[(nl + 32) * 132];
    const float* x3 = &Xl[(nl + 48) * 132];
    float a0 = bl[c], a1 = a0, a2 = a0, a3 = a0;
#pragma unroll 8
    for (int h = 0; h < HH; ++h) {
        float w = Wl[h * CC + c];
        a0 += x0[h] * w;
        a1 += x1[h] * w;
        a2 += x2[h] * w;
        a3 += x3[h] * w;
    }
    int n0 = row0 + nl;
    if (n0 < nrows) o[(size_t)n0 * CC + c] = a0;
    if (n0 + 16 < nrows) o[(size_t)(n0 + 16) * CC + c] = a1;
    if (n0 + 32 < nrows) o[(size_t)(n0 + 32) * CC + c] = a2;
    if (n0 + 48 < nrows) o[(size_t)(n0 + 48) * CC + c] = a3;
}

extern "C" void kernel_launch(void* const* d_in, const int* in_sizes, int n_in,
                              void* d_out, int out_size, void* d_ws, size_t ws_size,
                              hipStream_t stream) {
    const float* xA = (const float*)d_in[0];
    const float* xB = (const float*)d_in[1];
    const float* Wsrc = (const float*)d_in[2];
    const float* bsrc = (const float*)d_in[3];
    const float* Wdst = (const float*)d_in[4];
    const float* bdst = (const float*)d_in[5];
    const float* Wupd = (const float*)d_in[6];
    const float* bupd = (const float*)d_in[7];
    const float* attnW1 = (const float*)d_in[8];
    const float* attnb1 = (const float*)d_in[9];
    const float* attnw2 = (const float*)d_in[10];
    const float* gamma = (const float*)d_in[11];
    const float* beta = (const float*)d_in[12];
    const float* fcW = (const float*)d_in[13];
    const float* fcb = (const float*)d_in[14];
    const int* eAB = (const int*)d_in[15];
    const int* eBB = (const int*)d_in[16];
    const int* eBA = (const int*)d_in[17];
    float* out = (float*)d_out;

    // workspace layout == round-14 passing footprint
    float* ws = (float*)d_ws;
    const size_t NH = (size_t)NN * HH;
    const size_t LRHH = (size_t)LL * RR * HH * HH;
    const size_t LAH = (size_t)LL * AAA * HH;
    float* B0 = ws;
    float* B1 = B0 + NH;
    float* B2 = B1 + NH;
    float* B3 = B2 + NH;
    u16* uWdh = (u16*)(B3 + NH);
    u16* uWdl = uWdh + LRHH;
    u16* uWsh = uWdl + LRHH;
    u16* uWsl = uWsh + LRHH;
    u16* uA1h = uWsl + LRHH;        // L*AAA*HH
    u16* uA1l = uA1h + LAH;
    float* fB = (float*)(uA1l + LAH);
    float* csA = fB + LL * RR * HH;  // [sumA|sqA|sumB|sqB] 512
    float* csB = csA + 256;
    float* scA = csB + 256;          // [scA|sfA|scB|sfB] 512
    float* scB = scA + 256;
    float* scA2 = scB + 256;         // layer-1 head scales [scA2|sfA2|scB2|sfB2]
    float* scB2 = scA2 + 256;
    float* P1 = scB2 + 256;
    float* P2 = P1 + 1024;
    float* alp = P2 + 1024;
    int* icnt = (int*)(alp + 64);
    int* irs = icnt + 3 * NN;
    int* icsr = irs + 3 * NN;
    int* ifill = icsr + 3 * EE;     // unused (layout stability)
    int* ibsum = ifill + 3 * NN;
    int* pose = (int*)B3;           // 3*EE ints; B3 unused until layer 1
    const float invN = 1.0f / (float)NN;

    k_fuse_w<<<LL * RR * HH, 256, 0, stream>>>(Wsrc, Wdst, Wupd, uWdh, uWdl, uWsh, uWsl);
    k_fuse_b<<<LL * RR, HH, 0, stream>>>(bsrc, bdst, bupd, Wupd, fB);
    k_fuse_a<<<LL * AAA, HH, 0, stream>>>(attnW1, uA1h, uA1l);

    // CSR build: all 3 relations per kernel; k_count returns per-edge slot -> k_fill atomic-free
    hipMemsetAsync(icnt, 0, 3 * NN * 4, stream);
    k_count<<<dim3((EE + 255) / 256, 3), 256, 0, stream>>>(eAB, eBB, eBA, icnt, pose);
    k_scan1<<<dim3(SCAN_B, 3), 256, 0, stream>>>(icnt, irs, ibsum);
    k_scan2<<<3, 128, 0, stream>>>(ibsum);
    k_scan3<<<dim3((NN + 255) / 256, 3), 256, 0, stream>>>(irs, ibsum);
    k_fill<<<dim3((EE + 255) / 256, 3), 256, 0, stream>>>(eAB, eBB, eBA, pose, irs, icsr);

    const int GEMM_GRID = (NN + 127) / 128;
    const int AGGR_GRID = (NN + 7) / 8;

    // dest serves as packed X1 during aggr+cgemm, then holds f32 Y (in-place)
    auto conv = [&](float* dest, const float* xs, const float* xd, int rel, int lr,
                    const float* bn_xs, const float* bn_xd, float* stats) {
        k_aggr<<<AGGR_GRID, 256, 0, stream>>>((u16*)dest, xs, irs + rel * NN, icnt + rel * NN,
                                              icsr + (size_t)rel * EE, bn_xs);
        k_cgemm<<<GEMM_GRID, 256, 0, stream>>>(dest, (const u16*)dest, xd,
                                               uWsh + (size_t)lr * HH * HH, uWsl + (size_t)lr * HH * HH,
                                               uWdh + (size_t)lr * HH * HH, uWdl + (size_t)lr * HH * HH,
                                               fB + lr * HH, NN, bn_xd, stats);
    };

    // ================= layer 0 =================
    hipMemsetAsync(csA, 0, 512 * 4, stream);  // csA + csB
    conv(B0, xA, xB, 0, 0, nullptr, nullptr, nullptr);  // embB1
    conv(B1, xB, xB, 1, 1, nullptr, nullptr, nullptr);  // embB2
    conv(B2, xB, xA, 2, 2, nullptr, nullptr, csA);      // embA + stats
    k_attn<<<2 * ATTN_GRID, 256, 0, stream>>>(B0, B1, uA1h, uA1l, attnb1, attnw2, P1, P2, NN);
    k_alpha<<<1, 256, 0, stream>>>(P1, P2, alp, ATTN_GRID, invN);
    k_comb<<<512, 256, 0, stream>>>(B0, B1, alp, csB, csB + 128, NN);  // xB_new -> B0 (+stats)
    k_bnp2<<<2, 128, 0, stream>>>(csA, gamma + 0 * HH, beta + 0 * HH, scA, invN);
    // no BN-apply pass: B2/B0 stay pre-BN; scA/scB applied by layer-1 consumers.

    // ================= layer 1 =================
    hipMemsetAsync(csA, 0, 512 * 4, stream);  // csA + csB
    conv(B1, B2, B0, 0, 3, scA, scB, nullptr);  // embB1'
    conv(B3, B0, B0, 1, 4, scB, scB, nullptr);  // embB2'
    k_attn<<<2 * ATTN_GRID, 256, 0, stream>>>(B1, B3, uA1h + (size_t)AAA * HH,
                                              uA1l + (size_t)AAA * HH,
                                              attnb1 + AAA, attnw2 + AAA, P1, P2, NN);
    k_alpha<<<1, 256, 0, stream>>>(P1, P2, alp, ATTN_GRID, invN);
    k_comb<<<512, 256, 0, stream>>>(B1, B3, alp, csB, csB + 128, NN);  // xB_new -> B1 (+stats)
    conv(B3, B0, B2, 2, 5, scB, scA, csA);  // embA' + stats
    k_bnp2<<<2, 128, 0, stream>>>(csA, gamma + 2 * HH, beta + 2 * HH, scA2, invN);

    // ================= head: BN+leaky fused into FC staging =================
    k_fc<<<dim3((NN + 63) / 64, 2), 256, 0, stream>>>(B3, B1, scA2, scB2, fcW, fcb, out, NN);
}

// Round 16
// 939.914 us; speedup vs baseline: 2.7253x; 1.0523x over previous
//
#include <hip/hip_runtime.h>

#define NN 100000
#define HH 128
#define EE 600000
#define LL 2
#define RR 3
#define AAA 64
#define CC 16
#define SCAN_B 98   // 98 blocks x 1024 elems covers 100000
#define ATTN_GRID ((NN + 127) / 128)

typedef unsigned short u16;
typedef unsigned int u32;
typedef __attribute__((ext_vector_type(8))) short bf16x8;
typedef __attribute__((ext_vector_type(4))) float f32x4;

__device__ inline u16 f2bf(float f) {   // RNE f32 -> bf16
    unsigned int u = __float_as_uint(f);
    return (u16)((u + 0x7FFF + ((u >> 16) & 1)) >> 16);
}
__device__ inline float bf2f(u16 h) { return __uint_as_float((unsigned int)h << 16); }

// Packed X layout (per row: 512B, 4 chunks of 128B; chunk = 4 groups of [16B hi][16B lo],
// XOR-swizzled by row). row0 % 128 == 0 so block-local r has same r&7 as global row.
__device__ __forceinline__ int hi_off(int gi, int r) { return (gi * 32) ^ ((r & 7) << 4); }
__device__ __forceinline__ int lo_off(int gi, int r) { return (gi * 32 + 16) ^ ((r & 7) << 4); }

// async global->LDS, 16B per lane; dest must be linear (wave-uniform base + lane*16)
__device__ __forceinline__ void stage16(const void* g, void* l) {
    __builtin_amdgcn_global_load_lds((const __attribute__((address_space(1))) unsigned int*)g,
                                     (__attribute__((address_space(3))) unsigned int*)l, 16, 0, 0);
}

// ---------------- weight fusion: W transposed [n][k], split bf16 hi/lo ----------------
__global__ void k_fuse_w(const float* __restrict__ Wsrc, const float* __restrict__ Wdst,
                         const float* __restrict__ Wupd, u16* __restrict__ Wdt_hi,
                         u16* __restrict__ Wdt_lo, u16* __restrict__ Wst_hi,
                         u16* __restrict__ Wst_lo) {
    int b = blockIdx.x;
    int lr = b >> 7, i = b & 127;   // i = k index
    int t = threadIdx.x;
    int j = t & 127;                // j = n index
    const float* wu = Wupd + (size_t)lr * 2 * HH * HH;
    float acc = 0.f;
    size_t o = ((size_t)lr * HH + j) * HH + i;  // transposed store [n=j][k=i]
    if (t < 128) {
        const float* wd = Wdst + ((size_t)lr * HH + i) * HH;
        for (int k = 0; k < HH; ++k) acc += wd[k] * wu[k * HH + j];
        u16 h = f2bf(acc);
        Wdt_hi[o] = h;
        Wdt_lo[o] = f2bf(acc - bf2f(h));
    } else {
        const float* wsc = Wsrc + ((size_t)lr * HH + i) * HH;
        for (int k = 0; k < HH; ++k) acc += wsc[k] * wu[(HH + k) * HH + j];
        u16 h = f2bf(acc);
        Wst_hi[o] = h;
        Wst_lo[o] = f2bf(acc - bf2f(h));
    }
}

__global__ void k_fuse_b(const float* __restrict__ bsrc, const float* __restrict__ bdst,
                         const float* __restrict__ bupd, const float* __restrict__ Wupd,
                         float* __restrict__ fB) {
    int lr = blockIdx.x;
    int j = threadIdx.x;
    const float* wu = Wupd + (size_t)lr * 2 * HH * HH;
    const float* bd = bdst + lr * HH;
    const float* bs = bsrc + lr * HH;
    float acc = bupd[lr * HH + j];
    for (int k = 0; k < HH; ++k)
        acc += bd[k] * wu[k * HH + j] + bs[k] * wu[(HH + k) * HH + j];
    fB[lr * HH + j] = acc;
}

// attnW1 [L][H][A] -> transposed [L][A][H] bf16 hi/lo (for MFMA B-frags)
__global__ void k_fuse_a(const float* __restrict__ W1, u16* __restrict__ Ah,
                         u16* __restrict__ Al) {
    int b = blockIdx.x;            // l*AAA + a
    int l = b >> 6, a = b & 63;
    int k = threadIdx.x;           // 128 threads
    float v = W1[((size_t)l * HH + k) * AAA + a];
    u16 h = f2bf(v);
    size_t o = (size_t)b * HH + k;
    Ah[o] = h;
    Al[o] = f2bf(v - bf2f(h));
}

// ---------------- CSR build: batched over 3 relations; count stores per-edge slot ----------------
__global__ void k_count(const int* __restrict__ e0, const int* __restrict__ e1,
                        const int* __restrict__ e2, int* __restrict__ cnt,
                        int* __restrict__ pose) {
    int rel = blockIdx.y;
    const int* d = (rel == 0 ? e0 : rel == 1 ? e1 : e2) + EE;
    int i = blockIdx.x * 256 + threadIdx.x;
    if (i < EE) pose[rel * EE + i] = atomicAdd(&cnt[rel * NN + d[i]], 1);
}

__global__ void k_scan1(const int* __restrict__ cnt_all, int* __restrict__ rs_all,
                        int* __restrict__ bsum) {
    __shared__ int sd[256];
    int rel = blockIdx.y;
    const int* cnt = cnt_all + rel * NN;
    int* rs = rs_all + rel * NN;
    int blk = blockIdx.x, tid = threadIdx.x;
    int base = blk * 1024 + tid * 4;
    int c0 = 0, c1 = 0, c2 = 0, c3 = 0;
    if (base + 0 < NN) c0 = cnt[base + 0];
    if (base + 1 < NN) c1 = cnt[base + 1];
    if (base + 2 < NN) c2 = cnt[base + 2];
    if (base + 3 < NN) c3 = cnt[base + 3];
    int s = c0 + c1 + c2 + c3;
    sd[tid] = s;
    __syncthreads();
    for (int off = 1; off < 256; off <<= 1) {
        int v = (tid >= off) ? sd[tid - off] : 0;
        __syncthreads();
        sd[tid] += v;
        __syncthreads();
    }
    int excl = sd[tid] - s;
    if (tid == 255) bsum[rel * 128 + blk] = sd[255];
    if (base + 0 < NN) rs[base + 0] = excl;
    if (base + 1 < NN) rs[base + 1] = excl + c0;
    if (base + 2 < NN) rs[base + 2] = excl + c0 + c1;
    if (base + 3 < NN) rs[base + 3] = excl + c0 + c1 + c2;
}

__global__ void k_scan2(int* __restrict__ bsum) {  // grid = 3, 128 threads
    __shared__ int sd[128];
    int rel = blockIdx.x;
    int tid = threadIdx.x;
    int v = (tid < SCAN_B) ? bsum[rel * 128 + tid] : 0;
    sd[tid] = v;
    __syncthreads();
    for (int off = 1; off < 128; off <<= 1) {
        int u = (tid >= off) ? sd[tid - off] : 0;
        __syncthreads();
        sd[tid] += u;
        __syncthreads();
    }
    if (tid < SCAN_B) bsum[rel * 128 + tid] = sd[tid] - v;  // exclusive
}

__global__ void k_scan3(int* __restrict__ rs_all, const int* __restrict__ bsum) {
    int rel = blockIdx.y;
    int i = blockIdx.x * 256 + threadIdx.x;
    if (i < NN) rs_all[rel * NN + i] += bsum[rel * 128 + (i >> 10)];
}

// atomic-free scatter: slot precomputed by k_count
__global__ void k_fill(const int* __restrict__ e0, const int* __restrict__ e1,
                       const int* __restrict__ e2, const int* __restrict__ pose,
                       const int* __restrict__ rs_all, int* __restrict__ csr_all) {
    int rel = blockIdx.y;
    const int* e = rel == 0 ? e0 : rel == 1 ? e1 : e2;
    int i = blockIdx.x * 256 + threadIdx.x;
    if (i >= EE) return;
    int s = e[i], d = e[EE + i];
    csr_all[(size_t)rel * EE + rs_all[rel * NN + d] + pose[rel * EE + i]] = s;
}

// ---------------- aggregation: TWO nodes per wave; batched over up to 3 relations ----------------
// blockIdx.y = y selects {dest, src, bnsc}; relation index = rel0 + y.
__global__ __launch_bounds__(256) void k_aggr(u16* d0, u16* d1, u16* d2,
                                              const float* s0, const float* s1, const float* s2,
                                              const float* bn0, const float* bn1, const float* bn2,
                                              const int* __restrict__ irs, const int* __restrict__ icnt,
                                              const int* __restrict__ icsr, int rel0) {
    int y = blockIdx.y;
    u16* Xp = y == 0 ? d0 : (y == 1 ? d1 : d2);
    const float* xs = y == 0 ? s0 : (y == 1 ? s1 : s2);
    const float* bnsc = y == 0 ? bn0 : (y == 1 ? bn1 : bn2);
    int rel = rel0 + y;
    const int* rs = irs + rel * NN;
    const int* cnt = icnt + rel * NN;
    const int* csr = icsr + (size_t)rel * EE;

    int node = blockIdx.x * 8 + (threadIdx.x >> 5);
    if (node >= NN) return;
    int l = threadIdx.x & 31;
    int beg = rs[node], deg = cnt[node];
    const float4* xs4 = (const float4*)xs;
    bool bn = bnsc != nullptr;
    float4 scv = make_float4(1.f, 1.f, 1.f, 1.f), sfv = make_float4(0.f, 0.f, 0.f, 0.f);
    if (bn) {
        scv = *(const float4*)&bnsc[l * 4];
        sfv = *(const float4*)&bnsc[128 + l * 4];
    }
    auto xf = [&](float4 v) {
        if (bn) {
            v.x = v.x * scv.x + sfv.x; v.y = v.y * scv.y + sfv.y;
            v.z = v.z * scv.z + sfv.z; v.w = v.w * scv.w + sfv.w;
            v.x = v.x >= 0.f ? v.x : 0.01f * v.x;
            v.y = v.y >= 0.f ? v.y : 0.01f * v.y;
            v.z = v.z >= 0.f ? v.z : 0.01f * v.z;
            v.w = v.w >= 0.f ? v.w : 0.01f * v.w;
        }
        return v;
    };
    float ax = 0.f, ay = 0.f, az = 0.f, aw = 0.f;
    int j = 0;
    for (; j + 4 <= deg; j += 4) {
        int q0 = csr[beg + j], q1 = csr[beg + j + 1];
        int q2 = csr[beg + j + 2], q3 = csr[beg + j + 3];
        float4 v0 = xf(xs4[(size_t)q0 * 32 + l]);
        float4 v1 = xf(xs4[(size_t)q1 * 32 + l]);
        float4 v2 = xf(xs4[(size_t)q2 * 32 + l]);
        float4 v3 = xf(xs4[(size_t)q3 * 32 + l]);
        ax += (v0.x + v1.x) + (v2.x + v3.x);
        ay += (v0.y + v1.y) + (v2.y + v3.y);
        az += (v0.z + v1.z) + (v2.z + v3.z);
        aw += (v0.w + v1.w) + (v2.w + v3.w);
    }
    if (j + 2 <= deg) {
        int q0 = csr[beg + j], q1 = csr[beg + j + 1];
        float4 v0 = xf(xs4[(size_t)q0 * 32 + l]);
        float4 v1 = xf(xs4[(size_t)q1 * 32 + l]);
        ax += v0.x + v1.x; ay += v0.y + v1.y;
        az += v0.z + v1.z; aw += v0.w + v1.w;
        j += 2;
    }
    if (j < deg) {
        float4 v = xf(xs4[(size_t)csr[beg + j] * 32 + l]);
        ax += v.x; ay += v.y; az += v.z; aw += v.w;
    }
    float sc = 1.0f / fmaxf((float)deg, 1.0f);
    float vx = ax * sc, vy = ay * sc, vz = az * sc, vw = aw * sc;
    u16 h0 = f2bf(vx), h1 = f2bf(vy), h2 = f2bf(vz), h3 = f2bf(vw);
    u16 l0 = f2bf(vx - bf2f(h0)), l1 = f2bf(vy - bf2f(h1));
    u16 l2 = f2bf(vz - bf2f(h2)), l3 = f2bf(vw - bf2f(h3));
    int gi = (l >> 1) & 3;
    char* base = (char*)Xp + (size_t)node * 512 + (l >> 3) * 128;
    int jb = (l & 1) * 8;
    u32* hp = (u32*)(base + hi_off(gi, node) + jb);
    u32* lp = (u32*)(base + lo_off(gi, node) + jb);
    __builtin_nontemporal_store(((u32)h1 << 16) | h0, hp);
    __builtin_nontemporal_store(((u32)h3 << 16) | h2, hp + 1);
    __builtin_nontemporal_store(((u32)l1 << 16) | l0, lp);
    __builtin_nontemporal_store(((u32)l3 << 16) | l2, lp + 1);
}

// ---------------- fused conv GEMM, batched over up to 3 relations (blockIdx.y) ----------------
// Y = X1@Wsrc' + X2@Wdst' + bias via bf16x3 MFMA; chunk-level double-buffered LDS.
// X1 packed == Y buffer (in-place). lr = lr0 + y selects weights/bias.
__global__ __launch_bounds__(256) void k_cgemm(float* Y0, float* Y1, float* Y2,
                                               const float* X20, const float* X21, const float* X22,
                                               const u16* __restrict__ Wsh, const u16* __restrict__ Wsl,
                                               const u16* __restrict__ Wdh, const u16* __restrict__ Wdl,
                                               const float* __restrict__ fB, int lr0,
                                               const float* bn0, const float* bn1, const float* bn2,
                                               float* cs0, float* cs1, float* cs2, int nrows) {
    __shared__ __attribute__((aligned(16))) char Xt[2][16384];
    int y = blockIdx.y;
    float* Y = y == 0 ? Y0 : (y == 1 ? Y1 : Y2);
    const u16* X1p = (const u16*)Y;
    const float* X2 = y == 0 ? X20 : (y == 1 ? X21 : X22);
    const float* bnsc2 = y == 0 ? bn0 : (y == 1 ? bn1 : bn2);
    float* colsum = y == 0 ? cs0 : (y == 1 ? cs1 : cs2);
    int lr = lr0 + y;
    const u16* W1h = Wsh + (size_t)lr * HH * HH;
    const u16* W1l = Wsl + (size_t)lr * HH * HH;
    const u16* W2h = Wdh + (size_t)lr * HH * HH;
    const u16* W2l = Wdl + (size_t)lr * HH * HH;
    const float* bias = fB + lr * HH;

    int tid = threadIdx.x;
    int row0 = blockIdx.x * 128;
    int lane = tid & 63, wv = tid >> 6;
    int l15 = lane & 15, lg = lane >> 4;
    bool full = (row0 + 128 <= nrows);

    f32x4 acc[8][2];
#pragma unroll
    for (int i = 0; i < 8; ++i)
#pragma unroll
        for (int j = 0; j < 2; ++j) acc[i][j] = (f32x4)(0.f);

    auto stage_chunk = [&](int c) {
        char* dst = Xt[c & 1];
        if (c < 4) {
#pragma unroll
            for (int p = 0; p < 4; ++p) {
                int tb = p * 4096 + tid * 16;
                int r = tb >> 7, off = tb & 127;
                stage16((const char*)X1p + (size_t)(row0 + r) * 512 + (c & 3) * 128 + off,
                        dst + tb);
            }
        } else {
            int kc = (c & 3) * 32;
#pragma unroll
            for (int it = 0; it < 2; ++it) {
                int g2 = tid + it * 256;
                int r = g2 >> 2, gi = g2 & 3;
                float4 a = make_float4(0.f, 0.f, 0.f, 0.f), b = a;
                if (full || row0 + r < nrows) {
                    const float* xp = &X2[(size_t)(row0 + r) * HH + kc + gi * 8];
                    a = *(const float4*)xp;
                    b = *(const float4*)(xp + 4);
                }
                if (bnsc2) {
                    const float* scp = bnsc2 + kc + gi * 8;
                    const float* sfp = bnsc2 + 128 + kc + gi * 8;
                    float4 s0 = *(const float4*)scp, s1 = *(const float4*)(scp + 4);
                    float4 f0 = *(const float4*)sfp, f1 = *(const float4*)(sfp + 4);
                    a.x = a.x * s0.x + f0.x; a.y = a.y * s0.y + f0.y;
                    a.z = a.z * s0.z + f0.z; a.w = a.w * s0.w + f0.w;
                    b.x = b.x * s1.x + f1.x; b.y = b.y * s1.y + f1.y;
                    b.z = b.z * s1.z + f1.z; b.w = b.w * s1.w + f1.w;
                    a.x = a.x >= 0.f ? a.x : 0.01f * a.x;
                    a.y = a.y >= 0.f ? a.y : 0.01f * a.y;
                    a.z = a.z >= 0.f ? a.z : 0.01f * a.z;
                    a.w = a.w >= 0.f ? a.w : 0.01f * a.w;
                    b.x = b.x >= 0.f ? b.x : 0.01f * b.x;
                    b.y = b.y >= 0.f ? b.y : 0.01f * b.y;
                    b.z = b.z >= 0.f ? b.z : 0.01f * b.z;
                    b.w = b.w >= 0.f ? b.w : 0.01f * b.w;
                }
                u16 h0 = f2bf(a.x), h1 = f2bf(a.y), h2 = f2bf(a.z), h3 = f2bf(a.w);
                u16 h4 = f2bf(b.x), h5 = f2bf(b.y), h6 = f2bf(b.z), h7 = f2bf(b.w);
                bf16x8 hv = {(short)h0, (short)h1, (short)h2, (short)h3,
                             (short)h4, (short)h5, (short)h6, (short)h7};
                bf16x8 lv = {(short)f2bf(a.x - bf2f(h0)), (short)f2bf(a.y - bf2f(h1)),
                             (short)f2bf(a.z - bf2f(h2)), (short)f2bf(a.w - bf2f(h3)),
                             (short)f2bf(b.x - bf2f(h4)), (short)f2bf(b.y - bf2f(h5)),
                             (short)f2bf(b.z - bf2f(h6)), (short)f2bf(b.w - bf2f(h7))};
                char* rb = dst + r * 128;
                *(bf16x8*)(rb + hi_off(gi, r)) = hv;
                *(bf16x8*)(rb + lo_off(gi, r)) = lv;
            }
        }
    };

    stage_chunk(0);
#pragma unroll
    for (int c = 0; c < 8; ++c) {
        const u16* Wh = (c < 4) ? W1h : W2h;
        const u16* Wl = (c < 4) ? W1l : W2l;
        int kc = (c & 3) * 32;
        bf16x8 bh[2], bl[2];
#pragma unroll
        for (int nt = 0; nt < 2; ++nt) {
            int n = (wv * 2 + nt) * 16 + l15;
            bh[nt] = *(const bf16x8*)&Wh[(size_t)n * HH + kc + lg * 8];
            bl[nt] = *(const bf16x8*)&Wl[(size_t)n * HH + kc + lg * 8];
        }
        __syncthreads();  // chunk c staged & chunk c-1 fully consumed
        if (c < 7) stage_chunk(c + 1);  // overlaps with MFMA below
        const char* buf = Xt[c & 1];
#pragma unroll
        for (int mt = 0; mt < 8; ++mt) {
            int r = mt * 16 + l15;
            const char* rb = buf + r * 128;
            bf16x8 ah = *(const bf16x8*)(rb + hi_off(lg, r));
            bf16x8 al = *(const bf16x8*)(rb + lo_off(lg, r));
#pragma unroll
            for (int nt = 0; nt < 2; ++nt) {
                acc[mt][nt] = __builtin_amdgcn_mfma_f32_16x16x32_bf16(ah, bh[nt], acc[mt][nt], 0, 0, 0);
                acc[mt][nt] = __builtin_amdgcn_mfma_f32_16x16x32_bf16(ah, bl[nt], acc[mt][nt], 0, 0, 0);
                acc[mt][nt] = __builtin_amdgcn_mfma_f32_16x16x32_bf16(al, bh[nt], acc[mt][nt], 0, 0, 0);
            }
        }
    }
#pragma unroll
    for (int nt = 0; nt < 2; ++nt) {
        int ncol = (wv * 2 + nt) * 16 + l15;
        float bv = bias[ncol];
        float s = 0.f, q = 0.f;
#pragma unroll
        for (int mt = 0; mt < 8; ++mt)
#pragma unroll
            for (int j = 0; j < 4; ++j) {
                int r = row0 + mt * 16 + lg * 4 + j;
                if (r < nrows) {
                    float yv = acc[mt][nt][j] + bv;
                    Y[(size_t)r * HH + ncol] = yv;
                    s += yv;
                    q += yv * yv;
                }
            }
        if (colsum) {
            s += __shfl_xor(s, 16); s += __shfl_xor(s, 32);
            q += __shfl_xor(q, 16); q += __shfl_xor(q, 32);
            if (lg == 0) {
                atomicAdd(&colsum[ncol], s);
                atomicAdd(&colsum[128 + ncol], q);
            }
        }
    }
}

// ---------------- attention score: bf16x3 MFMA S = X@W1, tanh, dot w2, block-sum ----------------
__global__ __launch_bounds__(256) void k_attn(const float* __restrict__ XA, const float* __restrict__ XB,
                                              const u16* __restrict__ Ah, const u16* __restrict__ Al,
                                              const float* __restrict__ b1, const float* __restrict__ w2,
                                              float* __restrict__ PA, float* __restrict__ PB, int nrows) {
    __shared__ __attribute__((aligned(16))) char Xt[2][16384];
    __shared__ float red[4];
    int tid = threadIdx.x;
    bool second = blockIdx.x >= ATTN_GRID;
    const float* X = second ? XB : XA;
    float* partial = second ? PB : PA;
    int row0 = (second ? blockIdx.x - ATTN_GRID : blockIdx.x) * 128;
    int lane = tid & 63, wv = tid >> 6;
    int l15 = lane & 15, lg = lane >> 4;
    bool full = (row0 + 128 <= nrows);

    f32x4 acc[8];
#pragma unroll
    for (int i = 0; i < 8; ++i) acc[i] = (f32x4)(0.f);

    auto stage_chunk = [&](int c) {
        char* dst = Xt[c & 1];
        int kc = c * 32;
#pragma unroll
        for (int it = 0; it < 2; ++it) {
            int g2 = tid + it * 256;
            int r = g2 >> 2, gi = g2 & 3;
            float4 a = make_float4(0.f, 0.f, 0.f, 0.f), b = a;
            if (full || row0 + r < nrows) {
                const float* xp = &X[(size_t)(row0 + r) * HH + kc + gi * 8];
                a = *(const float4*)xp;
                b = *(const float4*)(xp + 4);
            }
            u16 h0 = f2bf(a.x), h1 = f2bf(a.y), h2 = f2bf(a.z), h3 = f2bf(a.w);
            u16 h4 = f2bf(b.x), h5 = f2bf(b.y), h6 = f2bf(b.z), h7 = f2bf(b.w);
            bf16x8 hv = {(short)h0, (short)h1, (short)h2, (short)h3,
                         (short)h4, (short)h5, (short)h6, (short)h7};
            bf16x8 lv = {(short)f2bf(a.x - bf2f(h0)), (short)f2bf(a.y - bf2f(h1)),
                         (short)f2bf(a.z - bf2f(h2)), (short)f2bf(a.w - bf2f(h3)),
                         (short)f2bf(b.x - bf2f(h4)), (short)f2bf(b.y - bf2f(h5)),
                         (short)f2bf(b.z - bf2f(h6)), (short)f2bf(b.w - bf2f(h7))};
            char* rb = dst + r * 128;
            *(bf16x8*)(rb + hi_off(gi, r)) = hv;
            *(bf16x8*)(rb + lo_off(gi, r)) = lv;
        }
    };

    stage_chunk(0);
#pragma unroll
    for (int c = 0; c < 4; ++c) {
        int kc = c * 32;
        int a = wv * 16 + l15;
        bf16x8 bh = *(const bf16x8*)&Ah[(size_t)a * HH + kc + lg * 8];
        bf16x8 bl = *(const bf16x8*)&Al[(size_t)a * HH + kc + lg * 8];
        __syncthreads();
        if (c < 3) stage_chunk(c + 1);
        const char* buf = Xt[c & 1];
#pragma unroll
        for (int mt = 0; mt < 8; ++mt) {
            int r = mt * 16 + l15;
            const char* rb = buf + r * 128;
            bf16x8 ah = *(const bf16x8*)(rb + hi_off(lg, r));
            bf16x8 al = *(const bf16x8*)(rb + lo_off(lg, r));
            acc[mt] = __builtin_amdgcn_mfma_f32_16x16x32_bf16(ah, bh, acc[mt], 0, 0, 0);
            acc[mt] = __builtin_amdgcn_mfma_f32_16x16x32_bf16(ah, bl, acc[mt], 0, 0, 0);
            acc[mt] = __builtin_amdgcn_mfma_f32_16x16x32_bf16(al, bh, acc[mt], 0, 0, 0);
        }
    }
    float b1v = b1[wv * 16 + l15];
    float w2v = w2[wv * 16 + l15];
    float tot = 0.f;
#pragma unroll
    for (int mt = 0; mt < 8; ++mt)
#pragma unroll
        for (int j = 0; j < 4; ++j) {
            int r = row0 + mt * 16 + lg * 4 + j;
            if (r < nrows) tot += tanhf(acc[mt][j] + b1v) * w2v;
        }
#pragma unroll
    for (int off = 32; off > 0; off >>= 1) tot += __shfl_xor(tot, off);
    if (lane == 0) red[wv] = tot;
    __syncthreads();
    if (tid == 0)
        partial[second ? (blockIdx.x - ATTN_GRID) : blockIdx.x] = red[0] + red[1] + red[2] + red[3];
}

__global__ void k_alpha(const float* __restrict__ P1, const float* __restrict__ P2,
                        float* __restrict__ alpha, int nparts, float invn) {
    __shared__ float s1[256], s2[256];
    int tid = threadIdx.x;
    float a = 0.f, b = 0.f;
    for (int i = tid; i < nparts; i += 256) { a += P1[i]; b += P2[i]; }
    s1[tid] = a; s2[tid] = b;
    __syncthreads();
    for (int off = 128; off > 0; off >>= 1) {
        if (tid < off) { s1[tid] += s1[tid + off]; s2[tid] += s2[tid + off]; }
        __syncthreads();
    }
    if (tid == 0) {
        float m1 = s1[0] * invn, m2 = s2[0] * invn;
        float mx = fmaxf(m1, m2);
        float e1 = expf(m1 - mx), e2 = expf(m2 - mx);
        float inv = 1.f / (e1 + e2);
        alpha[0] = e1 * inv; alpha[1] = e2 * inv;
    }
}

// ---------------- combine (attention mix) + column stats ----------------
__global__ __launch_bounds__(256) void k_comb(float* __restrict__ X, const float* __restrict__ Y,
                                              const float* __restrict__ alpha, float* __restrict__ colsum,
                                              float* __restrict__ colsq, int nrows) {
    int tid = threadIdx.x;
    int h = tid & 127, half = tid >> 7;
    float a0 = alpha[0], a1 = alpha[1];
    float s = 0.f, q = 0.f;
    for (int n = blockIdx.x * 2 + half; n < nrows; n += gridDim.x * 2) {
        size_t off = (size_t)n * HH + h;
        float v = a0 * X[off] + a1 * Y[off];
        X[off] = v;
        s += v; q += v * v;
    }
    __shared__ float ls[256], lq[256];
    ls[tid] = s; lq[tid] = q;
    __syncthreads();
    if (half == 0) {
        atomicAdd(&colsum[h], ls[tid] + ls[tid + 128]);
        atomicAdd(&colsq[h], lq[tid] + lq[tid + 128]);
    }
}

// both BN-param computations in one launch: blockIdx.x = which (0/1)
__global__ void k_bnp2(const float* __restrict__ cs, const float* __restrict__ gamma,
                       const float* __restrict__ beta, float* __restrict__ scout, float invn) {
    int which = blockIdx.x;
    int h = threadIdx.x;
    float mu = cs[which * 256 + h] * invn;
    float var = cs[which * 256 + 128 + h] * invn - mu * mu;
    float sc = gamma[which * HH + h] * rsqrtf(var + 1.0f);
    scout[which * 256 + h] = sc;
    scout[which * 256 + 128 + h] = beta[which * HH + h] - mu * sc;
}

// ---------------- final FC: 64-row LDS tile, BN+leaky applied ONCE during staging ----------------
__global__ __launch_bounds__(256) void k_fc(const float* __restrict__ X0, const float* __restrict__ X1,
                                            const float* __restrict__ sc0, const float* __restrict__ sc1,
                                            const float* __restrict__ Wall, const float* __restrict__ ball,
                                            float* __restrict__ out, int nrows) {
    __shared__ float Xl[64 * 132];   // 33 KB
    __shared__ float Wl[HH * CC];    // 8 KB
    __shared__ float bl[CC];
    __shared__ float scl[HH], sfl[HH];
    int which = blockIdx.y;
    const float* X = which ? X1 : X0;
    const float* scp = which ? sc1 : sc0;
    const float* W = Wall + which * HH * CC;
    float* o = out + (size_t)which * NN * CC;
    int tid = threadIdx.x;
    int row0 = blockIdx.x * 64;
    for (int i = tid * 4; i < HH * CC; i += 1024)
        *(float4*)&Wl[i] = *(const float4*)&W[i];
    if (tid < CC) bl[tid] = ball[which * CC + tid];
    if (tid < HH) { scl[tid] = scp[tid]; sfl[tid] = scp[128 + tid]; }
    __syncthreads();
    for (int idx = tid; idx < 2048; idx += 256) {
        int r = idx >> 5, cc = idx & 31;
        int n = row0 + r;
        float4 v = make_float4(0.f, 0.f, 0.f, 0.f);
        if (n < nrows) v = *(const float4*)&X[(size_t)n * HH + cc * 4];
        float4 sc = *(const float4*)&scl[cc * 4];
        float4 sf = *(const float4*)&sfl[cc * 4];
        v.x = v.x * sc.x + sf.x; v.y = v.y * sc.y + sf.y;
        v.z = v.z * sc.z + sf.z; v.w = v.w * sc.w + sf.w;
        v.x = v.x >= 0.f ? v.x : 0.01f * v.x;
        v.y = v.y >= 0.f ? v.y : 0.01f * v.y;
        v.z = v.z >= 0.f ? v.z : 0.01f * v.z;
        v.w = v.w >= 0.f ? v.w : 0.01f * v.w;
        *(float4*)&Xl[r * 132 + cc * 4] = v;
    }
    __syncthreads();
    int c = tid & 15, nl = tid >> 4;
    const float* x0 = &Xl[(nl + 0) * 132];
    const float* x1 = &Xl[(nl + 16) * 132];
    const float* x2 = &Xl[(nl + 32) * 132];
    const float* x3 = &Xl[(nl + 48) * 132];
    float a0 = bl[c], a1 = a0, a2 = a0, a3 = a0;
#pragma unroll 8
    for (int h = 0; h < HH; ++h) {
        float w = Wl[h * CC + c];
        a0 += x0[h] * w;
        a1 += x1[h] * w;
        a2 += x2[h] * w;
        a3 += x3[h] * w;
    }
    int n0 = row0 + nl;
    if (n0 < nrows) o[(size_t)n0 * CC + c] = a0;
    if (n0 + 16 < nrows) o[(size_t)(n0 + 16) * CC + c] = a1;
    if (n0 + 32 < nrows) o[(size_t)(n0 + 32) * CC + c] = a2;
    if (n0 + 48 < nrows) o[(size_t)(n0 + 48) * CC + c] = a3;
}

extern "C" void kernel_launch(void* const* d_in, const int* in_sizes, int n_in,
                              void* d_out, int out_size, void* d_ws, size_t ws_size,
                              hipStream_t stream) {
    const float* xA = (const float*)d_in[0];
    const float* xB = (const float*)d_in[1];
    const float* Wsrc = (const float*)d_in[2];
    const float* bsrc = (const float*)d_in[3];
    const float* Wdst = (const float*)d_in[4];
    const float* bdst = (const float*)d_in[5];
    const float* Wupd = (const float*)d_in[6];
    const float* bupd = (const float*)d_in[7];
    const float* attnW1 = (const float*)d_in[8];
    const float* attnb1 = (const float*)d_in[9];
    const float* attnw2 = (const float*)d_in[10];
    const float* gamma = (const float*)d_in[11];
    const float* beta = (const float*)d_in[12];
    const float* fcW = (const float*)d_in[13];
    const float* fcb = (const float*)d_in[14];
    const int* eAB = (const int*)d_in[15];
    const int* eBB = (const int*)d_in[16];
    const int* eBA = (const int*)d_in[17];
    float* out = (float*)d_out;

    // workspace layout == round-15 passing footprint
    float* ws = (float*)d_ws;
    const size_t NH = (size_t)NN * HH;
    const size_t LRHH = (size_t)LL * RR * HH * HH;
    const size_t LAH = (size_t)LL * AAA * HH;
    float* B0 = ws;
    float* B1 = B0 + NH;
    float* B2 = B1 + NH;
    float* B3 = B2 + NH;
    u16* uWdh = (u16*)(B3 + NH);
    u16* uWdl = uWdh + LRHH;
    u16* uWsh = uWdl + LRHH;
    u16* uWsl = uWsh + LRHH;
    u16* uA1h = uWsl + LRHH;        // L*AAA*HH
    u16* uA1l = uA1h + LAH;
    float* fB = (float*)(uA1l + LAH);
    float* csA = fB + LL * RR * HH;  // [sumA|sqA|sumB|sqB] 512
    float* csB = csA + 256;
    float* scA = csB + 256;          // [scA|sfA|scB|sfB] 512
    float* scB = scA + 256;
    float* scA2 = scB + 256;         // layer-1 head scales
    float* scB2 = scA2 + 256;
    float* P1 = scB2 + 256;
    float* P2 = P1 + 1024;
    float* alp = P2 + 1024;
    int* icnt = (int*)(alp + 64);
    int* irs = icnt + 3 * NN;
    int* icsr = irs + 3 * NN;
    int* ifill = icsr + 3 * EE;     // unused (layout stability)
    int* ibsum = ifill + 3 * NN;
    int* pose = (int*)B3;           // 3*EE ints; B3 unused until layer 1
    const float invN = 1.0f / (float)NN;

    k_fuse_w<<<LL * RR * HH, 256, 0, stream>>>(Wsrc, Wdst, Wupd, uWdh, uWdl, uWsh, uWsl);
    k_fuse_b<<<LL * RR, HH, 0, stream>>>(bsrc, bdst, bupd, Wupd, fB);
    k_fuse_a<<<LL * AAA, HH, 0, stream>>>(attnW1, uA1h, uA1l);

    // CSR build
    hipMemsetAsync(icnt, 0, 3 * NN * 4, stream);
    k_count<<<dim3((EE + 255) / 256, 3), 256, 0, stream>>>(eAB, eBB, eBA, icnt, pose);
    k_scan1<<<dim3(SCAN_B, 3), 256, 0, stream>>>(icnt, irs, ibsum);
    k_scan2<<<3, 128, 0, stream>>>(ibsum);
    k_scan3<<<dim3((NN + 255) / 256, 3), 256, 0, stream>>>(irs, ibsum);
    k_fill<<<dim3((EE + 255) / 256, 3), 256, 0, stream>>>(eAB, eBB, eBA, pose, irs, icsr);

    const int GEMM_GRID = (NN + 127) / 128;
    const int AGGR_GRID = (NN + 7) / 8;

    // ================= layer 0: 3 independent convs batched =================
    hipMemsetAsync(csA, 0, 512 * 4, stream);  // csA + csB
    k_aggr<<<dim3(AGGR_GRID, 3), 256, 0, stream>>>(
        (u16*)B0, (u16*)B1, (u16*)B2, xA, xB, xB,
        nullptr, nullptr, nullptr, irs, icnt, icsr, 0);
    k_cgemm<<<dim3(GEMM_GRID, 3), 256, 0, stream>>>(
        B0, B1, B2, xB, xB, xA, uWsh, uWsl, uWdh, uWdl, fB, 0,
        nullptr, nullptr, nullptr, nullptr, nullptr, csA, NN);
    k_attn<<<2 * ATTN_GRID, 256, 0, stream>>>(B0, B1, uA1h, uA1l, attnb1, attnw2, P1, P2, NN);
    k_alpha<<<1, 256, 0, stream>>>(P1, P2, alp, ATTN_GRID, invN);
    k_comb<<<512, 256, 0, stream>>>(B0, B1, alp, csB, csB + 128, NN);  // xB_new -> B0 (+stats)
    k_bnp2<<<2, 128, 0, stream>>>(csA, gamma + 0 * HH, beta + 0 * HH, scA, invN);
    // B2/B0 stay pre-BN; scA/scB applied by layer-1 consumers.

    // ================= layer 1 =================
    hipMemsetAsync(csA, 0, 512 * 4, stream);  // csA + csB
    // embB1' (dest B1, xs=B2 w/scA, xd=B0 w/scB, rel 0, lr 3) and
    // embB2' (dest B3, xs=B0 w/scB, xd=B0 w/scB, rel 1, lr 4): independent -> batched
    k_aggr<<<dim3(AGGR_GRID, 2), 256, 0, stream>>>(
        (u16*)B1, (u16*)B3, nullptr, B2, B0, nullptr,
        scA, scB, nullptr, irs, icnt, icsr, 0);
    k_cgemm<<<dim3(GEMM_GRID, 2), 256, 0, stream>>>(
        B1, B3, nullptr, B0, B0, nullptr, uWsh, uWsl, uWdh, uWdl, fB, 3,
        scB, scB, nullptr, nullptr, nullptr, nullptr, NN);
    k_attn<<<2 * ATTN_GRID, 256, 0, stream>>>(B1, B3, uA1h + (size_t)AAA * HH,
                                              uA1l + (size_t)AAA * HH,
                                              attnb1 + AAA, attnw2 + AAA, P1, P2, NN);
    k_alpha<<<1, 256, 0, stream>>>(P1, P2, alp, ATTN_GRID, invN);
    k_comb<<<512, 256, 0, stream>>>(B1, B3, alp, csB, csB + 128, NN);  // xB_new -> B1 (+stats)
    // embA' (dest B3, xs=B0 w/scB, xd=B2 w/scA, rel 2, lr 5, stats csA) after comb freed B3
    k_aggr<<<dim3(AGGR_GRID, 1), 256, 0, stream>>>(
        (u16*)B3, nullptr, nullptr, B0, nullptr, nullptr,
        scB, nullptr, nullptr, irs, icnt, icsr, 2);
    k_cgemm<<<dim3(GEMM_GRID, 1), 256, 0, stream>>>(
        B3, nullptr, nullptr, B2, nullptr, nullptr, uWsh, uWsl, uWdh, uWdl, fB, 5,
        scA, nullptr, nullptr, csA, nullptr, nullptr, NN);
    k_bnp2<<<2, 128, 0, stream>>>(csA, gamma + 2 * HH, beta + 2 * HH, scA2, invN);

    // ================= head: BN+leaky fused into FC staging =================
    k_fc<<<dim3((NN + 63) / 64, 2), 256, 0, stream>>>(B3, B1, scA2, scB2, fcW, fcb, out, NN);
}